// Round 5
// baseline (3926.133 us; speedup 1.0000x reference)
//
#include <hip/hip_runtime.h>
#include <cstddef>
#include <cstdint>
#include <cmath>

// Problem constants
constexpr int BB = 4, TT = 2048, DD = 768, HH = 8, HD = 96, FF = 2048, LL = 2;
constexpr int MM = BB * TT;              // 8192
constexpr size_t HROW = (size_t)MM * DD; // 6291456
constexpr int CH = 64;                   // scan chunk length
constexpr int NCH = TT / CH;             // 32 chunks per sequence
constexpr int RP = 100;                  // padded LDS row (floats)

typedef float f32x4 __attribute__((ext_vector_type(4)));
typedef short bf16x8 __attribute__((ext_vector_type(8)));

__device__ __forceinline__ void gload16(const void* g, void* l) {
    __builtin_amdgcn_global_load_lds(
        (const __attribute__((address_space(1))) void*)g,
        (__attribute__((address_space(3))) void*)l, 16, 0, 0);
}
__device__ __forceinline__ float bf2f(unsigned short u) {
    return __uint_as_float(((unsigned)u) << 16);
}
__device__ __forceinline__ unsigned short f2bf(float f) {
    unsigned u = __float_as_uint(f);
    unsigned r = (u + 0x7fffu + ((u >> 16) & 1u)) >> 16;
    return (unsigned short)r;
}

// ---------------------------------------------------------------- LayerNorm -> bf16
__global__ __launch_bounds__(256)
void layernorm_rows(const float* __restrict__ x, unsigned short* __restrict__ y,
                    const float* __restrict__ w, const float* __restrict__ b,
                    const float* mask)
{
    const int row = blockIdx.x;
    const int tid = threadIdx.x;
    const float* xr = x + (size_t)row * DD;
    float v0 = xr[tid], v1 = xr[tid + 256], v2 = xr[tid + 512];
    float s = v0 + v1 + v2;
    float ss = v0 * v0 + v1 * v1 + v2 * v2;
#pragma unroll
    for (int i = 1; i < 64; i <<= 1) { s += __shfl_xor(s, i); ss += __shfl_xor(ss, i); }
    __shared__ float red[8];
    const int wid = tid >> 6, lane = tid & 63;
    if (lane == 0) { red[wid] = s; red[4 + wid] = ss; }
    __syncthreads();
    const float S  = red[0] + red[1] + red[2] + red[3];
    const float SS = red[4] + red[5] + red[6] + red[7];
    const float mean = S * (1.f / DD);
    const float var  = SS * (1.f / DD) - mean * mean;
    const float rstd = rsqrtf(var + 1e-5f);
    const float m = mask ? mask[row] : 1.f;
    unsigned short* yr = y + (size_t)row * DD;
    yr[tid]       = f2bf(((v0 - mean) * rstd * w[tid]       + b[tid])       * m);
    yr[tid + 256] = f2bf(((v1 - mean) * rstd * w[tid + 256] + b[tid + 256]) * m);
    yr[tid + 512] = f2bf(((v2 - mean) * rstd * w[tid + 512] + b[tid + 512]) * m);
}

// ---------------------------------------------------------------- transpose+convert W
__global__ __launch_bounds__(256)
void transcvt(const float* __restrict__ in, unsigned short* __restrict__ out, int K, int N)
{
    __shared__ float t[32][33];
    const int tx = threadIdx.x & 31, ty = threadIdx.x >> 5;
    const int k0 = blockIdx.y * 32, n0 = blockIdx.x * 32;
#pragma unroll
    for (int i = 0; i < 4; ++i)
        t[ty + i * 8][tx] = in[(size_t)(k0 + ty + i * 8) * N + n0 + tx];
    __syncthreads();
#pragma unroll
    for (int i = 0; i < 4; ++i)
        out[(size_t)(n0 + ty + i * 8) * K + k0 + tx] = f2bf(t[tx][ty + i * 8]);
}

// ---------------------------------------------------------------- bf16 MFMA GEMM
enum { BE_BIAS = 0, BE_SILU, BE_EG, BE_F32, BE_BF16, BE_RES };

template <int EPI>
__global__ __launch_bounds__(256)
void bgemm(const unsigned short* __restrict__ A, const unsigned short* __restrict__ Bt,
           float* Cf, unsigned short* Cb,
           const float* P0, const float* __restrict__ P1,
           int M, int N, int K)
{
    __shared__ unsigned short As[128 * 32];
    __shared__ unsigned short Bs[128 * 32];
    const int tid = threadIdx.x;
    const int w = tid >> 6, l = tid & 63;
    const int wm = w >> 1, wn = w & 1;
    const int lr = l & 15, lh = l >> 4;
    const int m0 = blockIdx.y * 128, n0 = blockIdx.x * 128;

    f32x4 acc[4][4];
#pragma unroll
    for (int i = 0; i < 4; ++i)
#pragma unroll
        for (int j = 0; j < 4; ++j) acc[i][j] = (f32x4){0.f, 0.f, 0.f, 0.f};

    const int sr = l >> 2, sq = (l & 3) * 8;
    const unsigned short* Ag = A + (size_t)(m0 + w * 32 + sr) * K + sq;
    const unsigned short* Bg = Bt + (size_t)(n0 + w * 32 + sr) * K + sq;
    unsigned short* Al = &As[(w * 32) * 32];
    unsigned short* Bl = &Bs[(w * 32) * 32];

    for (int kt = 0; kt < K; kt += 32) {
        __syncthreads();
        gload16(Ag + kt, Al);
        gload16(Ag + kt + 16 * (size_t)K, Al + 16 * 32);
        gload16(Bg + kt, Bl);
        gload16(Bg + kt + 16 * (size_t)K, Bl + 16 * 32);
        __syncthreads();
        bf16x8 af[4], bfv[4];
#pragma unroll
        for (int mi = 0; mi < 4; ++mi)
            af[mi] = *(const bf16x8*)&As[(wm * 64 + mi * 16 + lr) * 32 + lh * 8];
#pragma unroll
        for (int ni = 0; ni < 4; ++ni)
            bfv[ni] = *(const bf16x8*)&Bs[(wn * 64 + ni * 16 + lr) * 32 + lh * 8];
#pragma unroll
        for (int mi = 0; mi < 4; ++mi)
#pragma unroll
            for (int ni = 0; ni < 4; ++ni)
                acc[mi][ni] = __builtin_amdgcn_mfma_f32_16x16x32_bf16(af[mi], bfv[ni], acc[mi][ni], 0, 0, 0);
    }

#pragma unroll
    for (int mi = 0; mi < 4; ++mi) {
#pragma unroll
        for (int j = 0; j < 4; ++j) {
            const int row = m0 + wm * 64 + mi * 16 + lh * 4 + j;
#pragma unroll
            for (int ni = 0; ni < 4; ++ni) {
                const int col = n0 + wn * 64 + ni * 16 + lr;
                const size_t idx = (size_t)row * N + col;
                float v = acc[mi][ni][j];
                if constexpr (EPI == BE_BIAS) { Cf[idx] = v + P0[col]; }
                else if constexpr (EPI == BE_SILU) { Cf[idx] = v / (1.f + expf(-v)); }
                else if constexpr (EPI == BE_EG) {
                    const float lin = v + P1[col];
                    const float sp = (lin > 20.f) ? lin : log1pf(expf(lin));
                    Cf[idx] = -expf(P0[col]) * sp;      // raw log-decay g
                }
                else if constexpr (EPI == BE_F32) { Cf[idx] = v; }
                else if constexpr (EPI == BE_BF16) { Cb[idx] = f2bf(v); }
                else if constexpr (EPI == BE_RES) { Cf[idx] = v + P0[idx]; }
            }
        }
    }
}

// Dual-B GEMM for SwiGLU
__global__ __launch_bounds__(256)
void bgemm_dual(const unsigned short* __restrict__ A,
                const unsigned short* __restrict__ Bg_, const unsigned short* __restrict__ Bu_,
                unsigned short* __restrict__ C, int M, int N, int K)
{
    __shared__ unsigned short As[128 * 32];
    __shared__ unsigned short Bs1[64 * 32];
    __shared__ unsigned short Bs2[64 * 32];
    const int tid = threadIdx.x;
    const int w = tid >> 6, l = tid & 63;
    const int wm = w >> 1, wn = w & 1;
    const int lr = l & 15, lh = l >> 4;
    const int m0 = blockIdx.y * 128, n0 = blockIdx.x * 64;

    f32x4 a1[4][2], a2[4][2];
#pragma unroll
    for (int i = 0; i < 4; ++i)
#pragma unroll
        for (int j = 0; j < 2; ++j) { a1[i][j] = (f32x4){0.f,0.f,0.f,0.f}; a2[i][j] = (f32x4){0.f,0.f,0.f,0.f}; }

    const int sr = l >> 2, sq = (l & 3) * 8;
    const unsigned short* Ag  = A   + (size_t)(m0 + w * 32 + sr) * K + sq;
    const unsigned short* B1g = Bg_ + (size_t)(n0 + w * 16 + sr) * K + sq;
    const unsigned short* B2g = Bu_ + (size_t)(n0 + w * 16 + sr) * K + sq;
    unsigned short* Al  = &As[(w * 32) * 32];
    unsigned short* B1l = &Bs1[(w * 16) * 32];
    unsigned short* B2l = &Bs2[(w * 16) * 32];

    for (int kt = 0; kt < K; kt += 32) {
        __syncthreads();
        gload16(Ag + kt, Al);
        gload16(Ag + kt + 16 * (size_t)K, Al + 16 * 32);
        gload16(B1g + kt, B1l);
        gload16(B2g + kt, B2l);
        __syncthreads();
        bf16x8 af[4], b1[2], b2[2];
#pragma unroll
        for (int mi = 0; mi < 4; ++mi)
            af[mi] = *(const bf16x8*)&As[(wm * 64 + mi * 16 + lr) * 32 + lh * 8];
#pragma unroll
        for (int ni = 0; ni < 2; ++ni) {
            b1[ni] = *(const bf16x8*)&Bs1[(wn * 32 + ni * 16 + lr) * 32 + lh * 8];
            b2[ni] = *(const bf16x8*)&Bs2[(wn * 32 + ni * 16 + lr) * 32 + lh * 8];
        }
#pragma unroll
        for (int mi = 0; mi < 4; ++mi)
#pragma unroll
            for (int ni = 0; ni < 2; ++ni) {
                a1[mi][ni] = __builtin_amdgcn_mfma_f32_16x16x32_bf16(af[mi], b1[ni], a1[mi][ni], 0, 0, 0);
                a2[mi][ni] = __builtin_amdgcn_mfma_f32_16x16x32_bf16(af[mi], b2[ni], a2[mi][ni], 0, 0, 0);
            }
    }

#pragma unroll
    for (int mi = 0; mi < 4; ++mi)
#pragma unroll
        for (int j = 0; j < 4; ++j) {
            const int row = m0 + wm * 64 + mi * 16 + lh * 4 + j;
#pragma unroll
            for (int ni = 0; ni < 2; ++ni) {
                const int col = n0 + wn * 32 + ni * 16 + lr;
                const float g = a1[mi][ni][j], u = a2[mi][ni][j];
                C[(size_t)row * N + col] = f2bf((g / (1.f + expf(-g))) * u);
            }
        }
}

// ---------------------------------------------------------------- small fp32 GEMM (A bf16)
template <int MODE>
__global__ __launch_bounds__(256)
void gemm_small(const unsigned short* __restrict__ A, const float* __restrict__ Bm,
                unsigned short* Cb, float* Cf, int M, int N, int K)
{
    __shared__ float As[16][64];
    __shared__ float Bs[16][64];
    const int tid = threadIdx.x;
    const int tx = tid & 15, ty = tid >> 4;
    const int row0 = blockIdx.y * 64;
    const int col0 = blockIdx.x * 64;
    float acc[4][4] = {};
    const int ar  = tid >> 2;
    const int ac4 = (tid & 3) << 2;
    const int br  = tid >> 4;
    const int bc  = (tid & 15) << 2;
    const int gc  = col0 + bc;
    const bool bok = gc < N;

    for (int kt = 0; kt < K; kt += 16) {
        const ushort4 a4 = *(const ushort4*)(A + (size_t)(row0 + ar) * K + kt + ac4);
        float4 b4 = make_float4(0.f, 0.f, 0.f, 0.f);
        if (bok) b4 = *(const float4*)(Bm + (size_t)(kt + br) * N + gc);
        __syncthreads();
        As[ac4 + 0][ar] = bf2f(a4.x); As[ac4 + 1][ar] = bf2f(a4.y);
        As[ac4 + 2][ar] = bf2f(a4.z); As[ac4 + 3][ar] = bf2f(a4.w);
        *(float4*)&Bs[br][bc] = b4;
        __syncthreads();
#pragma unroll
        for (int kk = 0; kk < 16; ++kk) {
            const float4 av = *(const float4*)&As[kk][ty << 2];
            const float4 bv = *(const float4*)&Bs[kk][tx << 2];
            const float a_[4] = {av.x, av.y, av.z, av.w};
            const float b_[4] = {bv.x, bv.y, bv.z, bv.w};
#pragma unroll
            for (int i = 0; i < 4; ++i)
#pragma unroll
                for (int j = 0; j < 4; ++j)
                    acc[i][j] = fmaf(a_[i], b_[j], acc[i][j]);
        }
    }
#pragma unroll
    for (int i = 0; i < 4; ++i) {
        const int row = row0 + (ty << 2) + i;
#pragma unroll
        for (int j = 0; j < 4; ++j) {
            const int col = col0 + (tx << 2) + j;
            if (col >= N) continue;
            const size_t idx = (size_t)row * N + col;
            if constexpr (MODE == 0) Cb[idx] = f2bf(acc[i][j]);
            else                     Cf[idx] = 1.f / (1.f + expf(-acc[i][j]));
        }
    }
}

// ---------------------------------------------------------------- row ops over HD=96
__global__ __launch_bounds__(256)
void l2norm_rows(float* x, float scale)
{
    const int row  = (blockIdx.x << 2) + (threadIdx.x >> 6);
    const int lane = threadIdx.x & 63;
    float* xr = x + (size_t)row * HD;
    const float a = xr[lane];
    const float b = (lane < 32) ? xr[64 + lane] : 0.f;
    float ss = a * a + b * b;
#pragma unroll
    for (int i = 1; i < 64; i <<= 1) ss += __shfl_xor(ss, i);
    const float r = rsqrtf(ss + 1e-6f) * scale;
    xr[lane] = a * r;
    if (lane < 32) xr[64 + lane] = b * r;
}

__global__ __launch_bounds__(256)
void onorm_gate2(unsigned short* o, const unsigned short* __restrict__ gate,
                 const float* __restrict__ w)
{
    const int row  = (blockIdx.x << 2) + (threadIdx.x >> 6);
    const int lane = threadIdx.x & 63;
    unsigned short* orow = o + (size_t)row * HD;
    const unsigned short* grow = gate + (size_t)row * HD;
    const float a = bf2f(orow[lane]);
    const float b = (lane < 32) ? bf2f(orow[64 + lane]) : 0.f;
    float ss = a * a + b * b;
#pragma unroll
    for (int i = 1; i < 64; i <<= 1) ss += __shfl_xor(ss, i);
    const float r = rsqrtf(ss * (1.f / HD) + 1e-6f);
    const float g0 = bf2f(grow[lane]);
    orow[lane] = f2bf(a * r * w[lane] * (g0 / (1.f + expf(-g0))));
    if (lane < 32) {
        const float g1 = bf2f(grow[64 + lane]);
        orow[64 + lane] = f2bf(b * r * w[64 + lane] * (g1 / (1.f + expf(-g1))));
    }
}

// ---------------------------------------------------------------- KDA chunkwise precompute
// One block per (bh, chunk). In-place outputs: kappa_tilde->q, W->k, U->v, Qe->g.
__global__ __launch_bounds__(256)
void kda_pre(float* q, float* k, float* v, float* g,
             const float* __restrict__ beta,
             unsigned short* __restrict__ ol, float* __restrict__ Bc)
{
    __shared__ float Kb[CH * RP];   // k, then kappa_tilde
    __shared__ float Kk[CH * RP];   // kappa
    __shared__ float Qp[CH * RP];   // g -> L -> q'
    __shared__ float Am[CH][68];
    __shared__ float sb[CH];

    const int blk = blockIdx.x;
    const int ch = blk & 31, bh = blk >> 5;
    const int b = bh >> 3, h = bh & 7;
    const int tid = threadIdx.x;
    const size_t base = (size_t)b * (TT * HH * HD) + (size_t)(ch * CH) * (HH * HD) + h * HD;

    // P0: stage k, g, beta
    for (int e = tid; e < CH * 24; e += 256) {
        const int t = e / 24, c4 = (e % 24) * 4;
        *(float4*)&Kb[t * RP + c4] = *(const float4*)(k + base + t * 768 + c4);
        *(float4*)&Qp[t * RP + c4] = *(const float4*)(g + base + t * 768 + c4);
    }
    if (tid < CH) sb[tid] = beta[((size_t)b * TT + ch * CH + tid) * HH + h];
    __syncthreads();

    // P1: per-channel cumsum of g
    if (tid < HD) {
        float L = 0.f;
        for (int t = 0; t < CH; ++t) { L += Qp[t * RP + tid]; Qp[t * RP + tid] = L; }
    }
    __syncthreads();

    // P2: kappa, kappa_tilde, q', Bc
    for (int e = tid; e < CH * HD; e += 256) {
        const int t = e / HD, c = e % HD;
        const float L = Qp[t * RP + c];
        const float B = expf(L), iB = expf(-L);
        const float kv = Kb[t * RP + c];
        if (t == CH - 1) Bc[(size_t)bh * NCH * HD + ch * HD + c] = B;
        Kk[t * RP + c] = kv * B;
        const float kti = kv * iB;
        const float qv = q[base + t * 768 + c];   // read q before overwrite
        Kb[t * RP + c] = kti;
        q[base + t * 768 + c] = kti;              // kappa_tilde out
        Qp[t * RP + c] = qv * B;                  // q'
    }
    __syncthreads();

    // P3: A[t][i] = beta_t * kappa_t . ktil_i  (i < t)
    {
        const int wv = tid >> 6, lt = tid & 63;
        for (int half = 0; half < 2; ++half) {
            float4 ca[12];
#pragma unroll
            for (int r = 0; r < 12; ++r)
                ca[r] = *(const float4*)&Kk[lt * RP + half * 48 + r * 4];
            for (int i = wv * 16; i < wv * 16 + 16; ++i) {
                float d0 = 0, d1 = 0, d2 = 0, d3 = 0;
#pragma unroll
                for (int r = 0; r < 12; ++r) {
                    const float4 cb = *(const float4*)&Kb[i * RP + half * 48 + r * 4];
                    d0 = fmaf(ca[r].x, cb.x, d0); d1 = fmaf(ca[r].y, cb.y, d1);
                    d2 = fmaf(ca[r].z, cb.z, d2); d3 = fmaf(ca[r].w, cb.w, d3);
                }
                const float d = ((d0 + d1) + (d2 + d3)) * sb[lt];
                const float val = (i < lt) ? d : 0.f;
                if (half == 0) Am[lt][i] = val; else Am[lt][i] += val;
            }
        }
    }
    __syncthreads();

    // P4: forward solve, column j of [U | W] in registers
    float X[CH];
    const int j = tid;
    if (j < 192) {
        if (j < HD) {
#pragma unroll
            for (int t = 0; t < CH; ++t) X[t] = sb[t] * v[base + t * 768 + j];
        } else {
#pragma unroll
            for (int t = 0; t < CH; ++t) X[t] = sb[t] * Kk[t * RP + (j - HD)];
        }
#pragma unroll
        for (int t = 1; t < CH; ++t) {
            float a0 = 0, a1 = 0, a2 = 0, a3 = 0;
#pragma unroll
            for (int i4 = 0; i4 * 4 < t; ++i4) {
                const float4 a = *(const float4*)&Am[t][i4 * 4];
                if (i4 * 4 + 0 < t) a0 = fmaf(a.x, X[i4 * 4 + 0], a0);
                if (i4 * 4 + 1 < t) a1 = fmaf(a.y, X[i4 * 4 + 1], a1);
                if (i4 * 4 + 2 < t) a2 = fmaf(a.z, X[i4 * 4 + 2], a2);
                if (i4 * 4 + 3 < t) a3 = fmaf(a.w, X[i4 * 4 + 3], a3);
            }
            X[t] -= ((a0 + a1) + (a2 + a3));
        }
        // P5: store U (over v) / W (over k)
        if (j < HD) {
#pragma unroll
            for (int t = 0; t < CH; ++t) v[base + t * 768 + j] = X[t];
        } else {
#pragma unroll
            for (int t = 0; t < CH; ++t) k[base + t * 768 + (j - HD)] = X[t];
        }
    }
    __syncthreads();

    // P6: T[t][i] = q'_t . ktil_i  (i <= t)
    {
        const int wv = tid >> 6, lt = tid & 63;
        for (int half = 0; half < 2; ++half) {
            float4 ca[12];
#pragma unroll
            for (int r = 0; r < 12; ++r)
                ca[r] = *(const float4*)&Qp[lt * RP + half * 48 + r * 4];
            for (int i = wv * 16; i < wv * 16 + 16; ++i) {
                float d0 = 0, d1 = 0, d2 = 0, d3 = 0;
#pragma unroll
                for (int r = 0; r < 12; ++r) {
                    const float4 cb = *(const float4*)&Kb[i * RP + half * 48 + r * 4];
                    d0 = fmaf(ca[r].x, cb.x, d0); d1 = fmaf(ca[r].y, cb.y, d1);
                    d2 = fmaf(ca[r].z, cb.z, d2); d3 = fmaf(ca[r].w, cb.w, d3);
                }
                const float d = (d0 + d1) + (d2 + d3);
                const float val = (i <= lt) ? d : 0.f;
                if (half == 0) Am[lt][i] = val; else Am[lt][i] += val;
            }
        }
    }
    __syncthreads();

    // P7: T @ X -> Ol (j<96) ; Qe = q' - T@W (j>=96, over g)
    if (j < 192) {
        for (int t = 0; t < CH; ++t) {
            float a0 = 0, a1 = 0, a2 = 0, a3 = 0;
#pragma unroll
            for (int i4 = 0; i4 < 16; ++i4) {
                const float4 a = *(const float4*)&Am[t][i4 * 4];
                a0 = fmaf(a.x, X[i4 * 4 + 0], a0); a1 = fmaf(a.y, X[i4 * 4 + 1], a1);
                a2 = fmaf(a.z, X[i4 * 4 + 2], a2); a3 = fmaf(a.w, X[i4 * 4 + 3], a3);
            }
            const float acc = (a0 + a1) + (a2 + a3);
            if (j < HD) ol[base + t * 768 + j] = f2bf(acc);
            else        g[base + t * 768 + (j - HD)] = Qp[t * RP + (j - HD)] - acc;
        }
    }
}

// ---------------------------------------------------------------- KDA sequential chunk recurrence
// grid: 128 = 32 bh x 4 v-quarters; 192 thr = 24 v x 8 kg. S[12] regs per thread.
constexpr int VS = 24;
__global__ __launch_bounds__(192)
void kda_seq(const float* __restrict__ Kt, const float* __restrict__ W,
             const float* __restrict__ U, const float* __restrict__ Qe,
             const unsigned short* __restrict__ ol, const float* __restrict__ Bc,
             unsigned short* __restrict__ obf, float* __restrict__ states)
{
    __shared__ float Wl[CH * HD];
    __shared__ float Ql[CH * HD];
    __shared__ float Kl[CH * HD];
    __shared__ float Ul[CH * VS];
    __shared__ float UE[CH * VS];

    const int blk = blockIdx.x;
    const int bh = blk >> 2, vq = blk & 3;
    const int b = bh >> 3, h = bh & 7;
    const int tid = threadIdx.x;
    const int vl = tid >> 3, kg = tid & 7;
    const int vcol = vq * VS + vl;
    const size_t base = (size_t)b * (TT * HH * HD) + h * HD;

    float S[12];
#pragma unroll
    for (int r = 0; r < 12; ++r) S[r] = 0.f;

    for (int ch = 0; ch < NCH; ++ch) {
        const size_t cb = base + (size_t)(ch * CH) * (HH * HD);
        __syncthreads();
        for (int e = tid; e < CH * 24; e += 192) {
            const int t = e / 24, c4 = (e % 24) * 4;
            *(float4*)&Wl[t * HD + c4] = *(const float4*)(W + cb + t * 768 + c4);
            *(float4*)&Ql[t * HD + c4] = *(const float4*)(Qe + cb + t * 768 + c4);
            *(float4*)&Kl[t * HD + c4] = *(const float4*)(Kt + cb + t * 768 + c4);
        }
        for (int e = tid; e < CH * 6; e += 192) {
            const int t = e / 6, c4 = (e % 6) * 4;
            *(float4*)&Ul[t * VS + c4] = *(const float4*)(U + cb + t * 768 + vq * VS + c4);
        }
        __syncthreads();
        // UE = U - W@S_in ; O = Qe@S_in + Ol
        for (int t = 0; t < CH; ++t) {
            const float4 w0 = *(const float4*)&Wl[t * HD + kg * 12];
            const float4 w1 = *(const float4*)&Wl[t * HD + kg * 12 + 4];
            const float4 w2 = *(const float4*)&Wl[t * HD + kg * 12 + 8];
            const float4 q0 = *(const float4*)&Ql[t * HD + kg * 12];
            const float4 q1 = *(const float4*)&Ql[t * HD + kg * 12 + 4];
            const float4 q2 = *(const float4*)&Ql[t * HD + kg * 12 + 8];
            float wp = w0.x * S[0]; wp = fmaf(w0.y, S[1], wp); wp = fmaf(w0.z, S[2], wp); wp = fmaf(w0.w, S[3], wp);
            wp = fmaf(w1.x, S[4], wp); wp = fmaf(w1.y, S[5], wp); wp = fmaf(w1.z, S[6], wp); wp = fmaf(w1.w, S[7], wp);
            wp = fmaf(w2.x, S[8], wp); wp = fmaf(w2.y, S[9], wp); wp = fmaf(w2.z, S[10], wp); wp = fmaf(w2.w, S[11], wp);
            float qp = q0.x * S[0]; qp = fmaf(q0.y, S[1], qp); qp = fmaf(q0.z, S[2], qp); qp = fmaf(q0.w, S[3], qp);
            qp = fmaf(q1.x, S[4], qp); qp = fmaf(q1.y, S[5], qp); qp = fmaf(q1.z, S[6], qp); qp = fmaf(q1.w, S[7], qp);
            qp = fmaf(q2.x, S[8], qp); qp = fmaf(q2.y, S[9], qp); qp = fmaf(q2.z, S[10], qp); qp = fmaf(q2.w, S[11], qp);
            wp += __shfl_xor(wp, 1); wp += __shfl_xor(wp, 2); wp += __shfl_xor(wp, 4);
            qp += __shfl_xor(qp, 1); qp += __shfl_xor(qp, 2); qp += __shfl_xor(qp, 4);
            if (kg == 0) {
                UE[t * VS + vl] = Ul[t * VS + vl] - wp;
                obf[cb + t * 768 + vcol] = f2bf(qp + bf2f(ol[cb + t * 768 + vcol]));
            }
        }
        __syncthreads();
        // S = Bc * (S + ktil^T @ UE)
        for (int t = 0; t < CH; ++t) {
            const float ue = UE[t * VS + vl];
            const float4 k0 = *(const float4*)&Kl[t * HD + kg * 12];
            const float4 k1 = *(const float4*)&Kl[t * HD + kg * 12 + 4];
            const float4 k2 = *(const float4*)&Kl[t * HD + kg * 12 + 8];
            S[0] = fmaf(k0.x, ue, S[0]); S[1] = fmaf(k0.y, ue, S[1]);
            S[2] = fmaf(k0.z, ue, S[2]); S[3] = fmaf(k0.w, ue, S[3]);
            S[4] = fmaf(k1.x, ue, S[4]); S[5] = fmaf(k1.y, ue, S[5]);
            S[6] = fmaf(k1.z, ue, S[6]); S[7] = fmaf(k1.w, ue, S[7]);
            S[8] = fmaf(k2.x, ue, S[8]); S[9] = fmaf(k2.y, ue, S[9]);
            S[10] = fmaf(k2.z, ue, S[10]); S[11] = fmaf(k2.w, ue, S[11]);
        }
        const float* bc = Bc + (size_t)bh * NCH * HD + ch * HD + kg * 12;
#pragma unroll
        for (int r = 0; r < 12; ++r) S[r] *= bc[r];
    }
    float* sp = states + (size_t)bh * (HD * HD);
#pragma unroll
    for (int r = 0; r < 12; ++r) sp[(size_t)(kg * 12 + r) * HD + vcol] = S[r];
}

// ---------------------------------------------------------------- host
extern "C" void kernel_launch(void* const* d_in, const int* in_sizes, int n_in,
                              void* d_out, int out_size, void* d_ws, size_t ws_size,
                              hipStream_t stream)
{
    (void)in_sizes; (void)n_in; (void)out_size; (void)ws_size;
    const float* hidden   = (const float*)d_in[0];
    const float* mask     = (const float*)d_in[1];
    const float* norm_a_w = (const float*)d_in[2];
    const float* norm_a_b = (const float*)d_in[3];
    const float* proj_a_w = (const float*)d_in[4];
    const float* proj_a_b = (const float*)d_in[5];
    const float* ln_w     = (const float*)d_in[6];
    const float* ln_b     = (const float*)d_in[7];
    const float* Wq       = (const float*)d_in[8];
    const float* Wk       = (const float*)d_in[9];
    const float* Wv       = (const float*)d_in[10];
    const float* Wfa      = (const float*)d_in[11];
    const float* Wfb      = (const float*)d_in[12];
    const float* dt_bias  = (const float*)d_in[13];
    const float* A_log    = (const float*)d_in[14];
    const float* Wb       = (const float*)d_in[15];
    const float* Wga      = (const float*)d_in[16];
    const float* Wgb      = (const float*)d_in[17];
    const float* onorm_w  = (const float*)d_in[18];
    const float* Wo       = (const float*)d_in[19];
    const float* Wgate    = (const float*)d_in[20];
    const float* Wup      = (const float*)d_in[21];
    const float* Wdown    = (const float*)d_in[22];

    float* ws    = (float*)d_ws;
    float* hbuf  = ws;
    float* qb    = ws + HROW;
    float* kb    = ws + 2 * HROW;
    float* vb    = ws + 3 * HROW;
    float* egb   = ws + 4 * HROW;
    float* betab = ws + 5 * HROW;                     // MM*HH
    float* BcP   = betab + (size_t)MM * HH;           // 32*32*96
    unsigned short* bfp = (unsigned short*)(BcP + 32 * NCH * HD);
    unsigned short* x_bf    = bfp;  bfp += HROW;
    unsigned short* fab_bf  = bfp;  bfp += (size_t)MM * HD;
    unsigned short* gate_bf = bfp;  bfp += HROW;
    unsigned short* olb_bf  = bfp;  bfp += HROW;
    unsigned short* wt_proj = bfp;  bfp += 768 * 768;
    unsigned short *wt_q[LL], *wt_k[LL], *wt_v[LL], *wt_o[LL], *wt_fb[LL], *wt_gb[LL],
                   *wt_gate[LL], *wt_up[LL], *wt_down[LL];
    for (int l = 0; l < LL; ++l) {
        wt_q[l] = bfp;    bfp += 768 * 768;
        wt_k[l] = bfp;    bfp += 768 * 768;
        wt_v[l] = bfp;    bfp += 768 * 768;
        wt_o[l] = bfp;    bfp += 768 * 768;
        wt_fb[l] = bfp;   bfp += 768 * 96;
        wt_gb[l] = bfp;   bfp += 768 * 96;
        wt_gate[l] = bfp; bfp += 2048 * 768;
        wt_up[l] = bfp;   bfp += 2048 * 768;
        wt_down[l] = bfp; bfp += 768 * 2048;
    }
    unsigned short* mg_bf = (unsigned short*)qb;   // SwiGLU mid (qb/kb dead there)
    unsigned short* a_bf  = (unsigned short*)vb;   // Wo output (vb dead there)

    float* out    = (float*)d_out;
    float* states = out + HROW;

    // weight transpose+convert
    transcvt<<<dim3(24, 24), 256, 0, stream>>>(proj_a_w, wt_proj, 768, 768);
    for (int l = 0; l < LL; ++l) {
        transcvt<<<dim3(24, 24), 256, 0, stream>>>(Wq + (size_t)l * 589824, wt_q[l], 768, 768);
        transcvt<<<dim3(24, 24), 256, 0, stream>>>(Wk + (size_t)l * 589824, wt_k[l], 768, 768);
        transcvt<<<dim3(24, 24), 256, 0, stream>>>(Wv + (size_t)l * 589824, wt_v[l], 768, 768);
        transcvt<<<dim3(24, 24), 256, 0, stream>>>(Wo + (size_t)l * 589824, wt_o[l], 768, 768);
        transcvt<<<dim3(24, 3), 256, 0, stream>>>(Wfb + (size_t)l * 73728, wt_fb[l], 96, 768);
        transcvt<<<dim3(24, 3), 256, 0, stream>>>(Wgb + (size_t)l * 73728, wt_gb[l], 96, 768);
        transcvt<<<dim3(64, 24), 256, 0, stream>>>(Wgate + (size_t)l * 1572864, wt_gate[l], 768, 2048);
        transcvt<<<dim3(64, 24), 256, 0, stream>>>(Wup + (size_t)l * 1572864, wt_up[l], 768, 2048);
        transcvt<<<dim3(24, 64), 256, 0, stream>>>(Wdown + (size_t)l * 1572864, wt_down[l], 2048, 768);
    }

    layernorm_rows<<<MM, 256, 0, stream>>>(hidden, x_bf, norm_a_w, norm_a_b, nullptr);
    bgemm<BE_BIAS><<<dim3(6, 64), 256, 0, stream>>>(x_bf, wt_proj, hbuf, nullptr,
                                                    proj_a_b, nullptr, MM, DD, DD);

    for (int l = 0; l < LL; ++l) {
        layernorm_rows<<<MM, 256, 0, stream>>>(hbuf, x_bf, ln_w + l * DD, ln_b + l * DD, mask);
        bgemm<BE_SILU><<<dim3(6, 64), 256, 0, stream>>>(x_bf, wt_q[l], qb, nullptr, nullptr, nullptr, MM, DD, DD);
        bgemm<BE_SILU><<<dim3(6, 64), 256, 0, stream>>>(x_bf, wt_k[l], kb, nullptr, nullptr, nullptr, MM, DD, DD);
        bgemm<BE_SILU><<<dim3(6, 64), 256, 0, stream>>>(x_bf, wt_v[l], vb, nullptr, nullptr, nullptr, MM, DD, DD);
        l2norm_rows<<<(MM * HH) / 4, 256, 0, stream>>>(qb, 0.1020620726159658f);
        l2norm_rows<<<(MM * HH) / 4, 256, 0, stream>>>(kb, 1.f);
        gemm_small<0><<<dim3(2, 128), 256, 0, stream>>>(x_bf, Wfa + (size_t)l * DD * HD, fab_bf, nullptr, MM, HD, DD);
        bgemm<BE_EG><<<dim3(6, 64), 256, 0, stream>>>(fab_bf, wt_fb[l], egb, nullptr,
                                                      A_log + l * DD, dt_bias + l * DD, MM, DD, HD);
        gemm_small<1><<<dim3(1, 128), 256, 0, stream>>>(x_bf, Wb + (size_t)l * DD * HH, nullptr, betab, MM, HH, DD);
        // gate before scan (x_bf gets overwritten by o)
        gemm_small<0><<<dim3(2, 128), 256, 0, stream>>>(x_bf, Wga + (size_t)l * DD * HD, fab_bf, nullptr, MM, HD, DD);
        bgemm<BE_BF16><<<dim3(6, 64), 256, 0, stream>>>(fab_bf, wt_gb[l], nullptr, gate_bf, nullptr, nullptr, MM, DD, HD);
        // chunkwise scan
        kda_pre<<<1024, 256, 0, stream>>>(qb, kb, vb, egb, betab, olb_bf, BcP);
        kda_seq<<<128, 192, 0, stream>>>(qb, kb, vb, egb, olb_bf, BcP, x_bf,
                                         states + (size_t)l * BB * HH * HD * HD);
        // o = onorm(o)*silu(gate), in place on x_bf
        onorm_gate2<<<(MM * HH) / 4, 256, 0, stream>>>(x_bf, gate_bf, onorm_w + l * HD);
        // a = o @ Wo
        bgemm<BE_BF16><<<dim3(6, 64), 256, 0, stream>>>(x_bf, wt_o[l], nullptr, a_bf, nullptr, nullptr, MM, DD, DD);
        // swiglu
        bgemm_dual<<<dim3(32, 64), 256, 0, stream>>>(a_bf, wt_gate[l], wt_up[l], mg_bf, MM, FF, DD);
        float* dst = (l == LL - 1) ? out : hbuf;
        bgemm<BE_RES><<<dim3(6, 64), 256, 0, stream>>>(mg_bf, wt_down[l], dst, nullptr,
                                                       hbuf, nullptr, MM, DD, FF);
    }
}

// Round 6
// 2531.022 us; speedup vs baseline: 1.5512x; 1.5512x over previous
//
#include <hip/hip_runtime.h>
#include <cstddef>
#include <cstdint>
#include <cmath>

// Problem constants
constexpr int BB = 4, TT = 2048, DD = 768, HH = 8, HD = 96, FF = 2048, LL = 2;
constexpr int MM = BB * TT;              // 8192
constexpr size_t HROW = (size_t)MM * DD; // 6291456
constexpr int CH = 64;                   // scan chunk length
constexpr int NCH = TT / CH;             // 32 chunks per sequence
constexpr int RP = 100;                  // padded LDS row (floats)

typedef float f32x4 __attribute__((ext_vector_type(4)));
typedef short bf16x8 __attribute__((ext_vector_type(8)));
typedef unsigned short u16x8 __attribute__((ext_vector_type(8)));

__device__ __forceinline__ void gload16(const void* g, void* l) {
    __builtin_amdgcn_global_load_lds(
        (const __attribute__((address_space(1))) void*)g,
        (__attribute__((address_space(3))) void*)l, 16, 0, 0);
}
__device__ __forceinline__ float bf2f(unsigned short u) {
    return __uint_as_float(((unsigned)u) << 16);
}
__device__ __forceinline__ unsigned short f2bf(float f) {
    unsigned u = __float_as_uint(f);
    unsigned r = (u + 0x7fffu + ((u >> 16) & 1u)) >> 16;
    return (unsigned short)r;
}

// ---------------------------------------------------------------- LayerNorm -> bf16
__global__ __launch_bounds__(256)
void layernorm_rows(const float* __restrict__ x, unsigned short* __restrict__ y,
                    const float* __restrict__ w, const float* __restrict__ b,
                    const float* mask)
{
    const int row = blockIdx.x;
    const int tid = threadIdx.x;
    const float* xr = x + (size_t)row * DD;
    float v0 = xr[tid], v1 = xr[tid + 256], v2 = xr[tid + 512];
    float s = v0 + v1 + v2;
    float ss = v0 * v0 + v1 * v1 + v2 * v2;
#pragma unroll
    for (int i = 1; i < 64; i <<= 1) { s += __shfl_xor(s, i); ss += __shfl_xor(ss, i); }
    __shared__ float red[8];
    const int wid = tid >> 6, lane = tid & 63;
    if (lane == 0) { red[wid] = s; red[4 + wid] = ss; }
    __syncthreads();
    const float S  = red[0] + red[1] + red[2] + red[3];
    const float SS = red[4] + red[5] + red[6] + red[7];
    const float mean = S * (1.f / DD);
    const float var  = SS * (1.f / DD) - mean * mean;
    const float rstd = rsqrtf(var + 1e-5f);
    const float m = mask ? mask[row] : 1.f;
    unsigned short* yr = y + (size_t)row * DD;
    yr[tid]       = f2bf(((v0 - mean) * rstd * w[tid]       + b[tid])       * m);
    yr[tid + 256] = f2bf(((v1 - mean) * rstd * w[tid + 256] + b[tid + 256]) * m);
    yr[tid + 512] = f2bf(((v2 - mean) * rstd * w[tid + 512] + b[tid + 512]) * m);
}

// ---------------------------------------------------------------- transpose+convert W
__global__ __launch_bounds__(256)
void transcvt(const float* __restrict__ in, unsigned short* __restrict__ out, int K, int N)
{
    __shared__ float t[32][33];
    const int tx = threadIdx.x & 31, ty = threadIdx.x >> 5;
    const int k0 = blockIdx.y * 32, n0 = blockIdx.x * 32;
#pragma unroll
    for (int i = 0; i < 4; ++i)
        t[ty + i * 8][tx] = in[(size_t)(k0 + ty + i * 8) * N + n0 + tx];
    __syncthreads();
#pragma unroll
    for (int i = 0; i < 4; ++i)
        out[(size_t)(n0 + ty + i * 8) * K + k0 + tx] = f2bf(t[tx][ty + i * 8]);
}

// ---------------------------------------------------------------- bf16 MFMA GEMM
enum { BE_BIAS = 0, BE_SILU, BE_EG, BE_F32, BE_BF16, BE_RES };

template <int EPI>
__global__ __launch_bounds__(256)
void bgemm(const unsigned short* __restrict__ A, const unsigned short* __restrict__ Bt,
           float* Cf, unsigned short* Cb,
           const float* P0, const float* __restrict__ P1,
           int M, int N, int K)
{
    __shared__ unsigned short As[128 * 32];
    __shared__ unsigned short Bs[128 * 32];
    const int tid = threadIdx.x;
    const int w = tid >> 6, l = tid & 63;
    const int wm = w >> 1, wn = w & 1;
    const int lr = l & 15, lh = l >> 4;
    const int m0 = blockIdx.y * 128, n0 = blockIdx.x * 128;

    f32x4 acc[4][4];
#pragma unroll
    for (int i = 0; i < 4; ++i)
#pragma unroll
        for (int j = 0; j < 4; ++j) acc[i][j] = (f32x4){0.f, 0.f, 0.f, 0.f};

    const int sr = l >> 2, sq = (l & 3) * 8;
    const unsigned short* Ag = A + (size_t)(m0 + w * 32 + sr) * K + sq;
    const unsigned short* Bg = Bt + (size_t)(n0 + w * 32 + sr) * K + sq;
    unsigned short* Al = &As[(w * 32) * 32];
    unsigned short* Bl = &Bs[(w * 32) * 32];

    for (int kt = 0; kt < K; kt += 32) {
        __syncthreads();
        gload16(Ag + kt, Al);
        gload16(Ag + kt + 16 * (size_t)K, Al + 16 * 32);
        gload16(Bg + kt, Bl);
        gload16(Bg + kt + 16 * (size_t)K, Bl + 16 * 32);
        __syncthreads();
        bf16x8 af[4], bfv[4];
#pragma unroll
        for (int mi = 0; mi < 4; ++mi)
            af[mi] = *(const bf16x8*)&As[(wm * 64 + mi * 16 + lr) * 32 + lh * 8];
#pragma unroll
        for (int ni = 0; ni < 4; ++ni)
            bfv[ni] = *(const bf16x8*)&Bs[(wn * 64 + ni * 16 + lr) * 32 + lh * 8];
#pragma unroll
        for (int mi = 0; mi < 4; ++mi)
#pragma unroll
            for (int ni = 0; ni < 4; ++ni)
                acc[mi][ni] = __builtin_amdgcn_mfma_f32_16x16x32_bf16(af[mi], bfv[ni], acc[mi][ni], 0, 0, 0);
    }

#pragma unroll
    for (int mi = 0; mi < 4; ++mi) {
#pragma unroll
        for (int j = 0; j < 4; ++j) {
            const int row = m0 + wm * 64 + mi * 16 + lh * 4 + j;
#pragma unroll
            for (int ni = 0; ni < 4; ++ni) {
                const int col = n0 + wn * 64 + ni * 16 + lr;
                const size_t idx = (size_t)row * N + col;
                float v = acc[mi][ni][j];
                if constexpr (EPI == BE_BIAS) { Cf[idx] = v + P0[col]; }
                else if constexpr (EPI == BE_SILU) { Cf[idx] = v / (1.f + expf(-v)); }
                else if constexpr (EPI == BE_EG) {
                    const float lin = v + P1[col];
                    const float sp = (lin > 20.f) ? lin : log1pf(expf(lin));
                    Cf[idx] = -expf(P0[col]) * sp;      // raw log-decay g
                }
                else if constexpr (EPI == BE_F32) { Cf[idx] = v; }
                else if constexpr (EPI == BE_BF16) { Cb[idx] = f2bf(v); }
                else if constexpr (EPI == BE_RES) { Cf[idx] = v + P0[idx]; }
            }
        }
    }
}

// Dual-B GEMM for SwiGLU
__global__ __launch_bounds__(256)
void bgemm_dual(const unsigned short* __restrict__ A,
                const unsigned short* __restrict__ Bg_, const unsigned short* __restrict__ Bu_,
                unsigned short* __restrict__ C, int M, int N, int K)
{
    __shared__ unsigned short As[128 * 32];
    __shared__ unsigned short Bs1[64 * 32];
    __shared__ unsigned short Bs2[64 * 32];
    const int tid = threadIdx.x;
    const int w = tid >> 6, l = tid & 63;
    const int wm = w >> 1, wn = w & 1;
    const int lr = l & 15, lh = l >> 4;
    const int m0 = blockIdx.y * 128, n0 = blockIdx.x * 64;

    f32x4 a1[4][2], a2[4][2];
#pragma unroll
    for (int i = 0; i < 4; ++i)
#pragma unroll
        for (int j = 0; j < 2; ++j) { a1[i][j] = (f32x4){0.f,0.f,0.f,0.f}; a2[i][j] = (f32x4){0.f,0.f,0.f,0.f}; }

    const int sr = l >> 2, sq = (l & 3) * 8;
    const unsigned short* Ag  = A   + (size_t)(m0 + w * 32 + sr) * K + sq;
    const unsigned short* B1g = Bg_ + (size_t)(n0 + w * 16 + sr) * K + sq;
    const unsigned short* B2g = Bu_ + (size_t)(n0 + w * 16 + sr) * K + sq;
    unsigned short* Al  = &As[(w * 32) * 32];
    unsigned short* B1l = &Bs1[(w * 16) * 32];
    unsigned short* B2l = &Bs2[(w * 16) * 32];

    for (int kt = 0; kt < K; kt += 32) {
        __syncthreads();
        gload16(Ag + kt, Al);
        gload16(Ag + kt + 16 * (size_t)K, Al + 16 * 32);
        gload16(B1g + kt, B1l);
        gload16(B2g + kt, B2l);
        __syncthreads();
        bf16x8 af[4], b1[2], b2[2];
#pragma unroll
        for (int mi = 0; mi < 4; ++mi)
            af[mi] = *(const bf16x8*)&As[(wm * 64 + mi * 16 + lr) * 32 + lh * 8];
#pragma unroll
        for (int ni = 0; ni < 2; ++ni) {
            b1[ni] = *(const bf16x8*)&Bs1[(wn * 32 + ni * 16 + lr) * 32 + lh * 8];
            b2[ni] = *(const bf16x8*)&Bs2[(wn * 32 + ni * 16 + lr) * 32 + lh * 8];
        }
#pragma unroll
        for (int mi = 0; mi < 4; ++mi)
#pragma unroll
            for (int ni = 0; ni < 2; ++ni) {
                a1[mi][ni] = __builtin_amdgcn_mfma_f32_16x16x32_bf16(af[mi], b1[ni], a1[mi][ni], 0, 0, 0);
                a2[mi][ni] = __builtin_amdgcn_mfma_f32_16x16x32_bf16(af[mi], b2[ni], a2[mi][ni], 0, 0, 0);
            }
    }

#pragma unroll
    for (int mi = 0; mi < 4; ++mi)
#pragma unroll
        for (int j = 0; j < 4; ++j) {
            const int row = m0 + wm * 64 + mi * 16 + lh * 4 + j;
#pragma unroll
            for (int ni = 0; ni < 2; ++ni) {
                const int col = n0 + wn * 32 + ni * 16 + lr;
                const float g = a1[mi][ni][j], u = a2[mi][ni][j];
                C[(size_t)row * N + col] = f2bf((g / (1.f + expf(-g))) * u);
            }
        }
}

// ---------------------------------------------------------------- small fp32 GEMM (A bf16)
template <int MODE>
__global__ __launch_bounds__(256)
void gemm_small(const unsigned short* __restrict__ A, const float* __restrict__ Bm,
                unsigned short* Cb, float* Cf, int M, int N, int K)
{
    __shared__ float As[16][64];
    __shared__ float Bs[16][64];
    const int tid = threadIdx.x;
    const int tx = tid & 15, ty = tid >> 4;
    const int row0 = blockIdx.y * 64;
    const int col0 = blockIdx.x * 64;
    float acc[4][4] = {};
    const int ar  = tid >> 2;
    const int ac4 = (tid & 3) << 2;
    const int br  = tid >> 4;
    const int bc  = (tid & 15) << 2;
    const int gc  = col0 + bc;
    const bool bok = gc < N;

    for (int kt = 0; kt < K; kt += 16) {
        const ushort4 a4 = *(const ushort4*)(A + (size_t)(row0 + ar) * K + kt + ac4);
        float4 b4 = make_float4(0.f, 0.f, 0.f, 0.f);
        if (bok) b4 = *(const float4*)(Bm + (size_t)(kt + br) * N + gc);
        __syncthreads();
        As[ac4 + 0][ar] = bf2f(a4.x); As[ac4 + 1][ar] = bf2f(a4.y);
        As[ac4 + 2][ar] = bf2f(a4.z); As[ac4 + 3][ar] = bf2f(a4.w);
        *(float4*)&Bs[br][bc] = b4;
        __syncthreads();
#pragma unroll
        for (int kk = 0; kk < 16; ++kk) {
            const float4 av = *(const float4*)&As[kk][ty << 2];
            const float4 bv = *(const float4*)&Bs[kk][tx << 2];
            const float a_[4] = {av.x, av.y, av.z, av.w};
            const float b_[4] = {bv.x, bv.y, bv.z, bv.w};
#pragma unroll
            for (int i = 0; i < 4; ++i)
#pragma unroll
                for (int j = 0; j < 4; ++j)
                    acc[i][j] = fmaf(a_[i], b_[j], acc[i][j]);
        }
    }
#pragma unroll
    for (int i = 0; i < 4; ++i) {
        const int row = row0 + (ty << 2) + i;
#pragma unroll
        for (int j = 0; j < 4; ++j) {
            const int col = col0 + (tx << 2) + j;
            if (col >= N) continue;
            const size_t idx = (size_t)row * N + col;
            if constexpr (MODE == 0) Cb[idx] = f2bf(acc[i][j]);
            else                     Cf[idx] = 1.f / (1.f + expf(-acc[i][j]));
        }
    }
}

// ---------------------------------------------------------------- l2norm over HD=96
__global__ __launch_bounds__(256)
void l2norm_rows(float* x, float scale)
{
    const int row  = (blockIdx.x << 2) + (threadIdx.x >> 6);
    const int lane = threadIdx.x & 63;
    float* xr = x + (size_t)row * HD;
    const float a = xr[lane];
    const float b = (lane < 32) ? xr[64 + lane] : 0.f;
    float ss = a * a + b * b;
#pragma unroll
    for (int i = 1; i < 64; i <<= 1) ss += __shfl_xor(ss, i);
    const float r = rsqrtf(ss + 1e-6f) * scale;
    xr[lane] = a * r;
    if (lane < 32) xr[64 + lane] = b * r;
}

// ---------------------------------------------------------------- KDA chunkwise precompute
// One block per (bh, chunk). Outputs: kappa_tilde->Kbf(bf16), W->Wbf(bf16), U->v(f32),
// Qe->g(f32), Ol->ol(bf16), Bc.
__global__ __launch_bounds__(256)
void kda_pre(const float* __restrict__ q, const float* __restrict__ k, float* v, float* g,
             const float* __restrict__ beta,
             unsigned short* __restrict__ ol, float* __restrict__ Bc,
             unsigned short* __restrict__ Wbf, unsigned short* __restrict__ Kbf)
{
    __shared__ float Kb[CH * RP];   // k, then kappa_tilde
    __shared__ float Kk[CH * RP];   // kappa
    __shared__ float Qp[CH * RP];   // g -> L -> q'
    __shared__ float Am[CH][68];
    __shared__ float sb[CH];

    const int blk = blockIdx.x;
    const int ch = blk & 31, bh = blk >> 5;
    const int b = bh >> 3, h = bh & 7;
    const int tid = threadIdx.x;
    const size_t base = (size_t)b * (TT * HH * HD) + (size_t)(ch * CH) * (HH * HD) + h * HD;

    // P0: stage k, g, beta
    for (int e = tid; e < CH * 24; e += 256) {
        const int t = e / 24, c4 = (e % 24) * 4;
        *(float4*)&Kb[t * RP + c4] = *(const float4*)(k + base + t * 768 + c4);
        *(float4*)&Qp[t * RP + c4] = *(const float4*)(g + base + t * 768 + c4);
    }
    if (tid < CH) sb[tid] = beta[((size_t)b * TT + ch * CH + tid) * HH + h];
    __syncthreads();

    // P1: per-channel cumsum of g
    if (tid < HD) {
        float L = 0.f;
        for (int t = 0; t < CH; ++t) { L += Qp[t * RP + tid]; Qp[t * RP + tid] = L; }
    }
    __syncthreads();

    // P2: kappa, kappa_tilde, q', Bc
    for (int e = tid; e < CH * HD; e += 256) {
        const int t = e / HD, c = e % HD;
        const float L = Qp[t * RP + c];
        const float B = expf(L), iB = expf(-L);
        const float kv = Kb[t * RP + c];
        if (t == CH - 1) Bc[((size_t)bh * NCH + ch) * HD + c] = B;
        Kk[t * RP + c] = kv * B;
        const float kti = kv * iB;
        const float qv = q[base + t * 768 + c];
        Kb[t * RP + c] = kti;
        Kbf[base + t * 768 + c] = f2bf(kti);      // kappa_tilde out (bf16)
        Qp[t * RP + c] = qv * B;                  // q'
    }
    __syncthreads();

    // P3: A[t][i] = beta_t * kappa_t . ktil_i  (i < t)
    {
        const int wv = tid >> 6, lt = tid & 63;
        for (int half = 0; half < 2; ++half) {
            float4 ca[12];
#pragma unroll
            for (int r = 0; r < 12; ++r)
                ca[r] = *(const float4*)&Kk[lt * RP + half * 48 + r * 4];
            for (int i = wv * 16; i < wv * 16 + 16; ++i) {
                float d0 = 0, d1 = 0, d2 = 0, d3 = 0;
#pragma unroll
                for (int r = 0; r < 12; ++r) {
                    const float4 cb = *(const float4*)&Kb[i * RP + half * 48 + r * 4];
                    d0 = fmaf(ca[r].x, cb.x, d0); d1 = fmaf(ca[r].y, cb.y, d1);
                    d2 = fmaf(ca[r].z, cb.z, d2); d3 = fmaf(ca[r].w, cb.w, d3);
                }
                const float d = ((d0 + d1) + (d2 + d3)) * sb[lt];
                const float val = (i < lt) ? d : 0.f;
                if (half == 0) Am[lt][i] = val; else Am[lt][i] += val;
            }
        }
    }
    __syncthreads();

    // P4: forward solve, column j of [U | W] in registers
    float X[CH];
    const int j = tid;
    if (j < 192) {
        if (j < HD) {
#pragma unroll
            for (int t = 0; t < CH; ++t) X[t] = sb[t] * v[base + t * 768 + j];
        } else {
#pragma unroll
            for (int t = 0; t < CH; ++t) X[t] = sb[t] * Kk[t * RP + (j - HD)];
        }
#pragma unroll
        for (int t = 1; t < CH; ++t) {
            float a0 = 0, a1 = 0, a2 = 0, a3 = 0;
#pragma unroll
            for (int i4 = 0; i4 * 4 < t; ++i4) {
                const float4 a = *(const float4*)&Am[t][i4 * 4];
                if (i4 * 4 + 0 < t) a0 = fmaf(a.x, X[i4 * 4 + 0], a0);
                if (i4 * 4 + 1 < t) a1 = fmaf(a.y, X[i4 * 4 + 1], a1);
                if (i4 * 4 + 2 < t) a2 = fmaf(a.z, X[i4 * 4 + 2], a2);
                if (i4 * 4 + 3 < t) a3 = fmaf(a.w, X[i4 * 4 + 3], a3);
            }
            X[t] -= ((a0 + a1) + (a2 + a3));
        }
        // P5: store U (f32 over v) / W (bf16)
        if (j < HD) {
#pragma unroll
            for (int t = 0; t < CH; ++t) v[base + t * 768 + j] = X[t];
        } else {
#pragma unroll
            for (int t = 0; t < CH; ++t) Wbf[base + t * 768 + (j - HD)] = f2bf(X[t]);
        }
    }
    __syncthreads();

    // P6: T[t][i] = q'_t . ktil_i  (i <= t)
    {
        const int wv = tid >> 6, lt = tid & 63;
        for (int half = 0; half < 2; ++half) {
            float4 ca[12];
#pragma unroll
            for (int r = 0; r < 12; ++r)
                ca[r] = *(const float4*)&Qp[lt * RP + half * 48 + r * 4];
            for (int i = wv * 16; i < wv * 16 + 16; ++i) {
                float d0 = 0, d1 = 0, d2 = 0, d3 = 0;
#pragma unroll
                for (int r = 0; r < 12; ++r) {
                    const float4 cb = *(const float4*)&Kb[i * RP + half * 48 + r * 4];
                    d0 = fmaf(ca[r].x, cb.x, d0); d1 = fmaf(ca[r].y, cb.y, d1);
                    d2 = fmaf(ca[r].z, cb.z, d2); d3 = fmaf(ca[r].w, cb.w, d3);
                }
                const float d = (d0 + d1) + (d2 + d3);
                const float val = (i <= lt) ? d : 0.f;
                if (half == 0) Am[lt][i] = val; else Am[lt][i] += val;
            }
        }
    }
    __syncthreads();

    // P7: T @ X -> Ol (j<96) ; Qe = q' - T@W (j>=96, over g)
    if (j < 192) {
        for (int t = 0; t < CH; ++t) {
            float a0 = 0, a1 = 0, a2 = 0, a3 = 0;
#pragma unroll
            for (int i4 = 0; i4 < 16; ++i4) {
                const float4 a = *(const float4*)&Am[t][i4 * 4];
                a0 = fmaf(a.x, X[i4 * 4 + 0], a0); a1 = fmaf(a.y, X[i4 * 4 + 1], a1);
                a2 = fmaf(a.z, X[i4 * 4 + 2], a2); a3 = fmaf(a.w, X[i4 * 4 + 3], a3);
            }
            const float acc = (a0 + a1) + (a2 + a3);
            if (j < HD) ol[base + t * 768 + j] = f2bf(acc);
            else        g[base + t * 768 + (j - HD)] = Qp[t * RP + (j - HD)] - acc;
        }
    }
}

// ---------------------------------------------------------------- KDA sequential recurrence only
// grid 128 = 32 bh x 4 vq; 192 thr = 24 vl x 8 kg; S[12] regs.
// Per chunk: Sin store, UE_t = U - W@S (fused, in-register), S = Bc*(S + ktil^T UE).
constexpr int VS = 24;
__global__ __launch_bounds__(192)
void kda_seq(const unsigned short* __restrict__ Wbf, const unsigned short* __restrict__ Kbf,
             const float* __restrict__ U, const float* __restrict__ Bc,
             float* __restrict__ Sin, float* __restrict__ states)
{
    __shared__ float Wl[CH * HD];
    __shared__ float Kl[CH * HD];
    __shared__ float Ul[CH * VS];

    const int blk = blockIdx.x;
    const int bh = blk >> 2, vq = blk & 3;
    const int b = bh >> 3, h = bh & 7;
    const int tid = threadIdx.x;
    const int vl = tid >> 3, kg = tid & 7;
    const int vcol = vq * VS + vl;
    const size_t base = (size_t)b * (TT * HH * HD) + h * HD;

    float S[12];
#pragma unroll
    for (int r = 0; r < 12; ++r) S[r] = 0.f;

    u16x8 wpf[4], kpf[4];
    f32x4 upf[2];

    // ---- load + stage chunk 0
#pragma unroll
    for (int i = 0; i < 4; ++i) {
        const int g = i * 192 + tid;
        const int t = g / 12, c8 = (g % 12) * 8;
        wpf[i] = *(const u16x8*)(Wbf + base + (size_t)t * 768 + c8);
        kpf[i] = *(const u16x8*)(Kbf + base + (size_t)t * 768 + c8);
    }
#pragma unroll
    for (int i = 0; i < 2; ++i) {
        const int g = i * 192 + tid;
        const int t = g / 6, c4 = (g % 6) * 4;
        upf[i] = *(const f32x4*)(U + base + (size_t)t * 768 + vq * VS + c4);
    }
#pragma unroll
    for (int i = 0; i < 4; ++i) {
        const int g = i * 192 + tid;
        const int t = g / 12, c8 = (g % 12) * 8;
#pragma unroll
        for (int j = 0; j < 8; ++j) {
            Wl[t * HD + c8 + j] = bf2f((unsigned short)wpf[i][j]);
            Kl[t * HD + c8 + j] = bf2f((unsigned short)kpf[i][j]);
        }
    }
#pragma unroll
    for (int i = 0; i < 2; ++i) {
        const int g = i * 192 + tid;
        const int t = g / 6, c4 = (g % 6) * 4;
        *(f32x4*)&Ul[t * VS + c4] = upf[i];
    }
    __syncthreads();

    for (int ch = 0; ch < NCH; ++ch) {
        // prefetch chunk ch+1 into registers (hidden under compute)
        if (ch + 1 < NCH) {
            const size_t cb = base + (size_t)((ch + 1) * CH) * (HH * HD);
#pragma unroll
            for (int i = 0; i < 4; ++i) {
                const int g = i * 192 + tid;
                const int t = g / 12, c8 = (g % 12) * 8;
                wpf[i] = *(const u16x8*)(Wbf + cb + (size_t)t * 768 + c8);
                kpf[i] = *(const u16x8*)(Kbf + cb + (size_t)t * 768 + c8);
            }
#pragma unroll
            for (int i = 0; i < 2; ++i) {
                const int g = i * 192 + tid;
                const int t = g / 6, c4 = (g % 6) * 4;
                upf[i] = *(const f32x4*)(U + cb + (size_t)t * 768 + vq * VS + c4);
            }
        }
        // store S_in for the O-epilogue
        {
            float* sp = Sin + ((size_t)(bh * NCH + ch) * HD + kg * 12) * HD + vcol;
#pragma unroll
            for (int r = 0; r < 12; ++r) sp[(size_t)r * HD] = S[r];
        }
        // fused recurrence
#pragma unroll 2
        for (int t = 0; t < CH; ++t) {
            const f32x4 w0 = *(const f32x4*)&Wl[t * HD + kg * 12];
            const f32x4 w1 = *(const f32x4*)&Wl[t * HD + kg * 12 + 4];
            const f32x4 w2 = *(const f32x4*)&Wl[t * HD + kg * 12 + 8];
            float wp = w0.x * S[0];
            wp = fmaf(w0.y, S[1], wp);  wp = fmaf(w0.z, S[2], wp);  wp = fmaf(w0.w, S[3], wp);
            wp = fmaf(w1.x, S[4], wp);  wp = fmaf(w1.y, S[5], wp);  wp = fmaf(w1.z, S[6], wp);
            wp = fmaf(w1.w, S[7], wp);  wp = fmaf(w2.x, S[8], wp);  wp = fmaf(w2.y, S[9], wp);
            wp = fmaf(w2.z, S[10], wp); wp = fmaf(w2.w, S[11], wp);
            wp += __shfl_xor(wp, 1); wp += __shfl_xor(wp, 2); wp += __shfl_xor(wp, 4);
            const float ue = Ul[t * VS + vl] - wp;
            const f32x4 k0 = *(const f32x4*)&Kl[t * HD + kg * 12];
            const f32x4 k1 = *(const f32x4*)&Kl[t * HD + kg * 12 + 4];
            const f32x4 k2 = *(const f32x4*)&Kl[t * HD + kg * 12 + 8];
            S[0] = fmaf(k0.x, ue, S[0]);  S[1] = fmaf(k0.y, ue, S[1]);
            S[2] = fmaf(k0.z, ue, S[2]);  S[3] = fmaf(k0.w, ue, S[3]);
            S[4] = fmaf(k1.x, ue, S[4]);  S[5] = fmaf(k1.y, ue, S[5]);
            S[6] = fmaf(k1.z, ue, S[6]);  S[7] = fmaf(k1.w, ue, S[7]);
            S[8] = fmaf(k2.x, ue, S[8]);  S[9] = fmaf(k2.y, ue, S[9]);
            S[10] = fmaf(k2.z, ue, S[10]); S[11] = fmaf(k2.w, ue, S[11]);
        }
        // decay to chunk exit
        {
            const float* bc = Bc + ((size_t)bh * NCH + ch) * HD + kg * 12;
#pragma unroll
            for (int r = 0; r < 12; ++r) S[r] *= bc[r];
        }
        __syncthreads();
        if (ch + 1 < NCH) {
#pragma unroll
            for (int i = 0; i < 4; ++i) {
                const int g = i * 192 + tid;
                const int t = g / 12, c8 = (g % 12) * 8;
#pragma unroll
                for (int j = 0; j < 8; ++j) {
                    Wl[t * HD + c8 + j] = bf2f((unsigned short)wpf[i][j]);
                    Kl[t * HD + c8 + j] = bf2f((unsigned short)kpf[i][j]);
                }
            }
#pragma unroll
            for (int i = 0; i < 2; ++i) {
                const int g = i * 192 + tid;
                const int t = g / 6, c4 = (g % 6) * 4;
                *(f32x4*)&Ul[t * VS + c4] = upf[i];
            }
        }
        __syncthreads();
    }
    float* sp = states + (size_t)bh * (HD * HD);
#pragma unroll
    for (int r = 0; r < 12; ++r) sp[(size_t)(kg * 12 + r) * HD + vcol] = S[r];
}

// ---------------------------------------------------------------- KDA parallel O epilogue
// O = Qe@S_in + Ol, then onorm * silu(gate) -> bf16. grid 1024 = bh x ch, 256 thr.
__global__ __launch_bounds__(256)
void kda_epi(const float* __restrict__ Sin, const float* __restrict__ Qe,
             const unsigned short* __restrict__ Ol, const unsigned short* __restrict__ Gt,
             const float* __restrict__ onw, unsigned short* __restrict__ obf)
{
    __shared__ float Sl[96 * 100];
    __shared__ float Ql[64 * 100];
    __shared__ unsigned short Olb[64 * 104];
    __shared__ unsigned short Gl[64 * 104];

    const int bx = blockIdx.x;
    const int bh = bx >> 5, ch = bx & 31;
    const int b = bh >> 3, h = bh & 7;
    const int tid = threadIdx.x;
    const size_t cb = (size_t)b * (TT * HH * HD) + (size_t)(ch * CH) * (HH * HD) + h * HD;
    const float* Sg = Sin + (size_t)(bh * NCH + ch) * HD * HD;

#pragma unroll
    for (int i = 0; i < 9; ++i) {
        const int g = i * 256 + tid;          // 2304 float4
        const int k = g / 24, c4 = (g % 24) * 4;
        *(f32x4*)&Sl[k * 100 + c4] = *(const f32x4*)(Sg + (size_t)k * HD + c4);
    }
#pragma unroll
    for (int i = 0; i < 6; ++i) {
        const int g = i * 256 + tid;          // 1536 float4
        const int t = g / 24, c4 = (g % 24) * 4;
        *(f32x4*)&Ql[t * 100 + c4] = *(const f32x4*)(Qe + cb + (size_t)t * 768 + c4);
    }
#pragma unroll
    for (int i = 0; i < 3; ++i) {
        const int g = i * 256 + tid;          // 768 ushort8
        const int t = g / 12, c8 = (g % 12) * 8;
        *(u16x8*)&Olb[t * 104 + c8] = *(const u16x8*)(Ol + cb + (size_t)t * 768 + c8);
        *(u16x8*)&Gl[t * 104 + c8]  = *(const u16x8*)(Gt + cb + (size_t)t * 768 + c8);
    }
    __syncthreads();

    const int t = tid >> 2, vq2 = tid & 3;
    const int v0 = vq2 * 24;
    f32x4 acc[6];
#pragma unroll
    for (int j = 0; j < 6; ++j) {
        acc[j].x = bf2f(Olb[t * 104 + v0 + j * 4 + 0]);
        acc[j].y = bf2f(Olb[t * 104 + v0 + j * 4 + 1]);
        acc[j].z = bf2f(Olb[t * 104 + v0 + j * 4 + 2]);
        acc[j].w = bf2f(Olb[t * 104 + v0 + j * 4 + 3]);
    }
#pragma unroll 2
    for (int k = 0; k < HD; ++k) {
        const float qv = Ql[t * 100 + k];
#pragma unroll
        for (int j = 0; j < 6; ++j)
            acc[j] += qv * *(const f32x4*)&Sl[k * 100 + v0 + j * 4];
    }
    float ss = 0.f;
#pragma unroll
    for (int j = 0; j < 6; ++j)
        ss += acc[j].x * acc[j].x + acc[j].y * acc[j].y + acc[j].z * acc[j].z + acc[j].w * acc[j].w;
    ss += __shfl_xor(ss, 1); ss += __shfl_xor(ss, 2);
    const float r = rsqrtf(ss * (1.f / HD) + 1e-6f);
#pragma unroll
    for (int j = 0; j < 6; ++j) {
#pragma unroll
        for (int e = 0; e < 4; ++e) {
            const int v = v0 + j * 4 + e;
            const float g = bf2f(Gl[t * 104 + v]);
            const float val = acc[j][e] * r * onw[v] * (g / (1.f + expf(-g)));
            obf[cb + (size_t)t * 768 + v] = f2bf(val);
        }
    }
}

// ---------------------------------------------------------------- host
extern "C" void kernel_launch(void* const* d_in, const int* in_sizes, int n_in,
                              void* d_out, int out_size, void* d_ws, size_t ws_size,
                              hipStream_t stream)
{
    (void)in_sizes; (void)n_in; (void)out_size; (void)ws_size;
    const float* hidden   = (const float*)d_in[0];
    const float* mask     = (const float*)d_in[1];
    const float* norm_a_w = (const float*)d_in[2];
    const float* norm_a_b = (const float*)d_in[3];
    const float* proj_a_w = (const float*)d_in[4];
    const float* proj_a_b = (const float*)d_in[5];
    const float* ln_w     = (const float*)d_in[6];
    const float* ln_b     = (const float*)d_in[7];
    const float* Wq       = (const float*)d_in[8];
    const float* Wk       = (const float*)d_in[9];
    const float* Wv       = (const float*)d_in[10];
    const float* Wfa      = (const float*)d_in[11];
    const float* Wfb      = (const float*)d_in[12];
    const float* dt_bias  = (const float*)d_in[13];
    const float* A_log    = (const float*)d_in[14];
    const float* Wb       = (const float*)d_in[15];
    const float* Wga      = (const float*)d_in[16];
    const float* Wgb      = (const float*)d_in[17];
    const float* onorm_w  = (const float*)d_in[18];
    const float* Wo       = (const float*)d_in[19];
    const float* Wgate    = (const float*)d_in[20];
    const float* Wup      = (const float*)d_in[21];
    const float* Wdown    = (const float*)d_in[22];

    float* ws    = (float*)d_ws;
    float* hbuf  = ws;
    float* qb    = ws + HROW;          // kappa-tilde fp32 dead after pre -> Sin lives here
    float* kb    = ws + 2 * HROW;      // (Sin spills into kb; both dead after pre)
    float* vb    = ws + 3 * HROW;      // U (f32)
    float* egb   = ws + 4 * HROW;      // g -> Qe (f32)
    float* betab = ws + 5 * HROW;                     // MM*HH
    float* BcP   = betab + (size_t)MM * HH;           // 32*32*96
    float* SinP  = qb;                                // 9.44M floats (qb+kb region)
    unsigned short* bfp = (unsigned short*)(BcP + 32 * NCH * HD);
    unsigned short* x_bf    = bfp;  bfp += HROW;
    unsigned short* fab_bf  = bfp;  bfp += (size_t)MM * HD;
    unsigned short* gate_bf = bfp;  bfp += HROW;
    unsigned short* olb_bf  = bfp;  bfp += HROW;
    unsigned short* w_bf    = bfp;  bfp += HROW;
    unsigned short* k_bf    = bfp;  bfp += HROW;
    unsigned short* wt_proj = bfp;  bfp += 768 * 768;
    unsigned short *wt_q[LL], *wt_k[LL], *wt_v[LL], *wt_o[LL], *wt_fb[LL], *wt_gb[LL],
                   *wt_gate[LL], *wt_up[LL], *wt_down[LL];
    for (int l = 0; l < LL; ++l) {
        wt_q[l] = bfp;    bfp += 768 * 768;
        wt_k[l] = bfp;    bfp += 768 * 768;
        wt_v[l] = bfp;    bfp += 768 * 768;
        wt_o[l] = bfp;    bfp += 768 * 768;
        wt_fb[l] = bfp;   bfp += 768 * 96;
        wt_gb[l] = bfp;   bfp += 768 * 96;
        wt_gate[l] = bfp; bfp += 2048 * 768;
        wt_up[l] = bfp;   bfp += 2048 * 768;
        wt_down[l] = bfp; bfp += 768 * 2048;
    }
    unsigned short* mg_bf = (unsigned short*)hbuf;  // NOT hbuf! see below
    // SwiGLU mid buffer must not clobber live data: use egb+betab region? egb (Qe) dead
    // after epi; mg needs 8192*2048 ushort = 16M ush = 32MB = egb(25MB)+... use egb+...
    mg_bf = (unsigned short*)egb;                   // egb dead after epi; spills into betab/BcP? no:
    // egb = 25.17MB, need 33.55MB -> spills 8.4MB into betab(0.26MB)+BcP(0.39MB)+x_bf...
    // NOT safe. Keep mg in SinP region instead: SinP(qb..kb, 50MB) dead after epi.
    mg_bf = (unsigned short*)SinP;
    unsigned short* a_bf  = (unsigned short*)vb;    // U dead after seq

    float* out    = (float*)d_out;
    float* states = out + HROW;

    // weight transpose+convert
    transcvt<<<dim3(24, 24), 256, 0, stream>>>(proj_a_w, wt_proj, 768, 768);
    for (int l = 0; l < LL; ++l) {
        transcvt<<<dim3(24, 24), 256, 0, stream>>>(Wq + (size_t)l * 589824, wt_q[l], 768, 768);
        transcvt<<<dim3(24, 24), 256, 0, stream>>>(Wk + (size_t)l * 589824, wt_k[l], 768, 768);
        transcvt<<<dim3(24, 24), 256, 0, stream>>>(Wv + (size_t)l * 589824, wt_v[l], 768, 768);
        transcvt<<<dim3(24, 24), 256, 0, stream>>>(Wo + (size_t)l * 589824, wt_o[l], 768, 768);
        transcvt<<<dim3(24, 3), 256, 0, stream>>>(Wfb + (size_t)l * 73728, wt_fb[l], 96, 768);
        transcvt<<<dim3(24, 3), 256, 0, stream>>>(Wgb + (size_t)l * 73728, wt_gb[l], 96, 768);
        transcvt<<<dim3(64, 24), 256, 0, stream>>>(Wgate + (size_t)l * 1572864, wt_gate[l], 768, 2048);
        transcvt<<<dim3(64, 24), 256, 0, stream>>>(Wup + (size_t)l * 1572864, wt_up[l], 768, 2048);
        transcvt<<<dim3(24, 64), 256, 0, stream>>>(Wdown + (size_t)l * 1572864, wt_down[l], 2048, 768);
    }

    layernorm_rows<<<MM, 256, 0, stream>>>(hidden, x_bf, norm_a_w, norm_a_b, nullptr);
    bgemm<BE_BIAS><<<dim3(6, 64), 256, 0, stream>>>(x_bf, wt_proj, hbuf, nullptr,
                                                    proj_a_b, nullptr, MM, DD, DD);

    for (int l = 0; l < LL; ++l) {
        layernorm_rows<<<MM, 256, 0, stream>>>(hbuf, x_bf, ln_w + l * DD, ln_b + l * DD, mask);
        bgemm<BE_SILU><<<dim3(6, 64), 256, 0, stream>>>(x_bf, wt_q[l], qb, nullptr, nullptr, nullptr, MM, DD, DD);
        bgemm<BE_SILU><<<dim3(6, 64), 256, 0, stream>>>(x_bf, wt_k[l], kb, nullptr, nullptr, nullptr, MM, DD, DD);
        bgemm<BE_SILU><<<dim3(6, 64), 256, 0, stream>>>(x_bf, wt_v[l], vb, nullptr, nullptr, nullptr, MM, DD, DD);
        l2norm_rows<<<(MM * HH) / 4, 256, 0, stream>>>(qb, 0.1020620726159658f);
        l2norm_rows<<<(MM * HH) / 4, 256, 0, stream>>>(kb, 1.f);
        gemm_small<0><<<dim3(2, 128), 256, 0, stream>>>(x_bf, Wfa + (size_t)l * DD * HD, fab_bf, nullptr, MM, HD, DD);
        bgemm<BE_EG><<<dim3(6, 64), 256, 0, stream>>>(fab_bf, wt_fb[l], egb, nullptr,
                                                      A_log + l * DD, dt_bias + l * DD, MM, DD, HD);
        gemm_small<1><<<dim3(1, 128), 256, 0, stream>>>(x_bf, Wb + (size_t)l * DD * HH, nullptr, betab, MM, HH, DD);
        // gate before scan (x_bf gets overwritten by o in epi)
        gemm_small<0><<<dim3(2, 128), 256, 0, stream>>>(x_bf, Wga + (size_t)l * DD * HD, fab_bf, nullptr, MM, HD, DD);
        bgemm<BE_BF16><<<dim3(6, 64), 256, 0, stream>>>(fab_bf, wt_gb[l], nullptr, gate_bf, nullptr, nullptr, MM, DD, HD);
        // chunkwise scan
        kda_pre<<<1024, 256, 0, stream>>>(qb, kb, vb, egb, betab, olb_bf, BcP, w_bf, k_bf);
        kda_seq<<<128, 192, 0, stream>>>(w_bf, k_bf, vb, BcP, SinP,
                                         states + (size_t)l * BB * HH * HD * HD);
        kda_epi<<<1024, 256, 0, stream>>>(SinP, egb, olb_bf, gate_bf, onorm_w + l * HD, x_bf);
        // a = o @ Wo
        bgemm<BE_BF16><<<dim3(6, 64), 256, 0, stream>>>(x_bf, wt_o[l], nullptr, a_bf, nullptr, nullptr, MM, DD, DD);
        // swiglu (mg in SinP region: Sin dead after epi)
        bgemm_dual<<<dim3(32, 64), 256, 0, stream>>>(a_bf, wt_gate[l], wt_up[l], mg_bf, MM, FF, DD);
        float* dst = (l == LL - 1) ? out : hbuf;
        bgemm<BE_RES><<<dim3(6, 64), 256, 0, stream>>>(mg_bf, wt_down[l], dst, nullptr,
                                                       hbuf, nullptr, MM, DD, FF);
    }
}

// Round 7
// 2044.508 us; speedup vs baseline: 1.9203x; 1.2380x over previous
//
#include <hip/hip_runtime.h>
#include <cstddef>
#include <cstdint>
#include <cmath>

// Problem constants
constexpr int BB = 4, TT = 2048, DD = 768, HH = 8, HD = 96, FF = 2048, LL = 2;
constexpr int MM = BB * TT;              // 8192
constexpr size_t HROW = (size_t)MM * DD; // 6291456
constexpr int CH = 64;                   // scan chunk length
constexpr int NCH = TT / CH;             // 32 chunks per sequence
constexpr int RP = 100;                  // padded LDS row (floats)

typedef float f32x4 __attribute__((ext_vector_type(4)));
typedef short bf16x8 __attribute__((ext_vector_type(8)));
typedef unsigned short u16x8 __attribute__((ext_vector_type(8)));

__device__ __forceinline__ void gload16(const void* g, void* l) {
    __builtin_amdgcn_global_load_lds(
        (const __attribute__((address_space(1))) void*)g,
        (__attribute__((address_space(3))) void*)l, 16, 0, 0);
}
__device__ __forceinline__ float bf2f(unsigned short u) {
    return __uint_as_float(((unsigned)u) << 16);
}
__device__ __forceinline__ unsigned short f2bf(float f) {
    unsigned u = __float_as_uint(f);
    unsigned r = (u + 0x7fffu + ((u >> 16) & 1u)) >> 16;
    return (unsigned short)r;
}

// ---------------------------------------------------------------- LayerNorm -> bf16
__global__ __launch_bounds__(256)
void layernorm_rows(const float* __restrict__ x, unsigned short* __restrict__ y,
                    const float* __restrict__ w, const float* __restrict__ b,
                    const float* mask)
{
    const int row = blockIdx.x;
    const int tid = threadIdx.x;
    const float* xr = x + (size_t)row * DD;
    float v0 = xr[tid], v1 = xr[tid + 256], v2 = xr[tid + 512];
    float s = v0 + v1 + v2;
    float ss = v0 * v0 + v1 * v1 + v2 * v2;
#pragma unroll
    for (int i = 1; i < 64; i <<= 1) { s += __shfl_xor(s, i); ss += __shfl_xor(ss, i); }
    __shared__ float red[8];
    const int wid = tid >> 6, lane = tid & 63;
    if (lane == 0) { red[wid] = s; red[4 + wid] = ss; }
    __syncthreads();
    const float S  = red[0] + red[1] + red[2] + red[3];
    const float SS = red[4] + red[5] + red[6] + red[7];
    const float mean = S * (1.f / DD);
    const float var  = SS * (1.f / DD) - mean * mean;
    const float rstd = rsqrtf(var + 1e-5f);
    const float m = mask ? mask[row] : 1.f;
    unsigned short* yr = y + (size_t)row * DD;
    yr[tid]       = f2bf(((v0 - mean) * rstd * w[tid]       + b[tid])       * m);
    yr[tid + 256] = f2bf(((v1 - mean) * rstd * w[tid + 256] + b[tid + 256]) * m);
    yr[tid + 512] = f2bf(((v2 - mean) * rstd * w[tid + 512] + b[tid + 512]) * m);
}

// ---------------------------------------------------------------- transpose+convert W
__global__ __launch_bounds__(256)
void transcvt(const float* __restrict__ in, unsigned short* __restrict__ out, int K, int N)
{
    __shared__ float t[32][33];
    const int tx = threadIdx.x & 31, ty = threadIdx.x >> 5;
    const int k0 = blockIdx.y * 32, n0 = blockIdx.x * 32;
#pragma unroll
    for (int i = 0; i < 4; ++i)
        t[ty + i * 8][tx] = in[(size_t)(k0 + ty + i * 8) * N + n0 + tx];
    __syncthreads();
#pragma unroll
    for (int i = 0; i < 4; ++i)
        out[(size_t)(n0 + ty + i * 8) * K + k0 + tx] = f2bf(t[tx][ty + i * 8]);
}

// ---------------------------------------------------------------- bf16 MFMA GEMM
enum { BE_BIAS = 0, BE_SILU, BE_EG, BE_F32, BE_BF16, BE_RES };

template <int EPI>
__global__ __launch_bounds__(256)
void bgemm(const unsigned short* __restrict__ A, const unsigned short* __restrict__ Bt,
           float* Cf, unsigned short* Cb,
           const float* P0, const float* __restrict__ P1,
           int M, int N, int K)
{
    __shared__ unsigned short As[128 * 32];
    __shared__ unsigned short Bs[128 * 32];
    const int tid = threadIdx.x;
    const int w = tid >> 6, l = tid & 63;
    const int wm = w >> 1, wn = w & 1;
    const int lr = l & 15, lh = l >> 4;
    const int m0 = blockIdx.y * 128, n0 = blockIdx.x * 128;

    f32x4 acc[4][4];
#pragma unroll
    for (int i = 0; i < 4; ++i)
#pragma unroll
        for (int j = 0; j < 4; ++j) acc[i][j] = (f32x4){0.f, 0.f, 0.f, 0.f};

    const int sr = l >> 2, sq = (l & 3) * 8;
    const unsigned short* Ag = A + (size_t)(m0 + w * 32 + sr) * K + sq;
    const unsigned short* Bg = Bt + (size_t)(n0 + w * 32 + sr) * K + sq;
    unsigned short* Al = &As[(w * 32) * 32];
    unsigned short* Bl = &Bs[(w * 32) * 32];

    for (int kt = 0; kt < K; kt += 32) {
        __syncthreads();
        gload16(Ag + kt, Al);
        gload16(Ag + kt + 16 * (size_t)K, Al + 16 * 32);
        gload16(Bg + kt, Bl);
        gload16(Bg + kt + 16 * (size_t)K, Bl + 16 * 32);
        __syncthreads();
        bf16x8 af[4], bfv[4];
#pragma unroll
        for (int mi = 0; mi < 4; ++mi)
            af[mi] = *(const bf16x8*)&As[(wm * 64 + mi * 16 + lr) * 32 + lh * 8];
#pragma unroll
        for (int ni = 0; ni < 4; ++ni)
            bfv[ni] = *(const bf16x8*)&Bs[(wn * 64 + ni * 16 + lr) * 32 + lh * 8];
#pragma unroll
        for (int mi = 0; mi < 4; ++mi)
#pragma unroll
            for (int ni = 0; ni < 4; ++ni)
                acc[mi][ni] = __builtin_amdgcn_mfma_f32_16x16x32_bf16(af[mi], bfv[ni], acc[mi][ni], 0, 0, 0);
    }

#pragma unroll
    for (int mi = 0; mi < 4; ++mi) {
#pragma unroll
        for (int j = 0; j < 4; ++j) {
            const int row = m0 + wm * 64 + mi * 16 + lh * 4 + j;
#pragma unroll
            for (int ni = 0; ni < 4; ++ni) {
                const int col = n0 + wn * 64 + ni * 16 + lr;
                const size_t idx = (size_t)row * N + col;
                float v = acc[mi][ni][j];
                if constexpr (EPI == BE_BIAS) { Cf[idx] = v + P0[col]; }
                else if constexpr (EPI == BE_SILU) { Cf[idx] = v / (1.f + expf(-v)); }
                else if constexpr (EPI == BE_EG) {
                    const float lin = v + P1[col];
                    const float sp = (lin > 20.f) ? lin : log1pf(expf(lin));
                    Cf[idx] = -expf(P0[col]) * sp;      // raw log-decay g
                }
                else if constexpr (EPI == BE_F32) { Cf[idx] = v; }
                else if constexpr (EPI == BE_BF16) { Cb[idx] = f2bf(v); }
                else if constexpr (EPI == BE_RES) { Cf[idx] = v + P0[idx]; }
            }
        }
    }
}

// Dual-B GEMM for SwiGLU
__global__ __launch_bounds__(256)
void bgemm_dual(const unsigned short* __restrict__ A,
                const unsigned short* __restrict__ Bg_, const unsigned short* __restrict__ Bu_,
                unsigned short* __restrict__ C, int M, int N, int K)
{
    __shared__ unsigned short As[128 * 32];
    __shared__ unsigned short Bs1[64 * 32];
    __shared__ unsigned short Bs2[64 * 32];
    const int tid = threadIdx.x;
    const int w = tid >> 6, l = tid & 63;
    const int wm = w >> 1, wn = w & 1;
    const int lr = l & 15, lh = l >> 4;
    const int m0 = blockIdx.y * 128, n0 = blockIdx.x * 64;

    f32x4 a1[4][2], a2[4][2];
#pragma unroll
    for (int i = 0; i < 4; ++i)
#pragma unroll
        for (int j = 0; j < 2; ++j) { a1[i][j] = (f32x4){0.f,0.f,0.f,0.f}; a2[i][j] = (f32x4){0.f,0.f,0.f,0.f}; }

    const int sr = l >> 2, sq = (l & 3) * 8;
    const unsigned short* Ag  = A   + (size_t)(m0 + w * 32 + sr) * K + sq;
    const unsigned short* B1g = Bg_ + (size_t)(n0 + w * 16 + sr) * K + sq;
    const unsigned short* B2g = Bu_ + (size_t)(n0 + w * 16 + sr) * K + sq;
    unsigned short* Al  = &As[(w * 32) * 32];
    unsigned short* B1l = &Bs1[(w * 16) * 32];
    unsigned short* B2l = &Bs2[(w * 16) * 32];

    for (int kt = 0; kt < K; kt += 32) {
        __syncthreads();
        gload16(Ag + kt, Al);
        gload16(Ag + kt + 16 * (size_t)K, Al + 16 * 32);
        gload16(B1g + kt, B1l);
        gload16(B2g + kt, B2l);
        __syncthreads();
        bf16x8 af[4], b1[2], b2[2];
#pragma unroll
        for (int mi = 0; mi < 4; ++mi)
            af[mi] = *(const bf16x8*)&As[(wm * 64 + mi * 16 + lr) * 32 + lh * 8];
#pragma unroll
        for (int ni = 0; ni < 2; ++ni) {
            b1[ni] = *(const bf16x8*)&Bs1[(wn * 32 + ni * 16 + lr) * 32 + lh * 8];
            b2[ni] = *(const bf16x8*)&Bs2[(wn * 32 + ni * 16 + lr) * 32 + lh * 8];
        }
#pragma unroll
        for (int mi = 0; mi < 4; ++mi)
#pragma unroll
            for (int ni = 0; ni < 2; ++ni) {
                a1[mi][ni] = __builtin_amdgcn_mfma_f32_16x16x32_bf16(af[mi], b1[ni], a1[mi][ni], 0, 0, 0);
                a2[mi][ni] = __builtin_amdgcn_mfma_f32_16x16x32_bf16(af[mi], b2[ni], a2[mi][ni], 0, 0, 0);
            }
    }

#pragma unroll
    for (int mi = 0; mi < 4; ++mi)
#pragma unroll
        for (int j = 0; j < 4; ++j) {
            const int row = m0 + wm * 64 + mi * 16 + lh * 4 + j;
#pragma unroll
            for (int ni = 0; ni < 2; ++ni) {
                const int col = n0 + wn * 32 + ni * 16 + lr;
                const float g = a1[mi][ni][j], u = a2[mi][ni][j];
                C[(size_t)row * N + col] = f2bf((g / (1.f + expf(-g))) * u);
            }
        }
}

// ---------------------------------------------------------------- small fp32 GEMM (A bf16)
template <int MODE>
__global__ __launch_bounds__(256)
void gemm_small(const unsigned short* __restrict__ A, const float* __restrict__ Bm,
                unsigned short* Cb, float* Cf, int M, int N, int K)
{
    __shared__ float As[16][64];
    __shared__ float Bs[16][64];
    const int tid = threadIdx.x;
    const int tx = tid & 15, ty = tid >> 4;
    const int row0 = blockIdx.y * 64;
    const int col0 = blockIdx.x * 64;
    float acc[4][4] = {};
    const int ar  = tid >> 2;
    const int ac4 = (tid & 3) << 2;
    const int br  = tid >> 4;
    const int bc  = (tid & 15) << 2;
    const int gc  = col0 + bc;
    const bool bok = gc < N;

    for (int kt = 0; kt < K; kt += 16) {
        const ushort4 a4 = *(const ushort4*)(A + (size_t)(row0 + ar) * K + kt + ac4);
        float4 b4 = make_float4(0.f, 0.f, 0.f, 0.f);
        if (bok) b4 = *(const float4*)(Bm + (size_t)(kt + br) * N + gc);
        __syncthreads();
        As[ac4 + 0][ar] = bf2f(a4.x); As[ac4 + 1][ar] = bf2f(a4.y);
        As[ac4 + 2][ar] = bf2f(a4.z); As[ac4 + 3][ar] = bf2f(a4.w);
        *(float4*)&Bs[br][bc] = b4;
        __syncthreads();
#pragma unroll
        for (int kk = 0; kk < 16; ++kk) {
            const float4 av = *(const float4*)&As[kk][ty << 2];
            const float4 bv = *(const float4*)&Bs[kk][tx << 2];
            const float a_[4] = {av.x, av.y, av.z, av.w};
            const float b_[4] = {bv.x, bv.y, bv.z, bv.w};
#pragma unroll
            for (int i = 0; i < 4; ++i)
#pragma unroll
                for (int j = 0; j < 4; ++j)
                    acc[i][j] = fmaf(a_[i], b_[j], acc[i][j]);
        }
    }
#pragma unroll
    for (int i = 0; i < 4; ++i) {
        const int row = row0 + (ty << 2) + i;
#pragma unroll
        for (int j = 0; j < 4; ++j) {
            const int col = col0 + (tx << 2) + j;
            if (col >= N) continue;
            const size_t idx = (size_t)row * N + col;
            if constexpr (MODE == 0) Cb[idx] = f2bf(acc[i][j]);
            else                     Cf[idx] = 1.f / (1.f + expf(-acc[i][j]));
        }
    }
}

// ---------------------------------------------------------------- l2norm over HD=96
__global__ __launch_bounds__(256)
void l2norm_rows(float* x, float scale)
{
    const int row  = (blockIdx.x << 2) + (threadIdx.x >> 6);
    const int lane = threadIdx.x & 63;
    float* xr = x + (size_t)row * HD;
    const float a = xr[lane];
    const float b = (lane < 32) ? xr[64 + lane] : 0.f;
    float ss = a * a + b * b;
#pragma unroll
    for (int i = 1; i < 64; i <<= 1) ss += __shfl_xor(ss, i);
    const float r = rsqrtf(ss + 1e-6f) * scale;
    xr[lane] = a * r;
    if (lane < 32) xr[64 + lane] = b * r;
}

// ---------------------------------------------------------------- KDA chunkwise precompute
__global__ __launch_bounds__(256)
void kda_pre(const float* __restrict__ q, const float* __restrict__ k, float* v, float* g,
             const float* __restrict__ beta,
             unsigned short* __restrict__ ol, float* __restrict__ Bc,
             unsigned short* __restrict__ Wbf, unsigned short* __restrict__ Kbf)
{
    __shared__ float Kb[CH * RP];   // k, then kappa_tilde
    __shared__ float Kk[CH * RP];   // kappa
    __shared__ float Qp[CH * RP];   // g -> L -> q'
    __shared__ float Am[CH][68];
    __shared__ float sb[CH];

    const int blk = blockIdx.x;
    const int ch = blk & 31, bh = blk >> 5;
    const int b = bh >> 3, h = bh & 7;
    const int tid = threadIdx.x;
    const size_t base = (size_t)b * (TT * HH * HD) + (size_t)(ch * CH) * (HH * HD) + h * HD;

    // P0: stage k, g, beta
    for (int e = tid; e < CH * 24; e += 256) {
        const int t = e / 24, c4 = (e % 24) * 4;
        *(float4*)&Kb[t * RP + c4] = *(const float4*)(k + base + t * 768 + c4);
        *(float4*)&Qp[t * RP + c4] = *(const float4*)(g + base + t * 768 + c4);
    }
    if (tid < CH) sb[tid] = beta[((size_t)b * TT + ch * CH + tid) * HH + h];
    __syncthreads();

    // P1: per-channel cumsum of g
    if (tid < HD) {
        float L = 0.f;
        for (int t = 0; t < CH; ++t) { L += Qp[t * RP + tid]; Qp[t * RP + tid] = L; }
    }
    __syncthreads();

    // P2: kappa, kappa_tilde, q', Bc
    for (int e = tid; e < CH * HD; e += 256) {
        const int t = e / HD, c = e % HD;
        const float L = Qp[t * RP + c];
        const float B = expf(L), iB = expf(-L);
        const float kv = Kb[t * RP + c];
        if (t == CH - 1) Bc[((size_t)bh * NCH + ch) * HD + c] = B;
        Kk[t * RP + c] = kv * B;
        const float kti = kv * iB;
        const float qv = q[base + t * 768 + c];
        Kb[t * RP + c] = kti;
        Kbf[base + t * 768 + c] = f2bf(kti);      // kappa_tilde out (bf16)
        Qp[t * RP + c] = qv * B;                  // q'
    }
    __syncthreads();

    // P3: A[t][i] = beta_t * kappa_t . ktil_i  (i < t)
    {
        const int wv = tid >> 6, lt = tid & 63;
        for (int half = 0; half < 2; ++half) {
            float4 ca[12];
#pragma unroll
            for (int r = 0; r < 12; ++r)
                ca[r] = *(const float4*)&Kk[lt * RP + half * 48 + r * 4];
            for (int i = wv * 16; i < wv * 16 + 16; ++i) {
                float d0 = 0, d1 = 0, d2 = 0, d3 = 0;
#pragma unroll
                for (int r = 0; r < 12; ++r) {
                    const float4 cb = *(const float4*)&Kb[i * RP + half * 48 + r * 4];
                    d0 = fmaf(ca[r].x, cb.x, d0); d1 = fmaf(ca[r].y, cb.y, d1);
                    d2 = fmaf(ca[r].z, cb.z, d2); d3 = fmaf(ca[r].w, cb.w, d3);
                }
                const float d = ((d0 + d1) + (d2 + d3)) * sb[lt];
                const float val = (i < lt) ? d : 0.f;
                if (half == 0) Am[lt][i] = val; else Am[lt][i] += val;
            }
        }
    }
    __syncthreads();

    // P4: forward solve, column j of [U | W] in registers
    float X[CH];
    const int j = tid;
    if (j < 192) {
        if (j < HD) {
#pragma unroll
            for (int t = 0; t < CH; ++t) X[t] = sb[t] * v[base + t * 768 + j];
        } else {
#pragma unroll
            for (int t = 0; t < CH; ++t) X[t] = sb[t] * Kk[t * RP + (j - HD)];
        }
#pragma unroll
        for (int t = 1; t < CH; ++t) {
            float a0 = 0, a1 = 0, a2 = 0, a3 = 0;
#pragma unroll
            for (int i4 = 0; i4 * 4 < t; ++i4) {
                const float4 a = *(const float4*)&Am[t][i4 * 4];
                if (i4 * 4 + 0 < t) a0 = fmaf(a.x, X[i4 * 4 + 0], a0);
                if (i4 * 4 + 1 < t) a1 = fmaf(a.y, X[i4 * 4 + 1], a1);
                if (i4 * 4 + 2 < t) a2 = fmaf(a.z, X[i4 * 4 + 2], a2);
                if (i4 * 4 + 3 < t) a3 = fmaf(a.w, X[i4 * 4 + 3], a3);
            }
            X[t] -= ((a0 + a1) + (a2 + a3));
        }
        // P5: store U (f32 over v) / W (bf16)
        if (j < HD) {
#pragma unroll
            for (int t = 0; t < CH; ++t) v[base + t * 768 + j] = X[t];
        } else {
#pragma unroll
            for (int t = 0; t < CH; ++t) Wbf[base + t * 768 + (j - HD)] = f2bf(X[t]);
        }
    }
    __syncthreads();

    // P6: T[t][i] = q'_t . ktil_i  (i <= t)
    {
        const int wv = tid >> 6, lt = tid & 63;
        for (int half = 0; half < 2; ++half) {
            float4 ca[12];
#pragma unroll
            for (int r = 0; r < 12; ++r)
                ca[r] = *(const float4*)&Qp[lt * RP + half * 48 + r * 4];
            for (int i = wv * 16; i < wv * 16 + 16; ++i) {
                float d0 = 0, d1 = 0, d2 = 0, d3 = 0;
#pragma unroll
                for (int r = 0; r < 12; ++r) {
                    const float4 cb = *(const float4*)&Kb[i * RP + half * 48 + r * 4];
                    d0 = fmaf(ca[r].x, cb.x, d0); d1 = fmaf(ca[r].y, cb.y, d1);
                    d2 = fmaf(ca[r].z, cb.z, d2); d3 = fmaf(ca[r].w, cb.w, d3);
                }
                const float d = (d0 + d1) + (d2 + d3);
                const float val = (i <= lt) ? d : 0.f;
                if (half == 0) Am[lt][i] = val; else Am[lt][i] += val;
            }
        }
    }
    __syncthreads();

    // P7: T @ X -> Ol (j<96) ; Qe = q' - T@W (j>=96, over g)
    if (j < 192) {
        for (int t = 0; t < CH; ++t) {
            float a0 = 0, a1 = 0, a2 = 0, a3 = 0;
#pragma unroll
            for (int i4 = 0; i4 < 16; ++i4) {
                const float4 a = *(const float4*)&Am[t][i4 * 4];
                a0 = fmaf(a.x, X[i4 * 4 + 0], a0); a1 = fmaf(a.y, X[i4 * 4 + 1], a1);
                a2 = fmaf(a.z, X[i4 * 4 + 2], a2); a3 = fmaf(a.w, X[i4 * 4 + 3], a3);
            }
            const float acc = (a0 + a1) + (a2 + a3);
            if (j < HD) ol[base + t * 768 + j] = f2bf(acc);
            else        g[base + t * 768 + (j - HD)] = Qp[t * RP + (j - HD)] - acc;
        }
    }
}

// ---------------------------------------------------------------- KDA sequential recurrence (parallel form, exact)
// grid 192 = bh*6 + vq (16 v-cols per block); 256 thr.
// Per chunk: Sin store; delta = U - W @ S_in (step A); S = Bc*(S_in + ktil^T @ delta) (step B).
constexpr int VSL = 16;  // v-slice per block
constexpr int SP = 20;   // Sl/Dl/Ul row pad (floats)
__global__ __launch_bounds__(256)
void kda_seq(const unsigned short* __restrict__ Wbf, const unsigned short* __restrict__ Kbf,
             const float* __restrict__ U, const float* __restrict__ Bc,
             float* __restrict__ Sin, float* __restrict__ states)
{
    __shared__ float Wl[CH * 97];
    __shared__ float Kl[CH * 97];
    __shared__ float Sl[96 * SP];
    __shared__ float Dl[CH * SP];
    __shared__ float Ul[CH * SP];

    const int blk = blockIdx.x;
    const int bh = blk / 6, vq = blk - bh * 6;
    const int b = bh >> 3, h = bh & 7;
    const int tid = threadIdx.x;
    const int ta = tid & 63, vga = tid >> 6;   // step A: row t, v-quad
    const int kb = tid & 31, vB = tid >> 5;    // step B: k-base, v-pair (0..7)
    const int v0 = vq * VSL;
    const size_t base = (size_t)b * (TT * HH * HD) + h * HD;

    for (int e = tid; e < 96 * SP; e += 256) Sl[e] = 0.f;

    u16x8 wpf[3], kpf[3];
    f32x4 upf;
    const int sr = tid / 12 < 64 ? tid / 12 : 0; // unused guard
    (void)sr;

    // stage chunk 0
    {
#pragma unroll
        for (int i = 0; i < 3; ++i) {
            const int g = i * 256 + tid;
            const int r = g / 12, c8 = (g % 12) * 8;
            wpf[i] = *(const u16x8*)(Wbf + base + (size_t)r * 768 + c8);
            kpf[i] = *(const u16x8*)(Kbf + base + (size_t)r * 768 + c8);
        }
        const int t = tid >> 2, c4 = (tid & 3) * 4;
        upf = *(const f32x4*)(U + base + (size_t)t * 768 + v0 + c4);
#pragma unroll
        for (int i = 0; i < 3; ++i) {
            const int g = i * 256 + tid;
            const int r = g / 12, c8 = (g % 12) * 8;
#pragma unroll
            for (int j = 0; j < 8; ++j) {
                Wl[r * 97 + c8 + j] = bf2f((unsigned short)wpf[i][j]);
                Kl[r * 97 + c8 + j] = bf2f((unsigned short)kpf[i][j]);
            }
        }
        *(f32x4*)&Ul[t * SP + c4] = upf;
    }
    __syncthreads();

    for (int ch = 0; ch < NCH; ++ch) {
        // prefetch next chunk into registers
        if (ch + 1 < NCH) {
            const size_t cb = base + (size_t)((ch + 1) * CH) * (HH * HD);
#pragma unroll
            for (int i = 0; i < 3; ++i) {
                const int g = i * 256 + tid;
                const int r = g / 12, c8 = (g % 12) * 8;
                wpf[i] = *(const u16x8*)(Wbf + cb + (size_t)r * 768 + c8);
                kpf[i] = *(const u16x8*)(Kbf + cb + (size_t)r * 768 + c8);
            }
            const int t = tid >> 2, c4 = (tid & 3) * 4;
            upf = *(const f32x4*)(U + cb + (size_t)t * 768 + v0 + c4);
        }
        // store S_in for the O-epilogue
        {
            float* sg = Sin + (size_t)(bh * NCH + ch) * (HD * HD);
#pragma unroll
            for (int i = 0; i < 2; ++i) {
                const int e = i * 256 + tid;
                if (e < 384) {
                    const int kk = e >> 2, c4 = (e & 3) * 4;
                    *(f32x4*)(sg + (size_t)kk * HD + v0 + c4) = *(const f32x4*)&Sl[kk * SP + c4];
                }
            }
        }
        // step A: Dl[t][v] = Ul - sum_k Wl[t][k] * Sl[k][v]
        {
            f32x4 acc = *(const f32x4*)&Ul[ta * SP + vga * 4];
            const float* wr = &Wl[ta * 97];
#pragma unroll 8
            for (int kk = 0; kk < 96; ++kk)
                acc -= wr[kk] * *(const f32x4*)&Sl[kk * SP + vga * 4];
            *(f32x4*)&Dl[ta * SP + vga * 4] = acc;
        }
        __syncthreads();
        // step B: S[k][v] = (S[k][v] + sum_t Kl[t][k]*Dl[t][v]) * Bc[k]
        {
            float a0[2] = {0.f, 0.f}, a1[2] = {0.f, 0.f}, a2[2] = {0.f, 0.f};
#pragma unroll 8
            for (int t = 0; t < CH; ++t) {
                const float d0 = Dl[t * SP + vB * 2];
                const float d1 = Dl[t * SP + vB * 2 + 1];
                const float k0 = Kl[t * 97 + kb];
                const float k1 = Kl[t * 97 + kb + 32];
                const float k2 = Kl[t * 97 + kb + 64];
                a0[0] = fmaf(k0, d0, a0[0]); a0[1] = fmaf(k0, d1, a0[1]);
                a1[0] = fmaf(k1, d0, a1[0]); a1[1] = fmaf(k1, d1, a1[1]);
                a2[0] = fmaf(k2, d0, a2[0]); a2[1] = fmaf(k2, d1, a2[1]);
            }
            const float* bc = Bc + ((size_t)bh * NCH + ch) * HD;
            const float b0 = bc[kb], b1 = bc[kb + 32], b2 = bc[kb + 64];
#pragma unroll
            for (int e = 0; e < 2; ++e) {
                const int v = vB * 2 + e;
                Sl[kb * SP + v]        = (Sl[kb * SP + v]        + a0[e]) * b0;
                Sl[(kb + 32) * SP + v] = (Sl[(kb + 32) * SP + v] + a1[e]) * b1;
                Sl[(kb + 64) * SP + v] = (Sl[(kb + 64) * SP + v] + a2[e]) * b2;
            }
        }
        __syncthreads();
        // write staged regs -> LDS for next chunk
        if (ch + 1 < NCH) {
#pragma unroll
            for (int i = 0; i < 3; ++i) {
                const int g = i * 256 + tid;
                const int r = g / 12, c8 = (g % 12) * 8;
#pragma unroll
                for (int j = 0; j < 8; ++j) {
                    Wl[r * 97 + c8 + j] = bf2f((unsigned short)wpf[i][j]);
                    Kl[r * 97 + c8 + j] = bf2f((unsigned short)kpf[i][j]);
                }
            }
            const int t = tid >> 2, c4 = (tid & 3) * 4;
            *(f32x4*)&Ul[t * SP + c4] = upf;
            __syncthreads();
        }
    }
    // final states
    {
        float* sp = states + (size_t)bh * (HD * HD);
#pragma unroll
        for (int i = 0; i < 2; ++i) {
            const int e = i * 256 + tid;
            if (e < 384) {
                const int kk = e >> 2, c4 = (e & 3) * 4;
                *(f32x4*)(sp + (size_t)kk * HD + v0 + c4) = *(const f32x4*)&Sl[kk * SP + c4];
            }
        }
    }
}

// ---------------------------------------------------------------- KDA parallel O epilogue
__global__ __launch_bounds__(256)
void kda_epi(const float* __restrict__ Sin, const float* __restrict__ Qe,
             const unsigned short* __restrict__ Ol, const unsigned short* __restrict__ Gt,
             const float* __restrict__ onw, unsigned short* __restrict__ obf)
{
    __shared__ float Sl[96 * 100];
    __shared__ float Ql[64 * 100];
    __shared__ unsigned short Olb[64 * 104];
    __shared__ unsigned short Gl[64 * 104];

    const int bx = blockIdx.x;
    const int bh = bx >> 5, ch = bx & 31;
    const int b = bh >> 3, h = bh & 7;
    const int tid = threadIdx.x;
    const size_t cb = (size_t)b * (TT * HH * HD) + (size_t)(ch * CH) * (HH * HD) + h * HD;
    const float* Sg = Sin + (size_t)(bh * NCH + ch) * HD * HD;

#pragma unroll
    for (int i = 0; i < 9; ++i) {
        const int g = i * 256 + tid;
        const int k = g / 24, c4 = (g % 24) * 4;
        *(f32x4*)&Sl[k * 100 + c4] = *(const f32x4*)(Sg + (size_t)k * HD + c4);
    }
#pragma unroll
    for (int i = 0; i < 6; ++i) {
        const int g = i * 256 + tid;
        const int t = g / 24, c4 = (g % 24) * 4;
        *(f32x4*)&Ql[t * 100 + c4] = *(const f32x4*)(Qe + cb + (size_t)t * 768 + c4);
    }
#pragma unroll
    for (int i = 0; i < 3; ++i) {
        const int g = i * 256 + tid;
        const int t = g / 12, c8 = (g % 12) * 8;
        *(u16x8*)&Olb[t * 104 + c8] = *(const u16x8*)(Ol + cb + (size_t)t * 768 + c8);
        *(u16x8*)&Gl[t * 104 + c8]  = *(const u16x8*)(Gt + cb + (size_t)t * 768 + c8);
    }
    __syncthreads();

    const int t = tid >> 2, vq2 = tid & 3;
    const int v0 = vq2 * 24;
    f32x4 acc[6];
#pragma unroll
    for (int j = 0; j < 6; ++j) {
        acc[j].x = bf2f(Olb[t * 104 + v0 + j * 4 + 0]);
        acc[j].y = bf2f(Olb[t * 104 + v0 + j * 4 + 1]);
        acc[j].z = bf2f(Olb[t * 104 + v0 + j * 4 + 2]);
        acc[j].w = bf2f(Olb[t * 104 + v0 + j * 4 + 3]);
    }
#pragma unroll 2
    for (int k = 0; k < HD; ++k) {
        const float qv = Ql[t * 100 + k];
#pragma unroll
        for (int j = 0; j < 6; ++j)
            acc[j] += qv * *(const f32x4*)&Sl[k * 100 + v0 + j * 4];
    }
    float ss = 0.f;
#pragma unroll
    for (int j = 0; j < 6; ++j)
        ss += acc[j].x * acc[j].x + acc[j].y * acc[j].y + acc[j].z * acc[j].z + acc[j].w * acc[j].w;
    ss += __shfl_xor(ss, 1); ss += __shfl_xor(ss, 2);
    const float r = rsqrtf(ss * (1.f / HD) + 1e-6f);
#pragma unroll
    for (int j = 0; j < 6; ++j) {
#pragma unroll
        for (int e = 0; e < 4; ++e) {
            const int v = v0 + j * 4 + e;
            const float g = bf2f(Gl[t * 104 + v]);
            const float val = acc[j][e] * r * onw[v] * (g / (1.f + expf(-g)));
            obf[cb + (size_t)t * 768 + v] = f2bf(val);
        }
    }
}

// ---------------------------------------------------------------- host
extern "C" void kernel_launch(void* const* d_in, const int* in_sizes, int n_in,
                              void* d_out, int out_size, void* d_ws, size_t ws_size,
                              hipStream_t stream)
{
    (void)in_sizes; (void)n_in; (void)out_size; (void)ws_size;
    const float* hidden   = (const float*)d_in[0];
    const float* mask     = (const float*)d_in[1];
    const float* norm_a_w = (const float*)d_in[2];
    const float* norm_a_b = (const float*)d_in[3];
    const float* proj_a_w = (const float*)d_in[4];
    const float* proj_a_b = (const float*)d_in[5];
    const float* ln_w     = (const float*)d_in[6];
    const float* ln_b     = (const float*)d_in[7];
    const float* Wq       = (const float*)d_in[8];
    const float* Wk       = (const float*)d_in[9];
    const float* Wv       = (const float*)d_in[10];
    const float* Wfa      = (const float*)d_in[11];
    const float* Wfb      = (const float*)d_in[12];
    const float* dt_bias  = (const float*)d_in[13];
    const float* A_log    = (const float*)d_in[14];
    const float* Wb       = (const float*)d_in[15];
    const float* Wga      = (const float*)d_in[16];
    const float* Wgb      = (const float*)d_in[17];
    const float* onorm_w  = (const float*)d_in[18];
    const float* Wo       = (const float*)d_in[19];
    const float* Wgate    = (const float*)d_in[20];
    const float* Wup      = (const float*)d_in[21];
    const float* Wdown    = (const float*)d_in[22];

    float* ws    = (float*)d_ws;
    float* hbuf  = ws;
    float* qb    = ws + HROW;          // dead after pre -> Sin/mg live here
    float* kb    = ws + 2 * HROW;
    float* vb    = ws + 3 * HROW;      // U (f32)
    float* egb   = ws + 4 * HROW;      // g -> Qe (f32)
    float* betab = ws + 5 * HROW;                     // MM*HH
    float* BcP   = betab + (size_t)MM * HH;           // 32*32*96
    float* SinP  = qb;                                // 9.44M floats (qb+kb region)
    unsigned short* bfp = (unsigned short*)(BcP + 32 * NCH * HD);
    unsigned short* x_bf    = bfp;  bfp += HROW;
    unsigned short* fab_bf  = bfp;  bfp += (size_t)MM * HD;
    unsigned short* gate_bf = bfp;  bfp += HROW;
    unsigned short* olb_bf  = bfp;  bfp += HROW;
    unsigned short* w_bf    = bfp;  bfp += HROW;
    unsigned short* k_bf    = bfp;  bfp += HROW;
    unsigned short* wt_proj = bfp;  bfp += 768 * 768;
    unsigned short *wt_q[LL], *wt_k[LL], *wt_v[LL], *wt_o[LL], *wt_fb[LL], *wt_gb[LL],
                   *wt_gate[LL], *wt_up[LL], *wt_down[LL];
    for (int l = 0; l < LL; ++l) {
        wt_q[l] = bfp;    bfp += 768 * 768;
        wt_k[l] = bfp;    bfp += 768 * 768;
        wt_v[l] = bfp;    bfp += 768 * 768;
        wt_o[l] = bfp;    bfp += 768 * 768;
        wt_fb[l] = bfp;   bfp += 768 * 96;
        wt_gb[l] = bfp;   bfp += 768 * 96;
        wt_gate[l] = bfp; bfp += 2048 * 768;
        wt_up[l] = bfp;   bfp += 2048 * 768;
        wt_down[l] = bfp; bfp += 768 * 2048;
    }
    unsigned short* mg_bf = (unsigned short*)SinP;  // Sin dead after epi
    unsigned short* a_bf  = (unsigned short*)vb;    // U dead after seq

    float* out    = (float*)d_out;
    float* states = out + HROW;

    // weight transpose+convert
    transcvt<<<dim3(24, 24), 256, 0, stream>>>(proj_a_w, wt_proj, 768, 768);
    for (int l = 0; l < LL; ++l) {
        transcvt<<<dim3(24, 24), 256, 0, stream>>>(Wq + (size_t)l * 589824, wt_q[l], 768, 768);
        transcvt<<<dim3(24, 24), 256, 0, stream>>>(Wk + (size_t)l * 589824, wt_k[l], 768, 768);
        transcvt<<<dim3(24, 24), 256, 0, stream>>>(Wv + (size_t)l * 589824, wt_v[l], 768, 768);
        transcvt<<<dim3(24, 24), 256, 0, stream>>>(Wo + (size_t)l * 589824, wt_o[l], 768, 768);
        transcvt<<<dim3(24, 3), 256, 0, stream>>>(Wfb + (size_t)l * 73728, wt_fb[l], 96, 768);
        transcvt<<<dim3(24, 3), 256, 0, stream>>>(Wgb + (size_t)l * 73728, wt_gb[l], 96, 768);
        transcvt<<<dim3(64, 24), 256, 0, stream>>>(Wgate + (size_t)l * 1572864, wt_gate[l], 768, 2048);
        transcvt<<<dim3(64, 24), 256, 0, stream>>>(Wup + (size_t)l * 1572864, wt_up[l], 768, 2048);
        transcvt<<<dim3(24, 64), 256, 0, stream>>>(Wdown + (size_t)l * 1572864, wt_down[l], 2048, 768);
    }

    layernorm_rows<<<MM, 256, 0, stream>>>(hidden, x_bf, norm_a_w, norm_a_b, nullptr);
    bgemm<BE_BIAS><<<dim3(6, 64), 256, 0, stream>>>(x_bf, wt_proj, hbuf, nullptr,
                                                    proj_a_b, nullptr, MM, DD, DD);

    for (int l = 0; l < LL; ++l) {
        layernorm_rows<<<MM, 256, 0, stream>>>(hbuf, x_bf, ln_w + l * DD, ln_b + l * DD, mask);
        bgemm<BE_SILU><<<dim3(6, 64), 256, 0, stream>>>(x_bf, wt_q[l], qb, nullptr, nullptr, nullptr, MM, DD, DD);
        bgemm<BE_SILU><<<dim3(6, 64), 256, 0, stream>>>(x_bf, wt_k[l], kb, nullptr, nullptr, nullptr, MM, DD, DD);
        bgemm<BE_SILU><<<dim3(6, 64), 256, 0, stream>>>(x_bf, wt_v[l], vb, nullptr, nullptr, nullptr, MM, DD, DD);
        l2norm_rows<<<(MM * HH) / 4, 256, 0, stream>>>(qb, 0.1020620726159658f);
        l2norm_rows<<<(MM * HH) / 4, 256, 0, stream>>>(kb, 1.f);
        gemm_small<0><<<dim3(2, 128), 256, 0, stream>>>(x_bf, Wfa + (size_t)l * DD * HD, fab_bf, nullptr, MM, HD, DD);
        bgemm<BE_EG><<<dim3(6, 64), 256, 0, stream>>>(fab_bf, wt_fb[l], egb, nullptr,
                                                      A_log + l * DD, dt_bias + l * DD, MM, DD, HD);
        gemm_small<1><<<dim3(1, 128), 256, 0, stream>>>(x_bf, Wb + (size_t)l * DD * HH, nullptr, betab, MM, HH, DD);
        // gate before scan (x_bf gets overwritten by o in epi)
        gemm_small<0><<<dim3(2, 128), 256, 0, stream>>>(x_bf, Wga + (size_t)l * DD * HD, fab_bf, nullptr, MM, HD, DD);
        bgemm<BE_BF16><<<dim3(6, 64), 256, 0, stream>>>(fab_bf, wt_gb[l], nullptr, gate_bf, nullptr, nullptr, MM, DD, HD);
        // chunkwise scan
        kda_pre<<<1024, 256, 0, stream>>>(qb, kb, vb, egb, betab, olb_bf, BcP, w_bf, k_bf);
        kda_seq<<<192, 256, 0, stream>>>(w_bf, k_bf, vb, BcP, SinP,
                                         states + (size_t)l * BB * HH * HD * HD);
        kda_epi<<<1024, 256, 0, stream>>>(SinP, egb, olb_bf, gate_bf, onorm_w + l * HD, x_bf);
        // a = o @ Wo
        bgemm<BE_BF16><<<dim3(6, 64), 256, 0, stream>>>(x_bf, wt_o[l], nullptr, a_bf, nullptr, nullptr, MM, DD, DD);
        // swiglu
        bgemm_dual<<<dim3(32, 64), 256, 0, stream>>>(a_bf, wt_gate[l], wt_up[l], mg_bf, MM, FF, DD);
        float* dst = (l == LL - 1) ? out : hbuf;
        bgemm<BE_RES><<<dim3(6, 64), 256, 0, stream>>>(mg_bf, wt_down[l], dst, nullptr,
                                                       hbuf, nullptr, MM, DD, FF);
    }
}

// Round 8
// 1703.434 us; speedup vs baseline: 2.3048x; 1.2002x over previous
//
#include <hip/hip_runtime.h>
#include <cstddef>
#include <cstdint>
#include <cmath>

// Problem constants
constexpr int BB = 4, TT = 2048, DD = 768, HH = 8, HD = 96, FF = 2048, LL = 2;
constexpr int MM = BB * TT;              // 8192
constexpr size_t HROW = (size_t)MM * DD; // 6291456
constexpr int CH = 64;                   // scan chunk length
constexpr int NCH = TT / CH;             // 32 chunks per sequence
constexpr int RP = 100;                  // padded LDS row (floats)
constexpr int KP = 104;                  // padded LDS row (ushorts, 16B-aligned rows)

typedef float f32x4 __attribute__((ext_vector_type(4)));
typedef short bf16x8 __attribute__((ext_vector_type(8)));
typedef unsigned short u16x8 __attribute__((ext_vector_type(8)));

__device__ __forceinline__ void gload16(const void* g, void* l) {
    __builtin_amdgcn_global_load_lds(
        (const __attribute__((address_space(1))) void*)g,
        (__attribute__((address_space(3))) void*)l, 16, 0, 0);
}
__device__ __forceinline__ float bf2f(unsigned short u) {
    return __uint_as_float(((unsigned)u) << 16);
}
__device__ __forceinline__ unsigned short f2bf(float f) {
    unsigned u = __float_as_uint(f);
    unsigned r = (u + 0x7fffu + ((u >> 16) & 1u)) >> 16;
    return (unsigned short)r;
}

// ---------------------------------------------------------------- LayerNorm -> bf16
__global__ __launch_bounds__(256)
void layernorm_rows(const float* __restrict__ x, unsigned short* __restrict__ y,
                    const float* __restrict__ w, const float* __restrict__ b,
                    const float* mask)
{
    const int row = blockIdx.x;
    const int tid = threadIdx.x;
    const float* xr = x + (size_t)row * DD;
    float v0 = xr[tid], v1 = xr[tid + 256], v2 = xr[tid + 512];
    float s = v0 + v1 + v2;
    float ss = v0 * v0 + v1 * v1 + v2 * v2;
#pragma unroll
    for (int i = 1; i < 64; i <<= 1) { s += __shfl_xor(s, i); ss += __shfl_xor(ss, i); }
    __shared__ float red[8];
    const int wid = tid >> 6, lane = tid & 63;
    if (lane == 0) { red[wid] = s; red[4 + wid] = ss; }
    __syncthreads();
    const float S  = red[0] + red[1] + red[2] + red[3];
    const float SS = red[4] + red[5] + red[6] + red[7];
    const float mean = S * (1.f / DD);
    const float var  = SS * (1.f / DD) - mean * mean;
    const float rstd = rsqrtf(var + 1e-5f);
    const float m = mask ? mask[row] : 1.f;
    unsigned short* yr = y + (size_t)row * DD;
    yr[tid]       = f2bf(((v0 - mean) * rstd * w[tid]       + b[tid])       * m);
    yr[tid + 256] = f2bf(((v1 - mean) * rstd * w[tid + 256] + b[tid + 256]) * m);
    yr[tid + 512] = f2bf(((v2 - mean) * rstd * w[tid + 512] + b[tid + 512]) * m);
}

// ---------------------------------------------------------------- transpose+convert W
__global__ __launch_bounds__(256)
void transcvt(const float* __restrict__ in, unsigned short* __restrict__ out, int K, int N)
{
    __shared__ float t[32][33];
    const int tx = threadIdx.x & 31, ty = threadIdx.x >> 5;
    const int k0 = blockIdx.y * 32, n0 = blockIdx.x * 32;
#pragma unroll
    for (int i = 0; i < 4; ++i)
        t[ty + i * 8][tx] = in[(size_t)(k0 + ty + i * 8) * N + n0 + tx];
    __syncthreads();
#pragma unroll
    for (int i = 0; i < 4; ++i)
        out[(size_t)(n0 + ty + i * 8) * K + k0 + tx] = f2bf(t[tx][ty + i * 8]);
}

// ---------------------------------------------------------------- bf16 MFMA GEMM
enum { BE_BIAS = 0, BE_SILU, BE_EG, BE_F32, BE_BF16, BE_RES, BE_QKV };

template <int EPI>
__global__ __launch_bounds__(256)
void bgemm(const unsigned short* __restrict__ A, const unsigned short* __restrict__ Bt,
           float* Cf, unsigned short* Cb,
           const float* P0, const float* P1,
           int M, int N, int K)
{
    __shared__ unsigned short As[128 * 32];
    __shared__ unsigned short Bs[128 * 32];
    const int tid = threadIdx.x;
    const int w = tid >> 6, l = tid & 63;
    const int wm = w >> 1, wn = w & 1;
    const int lr = l & 15, lh = l >> 4;
    const int m0 = blockIdx.y * 128, n0 = blockIdx.x * 128;

    f32x4 acc[4][4];
#pragma unroll
    for (int i = 0; i < 4; ++i)
#pragma unroll
        for (int j = 0; j < 4; ++j) acc[i][j] = (f32x4){0.f, 0.f, 0.f, 0.f};

    const int sr = l >> 2, sq = (l & 3) * 8;
    const unsigned short* Ag = A + (size_t)(m0 + w * 32 + sr) * K + sq;
    const unsigned short* Bg = Bt + (size_t)(n0 + w * 32 + sr) * K + sq;
    unsigned short* Al = &As[(w * 32) * 32];
    unsigned short* Bl = &Bs[(w * 32) * 32];

    for (int kt = 0; kt < K; kt += 32) {
        __syncthreads();
        gload16(Ag + kt, Al);
        gload16(Ag + kt + 16 * (size_t)K, Al + 16 * 32);
        gload16(Bg + kt, Bl);
        gload16(Bg + kt + 16 * (size_t)K, Bl + 16 * 32);
        __syncthreads();
        bf16x8 af[4], bfv[4];
#pragma unroll
        for (int mi = 0; mi < 4; ++mi)
            af[mi] = *(const bf16x8*)&As[(wm * 64 + mi * 16 + lr) * 32 + lh * 8];
#pragma unroll
        for (int ni = 0; ni < 4; ++ni)
            bfv[ni] = *(const bf16x8*)&Bs[(wn * 64 + ni * 16 + lr) * 32 + lh * 8];
#pragma unroll
        for (int mi = 0; mi < 4; ++mi)
#pragma unroll
            for (int ni = 0; ni < 4; ++ni)
                acc[mi][ni] = __builtin_amdgcn_mfma_f32_16x16x32_bf16(af[mi], bfv[ni], acc[mi][ni], 0, 0, 0);
    }

#pragma unroll
    for (int mi = 0; mi < 4; ++mi) {
#pragma unroll
        for (int j = 0; j < 4; ++j) {
            const int row = m0 + wm * 64 + mi * 16 + lh * 4 + j;
#pragma unroll
            for (int ni = 0; ni < 4; ++ni) {
                const int col = n0 + wn * 64 + ni * 16 + lr;
                const size_t idx = (size_t)row * N + col;
                float v = acc[mi][ni][j];
                if constexpr (EPI == BE_BIAS) { Cf[idx] = v + P0[col]; }
                else if constexpr (EPI == BE_SILU) { Cf[idx] = v / (1.f + expf(-v)); }
                else if constexpr (EPI == BE_EG) {
                    const float lin = v + P1[col];
                    const float sp = (lin > 20.f) ? lin : log1pf(expf(lin));
                    Cf[idx] = -expf(P0[col]) * sp;      // raw log-decay g
                }
                else if constexpr (EPI == BE_F32) { Cf[idx] = v; }
                else if constexpr (EPI == BE_BF16) { Cb[idx] = f2bf(v); }
                else if constexpr (EPI == BE_RES) { Cf[idx] = v + P0[idx]; }
                else if constexpr (EPI == BE_QKV) {
                    // fused q/k/v: col/768 selects target buffer (tiles never straddle)
                    const int tgt = col / 768;
                    const int cl = col - tgt * 768;
                    float* dst = (tgt == 0) ? Cf
                               : (tgt == 1) ? const_cast<float*>(P0)
                                            : const_cast<float*>(P1);
                    dst[(size_t)row * 768 + cl] = v / (1.f + expf(-v));
                }
            }
        }
    }
}

// Dual-B GEMM for SwiGLU
__global__ __launch_bounds__(256)
void bgemm_dual(const unsigned short* __restrict__ A,
                const unsigned short* __restrict__ Bg_, const unsigned short* __restrict__ Bu_,
                unsigned short* __restrict__ C, int M, int N, int K)
{
    __shared__ unsigned short As[128 * 32];
    __shared__ unsigned short Bs1[64 * 32];
    __shared__ unsigned short Bs2[64 * 32];
    const int tid = threadIdx.x;
    const int w = tid >> 6, l = tid & 63;
    const int wm = w >> 1, wn = w & 1;
    const int lr = l & 15, lh = l >> 4;
    const int m0 = blockIdx.y * 128, n0 = blockIdx.x * 64;

    f32x4 a1[4][2], a2[4][2];
#pragma unroll
    for (int i = 0; i < 4; ++i)
#pragma unroll
        for (int j = 0; j < 2; ++j) { a1[i][j] = (f32x4){0.f,0.f,0.f,0.f}; a2[i][j] = (f32x4){0.f,0.f,0.f,0.f}; }

    const int sr = l >> 2, sq = (l & 3) * 8;
    const unsigned short* Ag  = A   + (size_t)(m0 + w * 32 + sr) * K + sq;
    const unsigned short* B1g = Bg_ + (size_t)(n0 + w * 16 + sr) * K + sq;
    const unsigned short* B2g = Bu_ + (size_t)(n0 + w * 16 + sr) * K + sq;
    unsigned short* Al  = &As[(w * 32) * 32];
    unsigned short* B1l = &Bs1[(w * 16) * 32];
    unsigned short* B2l = &Bs2[(w * 16) * 32];

    for (int kt = 0; kt < K; kt += 32) {
        __syncthreads();
        gload16(Ag + kt, Al);
        gload16(Ag + kt + 16 * (size_t)K, Al + 16 * 32);
        gload16(B1g + kt, B1l);
        gload16(B2g + kt, B2l);
        __syncthreads();
        bf16x8 af[4], b1[2], b2[2];
#pragma unroll
        for (int mi = 0; mi < 4; ++mi)
            af[mi] = *(const bf16x8*)&As[(wm * 64 + mi * 16 + lr) * 32 + lh * 8];
#pragma unroll
        for (int ni = 0; ni < 2; ++ni) {
            b1[ni] = *(const bf16x8*)&Bs1[(wn * 32 + ni * 16 + lr) * 32 + lh * 8];
            b2[ni] = *(const bf16x8*)&Bs2[(wn * 32 + ni * 16 + lr) * 32 + lh * 8];
        }
#pragma unroll
        for (int mi = 0; mi < 4; ++mi)
#pragma unroll
            for (int ni = 0; ni < 2; ++ni) {
                a1[mi][ni] = __builtin_amdgcn_mfma_f32_16x16x32_bf16(af[mi], b1[ni], a1[mi][ni], 0, 0, 0);
                a2[mi][ni] = __builtin_amdgcn_mfma_f32_16x16x32_bf16(af[mi], b2[ni], a2[mi][ni], 0, 0, 0);
            }
    }

#pragma unroll
    for (int mi = 0; mi < 4; ++mi)
#pragma unroll
        for (int j = 0; j < 4; ++j) {
            const int row = m0 + wm * 64 + mi * 16 + lh * 4 + j;
#pragma unroll
            for (int ni = 0; ni < 2; ++ni) {
                const int col = n0 + wn * 32 + ni * 16 + lr;
                const float g = a1[mi][ni][j], u = a2[mi][ni][j];
                C[(size_t)row * N + col] = f2bf((g / (1.f + expf(-g))) * u);
            }
        }
}

// ---------------------------------------------------------------- small fp32 GEMM (A bf16)
template <int MODE>
__global__ __launch_bounds__(256)
void gemm_small(const unsigned short* __restrict__ A, const float* __restrict__ Bm,
                unsigned short* Cb, float* Cf, int M, int N, int K)
{
    __shared__ float As[16][64];
    __shared__ float Bs[16][64];
    const int tid = threadIdx.x;
    const int tx = tid & 15, ty = tid >> 4;
    const int row0 = blockIdx.y * 64;
    const int col0 = blockIdx.x * 64;
    float acc[4][4] = {};
    const int ar  = tid >> 2;
    const int ac4 = (tid & 3) << 2;
    const int br  = tid >> 4;
    const int bc  = (tid & 15) << 2;
    const int gc  = col0 + bc;
    const bool bok = gc < N;

    for (int kt = 0; kt < K; kt += 16) {
        const ushort4 a4 = *(const ushort4*)(A + (size_t)(row0 + ar) * K + kt + ac4);
        float4 b4 = make_float4(0.f, 0.f, 0.f, 0.f);
        if (bok) b4 = *(const float4*)(Bm + (size_t)(kt + br) * N + gc);
        __syncthreads();
        As[ac4 + 0][ar] = bf2f(a4.x); As[ac4 + 1][ar] = bf2f(a4.y);
        As[ac4 + 2][ar] = bf2f(a4.z); As[ac4 + 3][ar] = bf2f(a4.w);
        *(float4*)&Bs[br][bc] = b4;
        __syncthreads();
#pragma unroll
        for (int kk = 0; kk < 16; ++kk) {
            const float4 av = *(const float4*)&As[kk][ty << 2];
            const float4 bv = *(const float4*)&Bs[kk][tx << 2];
            const float a_[4] = {av.x, av.y, av.z, av.w};
            const float b_[4] = {bv.x, bv.y, bv.z, bv.w};
#pragma unroll
            for (int i = 0; i < 4; ++i)
#pragma unroll
                for (int j = 0; j < 4; ++j)
                    acc[i][j] = fmaf(a_[i], b_[j], acc[i][j]);
        }
    }
#pragma unroll
    for (int i = 0; i < 4; ++i) {
        const int row = row0 + (ty << 2) + i;
#pragma unroll
        for (int j = 0; j < 4; ++j) {
            const int col = col0 + (tx << 2) + j;
            if (col >= N) continue;
            const size_t idx = (size_t)row * N + col;
            if constexpr (MODE == 0) Cb[idx] = f2bf(acc[i][j]);
            else                     Cf[idx] = 1.f / (1.f + expf(-acc[i][j]));
        }
    }
}

// ---------------------------------------------------------------- l2norm over HD=96
__global__ __launch_bounds__(256)
void l2norm_rows(float* x, float scale)
{
    const int row  = (blockIdx.x << 2) + (threadIdx.x >> 6);
    const int lane = threadIdx.x & 63;
    float* xr = x + (size_t)row * HD;
    const float a = xr[lane];
    const float b = (lane < 32) ? xr[64 + lane] : 0.f;
    float ss = a * a + b * b;
#pragma unroll
    for (int i = 1; i < 64; i <<= 1) ss += __shfl_xor(ss, i);
    const float r = rsqrtf(ss + 1e-6f) * scale;
    xr[lane] = a * r;
    if (lane < 32) xr[64 + lane] = b * r;
}

// ---------------------------------------------------------------- KDA chunkwise precompute
// bf16 LDS for kappa/kappa_tilde -> 69.9KB LDS -> 2 blocks/CU.
__global__ __launch_bounds__(256)
void kda_pre(const float* __restrict__ q, const float* __restrict__ k, float* v, float* g,
             const float* __restrict__ beta,
             unsigned short* __restrict__ ol, float* __restrict__ Bc,
             unsigned short* __restrict__ Wbf, unsigned short* __restrict__ Kbf)
{
    __shared__ unsigned short Kb[CH * KP];   // k (bf16), then kappa_tilde (bf16)
    __shared__ unsigned short Kk[CH * KP];   // kappa (bf16)
    __shared__ float Qp[CH * RP];            // g -> L -> q'
    __shared__ float Am[CH][68];
    __shared__ float sb[CH];

    const int blk = blockIdx.x;
    const int ch = blk & 31, bh = blk >> 5;
    const int b = bh >> 3, h = bh & 7;
    const int tid = threadIdx.x;
    const size_t base = (size_t)b * (TT * HH * HD) + (size_t)(ch * CH) * (HH * HD) + h * HD;

    // P0: stage k (as bf16), g (f32), beta
    for (int e = tid; e < CH * 24; e += 256) {
        const int t = e / 24, c4 = (e % 24) * 4;
        const float4 kv = *(const float4*)(k + base + t * 768 + c4);
        ushort4 k4;
        k4.x = f2bf(kv.x); k4.y = f2bf(kv.y); k4.z = f2bf(kv.z); k4.w = f2bf(kv.w);
        *(ushort4*)&Kb[t * KP + c4] = k4;
        *(float4*)&Qp[t * RP + c4] = *(const float4*)(g + base + t * 768 + c4);
    }
    if (tid < CH) sb[tid] = beta[((size_t)b * TT + ch * CH + tid) * HH + h];
    __syncthreads();

    // P1: per-channel cumsum of g
    if (tid < HD) {
        float L = 0.f;
        for (int t = 0; t < CH; ++t) { L += Qp[t * RP + tid]; Qp[t * RP + tid] = L; }
    }
    __syncthreads();

    // P2: kappa, kappa_tilde (bf16), q', Bc
    for (int e = tid; e < CH * HD; e += 256) {
        const int t = e / HD, c = e % HD;
        const float L = Qp[t * RP + c];
        const float B = expf(L), iB = expf(-L);
        const float kv = bf2f(Kb[t * KP + c]);
        if (t == CH - 1) Bc[((size_t)bh * NCH + ch) * HD + c] = B;
        Kk[t * KP + c] = f2bf(kv * B);
        const unsigned short kti = f2bf(kv * iB);
        const float qv = q[base + t * 768 + c];
        Kb[t * KP + c] = kti;
        Kbf[base + t * 768 + c] = kti;            // kappa_tilde out (bf16)
        Qp[t * RP + c] = qv * B;                  // q'
    }
    __syncthreads();

    // P3: A[t][i] = beta_t * kappa_t . ktil_i  (i < t)
    {
        const int wv = tid >> 6, lt = tid & 63;
        for (int half = 0; half < 2; ++half) {
            float ca[48];
#pragma unroll
            for (int r = 0; r < 6; ++r) {
                const u16x8 u = *(const u16x8*)&Kk[lt * KP + half * 48 + r * 8];
#pragma unroll
                for (int j = 0; j < 8; ++j) ca[r * 8 + j] = bf2f((unsigned short)u[j]);
            }
            for (int i = wv * 16; i < wv * 16 + 16; ++i) {
                float d0 = 0, d1 = 0, d2 = 0, d3 = 0;
#pragma unroll
                for (int r = 0; r < 6; ++r) {
                    const u16x8 u = *(const u16x8*)&Kb[i * KP + half * 48 + r * 8];
                    d0 = fmaf(ca[r * 8 + 0], bf2f((unsigned short)u[0]), d0);
                    d1 = fmaf(ca[r * 8 + 1], bf2f((unsigned short)u[1]), d1);
                    d2 = fmaf(ca[r * 8 + 2], bf2f((unsigned short)u[2]), d2);
                    d3 = fmaf(ca[r * 8 + 3], bf2f((unsigned short)u[3]), d3);
                    d0 = fmaf(ca[r * 8 + 4], bf2f((unsigned short)u[4]), d0);
                    d1 = fmaf(ca[r * 8 + 5], bf2f((unsigned short)u[5]), d1);
                    d2 = fmaf(ca[r * 8 + 6], bf2f((unsigned short)u[6]), d2);
                    d3 = fmaf(ca[r * 8 + 7], bf2f((unsigned short)u[7]), d3);
                }
                const float d = ((d0 + d1) + (d2 + d3)) * sb[lt];
                const float val = (i < lt) ? d : 0.f;
                if (half == 0) Am[lt][i] = val; else Am[lt][i] += val;
            }
        }
    }
    __syncthreads();

    // P4: forward solve, column j of [U | W] in registers
    float X[CH];
    const int j = tid;
    if (j < 192) {
        if (j < HD) {
#pragma unroll
            for (int t = 0; t < CH; ++t) X[t] = sb[t] * v[base + t * 768 + j];
        } else {
#pragma unroll
            for (int t = 0; t < CH; ++t) X[t] = sb[t] * bf2f(Kk[t * KP + (j - HD)]);
        }
#pragma unroll
        for (int t = 1; t < CH; ++t) {
            float a0 = 0, a1 = 0, a2 = 0, a3 = 0;
#pragma unroll
            for (int i4 = 0; i4 * 4 < t; ++i4) {
                const float4 a = *(const float4*)&Am[t][i4 * 4];
                if (i4 * 4 + 0 < t) a0 = fmaf(a.x, X[i4 * 4 + 0], a0);
                if (i4 * 4 + 1 < t) a1 = fmaf(a.y, X[i4 * 4 + 1], a1);
                if (i4 * 4 + 2 < t) a2 = fmaf(a.z, X[i4 * 4 + 2], a2);
                if (i4 * 4 + 3 < t) a3 = fmaf(a.w, X[i4 * 4 + 3], a3);
            }
            X[t] -= ((a0 + a1) + (a2 + a3));
        }
        // P5: store U (f32 over v) / W (bf16)
        if (j < HD) {
#pragma unroll
            for (int t = 0; t < CH; ++t) v[base + t * 768 + j] = X[t];
        } else {
#pragma unroll
            for (int t = 0; t < CH; ++t) Wbf[base + t * 768 + (j - HD)] = f2bf(X[t]);
        }
    }
    __syncthreads();

    // P6: T[t][i] = q'_t . ktil_i  (i <= t)
    {
        const int wv = tid >> 6, lt = tid & 63;
        for (int half = 0; half < 2; ++half) {
            float ca[48];
#pragma unroll
            for (int r = 0; r < 12; ++r) {
                const float4 qv = *(const float4*)&Qp[lt * RP + half * 48 + r * 4];
                ca[r * 4 + 0] = qv.x; ca[r * 4 + 1] = qv.y;
                ca[r * 4 + 2] = qv.z; ca[r * 4 + 3] = qv.w;
            }
            for (int i = wv * 16; i < wv * 16 + 16; ++i) {
                float d0 = 0, d1 = 0, d2 = 0, d3 = 0;
#pragma unroll
                for (int r = 0; r < 6; ++r) {
                    const u16x8 u = *(const u16x8*)&Kb[i * KP + half * 48 + r * 8];
                    d0 = fmaf(ca[r * 8 + 0], bf2f((unsigned short)u[0]), d0);
                    d1 = fmaf(ca[r * 8 + 1], bf2f((unsigned short)u[1]), d1);
                    d2 = fmaf(ca[r * 8 + 2], bf2f((unsigned short)u[2]), d2);
                    d3 = fmaf(ca[r * 8 + 3], bf2f((unsigned short)u[3]), d3);
                    d0 = fmaf(ca[r * 8 + 4], bf2f((unsigned short)u[4]), d0);
                    d1 = fmaf(ca[r * 8 + 5], bf2f((unsigned short)u[5]), d1);
                    d2 = fmaf(ca[r * 8 + 6], bf2f((unsigned short)u[6]), d2);
                    d3 = fmaf(ca[r * 8 + 7], bf2f((unsigned short)u[7]), d3);
                }
                const float d = (d0 + d1) + (d2 + d3);
                const float val = (i <= lt) ? d : 0.f;
                if (half == 0) Am[lt][i] = val; else Am[lt][i] += val;
            }
        }
    }
    __syncthreads();

    // P7: T @ X -> Ol (j<96) ; Qe = q' - T@W (j>=96, over g)
    if (j < 192) {
        for (int t = 0; t < CH; ++t) {
            float a0 = 0, a1 = 0, a2 = 0, a3 = 0;
#pragma unroll
            for (int i4 = 0; i4 < 16; ++i4) {
                const float4 a = *(const float4*)&Am[t][i4 * 4];
                a0 = fmaf(a.x, X[i4 * 4 + 0], a0); a1 = fmaf(a.y, X[i4 * 4 + 1], a1);
                a2 = fmaf(a.z, X[i4 * 4 + 2], a2); a3 = fmaf(a.w, X[i4 * 4 + 3], a3);
            }
            const float acc = (a0 + a1) + (a2 + a3);
            if (j < HD) ol[base + t * 768 + j] = f2bf(acc);
            else        g[base + t * 768 + (j - HD)] = Qp[t * RP + (j - HD)] - acc;
        }
    }
}

// ---------------------------------------------------------------- KDA sequential recurrence (parallel form, exact)
constexpr int VSL = 16;  // v-slice per block
constexpr int SP = 20;   // Sl/Dl/Ul row pad (floats)
__global__ __launch_bounds__(256)
void kda_seq(const unsigned short* __restrict__ Wbf, const unsigned short* __restrict__ Kbf,
             const float* __restrict__ U, const float* __restrict__ Bc,
             float* __restrict__ Sin, float* __restrict__ states)
{
    __shared__ float Wl[CH * 97];
    __shared__ float Kl[CH * 97];
    __shared__ float Sl[96 * SP];
    __shared__ float Dl[CH * SP];
    __shared__ float Ul[CH * SP];

    const int blk = blockIdx.x;
    const int bh = blk / 6, vq = blk - bh * 6;
    const int b = bh >> 3, h = bh & 7;
    const int tid = threadIdx.x;
    const int ta = tid & 63, vga = tid >> 6;   // step A: row t, v-quad
    const int kb = tid & 31, vB = tid >> 5;    // step B: k-base, v-pair (0..7)
    const int v0 = vq * VSL;
    const size_t base = (size_t)b * (TT * HH * HD) + h * HD;

    for (int e = tid; e < 96 * SP; e += 256) Sl[e] = 0.f;

    u16x8 wpf[3], kpf[3];
    f32x4 upf;

    // stage chunk 0
    {
#pragma unroll
        for (int i = 0; i < 3; ++i) {
            const int g = i * 256 + tid;
            const int r = g / 12, c8 = (g % 12) * 8;
            wpf[i] = *(const u16x8*)(Wbf + base + (size_t)r * 768 + c8);
            kpf[i] = *(const u16x8*)(Kbf + base + (size_t)r * 768 + c8);
        }
        const int t = tid >> 2, c4 = (tid & 3) * 4;
        upf = *(const f32x4*)(U + base + (size_t)t * 768 + v0 + c4);
#pragma unroll
        for (int i = 0; i < 3; ++i) {
            const int g = i * 256 + tid;
            const int r = g / 12, c8 = (g % 12) * 8;
#pragma unroll
            for (int j = 0; j < 8; ++j) {
                Wl[r * 97 + c8 + j] = bf2f((unsigned short)wpf[i][j]);
                Kl[r * 97 + c8 + j] = bf2f((unsigned short)kpf[i][j]);
            }
        }
        *(f32x4*)&Ul[t * SP + c4] = upf;
    }
    __syncthreads();

    for (int ch = 0; ch < NCH; ++ch) {
        // prefetch next chunk into registers
        if (ch + 1 < NCH) {
            const size_t cb = base + (size_t)((ch + 1) * CH) * (HH * HD);
#pragma unroll
            for (int i = 0; i < 3; ++i) {
                const int g = i * 256 + tid;
                const int r = g / 12, c8 = (g % 12) * 8;
                wpf[i] = *(const u16x8*)(Wbf + cb + (size_t)r * 768 + c8);
                kpf[i] = *(const u16x8*)(Kbf + cb + (size_t)r * 768 + c8);
            }
            const int t = tid >> 2, c4 = (tid & 3) * 4;
            upf = *(const f32x4*)(U + cb + (size_t)t * 768 + v0 + c4);
        }
        // store S_in for the O-epilogue
        {
            float* sg = Sin + (size_t)(bh * NCH + ch) * (HD * HD);
#pragma unroll
            for (int i = 0; i < 2; ++i) {
                const int e = i * 256 + tid;
                if (e < 384) {
                    const int kk = e >> 2, c4 = (e & 3) * 4;
                    *(f32x4*)(sg + (size_t)kk * HD + v0 + c4) = *(const f32x4*)&Sl[kk * SP + c4];
                }
            }
        }
        // step A: Dl[t][v] = Ul - sum_k Wl[t][k] * Sl[k][v]
        {
            f32x4 acc = *(const f32x4*)&Ul[ta * SP + vga * 4];
            const float* wr = &Wl[ta * 97];
#pragma unroll 8
            for (int kk = 0; kk < 96; ++kk)
                acc -= wr[kk] * *(const f32x4*)&Sl[kk * SP + vga * 4];
            *(f32x4*)&Dl[ta * SP + vga * 4] = acc;
        }
        __syncthreads();
        // step B: S[k][v] = (S[k][v] + sum_t Kl[t][k]*Dl[t][v]) * Bc[k]
        {
            float a0[2] = {0.f, 0.f}, a1[2] = {0.f, 0.f}, a2[2] = {0.f, 0.f};
#pragma unroll 8
            for (int t = 0; t < CH; ++t) {
                const float d0 = Dl[t * SP + vB * 2];
                const float d1 = Dl[t * SP + vB * 2 + 1];
                const float k0 = Kl[t * 97 + kb];
                const float k1 = Kl[t * 97 + kb + 32];
                const float k2 = Kl[t * 97 + kb + 64];
                a0[0] = fmaf(k0, d0, a0[0]); a0[1] = fmaf(k0, d1, a0[1]);
                a1[0] = fmaf(k1, d0, a1[0]); a1[1] = fmaf(k1, d1, a1[1]);
                a2[0] = fmaf(k2, d0, a2[0]); a2[1] = fmaf(k2, d1, a2[1]);
            }
            const float* bc = Bc + ((size_t)bh * NCH + ch) * HD;
            const float b0 = bc[kb], b1 = bc[kb + 32], b2 = bc[kb + 64];
#pragma unroll
            for (int e = 0; e < 2; ++e) {
                const int v = vB * 2 + e;
                Sl[kb * SP + v]        = (Sl[kb * SP + v]        + a0[e]) * b0;
                Sl[(kb + 32) * SP + v] = (Sl[(kb + 32) * SP + v] + a1[e]) * b1;
                Sl[(kb + 64) * SP + v] = (Sl[(kb + 64) * SP + v] + a2[e]) * b2;
            }
        }
        __syncthreads();
        // write staged regs -> LDS for next chunk
        if (ch + 1 < NCH) {
#pragma unroll
            for (int i = 0; i < 3; ++i) {
                const int g = i * 256 + tid;
                const int r = g / 12, c8 = (g % 12) * 8;
#pragma unroll
                for (int j = 0; j < 8; ++j) {
                    Wl[r * 97 + c8 + j] = bf2f((unsigned short)wpf[i][j]);
                    Kl[r * 97 + c8 + j] = bf2f((unsigned short)kpf[i][j]);
                }
            }
            const int t = tid >> 2, c4 = (tid & 3) * 4;
            *(f32x4*)&Ul[t * SP + c4] = upf;
            __syncthreads();
        }
    }
    // final states
    {
        float* sp = states + (size_t)bh * (HD * HD);
#pragma unroll
        for (int i = 0; i < 2; ++i) {
            const int e = i * 256 + tid;
            if (e < 384) {
                const int kk = e >> 2, c4 = (e & 3) * 4;
                *(f32x4*)(sp + (size_t)kk * HD + v0 + c4) = *(const f32x4*)&Sl[kk * SP + c4];
            }
        }
    }
}

// ---------------------------------------------------------------- KDA parallel O epilogue
__global__ __launch_bounds__(256)
void kda_epi(const float* __restrict__ Sin, const float* __restrict__ Qe,
             const unsigned short* __restrict__ Ol, const unsigned short* __restrict__ Gt,
             const float* __restrict__ onw, unsigned short* __restrict__ obf)
{
    __shared__ float Sl[96 * 100];
    __shared__ float Ql[64 * 100];
    __shared__ unsigned short Olb[64 * 104];
    __shared__ unsigned short Gl[64 * 104];

    const int bx = blockIdx.x;
    const int bh = bx >> 5, ch = bx & 31;
    const int b = bh >> 3, h = bh & 7;
    const int tid = threadIdx.x;
    const size_t cb = (size_t)b * (TT * HH * HD) + (size_t)(ch * CH) * (HH * HD) + h * HD;
    const float* Sg = Sin + (size_t)(bh * NCH + ch) * HD * HD;

#pragma unroll
    for (int i = 0; i < 9; ++i) {
        const int g = i * 256 + tid;
        const int k = g / 24, c4 = (g % 24) * 4;
        *(f32x4*)&Sl[k * 100 + c4] = *(const f32x4*)(Sg + (size_t)k * HD + c4);
    }
#pragma unroll
    for (int i = 0; i < 6; ++i) {
        const int g = i * 256 + tid;
        const int t = g / 24, c4 = (g % 24) * 4;
        *(f32x4*)&Ql[t * 100 + c4] = *(const f32x4*)(Qe + cb + (size_t)t * 768 + c4);
    }
#pragma unroll
    for (int i = 0; i < 3; ++i) {
        const int g = i * 256 + tid;
        const int t = g / 12, c8 = (g % 12) * 8;
        *(u16x8*)&Olb[t * 104 + c8] = *(const u16x8*)(Ol + cb + (size_t)t * 768 + c8);
        *(u16x8*)&Gl[t * 104 + c8]  = *(const u16x8*)(Gt + cb + (size_t)t * 768 + c8);
    }
    __syncthreads();

    const int t = tid >> 2, vq2 = tid & 3;
    const int v0 = vq2 * 24;
    f32x4 acc[6];
#pragma unroll
    for (int j = 0; j < 6; ++j) {
        acc[j].x = bf2f(Olb[t * 104 + v0 + j * 4 + 0]);
        acc[j].y = bf2f(Olb[t * 104 + v0 + j * 4 + 1]);
        acc[j].z = bf2f(Olb[t * 104 + v0 + j * 4 + 2]);
        acc[j].w = bf2f(Olb[t * 104 + v0 + j * 4 + 3]);
    }
#pragma unroll 2
    for (int k = 0; k < HD; ++k) {
        const float qv = Ql[t * 100 + k];
#pragma unroll
        for (int j = 0; j < 6; ++j)
            acc[j] += qv * *(const f32x4*)&Sl[k * 100 + v0 + j * 4];
    }
    float ss = 0.f;
#pragma unroll
    for (int j = 0; j < 6; ++j)
        ss += acc[j].x * acc[j].x + acc[j].y * acc[j].y + acc[j].z * acc[j].z + acc[j].w * acc[j].w;
    ss += __shfl_xor(ss, 1); ss += __shfl_xor(ss, 2);
    const float r = rsqrtf(ss * (1.f / HD) + 1e-6f);
#pragma unroll
    for (int j = 0; j < 6; ++j) {
#pragma unroll
        for (int e = 0; e < 4; ++e) {
            const int v = v0 + j * 4 + e;
            const float g = bf2f(Gl[t * 104 + v]);
            const float val = acc[j][e] * r * onw[v] * (g / (1.f + expf(-g)));
            obf[cb + (size_t)t * 768 + v] = f2bf(val);
        }
    }
}

// ---------------------------------------------------------------- host
extern "C" void kernel_launch(void* const* d_in, const int* in_sizes, int n_in,
                              void* d_out, int out_size, void* d_ws, size_t ws_size,
                              hipStream_t stream)
{
    (void)in_sizes; (void)n_in; (void)out_size; (void)ws_size;
    const float* hidden   = (const float*)d_in[0];
    const float* mask     = (const float*)d_in[1];
    const float* norm_a_w = (const float*)d_in[2];
    const float* norm_a_b = (const float*)d_in[3];
    const float* proj_a_w = (const float*)d_in[4];
    const float* proj_a_b = (const float*)d_in[5];
    const float* ln_w     = (const float*)d_in[6];
    const float* ln_b     = (const float*)d_in[7];
    const float* Wq       = (const float*)d_in[8];
    const float* Wk       = (const float*)d_in[9];
    const float* Wv       = (const float*)d_in[10];
    const float* Wfa      = (const float*)d_in[11];
    const float* Wfb      = (const float*)d_in[12];
    const float* dt_bias  = (const float*)d_in[13];
    const float* A_log    = (const float*)d_in[14];
    const float* Wb       = (const float*)d_in[15];
    const float* Wga      = (const float*)d_in[16];
    const float* Wgb      = (const float*)d_in[17];
    const float* onorm_w  = (const float*)d_in[18];
    const float* Wo       = (const float*)d_in[19];
    const float* Wgate    = (const float*)d_in[20];
    const float* Wup      = (const float*)d_in[21];
    const float* Wdown    = (const float*)d_in[22];

    float* ws    = (float*)d_ws;
    float* hbuf  = ws;
    float* qb    = ws + HROW;          // dead after pre -> Sin/mg live here
    float* kb    = ws + 2 * HROW;
    float* vb    = ws + 3 * HROW;      // U (f32)
    float* egb   = ws + 4 * HROW;      // g -> Qe (f32)
    float* betab = ws + 5 * HROW;                     // MM*HH
    float* BcP   = betab + (size_t)MM * HH;           // 32*32*96
    float* SinP  = qb;                                // 9.44M floats (qb+kb region)
    unsigned short* bfp = (unsigned short*)(BcP + 32 * NCH * HD);
    unsigned short* x_bf    = bfp;  bfp += HROW;
    unsigned short* fab_bf  = bfp;  bfp += (size_t)MM * HD;
    unsigned short* gate_bf = bfp;  bfp += HROW;
    unsigned short* olb_bf  = bfp;  bfp += HROW;
    unsigned short* w_bf    = bfp;  bfp += HROW;
    unsigned short* k_bf    = bfp;  bfp += HROW;
    unsigned short* wt_proj = bfp;  bfp += 768 * 768;
    unsigned short *wt_q[LL], *wt_k[LL], *wt_v[LL], *wt_o[LL], *wt_fb[LL], *wt_gb[LL],
                   *wt_gate[LL], *wt_up[LL], *wt_down[LL];
    for (int l = 0; l < LL; ++l) {
        wt_q[l] = bfp;    bfp += 768 * 768;   // q,k,v contiguous -> fused N=2304 GEMM
        wt_k[l] = bfp;    bfp += 768 * 768;
        wt_v[l] = bfp;    bfp += 768 * 768;
        wt_o[l] = bfp;    bfp += 768 * 768;
        wt_fb[l] = bfp;   bfp += 768 * 96;
        wt_gb[l] = bfp;   bfp += 768 * 96;
        wt_gate[l] = bfp; bfp += 2048 * 768;
        wt_up[l] = bfp;   bfp += 2048 * 768;
        wt_down[l] = bfp; bfp += 768 * 2048;
    }
    unsigned short* mg_bf = (unsigned short*)SinP;  // Sin dead after epi
    unsigned short* a_bf  = (unsigned short*)vb;    // U dead after seq

    float* out    = (float*)d_out;
    float* states = out + HROW;

    // weight transpose+convert
    transcvt<<<dim3(24, 24), 256, 0, stream>>>(proj_a_w, wt_proj, 768, 768);
    for (int l = 0; l < LL; ++l) {
        transcvt<<<dim3(24, 24), 256, 0, stream>>>(Wq + (size_t)l * 589824, wt_q[l], 768, 768);
        transcvt<<<dim3(24, 24), 256, 0, stream>>>(Wk + (size_t)l * 589824, wt_k[l], 768, 768);
        transcvt<<<dim3(24, 24), 256, 0, stream>>>(Wv + (size_t)l * 589824, wt_v[l], 768, 768);
        transcvt<<<dim3(24, 24), 256, 0, stream>>>(Wo + (size_t)l * 589824, wt_o[l], 768, 768);
        transcvt<<<dim3(24, 3), 256, 0, stream>>>(Wfb + (size_t)l * 73728, wt_fb[l], 96, 768);
        transcvt<<<dim3(24, 3), 256, 0, stream>>>(Wgb + (size_t)l * 73728, wt_gb[l], 96, 768);
        transcvt<<<dim3(64, 24), 256, 0, stream>>>(Wgate + (size_t)l * 1572864, wt_gate[l], 768, 2048);
        transcvt<<<dim3(64, 24), 256, 0, stream>>>(Wup + (size_t)l * 1572864, wt_up[l], 768, 2048);
        transcvt<<<dim3(24, 64), 256, 0, stream>>>(Wdown + (size_t)l * 1572864, wt_down[l], 2048, 768);
    }

    layernorm_rows<<<MM, 256, 0, stream>>>(hidden, x_bf, norm_a_w, norm_a_b, nullptr);
    bgemm<BE_BIAS><<<dim3(6, 64), 256, 0, stream>>>(x_bf, wt_proj, hbuf, nullptr,
                                                    proj_a_b, nullptr, MM, DD, DD);

    for (int l = 0; l < LL; ++l) {
        layernorm_rows<<<MM, 256, 0, stream>>>(hbuf, x_bf, ln_w + l * DD, ln_b + l * DD, mask);
        // fused q|k|v = silu(x @ [Wq|Wk|Wv]) -> qb, kb, vb
        bgemm<BE_QKV><<<dim3(18, 64), 256, 0, stream>>>(x_bf, wt_q[l], qb, nullptr,
                                                        kb, vb, MM, 3 * DD, DD);
        l2norm_rows<<<(MM * HH) / 4, 256, 0, stream>>>(qb, 0.1020620726159658f);
        l2norm_rows<<<(MM * HH) / 4, 256, 0, stream>>>(kb, 1.f);
        gemm_small<0><<<dim3(2, 128), 256, 0, stream>>>(x_bf, Wfa + (size_t)l * DD * HD, fab_bf, nullptr, MM, HD, DD);
        bgemm<BE_EG><<<dim3(6, 64), 256, 0, stream>>>(fab_bf, wt_fb[l], egb, nullptr,
                                                      A_log + l * DD, dt_bias + l * DD, MM, DD, HD);
        gemm_small<1><<<dim3(1, 128), 256, 0, stream>>>(x_bf, Wb + (size_t)l * DD * HH, nullptr, betab, MM, HH, DD);
        // gate before scan (x_bf gets overwritten by o in epi)
        gemm_small<0><<<dim3(2, 128), 256, 0, stream>>>(x_bf, Wga + (size_t)l * DD * HD, fab_bf, nullptr, MM, HD, DD);
        bgemm<BE_BF16><<<dim3(6, 64), 256, 0, stream>>>(fab_bf, wt_gb[l], nullptr, gate_bf, nullptr, nullptr, MM, DD, HD);
        // chunkwise scan
        kda_pre<<<1024, 256, 0, stream>>>(qb, kb, vb, egb, betab, olb_bf, BcP, w_bf, k_bf);
        kda_seq<<<192, 256, 0, stream>>>(w_bf, k_bf, vb, BcP, SinP,
                                         states + (size_t)l * BB * HH * HD * HD);
        kda_epi<<<1024, 256, 0, stream>>>(SinP, egb, olb_bf, gate_bf, onorm_w + l * HD, x_bf);
        // a = o @ Wo
        bgemm<BE_BF16><<<dim3(6, 64), 256, 0, stream>>>(x_bf, wt_o[l], nullptr, a_bf, nullptr, nullptr, MM, DD, DD);
        // swiglu
        bgemm_dual<<<dim3(32, 64), 256, 0, stream>>>(a_bf, wt_gate[l], wt_up[l], mg_bf, MM, FF, DD);
        float* dst = (l == LL - 1) ? out : hbuf;
        bgemm<BE_RES><<<dim3(6, 64), 256, 0, stream>>>(mg_bf, wt_down[l], dst, nullptr,
                                                       hbuf, nullptr, MM, DD, FF);
    }
}

// Round 9
// 1452.405 us; speedup vs baseline: 2.7032x; 1.1728x over previous
//
#include <hip/hip_runtime.h>
#include <cstddef>
#include <cstdint>
#include <cmath>

// Problem constants
constexpr int BB = 4, TT = 2048, DD = 768, HH = 8, HD = 96, FF = 2048, LL = 2;
constexpr int MM = BB * TT;              // 8192
constexpr size_t HROW = (size_t)MM * DD; // 6291456
constexpr int CH = 64;                   // scan chunk length
constexpr int NCH = TT / CH;             // 32 chunks per sequence
constexpr int RP = 100;                  // padded LDS row (floats)
constexpr int KP = 104;                  // padded LDS row (ushorts, 16B-aligned rows)

typedef float f32x4 __attribute__((ext_vector_type(4)));
typedef short bf16x8 __attribute__((ext_vector_type(8)));
typedef unsigned short u16x8 __attribute__((ext_vector_type(8)));

__device__ __forceinline__ void gload16(const void* g, void* l) {
    __builtin_amdgcn_global_load_lds(
        (const __attribute__((address_space(1))) void*)g,
        (__attribute__((address_space(3))) void*)l, 16, 0, 0);
}
__device__ __forceinline__ float bf2f(unsigned short u) {
    return __uint_as_float(((unsigned)u) << 16);
}
__device__ __forceinline__ unsigned short f2bf(float f) {
    unsigned u = __float_as_uint(f);
    unsigned r = (u + 0x7fffu + ((u >> 16) & 1u)) >> 16;
    return (unsigned short)r;
}

// ---------------------------------------------------------------- LayerNorm -> bf16
__global__ __launch_bounds__(256)
void layernorm_rows(const float* __restrict__ x, unsigned short* __restrict__ y,
                    const float* __restrict__ w, const float* __restrict__ b,
                    const float* mask)
{
    const int row = blockIdx.x;
    const int tid = threadIdx.x;
    const float* xr = x + (size_t)row * DD;
    float v0 = xr[tid], v1 = xr[tid + 256], v2 = xr[tid + 512];
    float s = v0 + v1 + v2;
    float ss = v0 * v0 + v1 * v1 + v2 * v2;
#pragma unroll
    for (int i = 1; i < 64; i <<= 1) { s += __shfl_xor(s, i); ss += __shfl_xor(ss, i); }
    __shared__ float red[8];
    const int wid = tid >> 6, lane = tid & 63;
    if (lane == 0) { red[wid] = s; red[4 + wid] = ss; }
    __syncthreads();
    const float S  = red[0] + red[1] + red[2] + red[3];
    const float SS = red[4] + red[5] + red[6] + red[7];
    const float mean = S * (1.f / DD);
    const float var  = SS * (1.f / DD) - mean * mean;
    const float rstd = rsqrtf(var + 1e-5f);
    const float m = mask ? mask[row] : 1.f;
    unsigned short* yr = y + (size_t)row * DD;
    yr[tid]       = f2bf(((v0 - mean) * rstd * w[tid]       + b[tid])       * m);
    yr[tid + 256] = f2bf(((v1 - mean) * rstd * w[tid + 256] + b[tid + 256]) * m);
    yr[tid + 512] = f2bf(((v2 - mean) * rstd * w[tid + 512] + b[tid + 512]) * m);
}

// ---------------------------------------------------------------- transpose+convert W
__global__ __launch_bounds__(256)
void transcvt(const float* __restrict__ in, unsigned short* __restrict__ out, int K, int N)
{
    __shared__ float t[32][33];
    const int tx = threadIdx.x & 31, ty = threadIdx.x >> 5;
    const int k0 = blockIdx.y * 32, n0 = blockIdx.x * 32;
#pragma unroll
    for (int i = 0; i < 4; ++i)
        t[ty + i * 8][tx] = in[(size_t)(k0 + ty + i * 8) * N + n0 + tx];
    __syncthreads();
#pragma unroll
    for (int i = 0; i < 4; ++i)
        out[(size_t)(n0 + ty + i * 8) * K + k0 + tx] = f2bf(t[tx][ty + i * 8]);
}

// ---------------------------------------------------------------- bf16 MFMA GEMM
enum { BE_BIAS = 0, BE_SILU, BE_EG, BE_F32, BE_BF16, BE_RES, BE_QKV };

template <int EPI>
__global__ __launch_bounds__(256)
void bgemm(const unsigned short* __restrict__ A, const unsigned short* __restrict__ Bt,
           float* Cf, unsigned short* Cb,
           const float* P0, const float* P1,
           int M, int N, int K)
{
    __shared__ unsigned short As[128 * 32];
    __shared__ unsigned short Bs[128 * 32];
    const int tid = threadIdx.x;
    const int w = tid >> 6, l = tid & 63;
    const int wm = w >> 1, wn = w & 1;
    const int lr = l & 15, lh = l >> 4;
    const int m0 = blockIdx.y * 128, n0 = blockIdx.x * 128;

    f32x4 acc[4][4];
#pragma unroll
    for (int i = 0; i < 4; ++i)
#pragma unroll
        for (int j = 0; j < 4; ++j) acc[i][j] = (f32x4){0.f, 0.f, 0.f, 0.f};

    const int sr = l >> 2, sq = (l & 3) * 8;
    const unsigned short* Ag = A + (size_t)(m0 + w * 32 + sr) * K + sq;
    const unsigned short* Bg = Bt + (size_t)(n0 + w * 32 + sr) * K + sq;
    unsigned short* Al = &As[(w * 32) * 32];
    unsigned short* Bl = &Bs[(w * 32) * 32];

    for (int kt = 0; kt < K; kt += 32) {
        __syncthreads();
        gload16(Ag + kt, Al);
        gload16(Ag + kt + 16 * (size_t)K, Al + 16 * 32);
        gload16(Bg + kt, Bl);
        gload16(Bg + kt + 16 * (size_t)K, Bl + 16 * 32);
        __syncthreads();
        bf16x8 af[4], bfv[4];
#pragma unroll
        for (int mi = 0; mi < 4; ++mi)
            af[mi] = *(const bf16x8*)&As[(wm * 64 + mi * 16 + lr) * 32 + lh * 8];
#pragma unroll
        for (int ni = 0; ni < 4; ++ni)
            bfv[ni] = *(const bf16x8*)&Bs[(wn * 64 + ni * 16 + lr) * 32 + lh * 8];
#pragma unroll
        for (int mi = 0; mi < 4; ++mi)
#pragma unroll
            for (int ni = 0; ni < 4; ++ni)
                acc[mi][ni] = __builtin_amdgcn_mfma_f32_16x16x32_bf16(af[mi], bfv[ni], acc[mi][ni], 0, 0, 0);
    }

#pragma unroll
    for (int mi = 0; mi < 4; ++mi) {
#pragma unroll
        for (int j = 0; j < 4; ++j) {
            const int row = m0 + wm * 64 + mi * 16 + lh * 4 + j;
#pragma unroll
            for (int ni = 0; ni < 4; ++ni) {
                const int col = n0 + wn * 64 + ni * 16 + lr;
                const size_t idx = (size_t)row * N + col;
                float v = acc[mi][ni][j];
                if constexpr (EPI == BE_BIAS) { Cf[idx] = v + P0[col]; }
                else if constexpr (EPI == BE_SILU) { Cf[idx] = v / (1.f + expf(-v)); }
                else if constexpr (EPI == BE_EG) {
                    const float lin = v + P1[col];
                    const float sp = (lin > 20.f) ? lin : log1pf(expf(lin));
                    Cf[idx] = -expf(P0[col]) * sp;      // raw log-decay g
                }
                else if constexpr (EPI == BE_F32) { Cf[idx] = v; }
                else if constexpr (EPI == BE_BF16) { Cb[idx] = f2bf(v); }
                else if constexpr (EPI == BE_RES) { Cf[idx] = v + P0[idx]; }
                else if constexpr (EPI == BE_QKV) {
                    // fused q/k/v: col/768 selects target buffer (tiles never straddle)
                    const int tgt = col / 768;
                    const int cl = col - tgt * 768;
                    float* dst = (tgt == 0) ? Cf
                               : (tgt == 1) ? const_cast<float*>(P0)
                                            : const_cast<float*>(P1);
                    dst[(size_t)row * 768 + cl] = v / (1.f + expf(-v));
                }
            }
        }
    }
}

// Dual-B GEMM for SwiGLU
__global__ __launch_bounds__(256)
void bgemm_dual(const unsigned short* __restrict__ A,
                const unsigned short* __restrict__ Bg_, const unsigned short* __restrict__ Bu_,
                unsigned short* __restrict__ C, int M, int N, int K)
{
    __shared__ unsigned short As[128 * 32];
    __shared__ unsigned short Bs1[64 * 32];
    __shared__ unsigned short Bs2[64 * 32];
    const int tid = threadIdx.x;
    const int w = tid >> 6, l = tid & 63;
    const int wm = w >> 1, wn = w & 1;
    const int lr = l & 15, lh = l >> 4;
    const int m0 = blockIdx.y * 128, n0 = blockIdx.x * 64;

    f32x4 a1[4][2], a2[4][2];
#pragma unroll
    for (int i = 0; i < 4; ++i)
#pragma unroll
        for (int j = 0; j < 2; ++j) { a1[i][j] = (f32x4){0.f,0.f,0.f,0.f}; a2[i][j] = (f32x4){0.f,0.f,0.f,0.f}; }

    const int sr = l >> 2, sq = (l & 3) * 8;
    const unsigned short* Ag  = A   + (size_t)(m0 + w * 32 + sr) * K + sq;
    const unsigned short* B1g = Bg_ + (size_t)(n0 + w * 16 + sr) * K + sq;
    const unsigned short* B2g = Bu_ + (size_t)(n0 + w * 16 + sr) * K + sq;
    unsigned short* Al  = &As[(w * 32) * 32];
    unsigned short* B1l = &Bs1[(w * 16) * 32];
    unsigned short* B2l = &Bs2[(w * 16) * 32];

    for (int kt = 0; kt < K; kt += 32) {
        __syncthreads();
        gload16(Ag + kt, Al);
        gload16(Ag + kt + 16 * (size_t)K, Al + 16 * 32);
        gload16(B1g + kt, B1l);
        gload16(B2g + kt, B2l);
        __syncthreads();
        bf16x8 af[4], b1[2], b2[2];
#pragma unroll
        for (int mi = 0; mi < 4; ++mi)
            af[mi] = *(const bf16x8*)&As[(wm * 64 + mi * 16 + lr) * 32 + lh * 8];
#pragma unroll
        for (int ni = 0; ni < 2; ++ni) {
            b1[ni] = *(const bf16x8*)&Bs1[(wn * 32 + ni * 16 + lr) * 32 + lh * 8];
            b2[ni] = *(const bf16x8*)&Bs2[(wn * 32 + ni * 16 + lr) * 32 + lh * 8];
        }
#pragma unroll
        for (int mi = 0; mi < 4; ++mi)
#pragma unroll
            for (int ni = 0; ni < 2; ++ni) {
                a1[mi][ni] = __builtin_amdgcn_mfma_f32_16x16x32_bf16(af[mi], b1[ni], a1[mi][ni], 0, 0, 0);
                a2[mi][ni] = __builtin_amdgcn_mfma_f32_16x16x32_bf16(af[mi], b2[ni], a2[mi][ni], 0, 0, 0);
            }
    }

#pragma unroll
    for (int mi = 0; mi < 4; ++mi)
#pragma unroll
        for (int j = 0; j < 4; ++j) {
            const int row = m0 + wm * 64 + mi * 16 + lh * 4 + j;
#pragma unroll
            for (int ni = 0; ni < 2; ++ni) {
                const int col = n0 + wn * 32 + ni * 16 + lr;
                const float g = a1[mi][ni][j], u = a2[mi][ni][j];
                C[(size_t)row * N + col] = f2bf((g / (1.f + expf(-g))) * u);
            }
        }
}

// fa|ga fused GEMM: N fixed 192 ([Wfa|Wga]^T), routing epilogue -> two bf16 buffers.
__global__ __launch_bounds__(256)
void bgemm_fg(const unsigned short* __restrict__ A, const unsigned short* __restrict__ Bt,
              unsigned short* __restrict__ Cfa, unsigned short* __restrict__ Cga, int K)
{
    __shared__ unsigned short As[128 * 32];
    __shared__ unsigned short Bs[64 * 32];
    const int tid = threadIdx.x;
    const int w = tid >> 6, l = tid & 63;
    const int wm = w >> 1, wn = w & 1;
    const int lr = l & 15, lh = l >> 4;
    const int m0 = blockIdx.y * 128, n0 = blockIdx.x * 64;

    f32x4 acc[4][2];
#pragma unroll
    for (int i = 0; i < 4; ++i)
#pragma unroll
        for (int j = 0; j < 2; ++j) acc[i][j] = (f32x4){0.f, 0.f, 0.f, 0.f};

    const int sr = l >> 2, sq = (l & 3) * 8;
    const unsigned short* Ag = A + (size_t)(m0 + w * 32 + sr) * K + sq;
    const unsigned short* Bg = Bt + (size_t)(n0 + w * 16 + sr) * K + sq;
    unsigned short* Al = &As[(w * 32) * 32];
    unsigned short* Bl = &Bs[(w * 16) * 32];

    for (int kt = 0; kt < K; kt += 32) {
        __syncthreads();
        gload16(Ag + kt, Al);
        gload16(Ag + kt + 16 * (size_t)K, Al + 16 * 32);
        gload16(Bg + kt, Bl);
        __syncthreads();
        bf16x8 af[4], bfv[2];
#pragma unroll
        for (int mi = 0; mi < 4; ++mi)
            af[mi] = *(const bf16x8*)&As[(wm * 64 + mi * 16 + lr) * 32 + lh * 8];
#pragma unroll
        for (int ni = 0; ni < 2; ++ni)
            bfv[ni] = *(const bf16x8*)&Bs[(wn * 32 + ni * 16 + lr) * 32 + lh * 8];
#pragma unroll
        for (int mi = 0; mi < 4; ++mi)
#pragma unroll
            for (int ni = 0; ni < 2; ++ni)
                acc[mi][ni] = __builtin_amdgcn_mfma_f32_16x16x32_bf16(af[mi], bfv[ni], acc[mi][ni], 0, 0, 0);
    }

#pragma unroll
    for (int mi = 0; mi < 4; ++mi)
#pragma unroll
        for (int j = 0; j < 4; ++j) {
            const int row = m0 + wm * 64 + mi * 16 + lh * 4 + j;
#pragma unroll
            for (int ni = 0; ni < 2; ++ni) {
                const int col = n0 + wn * 32 + ni * 16 + lr;   // 0..191, 16-aligned tiles
                const int tgt = (col >= HD);
                const int cl = col - (tgt ? HD : 0);
                unsigned short* dst = tgt ? Cga : Cfa;
                dst[(size_t)row * HD + cl] = f2bf(acc[mi][ni][j]);
            }
        }
}

// ---------------------------------------------------------------- small fp32 GEMM (A bf16)
template <int MODE>
__global__ __launch_bounds__(256)
void gemm_small(const unsigned short* __restrict__ A, const float* __restrict__ Bm,
                unsigned short* Cb, float* Cf, int M, int N, int K)
{
    __shared__ float As[16][64];
    __shared__ float Bs[16][64];
    const int tid = threadIdx.x;
    const int tx = tid & 15, ty = tid >> 4;
    const int row0 = blockIdx.y * 64;
    const int col0 = blockIdx.x * 64;
    float acc[4][4] = {};
    const int ar  = tid >> 2;
    const int ac4 = (tid & 3) << 2;
    const int br  = tid >> 4;
    const int bc  = (tid & 15) << 2;
    const int gc  = col0 + bc;
    const bool bok = gc < N;

    for (int kt = 0; kt < K; kt += 16) {
        const ushort4 a4 = *(const ushort4*)(A + (size_t)(row0 + ar) * K + kt + ac4);
        float4 b4 = make_float4(0.f, 0.f, 0.f, 0.f);
        if (bok) b4 = *(const float4*)(Bm + (size_t)(kt + br) * N + gc);
        __syncthreads();
        As[ac4 + 0][ar] = bf2f(a4.x); As[ac4 + 1][ar] = bf2f(a4.y);
        As[ac4 + 2][ar] = bf2f(a4.z); As[ac4 + 3][ar] = bf2f(a4.w);
        *(float4*)&Bs[br][bc] = b4;
        __syncthreads();
#pragma unroll
        for (int kk = 0; kk < 16; ++kk) {
            const float4 av = *(const float4*)&As[kk][ty << 2];
            const float4 bv = *(const float4*)&Bs[kk][tx << 2];
            const float a_[4] = {av.x, av.y, av.z, av.w};
            const float b_[4] = {bv.x, bv.y, bv.z, bv.w};
#pragma unroll
            for (int i = 0; i < 4; ++i)
#pragma unroll
                for (int j = 0; j < 4; ++j)
                    acc[i][j] = fmaf(a_[i], b_[j], acc[i][j]);
        }
    }
#pragma unroll
    for (int i = 0; i < 4; ++i) {
        const int row = row0 + (ty << 2) + i;
#pragma unroll
        for (int j = 0; j < 4; ++j) {
            const int col = col0 + (tx << 2) + j;
            if (col >= N) continue;
            const size_t idx = (size_t)row * N + col;
            if constexpr (MODE == 0) Cb[idx] = f2bf(acc[i][j]);
            else                     Cf[idx] = 1.f / (1.f + expf(-acc[i][j]));
        }
    }
}

// ---------------------------------------------------------------- l2norm over HD=96
__global__ __launch_bounds__(256)
void l2norm_rows(float* x, float scale)
{
    const int row  = (blockIdx.x << 2) + (threadIdx.x >> 6);
    const int lane = threadIdx.x & 63;
    float* xr = x + (size_t)row * HD;
    const float a = xr[lane];
    const float b = (lane < 32) ? xr[64 + lane] : 0.f;
    float ss = a * a + b * b;
#pragma unroll
    for (int i = 1; i < 64; i <<= 1) ss += __shfl_xor(ss, i);
    const float r = rsqrtf(ss + 1e-6f) * scale;
    xr[lane] = a * r;
    if (lane < 32) xr[64 + lane] = b * r;
}

// ---------------------------------------------------------------- KDA chunkwise precompute
// bf16 LDS for kappa/kappa_tilde; P3/P6 via MFMA.
__global__ __launch_bounds__(256)
void kda_pre(const float* __restrict__ q, const float* __restrict__ k, float* v, float* g,
             const float* __restrict__ beta,
             unsigned short* __restrict__ ol, float* __restrict__ Bc,
             unsigned short* __restrict__ Wbf, unsigned short* __restrict__ Kbf)
{
    __shared__ unsigned short Kb[CH * KP];   // k (bf16), then kappa_tilde (bf16)
    __shared__ unsigned short Kk[CH * KP];   // kappa (bf16)
    __shared__ float Qp[CH * RP];            // g -> L -> q'
    __shared__ float Am[CH][68];
    __shared__ float sb[CH];

    const int blk = blockIdx.x;
    const int ch = blk & 31, bh = blk >> 5;
    const int b = bh >> 3, h = bh & 7;
    const int tid = threadIdx.x;
    const size_t base = (size_t)b * (TT * HH * HD) + (size_t)(ch * CH) * (HH * HD) + h * HD;

    // P0: stage k (as bf16), g (f32), beta
    for (int e = tid; e < CH * 24; e += 256) {
        const int t = e / 24, c4 = (e % 24) * 4;
        const float4 kv = *(const float4*)(k + base + t * 768 + c4);
        ushort4 k4;
        k4.x = f2bf(kv.x); k4.y = f2bf(kv.y); k4.z = f2bf(kv.z); k4.w = f2bf(kv.w);
        *(ushort4*)&Kb[t * KP + c4] = k4;
        *(float4*)&Qp[t * RP + c4] = *(const float4*)(g + base + t * 768 + c4);
    }
    if (tid < CH) sb[tid] = beta[((size_t)b * TT + ch * CH + tid) * HH + h];
    __syncthreads();

    // P1: per-channel cumsum of g
    if (tid < HD) {
        float L = 0.f;
        for (int t = 0; t < CH; ++t) { L += Qp[t * RP + tid]; Qp[t * RP + tid] = L; }
    }
    __syncthreads();

    // P2: kappa, kappa_tilde (bf16), q', Bc
    for (int e = tid; e < CH * HD; e += 256) {
        const int t = e / HD, c = e % HD;
        const float L = Qp[t * RP + c];
        const float B = expf(L), iB = expf(-L);
        const float kv = bf2f(Kb[t * KP + c]);
        if (t == CH - 1) Bc[((size_t)bh * NCH + ch) * HD + c] = B;
        Kk[t * KP + c] = f2bf(kv * B);
        const unsigned short kti = f2bf(kv * iB);
        const float qv = q[base + t * 768 + c];
        Kb[t * KP + c] = kti;
        Kbf[base + t * 768 + c] = kti;            // kappa_tilde out (bf16)
        Qp[t * RP + c] = qv * B;                  // q'
    }
    __syncthreads();

    // P3 (MFMA): A[t][i] = beta_t * (kappa_t . ktil_i), i < t
    {
        const int lane = tid & 63;
        const int lr = lane & 15, lh = lane >> 4;
        const int t0 = (tid >> 6) * 16;
        bf16x8 afr[3];
#pragma unroll
        for (int ks = 0; ks < 3; ++ks)
            afr[ks] = *(const bf16x8*)&Kk[(t0 + lr) * KP + ks * 32 + lh * 8];
#pragma unroll
        for (int i0 = 0; i0 < 64; i0 += 16) {
            f32x4 acc = (f32x4){0.f, 0.f, 0.f, 0.f};
#pragma unroll
            for (int ks = 0; ks < 3; ++ks) {
                const bf16x8 bfr = *(const bf16x8*)&Kb[(i0 + lr) * KP + ks * 32 + lh * 8];
                acc = __builtin_amdgcn_mfma_f32_16x16x32_bf16(afr[ks], bfr, acc, 0, 0, 0);
            }
#pragma unroll
            for (int r = 0; r < 4; ++r) {
                const int t = t0 + lh * 4 + r;
                const int i = i0 + lr;
                Am[t][i] = (i < t) ? acc[r] * sb[t] : 0.f;
            }
        }
    }
    __syncthreads();

    // P4: forward solve, column j of [U | W] in registers
    float X[CH];
    const int j = tid;
    if (j < 192) {
        if (j < HD) {
#pragma unroll
            for (int t = 0; t < CH; ++t) X[t] = sb[t] * v[base + t * 768 + j];
        } else {
#pragma unroll
            for (int t = 0; t < CH; ++t) X[t] = sb[t] * bf2f(Kk[t * KP + (j - HD)]);
        }
#pragma unroll
        for (int t = 1; t < CH; ++t) {
            float a0 = 0, a1 = 0, a2 = 0, a3 = 0;
#pragma unroll
            for (int i4 = 0; i4 * 4 < t; ++i4) {
                const float4 a = *(const float4*)&Am[t][i4 * 4];
                if (i4 * 4 + 0 < t) a0 = fmaf(a.x, X[i4 * 4 + 0], a0);
                if (i4 * 4 + 1 < t) a1 = fmaf(a.y, X[i4 * 4 + 1], a1);
                if (i4 * 4 + 2 < t) a2 = fmaf(a.z, X[i4 * 4 + 2], a2);
                if (i4 * 4 + 3 < t) a3 = fmaf(a.w, X[i4 * 4 + 3], a3);
            }
            X[t] -= ((a0 + a1) + (a2 + a3));
        }
        // P5: store U (f32 over v) / W (bf16)
        if (j < HD) {
#pragma unroll
            for (int t = 0; t < CH; ++t) v[base + t * 768 + j] = X[t];
        } else {
#pragma unroll
            for (int t = 0; t < CH; ++t) Wbf[base + t * 768 + (j - HD)] = f2bf(X[t]);
        }
    }
    __syncthreads();

    // P6 (MFMA): T[t][i] = q'_t . ktil_i, i <= t   (q' rounded to bf16)
    {
        const int lane = tid & 63;
        const int lr = lane & 15, lh = lane >> 4;
        const int t0 = (tid >> 6) * 16;
        bf16x8 afr[3];
#pragma unroll
        for (int ks = 0; ks < 3; ++ks) {
            const float4 qa = *(const float4*)&Qp[(t0 + lr) * RP + ks * 32 + lh * 8];
            const float4 qc = *(const float4*)&Qp[(t0 + lr) * RP + ks * 32 + lh * 8 + 4];
            bf16x8 a;
            a[0] = (short)f2bf(qa.x); a[1] = (short)f2bf(qa.y);
            a[2] = (short)f2bf(qa.z); a[3] = (short)f2bf(qa.w);
            a[4] = (short)f2bf(qc.x); a[5] = (short)f2bf(qc.y);
            a[6] = (short)f2bf(qc.z); a[7] = (short)f2bf(qc.w);
            afr[ks] = a;
        }
#pragma unroll
        for (int i0 = 0; i0 < 64; i0 += 16) {
            f32x4 acc = (f32x4){0.f, 0.f, 0.f, 0.f};
#pragma unroll
            for (int ks = 0; ks < 3; ++ks) {
                const bf16x8 bfr = *(const bf16x8*)&Kb[(i0 + lr) * KP + ks * 32 + lh * 8];
                acc = __builtin_amdgcn_mfma_f32_16x16x32_bf16(afr[ks], bfr, acc, 0, 0, 0);
            }
#pragma unroll
            for (int r = 0; r < 4; ++r) {
                const int t = t0 + lh * 4 + r;
                const int i = i0 + lr;
                Am[t][i] = (i <= t) ? acc[r] : 0.f;
            }
        }
    }
    __syncthreads();

    // P7: T @ X -> Ol (j<96) ; Qe = q' - T@W (j>=96, over g)
    if (j < 192) {
        for (int t = 0; t < CH; ++t) {
            float a0 = 0, a1 = 0, a2 = 0, a3 = 0;
#pragma unroll
            for (int i4 = 0; i4 < 16; ++i4) {
                const float4 a = *(const float4*)&Am[t][i4 * 4];
                a0 = fmaf(a.x, X[i4 * 4 + 0], a0); a1 = fmaf(a.y, X[i4 * 4 + 1], a1);
                a2 = fmaf(a.z, X[i4 * 4 + 2], a2); a3 = fmaf(a.w, X[i4 * 4 + 3], a3);
            }
            const float acc = (a0 + a1) + (a2 + a3);
            if (j < HD) ol[base + t * 768 + j] = f2bf(acc);
            else        g[base + t * 768 + (j - HD)] = Qp[t * RP + (j - HD)] - acc;
        }
    }
}

// ---------------------------------------------------------------- KDA sequential recurrence (parallel form, exact)
constexpr int VSL = 16;  // v-slice per block
constexpr int SP = 20;   // Sl/Dl/Ul row pad (floats)
__global__ __launch_bounds__(256)
void kda_seq(const unsigned short* __restrict__ Wbf, const unsigned short* __restrict__ Kbf,
             const float* __restrict__ U, const float* __restrict__ Bc,
             float* __restrict__ Sin, float* __restrict__ states)
{
    __shared__ float Wl[CH * 97];
    __shared__ float Kl[CH * 97];
    __shared__ float Sl[96 * SP];
    __shared__ float Dl[CH * SP];
    __shared__ float Ul[CH * SP];

    const int blk = blockIdx.x;
    const int bh = blk / 6, vq = blk - bh * 6;
    const int b = bh >> 3, h = bh & 7;
    const int tid = threadIdx.x;
    const int ta = tid & 63, vga = tid >> 6;   // step A: row t, v-quad
    const int kb = tid & 31, vB = tid >> 5;    // step B: k-base, v-pair (0..7)
    const int v0 = vq * VSL;
    const size_t base = (size_t)b * (TT * HH * HD) + h * HD;

    for (int e = tid; e < 96 * SP; e += 256) Sl[e] = 0.f;

    u16x8 wpf[3], kpf[3];
    f32x4 upf;

    // stage chunk 0
    {
#pragma unroll
        for (int i = 0; i < 3; ++i) {
            const int g = i * 256 + tid;
            const int r = g / 12, c8 = (g % 12) * 8;
            wpf[i] = *(const u16x8*)(Wbf + base + (size_t)r * 768 + c8);
            kpf[i] = *(const u16x8*)(Kbf + base + (size_t)r * 768 + c8);
        }
        const int t = tid >> 2, c4 = (tid & 3) * 4;
        upf = *(const f32x4*)(U + base + (size_t)t * 768 + v0 + c4);
#pragma unroll
        for (int i = 0; i < 3; ++i) {
            const int g = i * 256 + tid;
            const int r = g / 12, c8 = (g % 12) * 8;
#pragma unroll
            for (int j = 0; j < 8; ++j) {
                Wl[r * 97 + c8 + j] = bf2f((unsigned short)wpf[i][j]);
                Kl[r * 97 + c8 + j] = bf2f((unsigned short)kpf[i][j]);
            }
        }
        *(f32x4*)&Ul[t * SP + c4] = upf;
    }
    __syncthreads();

    for (int ch = 0; ch < NCH; ++ch) {
        // prefetch next chunk into registers
        if (ch + 1 < NCH) {
            const size_t cb = base + (size_t)((ch + 1) * CH) * (HH * HD);
#pragma unroll
            for (int i = 0; i < 3; ++i) {
                const int g = i * 256 + tid;
                const int r = g / 12, c8 = (g % 12) * 8;
                wpf[i] = *(const u16x8*)(Wbf + cb + (size_t)r * 768 + c8);
                kpf[i] = *(const u16x8*)(Kbf + cb + (size_t)r * 768 + c8);
            }
            const int t = tid >> 2, c4 = (tid & 3) * 4;
            upf = *(const f32x4*)(U + cb + (size_t)t * 768 + v0 + c4);
        }
        // store S_in for the O-epilogue
        {
            float* sg = Sin + (size_t)(bh * NCH + ch) * (HD * HD);
#pragma unroll
            for (int i = 0; i < 2; ++i) {
                const int e = i * 256 + tid;
                if (e < 384) {
                    const int kk = e >> 2, c4 = (e & 3) * 4;
                    *(f32x4*)(sg + (size_t)kk * HD + v0 + c4) = *(const f32x4*)&Sl[kk * SP + c4];
                }
            }
        }
        // step A: Dl[t][v] = Ul - sum_k Wl[t][k] * Sl[k][v]
        {
            f32x4 acc = *(const f32x4*)&Ul[ta * SP + vga * 4];
            const float* wr = &Wl[ta * 97];
#pragma unroll 8
            for (int kk = 0; kk < 96; ++kk)
                acc -= wr[kk] * *(const f32x4*)&Sl[kk * SP + vga * 4];
            *(f32x4*)&Dl[ta * SP + vga * 4] = acc;
        }
        __syncthreads();
        // step B: S[k][v] = (S[k][v] + sum_t Kl[t][k]*Dl[t][v]) * Bc[k]
        {
            float a0[2] = {0.f, 0.f}, a1[2] = {0.f, 0.f}, a2[2] = {0.f, 0.f};
#pragma unroll 8
            for (int t = 0; t < CH; ++t) {
                const float d0 = Dl[t * SP + vB * 2];
                const float d1 = Dl[t * SP + vB * 2 + 1];
                const float k0 = Kl[t * 97 + kb];
                const float k1 = Kl[t * 97 + kb + 32];
                const float k2 = Kl[t * 97 + kb + 64];
                a0[0] = fmaf(k0, d0, a0[0]); a0[1] = fmaf(k0, d1, a0[1]);
                a1[0] = fmaf(k1, d0, a1[0]); a1[1] = fmaf(k1, d1, a1[1]);
                a2[0] = fmaf(k2, d0, a2[0]); a2[1] = fmaf(k2, d1, a2[1]);
            }
            const float* bc = Bc + ((size_t)bh * NCH + ch) * HD;
            const float b0 = bc[kb], b1 = bc[kb + 32], b2 = bc[kb + 64];
#pragma unroll
            for (int e = 0; e < 2; ++e) {
                const int v = vB * 2 + e;
                Sl[kb * SP + v]        = (Sl[kb * SP + v]        + a0[e]) * b0;
                Sl[(kb + 32) * SP + v] = (Sl[(kb + 32) * SP + v] + a1[e]) * b1;
                Sl[(kb + 64) * SP + v] = (Sl[(kb + 64) * SP + v] + a2[e]) * b2;
            }
        }
        __syncthreads();
        // write staged regs -> LDS for next chunk
        if (ch + 1 < NCH) {
#pragma unroll
            for (int i = 0; i < 3; ++i) {
                const int g = i * 256 + tid;
                const int r = g / 12, c8 = (g % 12) * 8;
#pragma unroll
                for (int j = 0; j < 8; ++j) {
                    Wl[r * 97 + c8 + j] = bf2f((unsigned short)wpf[i][j]);
                    Kl[r * 97 + c8 + j] = bf2f((unsigned short)kpf[i][j]);
                }
            }
            const int t = tid >> 2, c4 = (tid & 3) * 4;
            *(f32x4*)&Ul[t * SP + c4] = upf;
            __syncthreads();
        }
    }
    // final states
    {
        float* sp = states + (size_t)bh * (HD * HD);
#pragma unroll
        for (int i = 0; i < 2; ++i) {
            const int e = i * 256 + tid;
            if (e < 384) {
                const int kk = e >> 2, c4 = (e & 3) * 4;
                *(f32x4*)(sp + (size_t)kk * HD + v0 + c4) = *(const f32x4*)&Sl[kk * SP + c4];
            }
        }
    }
}

// ---------------------------------------------------------------- KDA parallel O epilogue
__global__ __launch_bounds__(256)
void kda_epi(const float* __restrict__ Sin, const float* __restrict__ Qe,
             const unsigned short* __restrict__ Ol, const unsigned short* __restrict__ Gt,
             const float* __restrict__ onw, unsigned short* __restrict__ obf)
{
    __shared__ float Sl[96 * 100];
    __shared__ float Ql[64 * 100];
    __shared__ unsigned short Olb[64 * 104];
    __shared__ unsigned short Gl[64 * 104];

    const int bx = blockIdx.x;
    const int bh = bx >> 5, ch = bx & 31;
    const int b = bh >> 3, h = bh & 7;
    const int tid = threadIdx.x;
    const size_t cb = (size_t)b * (TT * HH * HD) + (size_t)(ch * CH) * (HH * HD) + h * HD;
    const float* Sg = Sin + (size_t)(bh * NCH + ch) * HD * HD;

#pragma unroll
    for (int i = 0; i < 9; ++i) {
        const int g = i * 256 + tid;
        const int k = g / 24, c4 = (g % 24) * 4;
        *(f32x4*)&Sl[k * 100 + c4] = *(const f32x4*)(Sg + (size_t)k * HD + c4);
    }
#pragma unroll
    for (int i = 0; i < 6; ++i) {
        const int g = i * 256 + tid;
        const int t = g / 24, c4 = (g % 24) * 4;
        *(f32x4*)&Ql[t * 100 + c4] = *(const f32x4*)(Qe + cb + (size_t)t * 768 + c4);
    }
#pragma unroll
    for (int i = 0; i < 3; ++i) {
        const int g = i * 256 + tid;
        const int t = g / 12, c8 = (g % 12) * 8;
        *(u16x8*)&Olb[t * 104 + c8] = *(const u16x8*)(Ol + cb + (size_t)t * 768 + c8);
        *(u16x8*)&Gl[t * 104 + c8]  = *(const u16x8*)(Gt + cb + (size_t)t * 768 + c8);
    }
    __syncthreads();

    const int t = tid >> 2, vq2 = tid & 3;
    const int v0 = vq2 * 24;
    f32x4 acc[6];
#pragma unroll
    for (int j = 0; j < 6; ++j) {
        acc[j].x = bf2f(Olb[t * 104 + v0 + j * 4 + 0]);
        acc[j].y = bf2f(Olb[t * 104 + v0 + j * 4 + 1]);
        acc[j].z = bf2f(Olb[t * 104 + v0 + j * 4 + 2]);
        acc[j].w = bf2f(Olb[t * 104 + v0 + j * 4 + 3]);
    }
#pragma unroll 2
    for (int k = 0; k < HD; ++k) {
        const float qv = Ql[t * 100 + k];
#pragma unroll
        for (int j = 0; j < 6; ++j)
            acc[j] += qv * *(const f32x4*)&Sl[k * 100 + v0 + j * 4];
    }
    float ss = 0.f;
#pragma unroll
    for (int j = 0; j < 6; ++j)
        ss += acc[j].x * acc[j].x + acc[j].y * acc[j].y + acc[j].z * acc[j].z + acc[j].w * acc[j].w;
    ss += __shfl_xor(ss, 1); ss += __shfl_xor(ss, 2);
    const float r = rsqrtf(ss * (1.f / HD) + 1e-6f);
#pragma unroll
    for (int j = 0; j < 6; ++j) {
#pragma unroll
        for (int e = 0; e < 4; ++e) {
            const int v = v0 + j * 4 + e;
            const float g = bf2f(Gl[t * 104 + v]);
            const float val = acc[j][e] * r * onw[v] * (g / (1.f + expf(-g)));
            obf[cb + (size_t)t * 768 + v] = f2bf(val);
        }
    }
}

// ---------------------------------------------------------------- host
extern "C" void kernel_launch(void* const* d_in, const int* in_sizes, int n_in,
                              void* d_out, int out_size, void* d_ws, size_t ws_size,
                              hipStream_t stream)
{
    (void)in_sizes; (void)n_in; (void)out_size; (void)ws_size;
    const float* hidden   = (const float*)d_in[0];
    const float* mask     = (const float*)d_in[1];
    const float* norm_a_w = (const float*)d_in[2];
    const float* norm_a_b = (const float*)d_in[3];
    const float* proj_a_w = (const float*)d_in[4];
    const float* proj_a_b = (const float*)d_in[5];
    const float* ln_w     = (const float*)d_in[6];
    const float* ln_b     = (const float*)d_in[7];
    const float* Wq       = (const float*)d_in[8];
    const float* Wk       = (const float*)d_in[9];
    const float* Wv       = (const float*)d_in[10];
    const float* Wfa      = (const float*)d_in[11];
    const float* Wfb      = (const float*)d_in[12];
    const float* dt_bias  = (const float*)d_in[13];
    const float* A_log    = (const float*)d_in[14];
    const float* Wb       = (const float*)d_in[15];
    const float* Wga      = (const float*)d_in[16];
    const float* Wgb      = (const float*)d_in[17];
    const float* onorm_w  = (const float*)d_in[18];
    const float* Wo       = (const float*)d_in[19];
    const float* Wgate    = (const float*)d_in[20];
    const float* Wup      = (const float*)d_in[21];
    const float* Wdown    = (const float*)d_in[22];

    float* ws    = (float*)d_ws;
    float* hbuf  = ws;
    float* qb    = ws + HROW;          // dead after pre -> Sin/mg live here
    float* kb    = ws + 2 * HROW;
    float* vb    = ws + 3 * HROW;      // U (f32)
    float* egb   = ws + 4 * HROW;      // g -> Qe (f32)
    float* betab = ws + 5 * HROW;                     // MM*HH
    float* BcP   = betab + (size_t)MM * HH;           // 32*32*96
    float* SinP  = qb;                                // 9.44M floats (qb+kb region)
    unsigned short* bfp = (unsigned short*)(BcP + 32 * NCH * HD);
    unsigned short* x_bf    = bfp;  bfp += HROW;
    unsigned short* fab_bf  = bfp;  bfp += (size_t)MM * HD;
    unsigned short* gab_bf  = bfp;  bfp += (size_t)MM * HD;
    unsigned short* gate_bf = bfp;  bfp += HROW;
    unsigned short* olb_bf  = bfp;  bfp += HROW;
    unsigned short* w_bf    = bfp;  bfp += HROW;
    unsigned short* k_bf    = bfp;  bfp += HROW;
    unsigned short* wt_proj = bfp;  bfp += 768 * 768;
    unsigned short *wt_q[LL], *wt_k[LL], *wt_v[LL], *wt_o[LL], *wt_fb[LL], *wt_gb[LL],
                   *wt_fg[LL], *wt_gate[LL], *wt_up[LL], *wt_down[LL];
    for (int l = 0; l < LL; ++l) {
        wt_q[l] = bfp;    bfp += 768 * 768;   // q,k,v contiguous -> fused N=2304 GEMM
        wt_k[l] = bfp;    bfp += 768 * 768;
        wt_v[l] = bfp;    bfp += 768 * 768;
        wt_o[l] = bfp;    bfp += 768 * 768;
        wt_fb[l] = bfp;   bfp += 768 * 96;
        wt_gb[l] = bfp;   bfp += 768 * 96;
        wt_fg[l] = bfp;   bfp += 192 * 768;   // [Wfa^T | Wga^T]
        wt_gate[l] = bfp; bfp += 2048 * 768;
        wt_up[l] = bfp;   bfp += 2048 * 768;
        wt_down[l] = bfp; bfp += 768 * 2048;
    }
    unsigned short* mg_bf = (unsigned short*)SinP;  // Sin dead after epi
    unsigned short* a_bf  = (unsigned short*)vb;    // U dead after seq

    float* out    = (float*)d_out;
    float* states = out + HROW;

    // weight transpose+convert
    transcvt<<<dim3(24, 24), 256, 0, stream>>>(proj_a_w, wt_proj, 768, 768);
    for (int l = 0; l < LL; ++l) {
        transcvt<<<dim3(24, 24), 256, 0, stream>>>(Wq + (size_t)l * 589824, wt_q[l], 768, 768);
        transcvt<<<dim3(24, 24), 256, 0, stream>>>(Wk + (size_t)l * 589824, wt_k[l], 768, 768);
        transcvt<<<dim3(24, 24), 256, 0, stream>>>(Wv + (size_t)l * 589824, wt_v[l], 768, 768);
        transcvt<<<dim3(24, 24), 256, 0, stream>>>(Wo + (size_t)l * 589824, wt_o[l], 768, 768);
        transcvt<<<dim3(24, 3), 256, 0, stream>>>(Wfb + (size_t)l * 73728, wt_fb[l], 96, 768);
        transcvt<<<dim3(24, 3), 256, 0, stream>>>(Wgb + (size_t)l * 73728, wt_gb[l], 96, 768);
        transcvt<<<dim3(3, 24), 256, 0, stream>>>(Wfa + (size_t)l * 73728, wt_fg[l], 768, 96);
        transcvt<<<dim3(3, 24), 256, 0, stream>>>(Wga + (size_t)l * 73728, wt_fg[l] + 96 * 768, 768, 96);
        transcvt<<<dim3(64, 24), 256, 0, stream>>>(Wgate + (size_t)l * 1572864, wt_gate[l], 768, 2048);
        transcvt<<<dim3(64, 24), 256, 0, stream>>>(Wup + (size_t)l * 1572864, wt_up[l], 768, 2048);
        transcvt<<<dim3(24, 64), 256, 0, stream>>>(Wdown + (size_t)l * 1572864, wt_down[l], 2048, 768);
    }

    layernorm_rows<<<MM, 256, 0, stream>>>(hidden, x_bf, norm_a_w, norm_a_b, nullptr);
    bgemm<BE_BIAS><<<dim3(6, 64), 256, 0, stream>>>(x_bf, wt_proj, hbuf, nullptr,
                                                    proj_a_b, nullptr, MM, DD, DD);

    for (int l = 0; l < LL; ++l) {
        layernorm_rows<<<MM, 256, 0, stream>>>(hbuf, x_bf, ln_w + l * DD, ln_b + l * DD, mask);
        // fused q|k|v = silu(x @ [Wq|Wk|Wv]) -> qb, kb, vb
        bgemm<BE_QKV><<<dim3(18, 64), 256, 0, stream>>>(x_bf, wt_q[l], qb, nullptr,
                                                        kb, vb, MM, 3 * DD, DD);
        l2norm_rows<<<(MM * HH) / 4, 256, 0, stream>>>(qb, 0.1020620726159658f);
        l2norm_rows<<<(MM * HH) / 4, 256, 0, stream>>>(kb, 1.f);
        // fa|ga = x @ [Wfa|Wga]  (bf16, one MFMA dispatch)
        bgemm_fg<<<dim3(3, 64), 256, 0, stream>>>(x_bf, wt_fg[l], fab_bf, gab_bf, DD);
        bgemm<BE_EG><<<dim3(6, 64), 256, 0, stream>>>(fab_bf, wt_fb[l], egb, nullptr,
                                                      A_log + l * DD, dt_bias + l * DD, MM, DD, HD);
        gemm_small<1><<<dim3(1, 128), 256, 0, stream>>>(x_bf, Wb + (size_t)l * DD * HH, nullptr, betab, MM, HH, DD);
        // gate before scan (x_bf gets overwritten by o in epi)
        bgemm<BE_BF16><<<dim3(6, 64), 256, 0, stream>>>(gab_bf, wt_gb[l], nullptr, gate_bf, nullptr, nullptr, MM, DD, HD);
        // chunkwise scan
        kda_pre<<<1024, 256, 0, stream>>>(qb, kb, vb, egb, betab, olb_bf, BcP, w_bf, k_bf);
        kda_seq<<<192, 256, 0, stream>>>(w_bf, k_bf, vb, BcP, SinP,
                                         states + (size_t)l * BB * HH * HD * HD);
        kda_epi<<<1024, 256, 0, stream>>>(SinP, egb, olb_bf, gate_bf, onorm_w + l * HD, x_bf);
        // a = o @ Wo
        bgemm<BE_BF16><<<dim3(6, 64), 256, 0, stream>>>(x_bf, wt_o[l], nullptr, a_bf, nullptr, nullptr, MM, DD, DD);
        // swiglu
        bgemm_dual<<<dim3(32, 64), 256, 0, stream>>>(a_bf, wt_gate[l], wt_up[l], mg_bf, MM, FF, DD);
        float* dst = (l == LL - 1) ? out : hbuf;
        bgemm<BE_RES><<<dim3(6, 64), 256, 0, stream>>>(mg_bf, wt_down[l], dst, nullptr,
                                                       hbuf, nullptr, MM, DD, FF);
    }
}

// Round 10
// 1272.998 us; speedup vs baseline: 3.0842x; 1.1409x over previous
//
#include <hip/hip_runtime.h>
#include <cstddef>
#include <cstdint>
#include <cmath>

// Problem constants
constexpr int BB = 4, TT = 2048, DD = 768, HH = 8, HD = 96, FF = 2048, LL = 2;
constexpr int MM = BB * TT;              // 8192
constexpr size_t HROW = (size_t)MM * DD; // 6291456
constexpr int CH = 64;                   // scan chunk length
constexpr int NCH = TT / CH;             // 32 chunks per sequence
constexpr int RP = 100;                  // padded LDS row (floats)
constexpr int KP = 104;                  // padded LDS row (ushorts)

typedef float f32x4 __attribute__((ext_vector_type(4)));
typedef short bf16x8 __attribute__((ext_vector_type(8)));
typedef unsigned short u16x8 __attribute__((ext_vector_type(8)));

__device__ __forceinline__ void gload16(const void* g, void* l) {
    __builtin_amdgcn_global_load_lds(
        (const __attribute__((address_space(1))) void*)g,
        (__attribute__((address_space(3))) void*)l, 16, 0, 0);
}
__device__ __forceinline__ float bf2f(unsigned short u) {
    return __uint_as_float(((unsigned)u) << 16);
}
__device__ __forceinline__ unsigned short f2bf(float f) {
    unsigned u = __float_as_uint(f);
    unsigned r = (u + 0x7fffu + ((u >> 16) & 1u)) >> 16;
    return (unsigned short)r;
}

// ---------------------------------------------------------------- LayerNorm -> bf16
__global__ __launch_bounds__(256)
void layernorm_rows(const float* __restrict__ x, unsigned short* __restrict__ y,
                    const float* __restrict__ w, const float* __restrict__ b,
                    const float* mask)
{
    const int row = blockIdx.x;
    const int tid = threadIdx.x;
    const float* xr = x + (size_t)row * DD;
    float v0 = xr[tid], v1 = xr[tid + 256], v2 = xr[tid + 512];
    float s = v0 + v1 + v2;
    float ss = v0 * v0 + v1 * v1 + v2 * v2;
#pragma unroll
    for (int i = 1; i < 64; i <<= 1) { s += __shfl_xor(s, i); ss += __shfl_xor(ss, i); }
    __shared__ float red[8];
    const int wid = tid >> 6, lane = tid & 63;
    if (lane == 0) { red[wid] = s; red[4 + wid] = ss; }
    __syncthreads();
    const float S  = red[0] + red[1] + red[2] + red[3];
    const float SS = red[4] + red[5] + red[6] + red[7];
    const float mean = S * (1.f / DD);
    const float var  = SS * (1.f / DD) - mean * mean;
    const float rstd = rsqrtf(var + 1e-5f);
    const float m = mask ? mask[row] : 1.f;
    unsigned short* yr = y + (size_t)row * DD;
    yr[tid]       = f2bf(((v0 - mean) * rstd * w[tid]       + b[tid])       * m);
    yr[tid + 256] = f2bf(((v1 - mean) * rstd * w[tid + 256] + b[tid + 256]) * m);
    yr[tid + 512] = f2bf(((v2 - mean) * rstd * w[tid + 512] + b[tid + 512]) * m);
}

// ---------------------------------------------------------------- transpose+convert W
__global__ __launch_bounds__(256)
void transcvt(const float* __restrict__ in, unsigned short* __restrict__ out, int K, int N)
{
    __shared__ float t[32][33];
    const int tx = threadIdx.x & 31, ty = threadIdx.x >> 5;
    const int k0 = blockIdx.y * 32, n0 = blockIdx.x * 32;
#pragma unroll
    for (int i = 0; i < 4; ++i)
        t[ty + i * 8][tx] = in[(size_t)(k0 + ty + i * 8) * N + n0 + tx];
    __syncthreads();
#pragma unroll
    for (int i = 0; i < 4; ++i)
        out[(size_t)(n0 + ty + i * 8) * K + k0 + tx] = f2bf(t[tx][ty + i * 8]);
}

// ---------------------------------------------------------------- bf16 MFMA GEMM
enum { BE_BIAS = 0, BE_SILU, BE_EG, BE_F32, BE_BF16, BE_RES, BE_QKV };

template <int EPI>
__global__ __launch_bounds__(256)
void bgemm(const unsigned short* __restrict__ A, const unsigned short* __restrict__ Bt,
           float* Cf, unsigned short* Cb,
           const float* P0, const float* P1,
           int M, int N, int K)
{
    __shared__ unsigned short As[128 * 32];
    __shared__ unsigned short Bs[128 * 32];
    const int tid = threadIdx.x;
    const int w = tid >> 6, l = tid & 63;
    const int wm = w >> 1, wn = w & 1;
    const int lr = l & 15, lh = l >> 4;
    const int m0 = blockIdx.y * 128, n0 = blockIdx.x * 128;

    f32x4 acc[4][4];
#pragma unroll
    for (int i = 0; i < 4; ++i)
#pragma unroll
        for (int j = 0; j < 4; ++j) acc[i][j] = (f32x4){0.f, 0.f, 0.f, 0.f};

    const int sr = l >> 2, sq = (l & 3) * 8;
    const unsigned short* Ag = A + (size_t)(m0 + w * 32 + sr) * K + sq;
    const unsigned short* Bg = Bt + (size_t)(n0 + w * 32 + sr) * K + sq;
    unsigned short* Al = &As[(w * 32) * 32];
    unsigned short* Bl = &Bs[(w * 32) * 32];

    for (int kt = 0; kt < K; kt += 32) {
        __syncthreads();
        gload16(Ag + kt, Al);
        gload16(Ag + kt + 16 * (size_t)K, Al + 16 * 32);
        gload16(Bg + kt, Bl);
        gload16(Bg + kt + 16 * (size_t)K, Bl + 16 * 32);
        __syncthreads();
        bf16x8 af[4], bfv[4];
#pragma unroll
        for (int mi = 0; mi < 4; ++mi)
            af[mi] = *(const bf16x8*)&As[(wm * 64 + mi * 16 + lr) * 32 + lh * 8];
#pragma unroll
        for (int ni = 0; ni < 4; ++ni)
            bfv[ni] = *(const bf16x8*)&Bs[(wn * 64 + ni * 16 + lr) * 32 + lh * 8];
#pragma unroll
        for (int mi = 0; mi < 4; ++mi)
#pragma unroll
            for (int ni = 0; ni < 4; ++ni)
                acc[mi][ni] = __builtin_amdgcn_mfma_f32_16x16x32_bf16(af[mi], bfv[ni], acc[mi][ni], 0, 0, 0);
    }

#pragma unroll
    for (int mi = 0; mi < 4; ++mi) {
#pragma unroll
        for (int j = 0; j < 4; ++j) {
            const int row = m0 + wm * 64 + mi * 16 + lh * 4 + j;
#pragma unroll
            for (int ni = 0; ni < 4; ++ni) {
                const int col = n0 + wn * 64 + ni * 16 + lr;
                const size_t idx = (size_t)row * N + col;
                float v = acc[mi][ni][j];
                if constexpr (EPI == BE_BIAS) { Cf[idx] = v + P0[col]; }
                else if constexpr (EPI == BE_SILU) { Cf[idx] = v / (1.f + expf(-v)); }
                else if constexpr (EPI == BE_EG) {
                    const float lin = v + P1[col];
                    const float sp = (lin > 20.f) ? lin : log1pf(expf(lin));
                    Cf[idx] = -expf(P0[col]) * sp;      // raw log-decay g
                }
                else if constexpr (EPI == BE_F32) { Cf[idx] = v; }
                else if constexpr (EPI == BE_BF16) { Cb[idx] = f2bf(v); }
                else if constexpr (EPI == BE_RES) { Cf[idx] = v + P0[idx]; }
                else if constexpr (EPI == BE_QKV) {
                    const int tgt = col / 768;
                    const int cl = col - tgt * 768;
                    float* dst = (tgt == 0) ? Cf
                               : (tgt == 1) ? const_cast<float*>(P0)
                                            : const_cast<float*>(P1);
                    dst[(size_t)row * 768 + cl] = v / (1.f + expf(-v));
                }
            }
        }
    }
}

// Dual-B GEMM for SwiGLU
__global__ __launch_bounds__(256)
void bgemm_dual(const unsigned short* __restrict__ A,
                const unsigned short* __restrict__ Bg_, const unsigned short* __restrict__ Bu_,
                unsigned short* __restrict__ C, int M, int N, int K)
{
    __shared__ unsigned short As[128 * 32];
    __shared__ unsigned short Bs1[64 * 32];
    __shared__ unsigned short Bs2[64 * 32];
    const int tid = threadIdx.x;
    const int w = tid >> 6, l = tid & 63;
    const int wm = w >> 1, wn = w & 1;
    const int lr = l & 15, lh = l >> 4;
    const int m0 = blockIdx.y * 128, n0 = blockIdx.x * 64;

    f32x4 a1[4][2], a2[4][2];
#pragma unroll
    for (int i = 0; i < 4; ++i)
#pragma unroll
        for (int j = 0; j < 2; ++j) { a1[i][j] = (f32x4){0.f,0.f,0.f,0.f}; a2[i][j] = (f32x4){0.f,0.f,0.f,0.f}; }

    const int sr = l >> 2, sq = (l & 3) * 8;
    const unsigned short* Ag  = A   + (size_t)(m0 + w * 32 + sr) * K + sq;
    const unsigned short* B1g = Bg_ + (size_t)(n0 + w * 16 + sr) * K + sq;
    const unsigned short* B2g = Bu_ + (size_t)(n0 + w * 16 + sr) * K + sq;
    unsigned short* Al  = &As[(w * 32) * 32];
    unsigned short* B1l = &Bs1[(w * 16) * 32];
    unsigned short* B2l = &Bs2[(w * 16) * 32];

    for (int kt = 0; kt < K; kt += 32) {
        __syncthreads();
        gload16(Ag + kt, Al);
        gload16(Ag + kt + 16 * (size_t)K, Al + 16 * 32);
        gload16(B1g + kt, B1l);
        gload16(B2g + kt, B2l);
        __syncthreads();
        bf16x8 af[4], b1[2], b2[2];
#pragma unroll
        for (int mi = 0; mi < 4; ++mi)
            af[mi] = *(const bf16x8*)&As[(wm * 64 + mi * 16 + lr) * 32 + lh * 8];
#pragma unroll
        for (int ni = 0; ni < 2; ++ni) {
            b1[ni] = *(const bf16x8*)&Bs1[(wn * 32 + ni * 16 + lr) * 32 + lh * 8];
            b2[ni] = *(const bf16x8*)&Bs2[(wn * 32 + ni * 16 + lr) * 32 + lh * 8];
        }
#pragma unroll
        for (int mi = 0; mi < 4; ++mi)
#pragma unroll
            for (int ni = 0; ni < 2; ++ni) {
                a1[mi][ni] = __builtin_amdgcn_mfma_f32_16x16x32_bf16(af[mi], b1[ni], a1[mi][ni], 0, 0, 0);
                a2[mi][ni] = __builtin_amdgcn_mfma_f32_16x16x32_bf16(af[mi], b2[ni], a2[mi][ni], 0, 0, 0);
            }
    }

#pragma unroll
    for (int mi = 0; mi < 4; ++mi)
#pragma unroll
        for (int j = 0; j < 4; ++j) {
            const int row = m0 + wm * 64 + mi * 16 + lh * 4 + j;
#pragma unroll
            for (int ni = 0; ni < 2; ++ni) {
                const int col = n0 + wn * 32 + ni * 16 + lr;
                const float g = a1[mi][ni][j], u = a2[mi][ni][j];
                C[(size_t)row * N + col] = f2bf((g / (1.f + expf(-g))) * u);
            }
        }
}

// fa|ga fused GEMM: N fixed 192 ([Wfa|Wga]^T), routing epilogue -> two bf16 buffers.
__global__ __launch_bounds__(256)
void bgemm_fg(const unsigned short* __restrict__ A, const unsigned short* __restrict__ Bt,
              unsigned short* __restrict__ Cfa, unsigned short* __restrict__ Cga, int K)
{
    __shared__ unsigned short As[128 * 32];
    __shared__ unsigned short Bs[64 * 32];
    const int tid = threadIdx.x;
    const int w = tid >> 6, l = tid & 63;
    const int wm = w >> 1, wn = w & 1;
    const int lr = l & 15, lh = l >> 4;
    const int m0 = blockIdx.y * 128, n0 = blockIdx.x * 64;

    f32x4 acc[4][2];
#pragma unroll
    for (int i = 0; i < 4; ++i)
#pragma unroll
        for (int j = 0; j < 2; ++j) acc[i][j] = (f32x4){0.f, 0.f, 0.f, 0.f};

    const int sr = l >> 2, sq = (l & 3) * 8;
    const unsigned short* Ag = A + (size_t)(m0 + w * 32 + sr) * K + sq;
    const unsigned short* Bg = Bt + (size_t)(n0 + w * 16 + sr) * K + sq;
    unsigned short* Al = &As[(w * 32) * 32];
    unsigned short* Bl = &Bs[(w * 16) * 32];

    for (int kt = 0; kt < K; kt += 32) {
        __syncthreads();
        gload16(Ag + kt, Al);
        gload16(Ag + kt + 16 * (size_t)K, Al + 16 * 32);
        gload16(Bg + kt, Bl);
        __syncthreads();
        bf16x8 af[4], bfv[2];
#pragma unroll
        for (int mi = 0; mi < 4; ++mi)
            af[mi] = *(const bf16x8*)&As[(wm * 64 + mi * 16 + lr) * 32 + lh * 8];
#pragma unroll
        for (int ni = 0; ni < 2; ++ni)
            bfv[ni] = *(const bf16x8*)&Bs[(wn * 32 + ni * 16 + lr) * 32 + lh * 8];
#pragma unroll
        for (int mi = 0; mi < 4; ++mi)
#pragma unroll
            for (int ni = 0; ni < 2; ++ni)
                acc[mi][ni] = __builtin_amdgcn_mfma_f32_16x16x32_bf16(af[mi], bfv[ni], acc[mi][ni], 0, 0, 0);
    }

#pragma unroll
    for (int mi = 0; mi < 4; ++mi)
#pragma unroll
        for (int j = 0; j < 4; ++j) {
            const int row = m0 + wm * 64 + mi * 16 + lh * 4 + j;
#pragma unroll
            for (int ni = 0; ni < 2; ++ni) {
                const int col = n0 + wn * 32 + ni * 16 + lr;   // 0..191, 16-aligned tiles
                const int tgt = (col >= HD);
                const int cl = col - (tgt ? HD : 0);
                unsigned short* dst = tgt ? Cga : Cfa;
                dst[(size_t)row * HD + cl] = f2bf(acc[mi][ni][j]);
            }
        }
}

// ---------------------------------------------------------------- small fp32 GEMM (A bf16)
template <int MODE>
__global__ __launch_bounds__(256)
void gemm_small(const unsigned short* __restrict__ A, const float* __restrict__ Bm,
                unsigned short* Cb, float* Cf, int M, int N, int K)
{
    __shared__ float As[16][64];
    __shared__ float Bs[16][64];
    const int tid = threadIdx.x;
    const int tx = tid & 15, ty = tid >> 4;
    const int row0 = blockIdx.y * 64;
    const int col0 = blockIdx.x * 64;
    float acc[4][4] = {};
    const int ar  = tid >> 2;
    const int ac4 = (tid & 3) << 2;
    const int br  = tid >> 4;
    const int bc  = (tid & 15) << 2;
    const int gc  = col0 + bc;
    const bool bok = gc < N;

    for (int kt = 0; kt < K; kt += 16) {
        const ushort4 a4 = *(const ushort4*)(A + (size_t)(row0 + ar) * K + kt + ac4);
        float4 b4 = make_float4(0.f, 0.f, 0.f, 0.f);
        if (bok) b4 = *(const float4*)(Bm + (size_t)(kt + br) * N + gc);
        __syncthreads();
        As[ac4 + 0][ar] = bf2f(a4.x); As[ac4 + 1][ar] = bf2f(a4.y);
        As[ac4 + 2][ar] = bf2f(a4.z); As[ac4 + 3][ar] = bf2f(a4.w);
        *(float4*)&Bs[br][bc] = b4;
        __syncthreads();
#pragma unroll
        for (int kk = 0; kk < 16; ++kk) {
            const float4 av = *(const float4*)&As[kk][ty << 2];
            const float4 bv = *(const float4*)&Bs[kk][tx << 2];
            const float a_[4] = {av.x, av.y, av.z, av.w};
            const float b_[4] = {bv.x, bv.y, bv.z, bv.w};
#pragma unroll
            for (int i = 0; i < 4; ++i)
#pragma unroll
                for (int j = 0; j < 4; ++j)
                    acc[i][j] = fmaf(a_[i], b_[j], acc[i][j]);
        }
    }
#pragma unroll
    for (int i = 0; i < 4; ++i) {
        const int row = row0 + (ty << 2) + i;
#pragma unroll
        for (int j = 0; j < 4; ++j) {
            const int col = col0 + (tx << 2) + j;
            if (col >= N) continue;
            const size_t idx = (size_t)row * N + col;
            if constexpr (MODE == 0) Cb[idx] = f2bf(acc[i][j]);
            else                     Cf[idx] = 1.f / (1.f + expf(-acc[i][j]));
        }
    }
}

// ---------------------------------------------------------------- l2norm over HD=96
__global__ __launch_bounds__(256)
void l2norm_rows(float* x, float scale)
{
    const int row  = (blockIdx.x << 2) + (threadIdx.x >> 6);
    const int lane = threadIdx.x & 63;
    float* xr = x + (size_t)row * HD;
    const float a = xr[lane];
    const float b = (lane < 32) ? xr[64 + lane] : 0.f;
    float ss = a * a + b * b;
#pragma unroll
    for (int i = 1; i < 64; i <<= 1) ss += __shfl_xor(ss, i);
    const float r = rsqrtf(ss + 1e-6f) * scale;
    xr[lane] = a * r;
    if (lane < 32) xr[64 + lane] = b * r;
}

// ---------------------------------------------------------------- KDA chunkwise precompute
// Emits: -W (bf16, row-major) -> Wbf; ktil^T (bf16, [c][t]) -> Ktg; U (f32 over v);
// Qe (f32 over g); Ol (bf16); Bc.
__global__ __launch_bounds__(256)
void kda_pre(const float* __restrict__ q, const float* __restrict__ k, float* v, float* g,
             const float* __restrict__ beta,
             unsigned short* __restrict__ ol, float* __restrict__ Bc,
             unsigned short* __restrict__ Wbf, unsigned short* __restrict__ Ktg)
{
    __shared__ unsigned short Kb[CH * KP];   // k (bf16), then kappa_tilde (bf16)
    __shared__ unsigned short Kk[CH * KP];   // kappa (bf16)
    __shared__ float Qp[CH * RP];            // g -> L -> q'
    __shared__ float Am[CH][68];
    __shared__ float sb[CH];

    const int blk = blockIdx.x;
    const int ch = blk & 31, bh = blk >> 5;
    const int b = bh >> 3, h = bh & 7;
    const int tid = threadIdx.x;
    const size_t base = (size_t)b * (TT * HH * HD) + (size_t)(ch * CH) * (HH * HD) + h * HD;

    // P0: stage k (as bf16), g (f32), beta
    for (int e = tid; e < CH * 24; e += 256) {
        const int t = e / 24, c4 = (e % 24) * 4;
        const float4 kv = *(const float4*)(k + base + t * 768 + c4);
        ushort4 k4;
        k4.x = f2bf(kv.x); k4.y = f2bf(kv.y); k4.z = f2bf(kv.z); k4.w = f2bf(kv.w);
        *(ushort4*)&Kb[t * KP + c4] = k4;
        *(float4*)&Qp[t * RP + c4] = *(const float4*)(g + base + t * 768 + c4);
    }
    if (tid < CH) sb[tid] = beta[((size_t)b * TT + ch * CH + tid) * HH + h];
    __syncthreads();

    // P1: per-channel cumsum of g
    if (tid < HD) {
        float L = 0.f;
        for (int t = 0; t < CH; ++t) { L += Qp[t * RP + tid]; Qp[t * RP + tid] = L; }
    }
    __syncthreads();

    // P2: kappa, kappa_tilde (bf16), q', Bc
    for (int e = tid; e < CH * HD; e += 256) {
        const int t = e / HD, c = e % HD;
        const float L = Qp[t * RP + c];
        const float B = expf(L), iB = expf(-L);
        const float kv = bf2f(Kb[t * KP + c]);
        if (t == CH - 1) Bc[((size_t)bh * NCH + ch) * HD + c] = B;
        Kk[t * KP + c] = f2bf(kv * B);
        const unsigned short kti = f2bf(kv * iB);
        const float qv = q[base + t * 768 + c];
        Kb[t * KP + c] = kti;
        Qp[t * RP + c] = qv * B;                  // q'
    }
    __syncthreads();

    // P2b: export ktil^T -> Ktg[(bh,ch)][c][t] (coalesced u16x8)
#pragma unroll
    for (int i = 0; i < 3; ++i) {
        const int u = i * 256 + tid;
        const int c = u / 8, t8 = (u % 8) * 8;
        u16x8 vv;
#pragma unroll
        for (int j = 0; j < 8; ++j) vv[j] = Kb[(t8 + j) * KP + c];
        *(u16x8*)(Ktg + (((size_t)bh * NCH + ch) * HD + c) * CH + t8) = vv;
    }

    // P3 (MFMA): A[t][i] = beta_t * (kappa_t . ktil_i), i < t
    {
        const int lane = tid & 63;
        const int lr = lane & 15, lh = lane >> 4;
        const int t0 = (tid >> 6) * 16;
        bf16x8 afr[3];
#pragma unroll
        for (int ks = 0; ks < 3; ++ks)
            afr[ks] = *(const bf16x8*)&Kk[(t0 + lr) * KP + ks * 32 + lh * 8];
#pragma unroll
        for (int i0 = 0; i0 < 64; i0 += 16) {
            f32x4 acc = (f32x4){0.f, 0.f, 0.f, 0.f};
#pragma unroll
            for (int ks = 0; ks < 3; ++ks) {
                const bf16x8 bfr = *(const bf16x8*)&Kb[(i0 + lr) * KP + ks * 32 + lh * 8];
                acc = __builtin_amdgcn_mfma_f32_16x16x32_bf16(afr[ks], bfr, acc, 0, 0, 0);
            }
#pragma unroll
            for (int r = 0; r < 4; ++r) {
                const int t = t0 + lh * 4 + r;
                const int i = i0 + lr;
                Am[t][i] = (i < t) ? acc[r] * sb[t] : 0.f;
            }
        }
    }
    __syncthreads();

    // P4: forward solve, column j of [U | W] in registers
    float X[CH];
    const int j = tid;
    if (j < 192) {
        if (j < HD) {
#pragma unroll
            for (int t = 0; t < CH; ++t) X[t] = sb[t] * v[base + t * 768 + j];
        } else {
#pragma unroll
            for (int t = 0; t < CH; ++t) X[t] = sb[t] * bf2f(Kk[t * KP + (j - HD)]);
        }
#pragma unroll
        for (int t = 1; t < CH; ++t) {
            float a0 = 0, a1 = 0, a2 = 0, a3 = 0;
#pragma unroll
            for (int i4 = 0; i4 * 4 < t; ++i4) {
                const float4 a = *(const float4*)&Am[t][i4 * 4];
                if (i4 * 4 + 0 < t) a0 = fmaf(a.x, X[i4 * 4 + 0], a0);
                if (i4 * 4 + 1 < t) a1 = fmaf(a.y, X[i4 * 4 + 1], a1);
                if (i4 * 4 + 2 < t) a2 = fmaf(a.z, X[i4 * 4 + 2], a2);
                if (i4 * 4 + 3 < t) a3 = fmaf(a.w, X[i4 * 4 + 3], a3);
            }
            X[t] -= ((a0 + a1) + (a2 + a3));
        }
        // P5: store U (f32 over v) / -W (bf16)
        if (j < HD) {
#pragma unroll
            for (int t = 0; t < CH; ++t) v[base + t * 768 + j] = X[t];
        } else {
#pragma unroll
            for (int t = 0; t < CH; ++t) Wbf[base + t * 768 + (j - HD)] = f2bf(-X[t]);
        }
    }
    __syncthreads();

    // P6 (MFMA): T[t][i] = q'_t . ktil_i, i <= t
    {
        const int lane = tid & 63;
        const int lr = lane & 15, lh = lane >> 4;
        const int t0 = (tid >> 6) * 16;
        bf16x8 afr[3];
#pragma unroll
        for (int ks = 0; ks < 3; ++ks) {
            const float4 qa = *(const float4*)&Qp[(t0 + lr) * RP + ks * 32 + lh * 8];
            const float4 qc = *(const float4*)&Qp[(t0 + lr) * RP + ks * 32 + lh * 8 + 4];
            bf16x8 a;
            a[0] = (short)f2bf(qa.x); a[1] = (short)f2bf(qa.y);
            a[2] = (short)f2bf(qa.z); a[3] = (short)f2bf(qa.w);
            a[4] = (short)f2bf(qc.x); a[5] = (short)f2bf(qc.y);
            a[6] = (short)f2bf(qc.z); a[7] = (short)f2bf(qc.w);
            afr[ks] = a;
        }
#pragma unroll
        for (int i0 = 0; i0 < 64; i0 += 16) {
            f32x4 acc = (f32x4){0.f, 0.f, 0.f, 0.f};
#pragma unroll
            for (int ks = 0; ks < 3; ++ks) {
                const bf16x8 bfr = *(const bf16x8*)&Kb[(i0 + lr) * KP + ks * 32 + lh * 8];
                acc = __builtin_amdgcn_mfma_f32_16x16x32_bf16(afr[ks], bfr, acc, 0, 0, 0);
            }
#pragma unroll
            for (int r = 0; r < 4; ++r) {
                const int t = t0 + lh * 4 + r;
                const int i = i0 + lr;
                Am[t][i] = (i <= t) ? acc[r] : 0.f;
            }
        }
    }
    __syncthreads();

    // P7: T @ X -> Ol (j<96) ; Qe = q' - T@W (j>=96, over g)
    if (j < 192) {
        for (int t = 0; t < CH; ++t) {
            float a0 = 0, a1 = 0, a2 = 0, a3 = 0;
#pragma unroll
            for (int i4 = 0; i4 < 16; ++i4) {
                const float4 a = *(const float4*)&Am[t][i4 * 4];
                a0 = fmaf(a.x, X[i4 * 4 + 0], a0); a1 = fmaf(a.y, X[i4 * 4 + 1], a1);
                a2 = fmaf(a.z, X[i4 * 4 + 2], a2); a3 = fmaf(a.w, X[i4 * 4 + 3], a3);
            }
            const float acc = (a0 + a1) + (a2 + a3);
            if (j < HD) ol[base + t * 768 + j] = f2bf(acc);
            else        g[base + t * 768 + (j - HD)] = Qp[t * RP + (j - HD)] - acc;
        }
    }
}

// ---------------------------------------------------------------- KDA sequential recurrence (MFMA form)
// grid 192 = bh*6 + vq, VSL=16 v-cols; 256 thr (4 waves).
// Master S[96x16] lives in f32 C-frags; per chunk:
//   delta = U + (-W)@Sbf (MFMA), S = Bc*(S + ktil^T@delta_bf) (MFMA).
constexpr int VSL = 16;
constexpr int WNP = 120;  // Wn row pad (u16) -> 240B rows, 2-way-free frag reads
constexpr int KTP2 = 72;  // Kt row pad
constexpr int DBP = 72;   // Dbt row pad
constexpr int SBP = 120;  // Sbt row pad
__global__ __launch_bounds__(256)
void kda_seq(const unsigned short* __restrict__ Wbf, const unsigned short* __restrict__ Ktg,
             const float* __restrict__ U, const float* __restrict__ Bc,
             float* __restrict__ Sin, float* __restrict__ states)
{
    __shared__ unsigned short Wn[CH * WNP];    // -W bf16, [t][k]
    __shared__ unsigned short Kt[HD * KTP2];   // ktil^T bf16, [k][t]
    __shared__ unsigned short Dbt[VSL * DBP];  // delta^T bf16, [v][t]
    __shared__ unsigned short Sbt[VSL * SBP];  // S^T bf16, [v][k]

    const int blk = blockIdx.x;
    const int bh = blk / 6, vq = blk - bh * 6;
    const int b = bh >> 3, h = bh & 7;
    const int tid = threadIdx.x;
    const int w = tid >> 6, lane = tid & 63;
    const int lr = lane & 15, lh = lane >> 4;
    const int v0 = vq * VSL;
    const size_t base = (size_t)b * (TT * HH * HD) + h * HD;
    const size_t cbase = (size_t)bh * NCH;

    const int t0 = w * 16;                    // step A t-tile
    const int k1 = w * 16;                    // step B k-tiles
    const int k2 = (w < 2) ? (4 + w) * 16 : -1;

    f32x4 accS1 = (f32x4){0.f, 0.f, 0.f, 0.f};
    f32x4 accS2 = (f32x4){0.f, 0.f, 0.f, 0.f};

    for (int e = tid; e < VSL * SBP; e += 256) Sbt[e] = 0;

    u16x8 wpf[3], kpf[3];
    float upf[4], ucur[4];

    // ---- stage chunk 0
    {
        const size_t cb = base;
#pragma unroll
        for (int i = 0; i < 3; ++i) {
            const int u = i * 256 + tid;
            const int r = u / 12, c8 = (u % 12) * 8;
            wpf[i] = *(const u16x8*)(Wbf + cb + (size_t)r * 768 + c8);
        }
        const size_t kb_ = (cbase * HD) * CH;
#pragma unroll
        for (int i = 0; i < 3; ++i) {
            const int u = i * 256 + tid;
            const int c = u / 8, t8 = (u % 8) * 8;
            kpf[i] = *(const u16x8*)(Ktg + kb_ + (size_t)c * CH + t8);
        }
#pragma unroll
        for (int r = 0; r < 4; ++r)
            ucur[r] = U[cb + (size_t)(t0 + lh * 4 + r) * 768 + v0 + lr];
#pragma unroll
        for (int i = 0; i < 3; ++i) {
            const int u = i * 256 + tid;
            const int r = u / 12, c8 = (u % 12) * 8;
            *(u16x8*)&Wn[r * WNP + c8] = wpf[i];
        }
#pragma unroll
        for (int i = 0; i < 3; ++i) {
            const int u = i * 256 + tid;
            const int c = u / 8, t8 = (u % 8) * 8;
            *(u16x8*)&Kt[c * KTP2 + t8] = kpf[i];
        }
    }
    __syncthreads();

    for (int ch = 0; ch < NCH; ++ch) {
        // prefetch next chunk into regs
        if (ch + 1 < NCH) {
            const size_t cb = base + (size_t)((ch + 1) * CH) * (HH * HD);
#pragma unroll
            for (int i = 0; i < 3; ++i) {
                const int u = i * 256 + tid;
                const int r = u / 12, c8 = (u % 12) * 8;
                wpf[i] = *(const u16x8*)(Wbf + cb + (size_t)r * 768 + c8);
            }
            const size_t kb_ = ((cbase + ch + 1) * HD) * CH;
#pragma unroll
            for (int i = 0; i < 3; ++i) {
                const int u = i * 256 + tid;
                const int c = u / 8, t8 = (u % 8) * 8;
                kpf[i] = *(const u16x8*)(Ktg + kb_ + (size_t)c * CH + t8);
            }
#pragma unroll
            for (int r = 0; r < 4; ++r)
                upf[r] = U[cb + (size_t)(t0 + lh * 4 + r) * 768 + v0 + lr];
        }

        // store S_in for the O-epilogue
        {
            float* sg = Sin + (cbase + ch) * (size_t)(HD * HD);
#pragma unroll
            for (int r = 0; r < 4; ++r)
                sg[(size_t)(k1 + lh * 4 + r) * HD + v0 + lr] = accS1[r];
            if (k2 >= 0) {
#pragma unroll
                for (int r = 0; r < 4; ++r)
                    sg[(size_t)(k2 + lh * 4 + r) * HD + v0 + lr] = accS2[r];
            }
        }

        // step A: delta = U + (-W)@S
        f32x4 del = (f32x4){ucur[0], ucur[1], ucur[2], ucur[3]};
#pragma unroll
        for (int ks = 0; ks < 3; ++ks) {
            const bf16x8 a = *(const bf16x8*)&Wn[(t0 + lr) * WNP + ks * 32 + lh * 8];
            const bf16x8 bb = *(const bf16x8*)&Sbt[lr * SBP + ks * 32 + lh * 8];
            del = __builtin_amdgcn_mfma_f32_16x16x32_bf16(a, bb, del, 0, 0, 0);
        }
#pragma unroll
        for (int r = 0; r < 4; ++r)
            Dbt[lr * DBP + t0 + lh * 4 + r] = f2bf(del[r]);
        __syncthreads();

        // step B: S = Bc * (S + ktil^T @ delta)
        const float* bc = Bc + (cbase + ch) * HD;
#pragma unroll
        for (int ks = 0; ks < 2; ++ks) {
            const bf16x8 a = *(const bf16x8*)&Kt[(k1 + lr) * KTP2 + ks * 32 + lh * 8];
            const bf16x8 bb = *(const bf16x8*)&Dbt[lr * DBP + ks * 32 + lh * 8];
            accS1 = __builtin_amdgcn_mfma_f32_16x16x32_bf16(a, bb, accS1, 0, 0, 0);
        }
#pragma unroll
        for (int r = 0; r < 4; ++r) accS1[r] *= bc[k1 + lh * 4 + r];
        if (k2 >= 0) {
#pragma unroll
            for (int ks = 0; ks < 2; ++ks) {
                const bf16x8 a = *(const bf16x8*)&Kt[(k2 + lr) * KTP2 + ks * 32 + lh * 8];
                const bf16x8 bb = *(const bf16x8*)&Dbt[lr * DBP + ks * 32 + lh * 8];
                accS2 = __builtin_amdgcn_mfma_f32_16x16x32_bf16(a, bb, accS2, 0, 0, 0);
            }
#pragma unroll
            for (int r = 0; r < 4; ++r) accS2[r] *= bc[k2 + lh * 4 + r];
        }
        __syncthreads();

        // export S -> Sbt; stage next chunk
#pragma unroll
        for (int r = 0; r < 4; ++r)
            Sbt[lr * SBP + k1 + lh * 4 + r] = f2bf(accS1[r]);
        if (k2 >= 0) {
#pragma unroll
            for (int r = 0; r < 4; ++r)
                Sbt[lr * SBP + k2 + lh * 4 + r] = f2bf(accS2[r]);
        }
        if (ch + 1 < NCH) {
#pragma unroll
            for (int i = 0; i < 3; ++i) {
                const int u = i * 256 + tid;
                const int r = u / 12, c8 = (u % 12) * 8;
                *(u16x8*)&Wn[r * WNP + c8] = wpf[i];
            }
#pragma unroll
            for (int i = 0; i < 3; ++i) {
                const int u = i * 256 + tid;
                const int c = u / 8, t8 = (u % 8) * 8;
                *(u16x8*)&Kt[c * KTP2 + t8] = kpf[i];
            }
#pragma unroll
            for (int r = 0; r < 4; ++r) ucur[r] = upf[r];
        }
        __syncthreads();
    }

    // final states
    {
        float* sp = states + (size_t)bh * (HD * HD);
#pragma unroll
        for (int r = 0; r < 4; ++r)
            sp[(size_t)(k1 + lh * 4 + r) * HD + v0 + lr] = accS1[r];
        if (k2 >= 0) {
#pragma unroll
            for (int r = 0; r < 4; ++r)
                sp[(size_t)(k2 + lh * 4 + r) * HD + v0 + lr] = accS2[r];
        }
    }
}

// ---------------------------------------------------------------- KDA parallel O epilogue
__global__ __launch_bounds__(256)
void kda_epi(const float* __restrict__ Sin, const float* __restrict__ Qe,
             const unsigned short* __restrict__ Ol, const unsigned short* __restrict__ Gt,
             const float* __restrict__ onw, unsigned short* __restrict__ obf)
{
    __shared__ float Sl[96 * 100];
    __shared__ float Ql[64 * 100];
    __shared__ unsigned short Olb[64 * 104];
    __shared__ unsigned short Gl[64 * 104];

    const int bx = blockIdx.x;
    const int bh = bx >> 5, ch = bx & 31;
    const int b = bh >> 3, h = bh & 7;
    const int tid = threadIdx.x;
    const size_t cb = (size_t)b * (TT * HH * HD) + (size_t)(ch * CH) * (HH * HD) + h * HD;
    const float* Sg = Sin + (size_t)(bh * NCH + ch) * HD * HD;

#pragma unroll
    for (int i = 0; i < 9; ++i) {
        const int g = i * 256 + tid;
        const int k = g / 24, c4 = (g % 24) * 4;
        *(f32x4*)&Sl[k * 100 + c4] = *(const f32x4*)(Sg + (size_t)k * HD + c4);
    }
#pragma unroll
    for (int i = 0; i < 6; ++i) {
        const int g = i * 256 + tid;
        const int t = g / 24, c4 = (g % 24) * 4;
        *(f32x4*)&Ql[t * 100 + c4] = *(const f32x4*)(Qe + cb + (size_t)t * 768 + c4);
    }
#pragma unroll
    for (int i = 0; i < 3; ++i) {
        const int g = i * 256 + tid;
        const int t = g / 12, c8 = (g % 12) * 8;
        *(u16x8*)&Olb[t * 104 + c8] = *(const u16x8*)(Ol + cb + (size_t)t * 768 + c8);
        *(u16x8*)&Gl[t * 104 + c8]  = *(const u16x8*)(Gt + cb + (size_t)t * 768 + c8);
    }
    __syncthreads();

    const int t = tid >> 2, vq2 = tid & 3;
    const int v0 = vq2 * 24;
    f32x4 acc[6];
#pragma unroll
    for (int j = 0; j < 6; ++j) {
        acc[j].x = bf2f(Olb[t * 104 + v0 + j * 4 + 0]);
        acc[j].y = bf2f(Olb[t * 104 + v0 + j * 4 + 1]);
        acc[j].z = bf2f(Olb[t * 104 + v0 + j * 4 + 2]);
        acc[j].w = bf2f(Olb[t * 104 + v0 + j * 4 + 3]);
    }
#pragma unroll 2
    for (int k = 0; k < HD; ++k) {
        const float qv = Ql[t * 100 + k];
#pragma unroll
        for (int j = 0; j < 6; ++j)
            acc[j] += qv * *(const f32x4*)&Sl[k * 100 + v0 + j * 4];
    }
    float ss = 0.f;
#pragma unroll
    for (int j = 0; j < 6; ++j)
        ss += acc[j].x * acc[j].x + acc[j].y * acc[j].y + acc[j].z * acc[j].z + acc[j].w * acc[j].w;
    ss += __shfl_xor(ss, 1); ss += __shfl_xor(ss, 2);
    const float r = rsqrtf(ss * (1.f / HD) + 1e-6f);
#pragma unroll
    for (int j = 0; j < 6; ++j) {
#pragma unroll
        for (int e = 0; e < 4; ++e) {
            const int v = v0 + j * 4 + e;
            const float g = bf2f(Gl[t * 104 + v]);
            const float val = acc[j][e] * r * onw[v] * (g / (1.f + expf(-g)));
            obf[cb + (size_t)t * 768 + v] = f2bf(val);
        }
    }
}

// ---------------------------------------------------------------- host
extern "C" void kernel_launch(void* const* d_in, const int* in_sizes, int n_in,
                              void* d_out, int out_size, void* d_ws, size_t ws_size,
                              hipStream_t stream)
{
    (void)in_sizes; (void)n_in; (void)out_size; (void)ws_size;
    const float* hidden   = (const float*)d_in[0];
    const float* mask     = (const float*)d_in[1];
    const float* norm_a_w = (const float*)d_in[2];
    const float* norm_a_b = (const float*)d_in[3];
    const float* proj_a_w = (const float*)d_in[4];
    const float* proj_a_b = (const float*)d_in[5];
    const float* ln_w     = (const float*)d_in[6];
    const float* ln_b     = (const float*)d_in[7];
    const float* Wq       = (const float*)d_in[8];
    const float* Wk       = (const float*)d_in[9];
    const float* Wv       = (const float*)d_in[10];
    const float* Wfa      = (const float*)d_in[11];
    const float* Wfb      = (const float*)d_in[12];
    const float* dt_bias  = (const float*)d_in[13];
    const float* A_log    = (const float*)d_in[14];
    const float* Wb       = (const float*)d_in[15];
    const float* Wga      = (const float*)d_in[16];
    const float* Wgb      = (const float*)d_in[17];
    const float* onorm_w  = (const float*)d_in[18];
    const float* Wo       = (const float*)d_in[19];
    const float* Wgate    = (const float*)d_in[20];
    const float* Wup      = (const float*)d_in[21];
    const float* Wdown    = (const float*)d_in[22];

    float* ws    = (float*)d_ws;
    float* hbuf  = ws;
    float* qb    = ws + HROW;          // dead after pre -> Sin/mg live here
    float* kb    = ws + 2 * HROW;
    float* vb    = ws + 3 * HROW;      // U (f32)
    float* egb   = ws + 4 * HROW;      // g -> Qe (f32)
    float* betab = ws + 5 * HROW;                     // MM*HH
    float* BcP   = betab + (size_t)MM * HH;           // 32*32*96
    float* SinP  = qb;                                // 9.44M floats (qb+kb region)
    unsigned short* bfp = (unsigned short*)(BcP + 32 * NCH * HD);
    unsigned short* x_bf    = bfp;  bfp += HROW;
    unsigned short* fab_bf  = bfp;  bfp += (size_t)MM * HD;
    unsigned short* gab_bf  = bfp;  bfp += (size_t)MM * HD;
    unsigned short* gate_bf = bfp;  bfp += HROW;
    unsigned short* olb_bf  = bfp;  bfp += HROW;
    unsigned short* w_bf    = bfp;  bfp += HROW;
    unsigned short* k_bf    = bfp;  bfp += HROW;      // ktil^T [bh][ch][96][64]
    unsigned short* wt_proj = bfp;  bfp += 768 * 768;
    unsigned short *wt_q[LL], *wt_k[LL], *wt_v[LL], *wt_o[LL], *wt_fb[LL], *wt_gb[LL],
                   *wt_fg[LL], *wt_gate[LL], *wt_up[LL], *wt_down[LL];
    for (int l = 0; l < LL; ++l) {
        wt_q[l] = bfp;    bfp += 768 * 768;   // q,k,v contiguous -> fused N=2304 GEMM
        wt_k[l] = bfp;    bfp += 768 * 768;
        wt_v[l] = bfp;    bfp += 768 * 768;
        wt_o[l] = bfp;    bfp += 768 * 768;
        wt_fb[l] = bfp;   bfp += 768 * 96;
        wt_gb[l] = bfp;   bfp += 768 * 96;
        wt_fg[l] = bfp;   bfp += 192 * 768;   // [Wfa^T | Wga^T]
        wt_gate[l] = bfp; bfp += 2048 * 768;
        wt_up[l] = bfp;   bfp += 2048 * 768;
        wt_down[l] = bfp; bfp += 768 * 2048;
    }
    unsigned short* mg_bf = (unsigned short*)SinP;  // Sin dead after epi
    unsigned short* a_bf  = (unsigned short*)vb;    // U dead after seq

    float* out    = (float*)d_out;
    float* states = out + HROW;

    // weight transpose+convert
    transcvt<<<dim3(24, 24), 256, 0, stream>>>(proj_a_w, wt_proj, 768, 768);
    for (int l = 0; l < LL; ++l) {
        transcvt<<<dim3(24, 24), 256, 0, stream>>>(Wq + (size_t)l * 589824, wt_q[l], 768, 768);
        transcvt<<<dim3(24, 24), 256, 0, stream>>>(Wk + (size_t)l * 589824, wt_k[l], 768, 768);
        transcvt<<<dim3(24, 24), 256, 0, stream>>>(Wv + (size_t)l * 589824, wt_v[l], 768, 768);
        transcvt<<<dim3(24, 24), 256, 0, stream>>>(Wo + (size_t)l * 589824, wt_o[l], 768, 768);
        transcvt<<<dim3(24, 3), 256, 0, stream>>>(Wfb + (size_t)l * 73728, wt_fb[l], 96, 768);
        transcvt<<<dim3(24, 3), 256, 0, stream>>>(Wgb + (size_t)l * 73728, wt_gb[l], 96, 768);
        transcvt<<<dim3(3, 24), 256, 0, stream>>>(Wfa + (size_t)l * 73728, wt_fg[l], 768, 96);
        transcvt<<<dim3(3, 24), 256, 0, stream>>>(Wga + (size_t)l * 73728, wt_fg[l] + 96 * 768, 768, 96);
        transcvt<<<dim3(64, 24), 256, 0, stream>>>(Wgate + (size_t)l * 1572864, wt_gate[l], 768, 2048);
        transcvt<<<dim3(64, 24), 256, 0, stream>>>(Wup + (size_t)l * 1572864, wt_up[l], 768, 2048);
        transcvt<<<dim3(24, 64), 256, 0, stream>>>(Wdown + (size_t)l * 1572864, wt_down[l], 2048, 768);
    }

    layernorm_rows<<<MM, 256, 0, stream>>>(hidden, x_bf, norm_a_w, norm_a_b, nullptr);
    bgemm<BE_BIAS><<<dim3(6, 64), 256, 0, stream>>>(x_bf, wt_proj, hbuf, nullptr,
                                                    proj_a_b, nullptr, MM, DD, DD);

    for (int l = 0; l < LL; ++l) {
        layernorm_rows<<<MM, 256, 0, stream>>>(hbuf, x_bf, ln_w + l * DD, ln_b + l * DD, mask);
        // fused q|k|v = silu(x @ [Wq|Wk|Wv]) -> qb, kb, vb
        bgemm<BE_QKV><<<dim3(18, 64), 256, 0, stream>>>(x_bf, wt_q[l], qb, nullptr,
                                                        kb, vb, MM, 3 * DD, DD);
        l2norm_rows<<<(MM * HH) / 4, 256, 0, stream>>>(qb, 0.1020620726159658f);
        l2norm_rows<<<(MM * HH) / 4, 256, 0, stream>>>(kb, 1.f);
        // fa|ga = x @ [Wfa|Wga]  (bf16, one MFMA dispatch)
        bgemm_fg<<<dim3(3, 64), 256, 0, stream>>>(x_bf, wt_fg[l], fab_bf, gab_bf, DD);
        bgemm<BE_EG><<<dim3(6, 64), 256, 0, stream>>>(fab_bf, wt_fb[l], egb, nullptr,
                                                      A_log + l * DD, dt_bias + l * DD, MM, DD, HD);
        gemm_small<1><<<dim3(1, 128), 256, 0, stream>>>(x_bf, Wb + (size_t)l * DD * HH, nullptr, betab, MM, HH, DD);
        // gate before scan (x_bf gets overwritten by o in epi)
        bgemm<BE_BF16><<<dim3(6, 64), 256, 0, stream>>>(gab_bf, wt_gb[l], nullptr, gate_bf, nullptr, nullptr, MM, DD, HD);
        // chunkwise scan
        kda_pre<<<1024, 256, 0, stream>>>(qb, kb, vb, egb, betab, olb_bf, BcP, w_bf, k_bf);
        kda_seq<<<192, 256, 0, stream>>>(w_bf, k_bf, vb, BcP, SinP,
                                         states + (size_t)l * BB * HH * HD * HD);
        kda_epi<<<1024, 256, 0, stream>>>(SinP, egb, olb_bf, gate_bf, onorm_w + l * HD, x_bf);
        // a = o @ Wo
        bgemm<BE_BF16><<<dim3(6, 64), 256, 0, stream>>>(x_bf, wt_o[l], nullptr, a_bf, nullptr, nullptr, MM, DD, DD);
        // swiglu
        bgemm_dual<<<dim3(32, 64), 256, 0, stream>>>(a_bf, wt_gate[l], wt_up[l], mg_bf, MM, FF, DD);
        float* dst = (l == LL - 1) ? out : hbuf;
        bgemm<BE_RES><<<dim3(6, 64), 256, 0, stream>>>(mg_bf, wt_down[l], dst, nullptr,
                                                       hbuf, nullptr, MM, DD, FF);
    }
}

// Round 11
// 1191.966 us; speedup vs baseline: 3.2938x; 1.0680x over previous
//
#include <hip/hip_runtime.h>
#include <cstddef>
#include <cstdint>
#include <cmath>

// Problem constants
constexpr int BB = 4, TT = 2048, DD = 768, HH = 8, HD = 96, FF = 2048, LL = 2;
constexpr int MM = BB * TT;              // 8192
constexpr size_t HROW = (size_t)MM * DD; // 6291456
constexpr int CH = 64;                   // scan chunk length
constexpr int NCH = TT / CH;             // 32 chunks per sequence
constexpr int RP = 100;                  // padded LDS row (floats)
constexpr int KP = 104;                  // padded LDS row (ushorts)

typedef float f32x4 __attribute__((ext_vector_type(4)));
typedef short bf16x8 __attribute__((ext_vector_type(8)));
typedef unsigned short u16x8 __attribute__((ext_vector_type(8)));

__device__ __forceinline__ void gload16(const void* g, void* l) {
    __builtin_amdgcn_global_load_lds(
        (const __attribute__((address_space(1))) void*)g,
        (__attribute__((address_space(3))) void*)l, 16, 0, 0);
}
__device__ __forceinline__ float bf2f(unsigned short u) {
    return __uint_as_float(((unsigned)u) << 16);
}
__device__ __forceinline__ unsigned short f2bf(float f) {
    unsigned u = __float_as_uint(f);
    unsigned r = (u + 0x7fffu + ((u >> 16) & 1u)) >> 16;
    return (unsigned short)r;
}

// ---------------------------------------------------------------- LayerNorm -> bf16
__global__ __launch_bounds__(256)
void layernorm_rows(const float* __restrict__ x, unsigned short* __restrict__ y,
                    const float* __restrict__ w, const float* __restrict__ b,
                    const float* mask)
{
    const int row = blockIdx.x;
    const int tid = threadIdx.x;
    const float* xr = x + (size_t)row * DD;
    float v0 = xr[tid], v1 = xr[tid + 256], v2 = xr[tid + 512];
    float s = v0 + v1 + v2;
    float ss = v0 * v0 + v1 * v1 + v2 * v2;
#pragma unroll
    for (int i = 1; i < 64; i <<= 1) { s += __shfl_xor(s, i); ss += __shfl_xor(ss, i); }
    __shared__ float red[8];
    const int wid = tid >> 6, lane = tid & 63;
    if (lane == 0) { red[wid] = s; red[4 + wid] = ss; }
    __syncthreads();
    const float S  = red[0] + red[1] + red[2] + red[3];
    const float SS = red[4] + red[5] + red[6] + red[7];
    const float mean = S * (1.f / DD);
    const float var  = SS * (1.f / DD) - mean * mean;
    const float rstd = rsqrtf(var + 1e-5f);
    const float m = mask ? mask[row] : 1.f;
    unsigned short* yr = y + (size_t)row * DD;
    yr[tid]       = f2bf(((v0 - mean) * rstd * w[tid]       + b[tid])       * m);
    yr[tid + 256] = f2bf(((v1 - mean) * rstd * w[tid + 256] + b[tid + 256]) * m);
    yr[tid + 512] = f2bf(((v2 - mean) * rstd * w[tid + 512] + b[tid + 512]) * m);
}

// ---------------------------------------------------------------- transpose+convert W
__global__ __launch_bounds__(256)
void transcvt(const float* __restrict__ in, unsigned short* __restrict__ out, int K, int N)
{
    __shared__ float t[32][33];
    const int tx = threadIdx.x & 31, ty = threadIdx.x >> 5;
    const int k0 = blockIdx.y * 32, n0 = blockIdx.x * 32;
#pragma unroll
    for (int i = 0; i < 4; ++i)
        t[ty + i * 8][tx] = in[(size_t)(k0 + ty + i * 8) * N + n0 + tx];
    __syncthreads();
#pragma unroll
    for (int i = 0; i < 4; ++i)
        out[(size_t)(n0 + ty + i * 8) * K + k0 + tx] = f2bf(t[tx][ty + i * 8]);
}

// ---------------------------------------------------------------- bf16 MFMA GEMM
enum { BE_BIAS = 0, BE_SILU, BE_EG, BE_F32, BE_BF16, BE_RES, BE_QKV };

template <int EPI>
__global__ __launch_bounds__(256)
void bgemm(const unsigned short* __restrict__ A, const unsigned short* __restrict__ Bt,
           float* Cf, unsigned short* Cb,
           const float* P0, const float* P1,
           int M, int N, int K)
{
    __shared__ unsigned short As[128 * 32];
    __shared__ unsigned short Bs[128 * 32];
    const int tid = threadIdx.x;
    const int w = tid >> 6, l = tid & 63;
    const int wm = w >> 1, wn = w & 1;
    const int lr = l & 15, lh = l >> 4;
    const int m0 = blockIdx.y * 128, n0 = blockIdx.x * 128;

    f32x4 acc[4][4];
#pragma unroll
    for (int i = 0; i < 4; ++i)
#pragma unroll
        for (int j = 0; j < 4; ++j) acc[i][j] = (f32x4){0.f, 0.f, 0.f, 0.f};

    const int sr = l >> 2, sq = (l & 3) * 8;
    const unsigned short* Ag = A + (size_t)(m0 + w * 32 + sr) * K + sq;
    const unsigned short* Bg = Bt + (size_t)(n0 + w * 32 + sr) * K + sq;
    unsigned short* Al = &As[(w * 32) * 32];
    unsigned short* Bl = &Bs[(w * 32) * 32];

    for (int kt = 0; kt < K; kt += 32) {
        __syncthreads();
        gload16(Ag + kt, Al);
        gload16(Ag + kt + 16 * (size_t)K, Al + 16 * 32);
        gload16(Bg + kt, Bl);
        gload16(Bg + kt + 16 * (size_t)K, Bl + 16 * 32);
        __syncthreads();
        bf16x8 af[4], bfv[4];
#pragma unroll
        for (int mi = 0; mi < 4; ++mi)
            af[mi] = *(const bf16x8*)&As[(wm * 64 + mi * 16 + lr) * 32 + lh * 8];
#pragma unroll
        for (int ni = 0; ni < 4; ++ni)
            bfv[ni] = *(const bf16x8*)&Bs[(wn * 64 + ni * 16 + lr) * 32 + lh * 8];
#pragma unroll
        for (int mi = 0; mi < 4; ++mi)
#pragma unroll
            for (int ni = 0; ni < 4; ++ni)
                acc[mi][ni] = __builtin_amdgcn_mfma_f32_16x16x32_bf16(af[mi], bfv[ni], acc[mi][ni], 0, 0, 0);
    }

#pragma unroll
    for (int mi = 0; mi < 4; ++mi) {
#pragma unroll
        for (int j = 0; j < 4; ++j) {
            const int row = m0 + wm * 64 + mi * 16 + lh * 4 + j;
#pragma unroll
            for (int ni = 0; ni < 4; ++ni) {
                const int col = n0 + wn * 64 + ni * 16 + lr;
                const size_t idx = (size_t)row * N + col;
                float v = acc[mi][ni][j];
                if constexpr (EPI == BE_BIAS) { Cf[idx] = v + P0[col]; }
                else if constexpr (EPI == BE_SILU) { Cf[idx] = v / (1.f + expf(-v)); }
                else if constexpr (EPI == BE_EG) {
                    const float lin = v + P1[col];
                    const float sp = (lin > 20.f) ? lin : log1pf(expf(lin));
                    Cf[idx] = -expf(P0[col]) * sp;      // raw log-decay g
                }
                else if constexpr (EPI == BE_F32) { Cf[idx] = v; }
                else if constexpr (EPI == BE_BF16) { Cb[idx] = f2bf(v); }
                else if constexpr (EPI == BE_RES) { Cf[idx] = v + P0[idx]; }
                else if constexpr (EPI == BE_QKV) {
                    const int tgt = col / 768;
                    const int cl = col - tgt * 768;
                    float* dst = (tgt == 0) ? Cf
                               : (tgt == 1) ? const_cast<float*>(P0)
                                            : const_cast<float*>(P1);
                    dst[(size_t)row * 768 + cl] = v / (1.f + expf(-v));
                }
            }
        }
    }
}

// Dual-B GEMM for SwiGLU
__global__ __launch_bounds__(256)
void bgemm_dual(const unsigned short* __restrict__ A,
                const unsigned short* __restrict__ Bg_, const unsigned short* __restrict__ Bu_,
                unsigned short* __restrict__ C, int M, int N, int K)
{
    __shared__ unsigned short As[128 * 32];
    __shared__ unsigned short Bs1[64 * 32];
    __shared__ unsigned short Bs2[64 * 32];
    const int tid = threadIdx.x;
    const int w = tid >> 6, l = tid & 63;
    const int wm = w >> 1, wn = w & 1;
    const int lr = l & 15, lh = l >> 4;
    const int m0 = blockIdx.y * 128, n0 = blockIdx.x * 64;

    f32x4 a1[4][2], a2[4][2];
#pragma unroll
    for (int i = 0; i < 4; ++i)
#pragma unroll
        for (int j = 0; j < 2; ++j) { a1[i][j] = (f32x4){0.f,0.f,0.f,0.f}; a2[i][j] = (f32x4){0.f,0.f,0.f,0.f}; }

    const int sr = l >> 2, sq = (l & 3) * 8;
    const unsigned short* Ag  = A   + (size_t)(m0 + w * 32 + sr) * K + sq;
    const unsigned short* B1g = Bg_ + (size_t)(n0 + w * 16 + sr) * K + sq;
    const unsigned short* B2g = Bu_ + (size_t)(n0 + w * 16 + sr) * K + sq;
    unsigned short* Al  = &As[(w * 32) * 32];
    unsigned short* B1l = &Bs1[(w * 16) * 32];
    unsigned short* B2l = &Bs2[(w * 16) * 32];

    for (int kt = 0; kt < K; kt += 32) {
        __syncthreads();
        gload16(Ag + kt, Al);
        gload16(Ag + kt + 16 * (size_t)K, Al + 16 * 32);
        gload16(B1g + kt, B1l);
        gload16(B2g + kt, B2l);
        __syncthreads();
        bf16x8 af[4], b1[2], b2[2];
#pragma unroll
        for (int mi = 0; mi < 4; ++mi)
            af[mi] = *(const bf16x8*)&As[(wm * 64 + mi * 16 + lr) * 32 + lh * 8];
#pragma unroll
        for (int ni = 0; ni < 2; ++ni) {
            b1[ni] = *(const bf16x8*)&Bs1[(wn * 32 + ni * 16 + lr) * 32 + lh * 8];
            b2[ni] = *(const bf16x8*)&Bs2[(wn * 32 + ni * 16 + lr) * 32 + lh * 8];
        }
#pragma unroll
        for (int mi = 0; mi < 4; ++mi)
#pragma unroll
            for (int ni = 0; ni < 2; ++ni) {
                a1[mi][ni] = __builtin_amdgcn_mfma_f32_16x16x32_bf16(af[mi], b1[ni], a1[mi][ni], 0, 0, 0);
                a2[mi][ni] = __builtin_amdgcn_mfma_f32_16x16x32_bf16(af[mi], b2[ni], a2[mi][ni], 0, 0, 0);
            }
    }

#pragma unroll
    for (int mi = 0; mi < 4; ++mi)
#pragma unroll
        for (int j = 0; j < 4; ++j) {
            const int row = m0 + wm * 64 + mi * 16 + lh * 4 + j;
#pragma unroll
            for (int ni = 0; ni < 2; ++ni) {
                const int col = n0 + wn * 32 + ni * 16 + lr;
                const float g = a1[mi][ni][j], u = a2[mi][ni][j];
                C[(size_t)row * N + col] = f2bf((g / (1.f + expf(-g))) * u);
            }
        }
}

// fa|ga fused GEMM: N fixed 192 ([Wfa|Wga]^T), routing epilogue -> two bf16 buffers.
__global__ __launch_bounds__(256)
void bgemm_fg(const unsigned short* __restrict__ A, const unsigned short* __restrict__ Bt,
              unsigned short* __restrict__ Cfa, unsigned short* __restrict__ Cga, int K)
{
    __shared__ unsigned short As[128 * 32];
    __shared__ unsigned short Bs[64 * 32];
    const int tid = threadIdx.x;
    const int w = tid >> 6, l = tid & 63;
    const int wm = w >> 1, wn = w & 1;
    const int lr = l & 15, lh = l >> 4;
    const int m0 = blockIdx.y * 128, n0 = blockIdx.x * 64;

    f32x4 acc[4][2];
#pragma unroll
    for (int i = 0; i < 4; ++i)
#pragma unroll
        for (int j = 0; j < 2; ++j) acc[i][j] = (f32x4){0.f, 0.f, 0.f, 0.f};

    const int sr = l >> 2, sq = (l & 3) * 8;
    const unsigned short* Ag = A + (size_t)(m0 + w * 32 + sr) * K + sq;
    const unsigned short* Bg = Bt + (size_t)(n0 + w * 16 + sr) * K + sq;
    unsigned short* Al = &As[(w * 32) * 32];
    unsigned short* Bl = &Bs[(w * 16) * 32];

    for (int kt = 0; kt < K; kt += 32) {
        __syncthreads();
        gload16(Ag + kt, Al);
        gload16(Ag + kt + 16 * (size_t)K, Al + 16 * 32);
        gload16(Bg + kt, Bl);
        __syncthreads();
        bf16x8 af[4], bfv[2];
#pragma unroll
        for (int mi = 0; mi < 4; ++mi)
            af[mi] = *(const bf16x8*)&As[(wm * 64 + mi * 16 + lr) * 32 + lh * 8];
#pragma unroll
        for (int ni = 0; ni < 2; ++ni)
            bfv[ni] = *(const bf16x8*)&Bs[(wn * 32 + ni * 16 + lr) * 32 + lh * 8];
#pragma unroll
        for (int mi = 0; mi < 4; ++mi)
#pragma unroll
            for (int ni = 0; ni < 2; ++ni)
                acc[mi][ni] = __builtin_amdgcn_mfma_f32_16x16x32_bf16(af[mi], bfv[ni], acc[mi][ni], 0, 0, 0);
    }

#pragma unroll
    for (int mi = 0; mi < 4; ++mi)
#pragma unroll
        for (int j = 0; j < 4; ++j) {
            const int row = m0 + wm * 64 + mi * 16 + lh * 4 + j;
#pragma unroll
            for (int ni = 0; ni < 2; ++ni) {
                const int col = n0 + wn * 32 + ni * 16 + lr;   // 0..191, 16-aligned tiles
                const int tgt = (col >= HD);
                const int cl = col - (tgt ? HD : 0);
                unsigned short* dst = tgt ? Cga : Cfa;
                dst[(size_t)row * HD + cl] = f2bf(acc[mi][ni][j]);
            }
        }
}

// ---------------------------------------------------------------- small fp32 GEMM (A bf16)
template <int MODE>
__global__ __launch_bounds__(256)
void gemm_small(const unsigned short* __restrict__ A, const float* __restrict__ Bm,
                unsigned short* Cb, float* Cf, int M, int N, int K)
{
    __shared__ float As[16][64];
    __shared__ float Bs[16][64];
    const int tid = threadIdx.x;
    const int tx = tid & 15, ty = tid >> 4;
    const int row0 = blockIdx.y * 64;
    const int col0 = blockIdx.x * 64;
    float acc[4][4] = {};
    const int ar  = tid >> 2;
    const int ac4 = (tid & 3) << 2;
    const int br  = tid >> 4;
    const int bc  = (tid & 15) << 2;
    const int gc  = col0 + bc;
    const bool bok = gc < N;

    for (int kt = 0; kt < K; kt += 16) {
        const ushort4 a4 = *(const ushort4*)(A + (size_t)(row0 + ar) * K + kt + ac4);
        float4 b4 = make_float4(0.f, 0.f, 0.f, 0.f);
        if (bok) b4 = *(const float4*)(Bm + (size_t)(kt + br) * N + gc);
        __syncthreads();
        As[ac4 + 0][ar] = bf2f(a4.x); As[ac4 + 1][ar] = bf2f(a4.y);
        As[ac4 + 2][ar] = bf2f(a4.z); As[ac4 + 3][ar] = bf2f(a4.w);
        *(float4*)&Bs[br][bc] = b4;
        __syncthreads();
#pragma unroll
        for (int kk = 0; kk < 16; ++kk) {
            const float4 av = *(const float4*)&As[kk][ty << 2];
            const float4 bv = *(const float4*)&Bs[kk][tx << 2];
            const float a_[4] = {av.x, av.y, av.z, av.w};
            const float b_[4] = {bv.x, bv.y, bv.z, bv.w};
#pragma unroll
            for (int i = 0; i < 4; ++i)
#pragma unroll
                for (int j = 0; j < 4; ++j)
                    acc[i][j] = fmaf(a_[i], b_[j], acc[i][j]);
        }
    }
#pragma unroll
    for (int i = 0; i < 4; ++i) {
        const int row = row0 + (ty << 2) + i;
#pragma unroll
        for (int j = 0; j < 4; ++j) {
            const int col = col0 + (tx << 2) + j;
            if (col >= N) continue;
            const size_t idx = (size_t)row * N + col;
            if constexpr (MODE == 0) Cb[idx] = f2bf(acc[i][j]);
            else                     Cf[idx] = 1.f / (1.f + expf(-acc[i][j]));
        }
    }
}

// ---------------------------------------------------------------- l2norm over HD=96
__global__ __launch_bounds__(256)
void l2norm_rows(float* x, float scale)
{
    const int row  = (blockIdx.x << 2) + (threadIdx.x >> 6);
    const int lane = threadIdx.x & 63;
    float* xr = x + (size_t)row * HD;
    const float a = xr[lane];
    const float b = (lane < 32) ? xr[64 + lane] : 0.f;
    float ss = a * a + b * b;
#pragma unroll
    for (int i = 1; i < 64; i <<= 1) ss += __shfl_xor(ss, i);
    const float r = rsqrtf(ss + 1e-6f) * scale;
    xr[lane] = a * r;
    if (lane < 32) xr[64 + lane] = b * r;
}

// ---------------------------------------------------------------- KDA chunkwise precompute
// Emits: -W (bf16) -> Wbf; ktil^T (bf16, [c][t]) -> Ktg; U (f32 over v);
// Qe (f32 over g); Ol (bf16); Bc. P3/P6/P7 via MFMA.
constexpr int TBP = 72;   // Tb row pad (u16)
constexpr int XLP = 72;   // Xl row pad (u16)
__global__ __launch_bounds__(256)
void kda_pre(const float* __restrict__ q, const float* __restrict__ k, float* v, float* g,
             const float* __restrict__ beta,
             unsigned short* __restrict__ ol, float* __restrict__ Bc,
             unsigned short* __restrict__ Wbf, unsigned short* __restrict__ Ktg)
{
    __shared__ unsigned short Kb[CH * KP];   // k (bf16), then kappa_tilde (bf16)
    __shared__ float Qp[CH * RP];            // g -> L -> q'
    __shared__ float sb[CH];
    __shared__ __align__(16) char uR[36864];
    // phase 1 (P0-P4): Kk u16[CH*KP]=13312B @0 ; Am f32[CH][68]=17408B @13312
    // phase 2 (P6-P7): Tb u16[CH*TBP]=9216B @0 ; Xl u16[192*XLP]=27648B @9216
    unsigned short* Kk = (unsigned short*)uR;
    float (*Am)[68] = (float(*)[68])(uR + 13312);
    unsigned short* Tb = (unsigned short*)uR;
    unsigned short* Xl = (unsigned short*)(uR + 9216);

    const int blk = blockIdx.x;
    const int ch = blk & 31, bh = blk >> 5;
    const int b = bh >> 3, h = bh & 7;
    const int tid = threadIdx.x;
    const size_t base = (size_t)b * (TT * HH * HD) + (size_t)(ch * CH) * (HH * HD) + h * HD;

    // P0: stage k (as bf16), g (f32), beta
    for (int e = tid; e < CH * 24; e += 256) {
        const int t = e / 24, c4 = (e % 24) * 4;
        const float4 kv = *(const float4*)(k + base + t * 768 + c4);
        ushort4 k4;
        k4.x = f2bf(kv.x); k4.y = f2bf(kv.y); k4.z = f2bf(kv.z); k4.w = f2bf(kv.w);
        *(ushort4*)&Kb[t * KP + c4] = k4;
        *(float4*)&Qp[t * RP + c4] = *(const float4*)(g + base + t * 768 + c4);
    }
    if (tid < CH) sb[tid] = beta[((size_t)b * TT + ch * CH + tid) * HH + h];
    __syncthreads();

    // P1: per-channel cumsum of g
    if (tid < HD) {
        float L = 0.f;
        for (int t = 0; t < CH; ++t) { L += Qp[t * RP + tid]; Qp[t * RP + tid] = L; }
    }
    __syncthreads();

    // P2: kappa, kappa_tilde (bf16), q', Bc
    for (int e = tid; e < CH * HD; e += 256) {
        const int t = e / HD, c = e % HD;
        const float L = Qp[t * RP + c];
        const float B = expf(L), iB = expf(-L);
        const float kv = bf2f(Kb[t * KP + c]);
        if (t == CH - 1) Bc[((size_t)bh * NCH + ch) * HD + c] = B;
        Kk[t * KP + c] = f2bf(kv * B);
        const unsigned short kti = f2bf(kv * iB);
        const float qv = q[base + t * 768 + c];
        Kb[t * KP + c] = kti;
        Qp[t * RP + c] = qv * B;                  // q'
    }
    __syncthreads();

    // P2b: export ktil^T -> Ktg[(bh,ch)][c][t] (coalesced u16x8)
#pragma unroll
    for (int i = 0; i < 3; ++i) {
        const int u = i * 256 + tid;
        const int c = u / 8, t8 = (u % 8) * 8;
        u16x8 vv;
#pragma unroll
        for (int j = 0; j < 8; ++j) vv[j] = Kb[(t8 + j) * KP + c];
        *(u16x8*)(Ktg + (((size_t)bh * NCH + ch) * HD + c) * CH + t8) = vv;
    }

    // P3 (MFMA): A[t][i] = beta_t * (kappa_t . ktil_i), i < t  (f32 -> Am)
    {
        const int lane = tid & 63;
        const int lr = lane & 15, lh = lane >> 4;
        const int t0 = (tid >> 6) * 16;
        bf16x8 afr[3];
#pragma unroll
        for (int ks = 0; ks < 3; ++ks)
            afr[ks] = *(const bf16x8*)&Kk[(t0 + lr) * KP + ks * 32 + lh * 8];
#pragma unroll
        for (int i0 = 0; i0 < 64; i0 += 16) {
            f32x4 acc = (f32x4){0.f, 0.f, 0.f, 0.f};
#pragma unroll
            for (int ks = 0; ks < 3; ++ks) {
                const bf16x8 bfr = *(const bf16x8*)&Kb[(i0 + lr) * KP + ks * 32 + lh * 8];
                acc = __builtin_amdgcn_mfma_f32_16x16x32_bf16(afr[ks], bfr, acc, 0, 0, 0);
            }
#pragma unroll
            for (int r = 0; r < 4; ++r) {
                const int t = t0 + lh * 4 + r;
                const int i = i0 + lr;
                Am[t][i] = (i < t) ? acc[r] * sb[t] : 0.f;
            }
        }
    }
    __syncthreads();

    // P4: forward solve, column j of [U | W] in registers
    float X[CH];
    const int j = tid;
    if (j < 192) {
        if (j < HD) {
#pragma unroll
            for (int t = 0; t < CH; ++t) X[t] = sb[t] * v[base + t * 768 + j];
        } else {
#pragma unroll
            for (int t = 0; t < CH; ++t) X[t] = sb[t] * bf2f(Kk[t * KP + (j - HD)]);
        }
#pragma unroll
        for (int t = 1; t < CH; ++t) {
            float a0 = 0, a1 = 0, a2 = 0, a3 = 0;
#pragma unroll
            for (int i4 = 0; i4 * 4 < t; ++i4) {
                const float4 a = *(const float4*)&Am[t][i4 * 4];
                if (i4 * 4 + 0 < t) a0 = fmaf(a.x, X[i4 * 4 + 0], a0);
                if (i4 * 4 + 1 < t) a1 = fmaf(a.y, X[i4 * 4 + 1], a1);
                if (i4 * 4 + 2 < t) a2 = fmaf(a.z, X[i4 * 4 + 2], a2);
                if (i4 * 4 + 3 < t) a3 = fmaf(a.w, X[i4 * 4 + 3], a3);
            }
            X[t] -= ((a0 + a1) + (a2 + a3));
        }
        // P5: store U (f32 over v) / -W (bf16)
        if (j < HD) {
#pragma unroll
            for (int t = 0; t < CH; ++t) v[base + t * 768 + j] = X[t];
        } else {
#pragma unroll
            for (int t = 0; t < CH; ++t) Wbf[base + t * 768 + (j - HD)] = f2bf(-X[t]);
        }
    }
    __syncthreads();   // Am/Kk dead past here (uR reused as Tb/Xl)

    // phase 2a: X -> Xl (bf16, [j][t]); P6 (MFMA): T -> Tb (bf16, [t][i])
    if (j < 192) {
#pragma unroll
        for (int t8 = 0; t8 < 8; ++t8) {
            u16x8 xv;
#pragma unroll
            for (int jj = 0; jj < 8; ++jj) xv[jj] = f2bf(X[t8 * 8 + jj]);
            *(u16x8*)&Xl[j * XLP + t8 * 8] = xv;
        }
    }
    {
        const int lane = tid & 63;
        const int lr = lane & 15, lh = lane >> 4;
        const int t0 = (tid >> 6) * 16;
        bf16x8 afr[3];
#pragma unroll
        for (int ks = 0; ks < 3; ++ks) {
            const float4 qa = *(const float4*)&Qp[(t0 + lr) * RP + ks * 32 + lh * 8];
            const float4 qc = *(const float4*)&Qp[(t0 + lr) * RP + ks * 32 + lh * 8 + 4];
            bf16x8 a;
            a[0] = (short)f2bf(qa.x); a[1] = (short)f2bf(qa.y);
            a[2] = (short)f2bf(qa.z); a[3] = (short)f2bf(qa.w);
            a[4] = (short)f2bf(qc.x); a[5] = (short)f2bf(qc.y);
            a[6] = (short)f2bf(qc.z); a[7] = (short)f2bf(qc.w);
            afr[ks] = a;
        }
#pragma unroll
        for (int i0 = 0; i0 < 64; i0 += 16) {
            f32x4 acc = (f32x4){0.f, 0.f, 0.f, 0.f};
#pragma unroll
            for (int ks = 0; ks < 3; ++ks) {
                const bf16x8 bfr = *(const bf16x8*)&Kb[(i0 + lr) * KP + ks * 32 + lh * 8];
                acc = __builtin_amdgcn_mfma_f32_16x16x32_bf16(afr[ks], bfr, acc, 0, 0, 0);
            }
#pragma unroll
            for (int r = 0; r < 4; ++r) {
                const int t = t0 + lh * 4 + r;
                const int i = i0 + lr;
                Tb[t * TBP + i] = (i <= t) ? f2bf(acc[r]) : (unsigned short)0;
            }
        }
    }
    __syncthreads();

    // P7 (MFMA): res = T @ X ; j<96 -> Ol ; j>=96 -> Qe = q' - res
    {
        const int lane = tid & 63;
        const int lr = lane & 15, lh = lane >> 4;
        const int w = tid >> 6;
        const int t0 = w * 16;
        bf16x8 af0 = *(const bf16x8*)&Tb[(t0 + lr) * TBP + lh * 8];
        bf16x8 af1 = *(const bf16x8*)&Tb[(t0 + lr) * TBP + 32 + lh * 8];
#pragma unroll
        for (int nt = 0; nt < 12; ++nt) {
            const int n0 = nt * 16;
            f32x4 acc = (f32x4){0.f, 0.f, 0.f, 0.f};
            acc = __builtin_amdgcn_mfma_f32_16x16x32_bf16(
                af0, *(const bf16x8*)&Xl[(n0 + lr) * XLP + lh * 8], acc, 0, 0, 0);
            acc = __builtin_amdgcn_mfma_f32_16x16x32_bf16(
                af1, *(const bf16x8*)&Xl[(n0 + lr) * XLP + 32 + lh * 8], acc, 0, 0, 0);
            const int jc = n0 + lr;
#pragma unroll
            for (int r = 0; r < 4; ++r) {
                const int t = t0 + lh * 4 + r;
                if (jc < HD) ol[base + t * 768 + jc] = f2bf(acc[r]);
                else         g[base + t * 768 + (jc - HD)] = Qp[t * RP + (jc - HD)] - acc[r];
            }
        }
    }
}

// ---------------------------------------------------------------- KDA sequential recurrence (MFMA form)
constexpr int VSL = 16;
constexpr int WNP = 120;  // Wn row pad (u16)
constexpr int KTP2 = 72;  // Kt row pad
constexpr int DBP = 72;   // Dbt row pad
constexpr int SBP = 120;  // Sbt row pad
__global__ __launch_bounds__(256)
void kda_seq(const unsigned short* __restrict__ Wbf, const unsigned short* __restrict__ Ktg,
             const float* __restrict__ U, const float* __restrict__ Bc,
             float* __restrict__ Sin, float* __restrict__ states)
{
    __shared__ unsigned short Wn[CH * WNP];    // -W bf16, [t][k]
    __shared__ unsigned short Kt[HD * KTP2];   // ktil^T bf16, [k][t]
    __shared__ unsigned short Dbt[VSL * DBP];  // delta^T bf16, [v][t]
    __shared__ unsigned short Sbt[VSL * SBP];  // S^T bf16, [v][k]

    const int blk = blockIdx.x;
    const int bh = blk / 6, vq = blk - bh * 6;
    const int b = bh >> 3, h = bh & 7;
    const int tid = threadIdx.x;
    const int w = tid >> 6, lane = tid & 63;
    const int lr = lane & 15, lh = lane >> 4;
    const int v0 = vq * VSL;
    const size_t base = (size_t)b * (TT * HH * HD) + h * HD;
    const size_t cbase = (size_t)bh * NCH;

    const int t0 = w * 16;                    // step A t-tile
    const int k1 = w * 16;                    // step B k-tiles
    const int k2 = (w < 2) ? (4 + w) * 16 : -1;

    f32x4 accS1 = (f32x4){0.f, 0.f, 0.f, 0.f};
    f32x4 accS2 = (f32x4){0.f, 0.f, 0.f, 0.f};

    for (int e = tid; e < VSL * SBP; e += 256) Sbt[e] = 0;

    u16x8 wpf[3], kpf[3];
    float upf[4], ucur[4];

    // ---- stage chunk 0
    {
        const size_t cb = base;
#pragma unroll
        for (int i = 0; i < 3; ++i) {
            const int u = i * 256 + tid;
            const int r = u / 12, c8 = (u % 12) * 8;
            wpf[i] = *(const u16x8*)(Wbf + cb + (size_t)r * 768 + c8);
        }
        const size_t kb_ = (cbase * HD) * CH;
#pragma unroll
        for (int i = 0; i < 3; ++i) {
            const int u = i * 256 + tid;
            const int c = u / 8, t8 = (u % 8) * 8;
            kpf[i] = *(const u16x8*)(Ktg + kb_ + (size_t)c * CH + t8);
        }
#pragma unroll
        for (int r = 0; r < 4; ++r)
            ucur[r] = U[cb + (size_t)(t0 + lh * 4 + r) * 768 + v0 + lr];
#pragma unroll
        for (int i = 0; i < 3; ++i) {
            const int u = i * 256 + tid;
            const int r = u / 12, c8 = (u % 12) * 8;
            *(u16x8*)&Wn[r * WNP + c8] = wpf[i];
        }
#pragma unroll
        for (int i = 0; i < 3; ++i) {
            const int u = i * 256 + tid;
            const int c = u / 8, t8 = (u % 8) * 8;
            *(u16x8*)&Kt[c * KTP2 + t8] = kpf[i];
        }
    }
    __syncthreads();

    for (int ch = 0; ch < NCH; ++ch) {
        // prefetch next chunk into regs
        if (ch + 1 < NCH) {
            const size_t cb = base + (size_t)((ch + 1) * CH) * (HH * HD);
#pragma unroll
            for (int i = 0; i < 3; ++i) {
                const int u = i * 256 + tid;
                const int r = u / 12, c8 = (u % 12) * 8;
                wpf[i] = *(const u16x8*)(Wbf + cb + (size_t)r * 768 + c8);
            }
            const size_t kb_ = ((cbase + ch + 1) * HD) * CH;
#pragma unroll
            for (int i = 0; i < 3; ++i) {
                const int u = i * 256 + tid;
                const int c = u / 8, t8 = (u % 8) * 8;
                kpf[i] = *(const u16x8*)(Ktg + kb_ + (size_t)c * CH + t8);
            }
#pragma unroll
            for (int r = 0; r < 4; ++r)
                upf[r] = U[cb + (size_t)(t0 + lh * 4 + r) * 768 + v0 + lr];
        }

        // store S_in for the O-epilogue
        {
            float* sg = Sin + (cbase + ch) * (size_t)(HD * HD);
#pragma unroll
            for (int r = 0; r < 4; ++r)
                sg[(size_t)(k1 + lh * 4 + r) * HD + v0 + lr] = accS1[r];
            if (k2 >= 0) {
#pragma unroll
                for (int r = 0; r < 4; ++r)
                    sg[(size_t)(k2 + lh * 4 + r) * HD + v0 + lr] = accS2[r];
            }
        }

        // step A: delta = U + (-W)@S
        f32x4 del = (f32x4){ucur[0], ucur[1], ucur[2], ucur[3]};
#pragma unroll
        for (int ks = 0; ks < 3; ++ks) {
            const bf16x8 a = *(const bf16x8*)&Wn[(t0 + lr) * WNP + ks * 32 + lh * 8];
            const bf16x8 bb = *(const bf16x8*)&Sbt[lr * SBP + ks * 32 + lh * 8];
            del = __builtin_amdgcn_mfma_f32_16x16x32_bf16(a, bb, del, 0, 0, 0);
        }
#pragma unroll
        for (int r = 0; r < 4; ++r)
            Dbt[lr * DBP + t0 + lh * 4 + r] = f2bf(del[r]);
        __syncthreads();

        // step B: S = Bc * (S + ktil^T @ delta)
        const float* bc = Bc + (cbase + ch) * HD;
#pragma unroll
        for (int ks = 0; ks < 2; ++ks) {
            const bf16x8 a = *(const bf16x8*)&Kt[(k1 + lr) * KTP2 + ks * 32 + lh * 8];
            const bf16x8 bb = *(const bf16x8*)&Dbt[lr * DBP + ks * 32 + lh * 8];
            accS1 = __builtin_amdgcn_mfma_f32_16x16x32_bf16(a, bb, accS1, 0, 0, 0);
        }
#pragma unroll
        for (int r = 0; r < 4; ++r) accS1[r] *= bc[k1 + lh * 4 + r];
        if (k2 >= 0) {
#pragma unroll
            for (int ks = 0; ks < 2; ++ks) {
                const bf16x8 a = *(const bf16x8*)&Kt[(k2 + lr) * KTP2 + ks * 32 + lh * 8];
                const bf16x8 bb = *(const bf16x8*)&Dbt[lr * DBP + ks * 32 + lh * 8];
                accS2 = __builtin_amdgcn_mfma_f32_16x16x32_bf16(a, bb, accS2, 0, 0, 0);
            }
#pragma unroll
            for (int r = 0; r < 4; ++r) accS2[r] *= bc[k2 + lh * 4 + r];
        }
        __syncthreads();

        // export S -> Sbt; stage next chunk
#pragma unroll
        for (int r = 0; r < 4; ++r)
            Sbt[lr * SBP + k1 + lh * 4 + r] = f2bf(accS1[r]);
        if (k2 >= 0) {
#pragma unroll
            for (int r = 0; r < 4; ++r)
                Sbt[lr * SBP + k2 + lh * 4 + r] = f2bf(accS2[r]);
        }
        if (ch + 1 < NCH) {
#pragma unroll
            for (int i = 0; i < 3; ++i) {
                const int u = i * 256 + tid;
                const int r = u / 12, c8 = (u % 12) * 8;
                *(u16x8*)&Wn[r * WNP + c8] = wpf[i];
            }
#pragma unroll
            for (int i = 0; i < 3; ++i) {
                const int u = i * 256 + tid;
                const int c = u / 8, t8 = (u % 8) * 8;
                *(u16x8*)&Kt[c * KTP2 + t8] = kpf[i];
            }
#pragma unroll
            for (int r = 0; r < 4; ++r) ucur[r] = upf[r];
        }
        __syncthreads();
    }

    // final states
    {
        float* sp = states + (size_t)bh * (HD * HD);
#pragma unroll
        for (int r = 0; r < 4; ++r)
            sp[(size_t)(k1 + lh * 4 + r) * HD + v0 + lr] = accS1[r];
        if (k2 >= 0) {
#pragma unroll
            for (int r = 0; r < 4; ++r)
                sp[(size_t)(k2 + lh * 4 + r) * HD + v0 + lr] = accS2[r];
        }
    }
}

// ---------------------------------------------------------------- KDA parallel O epilogue
__global__ __launch_bounds__(256)
void kda_epi(const float* __restrict__ Sin, const float* __restrict__ Qe,
             const unsigned short* __restrict__ Ol, const unsigned short* __restrict__ Gt,
             const float* __restrict__ onw, unsigned short* __restrict__ obf)
{
    __shared__ float Sl[96 * 100];
    __shared__ float Ql[64 * 100];
    __shared__ unsigned short Olb[64 * 104];
    __shared__ unsigned short Gl[64 * 104];

    const int bx = blockIdx.x;
    const int bh = bx >> 5, ch = bx & 31;
    const int b = bh >> 3, h = bh & 7;
    const int tid = threadIdx.x;
    const size_t cb = (size_t)b * (TT * HH * HD) + (size_t)(ch * CH) * (HH * HD) + h * HD;
    const float* Sg = Sin + (size_t)(bh * NCH + ch) * HD * HD;

#pragma unroll
    for (int i = 0; i < 9; ++i) {
        const int g = i * 256 + tid;
        const int k = g / 24, c4 = (g % 24) * 4;
        *(f32x4*)&Sl[k * 100 + c4] = *(const f32x4*)(Sg + (size_t)k * HD + c4);
    }
#pragma unroll
    for (int i = 0; i < 6; ++i) {
        const int g = i * 256 + tid;
        const int t = g / 24, c4 = (g % 24) * 4;
        *(f32x4*)&Ql[t * 100 + c4] = *(const f32x4*)(Qe + cb + (size_t)t * 768 + c4);
    }
#pragma unroll
    for (int i = 0; i < 3; ++i) {
        const int g = i * 256 + tid;
        const int t = g / 12, c8 = (g % 12) * 8;
        *(u16x8*)&Olb[t * 104 + c8] = *(const u16x8*)(Ol + cb + (size_t)t * 768 + c8);
        *(u16x8*)&Gl[t * 104 + c8]  = *(const u16x8*)(Gt + cb + (size_t)t * 768 + c8);
    }
    __syncthreads();

    const int t = tid >> 2, vq2 = tid & 3;
    const int v0 = vq2 * 24;
    f32x4 acc[6];
#pragma unroll
    for (int j = 0; j < 6; ++j) {
        acc[j].x = bf2f(Olb[t * 104 + v0 + j * 4 + 0]);
        acc[j].y = bf2f(Olb[t * 104 + v0 + j * 4 + 1]);
        acc[j].z = bf2f(Olb[t * 104 + v0 + j * 4 + 2]);
        acc[j].w = bf2f(Olb[t * 104 + v0 + j * 4 + 3]);
    }
#pragma unroll 2
    for (int k = 0; k < HD; ++k) {
        const float qv = Ql[t * 100 + k];
#pragma unroll
        for (int j = 0; j < 6; ++j)
            acc[j] += qv * *(const f32x4*)&Sl[k * 100 + v0 + j * 4];
    }
    float ss = 0.f;
#pragma unroll
    for (int j = 0; j < 6; ++j)
        ss += acc[j].x * acc[j].x + acc[j].y * acc[j].y + acc[j].z * acc[j].z + acc[j].w * acc[j].w;
    ss += __shfl_xor(ss, 1); ss += __shfl_xor(ss, 2);
    const float r = rsqrtf(ss * (1.f / HD) + 1e-6f);
#pragma unroll
    for (int j = 0; j < 6; ++j) {
#pragma unroll
        for (int e = 0; e < 4; ++e) {
            const int v = v0 + j * 4 + e;
            const float g = bf2f(Gl[t * 104 + v]);
            const float val = acc[j][e] * r * onw[v] * (g / (1.f + expf(-g)));
            obf[cb + (size_t)t * 768 + v] = f2bf(val);
        }
    }
}

// ---------------------------------------------------------------- host
extern "C" void kernel_launch(void* const* d_in, const int* in_sizes, int n_in,
                              void* d_out, int out_size, void* d_ws, size_t ws_size,
                              hipStream_t stream)
{
    (void)in_sizes; (void)n_in; (void)out_size; (void)ws_size;
    const float* hidden   = (const float*)d_in[0];
    const float* mask     = (const float*)d_in[1];
    const float* norm_a_w = (const float*)d_in[2];
    const float* norm_a_b = (const float*)d_in[3];
    const float* proj_a_w = (const float*)d_in[4];
    const float* proj_a_b = (const float*)d_in[5];
    const float* ln_w     = (const float*)d_in[6];
    const float* ln_b     = (const float*)d_in[7];
    const float* Wq       = (const float*)d_in[8];
    const float* Wk       = (const float*)d_in[9];
    const float* Wv       = (const float*)d_in[10];
    const float* Wfa      = (const float*)d_in[11];
    const float* Wfb      = (const float*)d_in[12];
    const float* dt_bias  = (const float*)d_in[13];
    const float* A_log    = (const float*)d_in[14];
    const float* Wb       = (const float*)d_in[15];
    const float* Wga      = (const float*)d_in[16];
    const float* Wgb      = (const float*)d_in[17];
    const float* onorm_w  = (const float*)d_in[18];
    const float* Wo       = (const float*)d_in[19];
    const float* Wgate    = (const float*)d_in[20];
    const float* Wup      = (const float*)d_in[21];
    const float* Wdown    = (const float*)d_in[22];

    float* ws    = (float*)d_ws;
    float* hbuf  = ws;
    float* qb    = ws + HROW;          // dead after pre -> Sin/mg live here
    float* kb    = ws + 2 * HROW;
    float* vb    = ws + 3 * HROW;      // U (f32)
    float* egb   = ws + 4 * HROW;      // g -> Qe (f32)
    float* betab = ws + 5 * HROW;                     // MM*HH
    float* BcP   = betab + (size_t)MM * HH;           // 32*32*96
    float* SinP  = qb;                                // 9.44M floats (qb+kb region)
    unsigned short* bfp = (unsigned short*)(BcP + 32 * NCH * HD);
    unsigned short* x_bf    = bfp;  bfp += HROW;
    unsigned short* fab_bf  = bfp;  bfp += (size_t)MM * HD;
    unsigned short* gab_bf  = bfp;  bfp += (size_t)MM * HD;
    unsigned short* gate_bf = bfp;  bfp += HROW;
    unsigned short* olb_bf  = bfp;  bfp += HROW;
    unsigned short* w_bf    = bfp;  bfp += HROW;
    unsigned short* k_bf    = bfp;  bfp += HROW;      // ktil^T [bh][ch][96][64]
    unsigned short* wt_proj = bfp;  bfp += 768 * 768;
    unsigned short *wt_q[LL], *wt_k[LL], *wt_v[LL], *wt_o[LL], *wt_fb[LL], *wt_gb[LL],
                   *wt_fg[LL], *wt_gate[LL], *wt_up[LL], *wt_down[LL];
    for (int l = 0; l < LL; ++l) {
        wt_q[l] = bfp;    bfp += 768 * 768;   // q,k,v contiguous -> fused N=2304 GEMM
        wt_k[l] = bfp;    bfp += 768 * 768;
        wt_v[l] = bfp;    bfp += 768 * 768;
        wt_o[l] = bfp;    bfp += 768 * 768;
        wt_fb[l] = bfp;   bfp += 768 * 96;
        wt_gb[l] = bfp;   bfp += 768 * 96;
        wt_fg[l] = bfp;   bfp += 192 * 768;   // [Wfa^T | Wga^T]
        wt_gate[l] = bfp; bfp += 2048 * 768;
        wt_up[l] = bfp;   bfp += 2048 * 768;
        wt_down[l] = bfp; bfp += 768 * 2048;
    }
    unsigned short* mg_bf = (unsigned short*)SinP;  // Sin dead after epi
    unsigned short* a_bf  = (unsigned short*)vb;    // U dead after seq

    float* out    = (float*)d_out;
    float* states = out + HROW;

    // weight transpose+convert
    transcvt<<<dim3(24, 24), 256, 0, stream>>>(proj_a_w, wt_proj, 768, 768);
    for (int l = 0; l < LL; ++l) {
        transcvt<<<dim3(24, 24), 256, 0, stream>>>(Wq + (size_t)l * 589824, wt_q[l], 768, 768);
        transcvt<<<dim3(24, 24), 256, 0, stream>>>(Wk + (size_t)l * 589824, wt_k[l], 768, 768);
        transcvt<<<dim3(24, 24), 256, 0, stream>>>(Wv + (size_t)l * 589824, wt_v[l], 768, 768);
        transcvt<<<dim3(24, 24), 256, 0, stream>>>(Wo + (size_t)l * 589824, wt_o[l], 768, 768);
        transcvt<<<dim3(24, 3), 256, 0, stream>>>(Wfb + (size_t)l * 73728, wt_fb[l], 96, 768);
        transcvt<<<dim3(24, 3), 256, 0, stream>>>(Wgb + (size_t)l * 73728, wt_gb[l], 96, 768);
        transcvt<<<dim3(3, 24), 256, 0, stream>>>(Wfa + (size_t)l * 73728, wt_fg[l], 768, 96);
        transcvt<<<dim3(3, 24), 256, 0, stream>>>(Wga + (size_t)l * 73728, wt_fg[l] + 96 * 768, 768, 96);
        transcvt<<<dim3(64, 24), 256, 0, stream>>>(Wgate + (size_t)l * 1572864, wt_gate[l], 768, 2048);
        transcvt<<<dim3(64, 24), 256, 0, stream>>>(Wup + (size_t)l * 1572864, wt_up[l], 768, 2048);
        transcvt<<<dim3(24, 64), 256, 0, stream>>>(Wdown + (size_t)l * 1572864, wt_down[l], 2048, 768);
    }

    layernorm_rows<<<MM, 256, 0, stream>>>(hidden, x_bf, norm_a_w, norm_a_b, nullptr);
    bgemm<BE_BIAS><<<dim3(6, 64), 256, 0, stream>>>(x_bf, wt_proj, hbuf, nullptr,
                                                    proj_a_b, nullptr, MM, DD, DD);

    for (int l = 0; l < LL; ++l) {
        layernorm_rows<<<MM, 256, 0, stream>>>(hbuf, x_bf, ln_w + l * DD, ln_b + l * DD, mask);
        // fused q|k|v = silu(x @ [Wq|Wk|Wv]) -> qb, kb, vb
        bgemm<BE_QKV><<<dim3(18, 64), 256, 0, stream>>>(x_bf, wt_q[l], qb, nullptr,
                                                        kb, vb, MM, 3 * DD, DD);
        l2norm_rows<<<(MM * HH) / 4, 256, 0, stream>>>(qb, 0.1020620726159658f);
        l2norm_rows<<<(MM * HH) / 4, 256, 0, stream>>>(kb, 1.f);
        // fa|ga = x @ [Wfa|Wga]  (bf16, one MFMA dispatch)
        bgemm_fg<<<dim3(3, 64), 256, 0, stream>>>(x_bf, wt_fg[l], fab_bf, gab_bf, DD);
        bgemm<BE_EG><<<dim3(6, 64), 256, 0, stream>>>(fab_bf, wt_fb[l], egb, nullptr,
                                                      A_log + l * DD, dt_bias + l * DD, MM, DD, HD);
        gemm_small<1><<<dim3(1, 128), 256, 0, stream>>>(x_bf, Wb + (size_t)l * DD * HH, nullptr, betab, MM, HH, DD);
        // gate before scan (x_bf gets overwritten by o in epi)
        bgemm<BE_BF16><<<dim3(6, 64), 256, 0, stream>>>(gab_bf, wt_gb[l], nullptr, gate_bf, nullptr, nullptr, MM, DD, HD);
        // chunkwise scan
        kda_pre<<<1024, 256, 0, stream>>>(qb, kb, vb, egb, betab, olb_bf, BcP, w_bf, k_bf);
        kda_seq<<<192, 256, 0, stream>>>(w_bf, k_bf, vb, BcP, SinP,
                                         states + (size_t)l * BB * HH * HD * HD);
        kda_epi<<<1024, 256, 0, stream>>>(SinP, egb, olb_bf, gate_bf, onorm_w + l * HD, x_bf);
        // a = o @ Wo
        bgemm<BE_BF16><<<dim3(6, 64), 256, 0, stream>>>(x_bf, wt_o[l], nullptr, a_bf, nullptr, nullptr, MM, DD, DD);
        // swiglu
        bgemm_dual<<<dim3(32, 64), 256, 0, stream>>>(a_bf, wt_gate[l], wt_up[l], mg_bf, MM, FF, DD);
        float* dst = (l == LL - 1) ? out : hbuf;
        bgemm<BE_RES><<<dim3(6, 64), 256, 0, stream>>>(mg_bf, wt_down[l], dst, nullptr,
                                                       hbuf, nullptr, MM, DD, FF);
    }
}

// Round 12
// 1164.955 us; speedup vs baseline: 3.3702x; 1.0232x over previous
//
#include <hip/hip_runtime.h>
#include <cstddef>
#include <cstdint>
#include <cmath>

// Problem constants
constexpr int BB = 4, TT = 2048, DD = 768, HH = 8, HD = 96, FF = 2048, LL = 2;
constexpr int MM = BB * TT;              // 8192
constexpr size_t HROW = (size_t)MM * DD; // 6291456
constexpr int CH = 64;                   // scan chunk length
constexpr int NCH = TT / CH;             // 32 chunks per sequence
constexpr int RP = 100;                  // padded LDS row (floats)
constexpr int KP = 104;                  // padded LDS row (ushorts)

typedef float f32x4 __attribute__((ext_vector_type(4)));
typedef short bf16x8 __attribute__((ext_vector_type(8)));
typedef unsigned short u16x8 __attribute__((ext_vector_type(8)));

__device__ __forceinline__ void gload16(const void* g, void* l) {
    __builtin_amdgcn_global_load_lds(
        (const __attribute__((address_space(1))) void*)g,
        (__attribute__((address_space(3))) void*)l, 16, 0, 0);
}
__device__ __forceinline__ float bf2f(unsigned short u) {
    return __uint_as_float(((unsigned)u) << 16);
}
__device__ __forceinline__ unsigned short f2bf(float f) {
    unsigned u = __float_as_uint(f);
    unsigned r = (u + 0x7fffu + ((u >> 16) & 1u)) >> 16;
    return (unsigned short)r;
}

// ---------------------------------------------------------------- LayerNorm -> bf16
__global__ __launch_bounds__(256)
void layernorm_rows(const float* __restrict__ x, unsigned short* __restrict__ y,
                    const float* __restrict__ w, const float* __restrict__ b,
                    const float* mask)
{
    const int row = blockIdx.x;
    const int tid = threadIdx.x;
    const float* xr = x + (size_t)row * DD;
    float v0 = xr[tid], v1 = xr[tid + 256], v2 = xr[tid + 512];
    float s = v0 + v1 + v2;
    float ss = v0 * v0 + v1 * v1 + v2 * v2;
#pragma unroll
    for (int i = 1; i < 64; i <<= 1) { s += __shfl_xor(s, i); ss += __shfl_xor(ss, i); }
    __shared__ float red[8];
    const int wid = tid >> 6, lane = tid & 63;
    if (lane == 0) { red[wid] = s; red[4 + wid] = ss; }
    __syncthreads();
    const float S  = red[0] + red[1] + red[2] + red[3];
    const float SS = red[4] + red[5] + red[6] + red[7];
    const float mean = S * (1.f / DD);
    const float var  = SS * (1.f / DD) - mean * mean;
    const float rstd = rsqrtf(var + 1e-5f);
    const float m = mask ? mask[row] : 1.f;
    unsigned short* yr = y + (size_t)row * DD;
    yr[tid]       = f2bf(((v0 - mean) * rstd * w[tid]       + b[tid])       * m);
    yr[tid + 256] = f2bf(((v1 - mean) * rstd * w[tid + 256] + b[tid + 256]) * m);
    yr[tid + 512] = f2bf(((v2 - mean) * rstd * w[tid + 512] + b[tid + 512]) * m);
}

// ---------------------------------------------------------------- transpose+convert W
__global__ __launch_bounds__(256)
void transcvt(const float* __restrict__ in, unsigned short* __restrict__ out, int K, int N)
{
    __shared__ float t[32][33];
    const int tx = threadIdx.x & 31, ty = threadIdx.x >> 5;
    const int k0 = blockIdx.y * 32, n0 = blockIdx.x * 32;
#pragma unroll
    for (int i = 0; i < 4; ++i)
        t[ty + i * 8][tx] = in[(size_t)(k0 + ty + i * 8) * N + n0 + tx];
    __syncthreads();
#pragma unroll
    for (int i = 0; i < 4; ++i)
        out[(size_t)(n0 + ty + i * 8) * K + k0 + tx] = f2bf(t[tx][ty + i * 8]);
}

// ---------------------------------------------------------------- bf16 MFMA GEMM
// NH = number of 32-col K-halves staged per barrier phase (1 or 2).
enum { BE_BIAS = 0, BE_SILU, BE_EG, BE_F32, BE_BF16, BE_RES, BE_QKV };

template <int EPI, int NH>
__global__ __launch_bounds__(256)
void bgemm(const unsigned short* __restrict__ A, const unsigned short* __restrict__ Bt,
           float* Cf, unsigned short* Cb,
           const float* P0, const float* P1,
           int M, int N, int K)
{
    __shared__ unsigned short As[NH][128 * 32];
    __shared__ unsigned short Bs[NH][128 * 32];
    const int tid = threadIdx.x;
    const int w = tid >> 6, l = tid & 63;
    const int wm = w >> 1, wn = w & 1;
    const int lr = l & 15, lh = l >> 4;
    const int m0 = blockIdx.y * 128, n0 = blockIdx.x * 128;

    f32x4 acc[4][4];
#pragma unroll
    for (int i = 0; i < 4; ++i)
#pragma unroll
        for (int j = 0; j < 4; ++j) acc[i][j] = (f32x4){0.f, 0.f, 0.f, 0.f};

    const int sr = l >> 2, sq = (l & 3) * 8;
    const unsigned short* Ag = A + (size_t)(m0 + w * 32 + sr) * K + sq;
    const unsigned short* Bg = Bt + (size_t)(n0 + w * 32 + sr) * K + sq;
    const int lofs = (w * 32) * 32;

    for (int kt = 0; kt < K; kt += 32 * NH) {
        __syncthreads();
#pragma unroll
        for (int hh = 0; hh < NH; ++hh) {
            gload16(Ag + kt + hh * 32, &As[hh][lofs]);
            gload16(Ag + kt + hh * 32 + 16 * (size_t)K, &As[hh][lofs + 16 * 32]);
            gload16(Bg + kt + hh * 32, &Bs[hh][lofs]);
            gload16(Bg + kt + hh * 32 + 16 * (size_t)K, &Bs[hh][lofs + 16 * 32]);
        }
        __syncthreads();
#pragma unroll
        for (int hh = 0; hh < NH; ++hh) {
            bf16x8 af[4], bfv[4];
#pragma unroll
            for (int mi = 0; mi < 4; ++mi)
                af[mi] = *(const bf16x8*)&As[hh][(wm * 64 + mi * 16 + lr) * 32 + lh * 8];
#pragma unroll
            for (int ni = 0; ni < 4; ++ni)
                bfv[ni] = *(const bf16x8*)&Bs[hh][(wn * 64 + ni * 16 + lr) * 32 + lh * 8];
#pragma unroll
            for (int mi = 0; mi < 4; ++mi)
#pragma unroll
                for (int ni = 0; ni < 4; ++ni)
                    acc[mi][ni] = __builtin_amdgcn_mfma_f32_16x16x32_bf16(af[mi], bfv[ni], acc[mi][ni], 0, 0, 0);
        }
    }

#pragma unroll
    for (int mi = 0; mi < 4; ++mi) {
#pragma unroll
        for (int j = 0; j < 4; ++j) {
            const int row = m0 + wm * 64 + mi * 16 + lh * 4 + j;
#pragma unroll
            for (int ni = 0; ni < 4; ++ni) {
                const int col = n0 + wn * 64 + ni * 16 + lr;
                const size_t idx = (size_t)row * N + col;
                float v = acc[mi][ni][j];
                if constexpr (EPI == BE_BIAS) { Cf[idx] = v + P0[col]; }
                else if constexpr (EPI == BE_SILU) { Cf[idx] = v / (1.f + expf(-v)); }
                else if constexpr (EPI == BE_EG) {
                    const float lin = v + P1[col];
                    const float sp = (lin > 20.f) ? lin : log1pf(expf(lin));
                    Cf[idx] = -expf(P0[col]) * sp;      // raw log-decay g
                }
                else if constexpr (EPI == BE_F32) { Cf[idx] = v; }
                else if constexpr (EPI == BE_BF16) { Cb[idx] = f2bf(v); }
                else if constexpr (EPI == BE_RES) { Cf[idx] = v + P0[idx]; }
                else if constexpr (EPI == BE_QKV) {
                    const int tgt = col / 768;
                    const int cl = col - tgt * 768;
                    float* dst = (tgt == 0) ? Cf
                               : (tgt == 1) ? const_cast<float*>(P0)
                                            : const_cast<float*>(P1);
                    dst[(size_t)row * 768 + cl] = v / (1.f + expf(-v));
                }
            }
        }
    }
}

// Dual-B GEMM for SwiGLU (BK=64 via half-buffers)
__global__ __launch_bounds__(256)
void bgemm_dual(const unsigned short* __restrict__ A,
                const unsigned short* __restrict__ Bg_, const unsigned short* __restrict__ Bu_,
                unsigned short* __restrict__ C, int M, int N, int K)
{
    __shared__ unsigned short As[2][128 * 32];
    __shared__ unsigned short Bs1[2][64 * 32];
    __shared__ unsigned short Bs2[2][64 * 32];
    const int tid = threadIdx.x;
    const int w = tid >> 6, l = tid & 63;
    const int wm = w >> 1, wn = w & 1;
    const int lr = l & 15, lh = l >> 4;
    const int m0 = blockIdx.y * 128, n0 = blockIdx.x * 64;

    f32x4 a1[4][2], a2[4][2];
#pragma unroll
    for (int i = 0; i < 4; ++i)
#pragma unroll
        for (int j = 0; j < 2; ++j) { a1[i][j] = (f32x4){0.f,0.f,0.f,0.f}; a2[i][j] = (f32x4){0.f,0.f,0.f,0.f}; }

    const int sr = l >> 2, sq = (l & 3) * 8;
    const unsigned short* Ag  = A   + (size_t)(m0 + w * 32 + sr) * K + sq;
    const unsigned short* B1g = Bg_ + (size_t)(n0 + w * 16 + sr) * K + sq;
    const unsigned short* B2g = Bu_ + (size_t)(n0 + w * 16 + sr) * K + sq;
    const int aofs = (w * 32) * 32;
    const int bofs = (w * 16) * 32;

    for (int kt = 0; kt < K; kt += 64) {
        __syncthreads();
#pragma unroll
        for (int hh = 0; hh < 2; ++hh) {
            gload16(Ag + kt + hh * 32, &As[hh][aofs]);
            gload16(Ag + kt + hh * 32 + 16 * (size_t)K, &As[hh][aofs + 16 * 32]);
            gload16(B1g + kt + hh * 32, &Bs1[hh][bofs]);
            gload16(B2g + kt + hh * 32, &Bs2[hh][bofs]);
        }
        __syncthreads();
#pragma unroll
        for (int hh = 0; hh < 2; ++hh) {
            bf16x8 af[4], b1[2], b2[2];
#pragma unroll
            for (int mi = 0; mi < 4; ++mi)
                af[mi] = *(const bf16x8*)&As[hh][(wm * 64 + mi * 16 + lr) * 32 + lh * 8];
#pragma unroll
            for (int ni = 0; ni < 2; ++ni) {
                b1[ni] = *(const bf16x8*)&Bs1[hh][(wn * 32 + ni * 16 + lr) * 32 + lh * 8];
                b2[ni] = *(const bf16x8*)&Bs2[hh][(wn * 32 + ni * 16 + lr) * 32 + lh * 8];
            }
#pragma unroll
            for (int mi = 0; mi < 4; ++mi)
#pragma unroll
                for (int ni = 0; ni < 2; ++ni) {
                    a1[mi][ni] = __builtin_amdgcn_mfma_f32_16x16x32_bf16(af[mi], b1[ni], a1[mi][ni], 0, 0, 0);
                    a2[mi][ni] = __builtin_amdgcn_mfma_f32_16x16x32_bf16(af[mi], b2[ni], a2[mi][ni], 0, 0, 0);
                }
        }
    }

#pragma unroll
    for (int mi = 0; mi < 4; ++mi)
#pragma unroll
        for (int j = 0; j < 4; ++j) {
            const int row = m0 + wm * 64 + mi * 16 + lh * 4 + j;
#pragma unroll
            for (int ni = 0; ni < 2; ++ni) {
                const int col = n0 + wn * 32 + ni * 16 + lr;
                const float g = a1[mi][ni][j], u = a2[mi][ni][j];
                C[(size_t)row * N + col] = f2bf((g / (1.f + expf(-g))) * u);
            }
        }
}

// fa|ga fused GEMM (BK=64): N fixed 192 ([Wfa|Wga]^T), routing epilogue.
__global__ __launch_bounds__(256)
void bgemm_fg(const unsigned short* __restrict__ A, const unsigned short* __restrict__ Bt,
              unsigned short* __restrict__ Cfa, unsigned short* __restrict__ Cga, int K)
{
    __shared__ unsigned short As[2][128 * 32];
    __shared__ unsigned short Bs[2][64 * 32];
    const int tid = threadIdx.x;
    const int w = tid >> 6, l = tid & 63;
    const int wm = w >> 1, wn = w & 1;
    const int lr = l & 15, lh = l >> 4;
    const int m0 = blockIdx.y * 128, n0 = blockIdx.x * 64;

    f32x4 acc[4][2];
#pragma unroll
    for (int i = 0; i < 4; ++i)
#pragma unroll
        for (int j = 0; j < 2; ++j) acc[i][j] = (f32x4){0.f, 0.f, 0.f, 0.f};

    const int sr = l >> 2, sq = (l & 3) * 8;
    const unsigned short* Ag = A + (size_t)(m0 + w * 32 + sr) * K + sq;
    const unsigned short* Bg = Bt + (size_t)(n0 + w * 16 + sr) * K + sq;
    const int aofs = (w * 32) * 32;
    const int bofs = (w * 16) * 32;

    for (int kt = 0; kt < K; kt += 64) {
        __syncthreads();
#pragma unroll
        for (int hh = 0; hh < 2; ++hh) {
            gload16(Ag + kt + hh * 32, &As[hh][aofs]);
            gload16(Ag + kt + hh * 32 + 16 * (size_t)K, &As[hh][aofs + 16 * 32]);
            gload16(Bg + kt + hh * 32, &Bs[hh][bofs]);
        }
        __syncthreads();
#pragma unroll
        for (int hh = 0; hh < 2; ++hh) {
            bf16x8 af[4], bfv[2];
#pragma unroll
            for (int mi = 0; mi < 4; ++mi)
                af[mi] = *(const bf16x8*)&As[hh][(wm * 64 + mi * 16 + lr) * 32 + lh * 8];
#pragma unroll
            for (int ni = 0; ni < 2; ++ni)
                bfv[ni] = *(const bf16x8*)&Bs[hh][(wn * 32 + ni * 16 + lr) * 32 + lh * 8];
#pragma unroll
            for (int mi = 0; mi < 4; ++mi)
#pragma unroll
                for (int ni = 0; ni < 2; ++ni)
                    acc[mi][ni] = __builtin_amdgcn_mfma_f32_16x16x32_bf16(af[mi], bfv[ni], acc[mi][ni], 0, 0, 0);
        }
    }

#pragma unroll
    for (int mi = 0; mi < 4; ++mi)
#pragma unroll
        for (int j = 0; j < 4; ++j) {
            const int row = m0 + wm * 64 + mi * 16 + lh * 4 + j;
#pragma unroll
            for (int ni = 0; ni < 2; ++ni) {
                const int col = n0 + wn * 32 + ni * 16 + lr;   // 0..191, 16-aligned tiles
                const int tgt = (col >= HD);
                const int cl = col - (tgt ? HD : 0);
                unsigned short* dst = tgt ? Cga : Cfa;
                dst[(size_t)row * HD + cl] = f2bf(acc[mi][ni][j]);
            }
        }
}

// ---------------------------------------------------------------- small fp32 GEMM (A bf16)
template <int MODE>
__global__ __launch_bounds__(256)
void gemm_small(const unsigned short* __restrict__ A, const float* __restrict__ Bm,
                unsigned short* Cb, float* Cf, int M, int N, int K)
{
    __shared__ float As[16][64];
    __shared__ float Bs[16][64];
    const int tid = threadIdx.x;
    const int tx = tid & 15, ty = tid >> 4;
    const int row0 = blockIdx.y * 64;
    const int col0 = blockIdx.x * 64;
    float acc[4][4] = {};
    const int ar  = tid >> 2;
    const int ac4 = (tid & 3) << 2;
    const int br  = tid >> 4;
    const int bc  = (tid & 15) << 2;
    const int gc  = col0 + bc;
    const bool bok = gc < N;

    for (int kt = 0; kt < K; kt += 16) {
        const ushort4 a4 = *(const ushort4*)(A + (size_t)(row0 + ar) * K + kt + ac4);
        float4 b4 = make_float4(0.f, 0.f, 0.f, 0.f);
        if (bok) b4 = *(const float4*)(Bm + (size_t)(kt + br) * N + gc);
        __syncthreads();
        As[ac4 + 0][ar] = bf2f(a4.x); As[ac4 + 1][ar] = bf2f(a4.y);
        As[ac4 + 2][ar] = bf2f(a4.z); As[ac4 + 3][ar] = bf2f(a4.w);
        *(float4*)&Bs[br][bc] = b4;
        __syncthreads();
#pragma unroll
        for (int kk = 0; kk < 16; ++kk) {
            const float4 av = *(const float4*)&As[kk][ty << 2];
            const float4 bv = *(const float4*)&Bs[kk][tx << 2];
            const float a_[4] = {av.x, av.y, av.z, av.w};
            const float b_[4] = {bv.x, bv.y, bv.z, bv.w};
#pragma unroll
            for (int i = 0; i < 4; ++i)
#pragma unroll
                for (int j = 0; j < 4; ++j)
                    acc[i][j] = fmaf(a_[i], b_[j], acc[i][j]);
        }
    }
#pragma unroll
    for (int i = 0; i < 4; ++i) {
        const int row = row0 + (ty << 2) + i;
#pragma unroll
        for (int j = 0; j < 4; ++j) {
            const int col = col0 + (tx << 2) + j;
            if (col >= N) continue;
            const size_t idx = (size_t)row * N + col;
            if constexpr (MODE == 0) Cb[idx] = f2bf(acc[i][j]);
            else                     Cf[idx] = 1.f / (1.f + expf(-acc[i][j]));
        }
    }
}

// ---------------------------------------------------------------- l2norm over HD=96
__global__ __launch_bounds__(256)
void l2norm_rows(float* x, float scale)
{
    const int row  = (blockIdx.x << 2) + (threadIdx.x >> 6);
    const int lane = threadIdx.x & 63;
    float* xr = x + (size_t)row * HD;
    const float a = xr[lane];
    const float b = (lane < 32) ? xr[64 + lane] : 0.f;
    float ss = a * a + b * b;
#pragma unroll
    for (int i = 1; i < 64; i <<= 1) ss += __shfl_xor(ss, i);
    const float r = rsqrtf(ss + 1e-6f) * scale;
    xr[lane] = a * r;
    if (lane < 32) xr[64 + lane] = b * r;
}

// ---------------------------------------------------------------- KDA chunkwise precompute
constexpr int TBP = 72;   // Tb row pad (u16)
constexpr int XLP = 72;   // Xl row pad (u16)
__global__ __launch_bounds__(256)
void kda_pre(const float* __restrict__ q, const float* __restrict__ k, float* v, float* g,
             const float* __restrict__ beta,
             unsigned short* __restrict__ ol, float* __restrict__ Bc,
             unsigned short* __restrict__ Wbf, unsigned short* __restrict__ Ktg)
{
    __shared__ unsigned short Kb[CH * KP];   // k (bf16), then kappa_tilde (bf16)
    __shared__ float Qp[CH * RP];            // g -> L -> q'
    __shared__ float sb[CH];
    __shared__ __align__(16) char uR[36864];
    unsigned short* Kk = (unsigned short*)uR;
    float (*Am)[68] = (float(*)[68])(uR + 13312);
    unsigned short* Tb = (unsigned short*)uR;
    unsigned short* Xl = (unsigned short*)(uR + 9216);

    const int blk = blockIdx.x;
    const int ch = blk & 31, bh = blk >> 5;
    const int b = bh >> 3, h = bh & 7;
    const int tid = threadIdx.x;
    const size_t base = (size_t)b * (TT * HH * HD) + (size_t)(ch * CH) * (HH * HD) + h * HD;

    // P0: stage k (as bf16), g (f32), beta
    for (int e = tid; e < CH * 24; e += 256) {
        const int t = e / 24, c4 = (e % 24) * 4;
        const float4 kv = *(const float4*)(k + base + t * 768 + c4);
        ushort4 k4;
        k4.x = f2bf(kv.x); k4.y = f2bf(kv.y); k4.z = f2bf(kv.z); k4.w = f2bf(kv.w);
        *(ushort4*)&Kb[t * KP + c4] = k4;
        *(float4*)&Qp[t * RP + c4] = *(const float4*)(g + base + t * 768 + c4);
    }
    if (tid < CH) sb[tid] = beta[((size_t)b * TT + ch * CH + tid) * HH + h];
    __syncthreads();

    // P1: per-channel cumsum of g
    if (tid < HD) {
        float L = 0.f;
        for (int t = 0; t < CH; ++t) { L += Qp[t * RP + tid]; Qp[t * RP + tid] = L; }
    }
    __syncthreads();

    // P2: kappa, kappa_tilde (bf16), q', Bc
    for (int e = tid; e < CH * HD; e += 256) {
        const int t = e / HD, c = e % HD;
        const float L = Qp[t * RP + c];
        const float B = expf(L), iB = expf(-L);
        const float kv = bf2f(Kb[t * KP + c]);
        if (t == CH - 1) Bc[((size_t)bh * NCH + ch) * HD + c] = B;
        Kk[t * KP + c] = f2bf(kv * B);
        const unsigned short kti = f2bf(kv * iB);
        const float qv = q[base + t * 768 + c];
        Kb[t * KP + c] = kti;
        Qp[t * RP + c] = qv * B;                  // q'
    }
    __syncthreads();

    // P2b: export ktil^T -> Ktg[(bh,ch)][c][t]
#pragma unroll
    for (int i = 0; i < 3; ++i) {
        const int u = i * 256 + tid;
        const int c = u / 8, t8 = (u % 8) * 8;
        u16x8 vv;
#pragma unroll
        for (int j = 0; j < 8; ++j) vv[j] = Kb[(t8 + j) * KP + c];
        *(u16x8*)(Ktg + (((size_t)bh * NCH + ch) * HD + c) * CH + t8) = vv;
    }

    // P3 (MFMA): A[t][i] = beta_t * (kappa_t . ktil_i), i < t
    {
        const int lane = tid & 63;
        const int lr = lane & 15, lh = lane >> 4;
        const int t0 = (tid >> 6) * 16;
        bf16x8 afr[3];
#pragma unroll
        for (int ks = 0; ks < 3; ++ks)
            afr[ks] = *(const bf16x8*)&Kk[(t0 + lr) * KP + ks * 32 + lh * 8];
#pragma unroll
        for (int i0 = 0; i0 < 64; i0 += 16) {
            f32x4 acc = (f32x4){0.f, 0.f, 0.f, 0.f};
#pragma unroll
            for (int ks = 0; ks < 3; ++ks) {
                const bf16x8 bfr = *(const bf16x8*)&Kb[(i0 + lr) * KP + ks * 32 + lh * 8];
                acc = __builtin_amdgcn_mfma_f32_16x16x32_bf16(afr[ks], bfr, acc, 0, 0, 0);
            }
#pragma unroll
            for (int r = 0; r < 4; ++r) {
                const int t = t0 + lh * 4 + r;
                const int i = i0 + lr;
                Am[t][i] = (i < t) ? acc[r] * sb[t] : 0.f;
            }
        }
    }
    __syncthreads();

    // P4: forward solve, column j of [U | W] in registers
    float X[CH];
    const int j = tid;
    if (j < 192) {
        if (j < HD) {
#pragma unroll
            for (int t = 0; t < CH; ++t) X[t] = sb[t] * v[base + t * 768 + j];
        } else {
#pragma unroll
            for (int t = 0; t < CH; ++t) X[t] = sb[t] * bf2f(Kk[t * KP + (j - HD)]);
        }
#pragma unroll
        for (int t = 1; t < CH; ++t) {
            float a0 = 0, a1 = 0, a2 = 0, a3 = 0;
#pragma unroll
            for (int i4 = 0; i4 * 4 < t; ++i4) {
                const float4 a = *(const float4*)&Am[t][i4 * 4];
                if (i4 * 4 + 0 < t) a0 = fmaf(a.x, X[i4 * 4 + 0], a0);
                if (i4 * 4 + 1 < t) a1 = fmaf(a.y, X[i4 * 4 + 1], a1);
                if (i4 * 4 + 2 < t) a2 = fmaf(a.z, X[i4 * 4 + 2], a2);
                if (i4 * 4 + 3 < t) a3 = fmaf(a.w, X[i4 * 4 + 3], a3);
            }
            X[t] -= ((a0 + a1) + (a2 + a3));
        }
        // P5: store U (f32 over v) / -W (bf16)
        if (j < HD) {
#pragma unroll
            for (int t = 0; t < CH; ++t) v[base + t * 768 + j] = X[t];
        } else {
#pragma unroll
            for (int t = 0; t < CH; ++t) Wbf[base + t * 768 + (j - HD)] = f2bf(-X[t]);
        }
    }
    __syncthreads();   // Am/Kk dead past here

    // phase 2a: X -> Xl (bf16, [j][t]); P6 (MFMA): T -> Tb (bf16, [t][i])
    if (j < 192) {
#pragma unroll
        for (int t8 = 0; t8 < 8; ++t8) {
            u16x8 xv;
#pragma unroll
            for (int jj = 0; jj < 8; ++jj) xv[jj] = f2bf(X[t8 * 8 + jj]);
            *(u16x8*)&Xl[j * XLP + t8 * 8] = xv;
        }
    }
    {
        const int lane = tid & 63;
        const int lr = lane & 15, lh = lane >> 4;
        const int t0 = (tid >> 6) * 16;
        bf16x8 afr[3];
#pragma unroll
        for (int ks = 0; ks < 3; ++ks) {
            const float4 qa = *(const float4*)&Qp[(t0 + lr) * RP + ks * 32 + lh * 8];
            const float4 qc = *(const float4*)&Qp[(t0 + lr) * RP + ks * 32 + lh * 8 + 4];
            bf16x8 a;
            a[0] = (short)f2bf(qa.x); a[1] = (short)f2bf(qa.y);
            a[2] = (short)f2bf(qa.z); a[3] = (short)f2bf(qa.w);
            a[4] = (short)f2bf(qc.x); a[5] = (short)f2bf(qc.y);
            a[6] = (short)f2bf(qc.z); a[7] = (short)f2bf(qc.w);
            afr[ks] = a;
        }
#pragma unroll
        for (int i0 = 0; i0 < 64; i0 += 16) {
            f32x4 acc = (f32x4){0.f, 0.f, 0.f, 0.f};
#pragma unroll
            for (int ks = 0; ks < 3; ++ks) {
                const bf16x8 bfr = *(const bf16x8*)&Kb[(i0 + lr) * KP + ks * 32 + lh * 8];
                acc = __builtin_amdgcn_mfma_f32_16x16x32_bf16(afr[ks], bfr, acc, 0, 0, 0);
            }
#pragma unroll
            for (int r = 0; r < 4; ++r) {
                const int t = t0 + lh * 4 + r;
                const int i = i0 + lr;
                Tb[t * TBP + i] = (i <= t) ? f2bf(acc[r]) : (unsigned short)0;
            }
        }
    }
    __syncthreads();

    // P7 (MFMA): res = T @ X ; j<96 -> Ol ; j>=96 -> Qe = q' - res
    {
        const int lane = tid & 63;
        const int lr = lane & 15, lh = lane >> 4;
        const int w = tid >> 6;
        const int t0 = w * 16;
        bf16x8 af0 = *(const bf16x8*)&Tb[(t0 + lr) * TBP + lh * 8];
        bf16x8 af1 = *(const bf16x8*)&Tb[(t0 + lr) * TBP + 32 + lh * 8];
#pragma unroll
        for (int nt = 0; nt < 12; ++nt) {
            const int n0 = nt * 16;
            f32x4 acc = (f32x4){0.f, 0.f, 0.f, 0.f};
            acc = __builtin_amdgcn_mfma_f32_16x16x32_bf16(
                af0, *(const bf16x8*)&Xl[(n0 + lr) * XLP + lh * 8], acc, 0, 0, 0);
            acc = __builtin_amdgcn_mfma_f32_16x16x32_bf16(
                af1, *(const bf16x8*)&Xl[(n0 + lr) * XLP + 32 + lh * 8], acc, 0, 0, 0);
            const int jc = n0 + lr;
#pragma unroll
            for (int r = 0; r < 4; ++r) {
                const int t = t0 + lh * 4 + r;
                if (jc < HD) ol[base + t * 768 + jc] = f2bf(acc[r]);
                else         g[base + t * 768 + (jc - HD)] = Qp[t * RP + (jc - HD)] - acc[r];
            }
        }
    }
}

// ---------------------------------------------------------------- KDA sequential recurrence (MFMA form)
constexpr int VSL = 16;
constexpr int WNP = 120;  // Wn row pad (u16)
constexpr int KTP2 = 72;  // Kt row pad
constexpr int DBP = 72;   // Dbt row pad
constexpr int SBP = 120;  // Sbt row pad
__global__ __launch_bounds__(256)
void kda_seq(const unsigned short* __restrict__ Wbf, const unsigned short* __restrict__ Ktg,
             const float* __restrict__ U, const float* __restrict__ Bc,
             float* __restrict__ Sin, float* __restrict__ states)
{
    __shared__ unsigned short Wn[CH * WNP];    // -W bf16, [t][k]
    __shared__ unsigned short Kt[HD * KTP2];   // ktil^T bf16, [k][t]
    __shared__ unsigned short Dbt[VSL * DBP];  // delta^T bf16, [v][t]
    __shared__ unsigned short Sbt[VSL * SBP];  // S^T bf16, [v][k]

    const int blk = blockIdx.x;
    const int bh = blk / 6, vq = blk - bh * 6;
    const int b = bh >> 3, h = bh & 7;
    const int tid = threadIdx.x;
    const int w = tid >> 6, lane = tid & 63;
    const int lr = lane & 15, lh = lane >> 4;
    const int v0 = vq * VSL;
    const size_t base = (size_t)b * (TT * HH * HD) + h * HD;
    const size_t cbase = (size_t)bh * NCH;

    const int t0 = w * 16;
    const int k1 = w * 16;
    const int k2 = (w < 2) ? (4 + w) * 16 : -1;

    f32x4 accS1 = (f32x4){0.f, 0.f, 0.f, 0.f};
    f32x4 accS2 = (f32x4){0.f, 0.f, 0.f, 0.f};

    for (int e = tid; e < VSL * SBP; e += 256) Sbt[e] = 0;

    u16x8 wpf[3], kpf[3];
    float upf[4], ucur[4];

    // ---- stage chunk 0
    {
        const size_t cb = base;
#pragma unroll
        for (int i = 0; i < 3; ++i) {
            const int u = i * 256 + tid;
            const int r = u / 12, c8 = (u % 12) * 8;
            wpf[i] = *(const u16x8*)(Wbf + cb + (size_t)r * 768 + c8);
        }
        const size_t kb_ = (cbase * HD) * CH;
#pragma unroll
        for (int i = 0; i < 3; ++i) {
            const int u = i * 256 + tid;
            const int c = u / 8, t8 = (u % 8) * 8;
            kpf[i] = *(const u16x8*)(Ktg + kb_ + (size_t)c * CH + t8);
        }
#pragma unroll
        for (int r = 0; r < 4; ++r)
            ucur[r] = U[cb + (size_t)(t0 + lh * 4 + r) * 768 + v0 + lr];
#pragma unroll
        for (int i = 0; i < 3; ++i) {
            const int u = i * 256 + tid;
            const int r = u / 12, c8 = (u % 12) * 8;
            *(u16x8*)&Wn[r * WNP + c8] = wpf[i];
        }
#pragma unroll
        for (int i = 0; i < 3; ++i) {
            const int u = i * 256 + tid;
            const int c = u / 8, t8 = (u % 8) * 8;
            *(u16x8*)&Kt[c * KTP2 + t8] = kpf[i];
        }
    }
    __syncthreads();

    for (int ch = 0; ch < NCH; ++ch) {
        if (ch + 1 < NCH) {
            const size_t cb = base + (size_t)((ch + 1) * CH) * (HH * HD);
#pragma unroll
            for (int i = 0; i < 3; ++i) {
                const int u = i * 256 + tid;
                const int r = u / 12, c8 = (u % 12) * 8;
                wpf[i] = *(const u16x8*)(Wbf + cb + (size_t)r * 768 + c8);
            }
            const size_t kb_ = ((cbase + ch + 1) * HD) * CH;
#pragma unroll
            for (int i = 0; i < 3; ++i) {
                const int u = i * 256 + tid;
                const int c = u / 8, t8 = (u % 8) * 8;
                kpf[i] = *(const u16x8*)(Ktg + kb_ + (size_t)c * CH + t8);
            }
#pragma unroll
            for (int r = 0; r < 4; ++r)
                upf[r] = U[cb + (size_t)(t0 + lh * 4 + r) * 768 + v0 + lr];
        }

        // store S_in for the O-epilogue
        {
            float* sg = Sin + (cbase + ch) * (size_t)(HD * HD);
#pragma unroll
            for (int r = 0; r < 4; ++r)
                sg[(size_t)(k1 + lh * 4 + r) * HD + v0 + lr] = accS1[r];
            if (k2 >= 0) {
#pragma unroll
                for (int r = 0; r < 4; ++r)
                    sg[(size_t)(k2 + lh * 4 + r) * HD + v0 + lr] = accS2[r];
            }
        }

        // step A: delta = U + (-W)@S
        f32x4 del = (f32x4){ucur[0], ucur[1], ucur[2], ucur[3]};
#pragma unroll
        for (int ks = 0; ks < 3; ++ks) {
            const bf16x8 a = *(const bf16x8*)&Wn[(t0 + lr) * WNP + ks * 32 + lh * 8];
            const bf16x8 bb = *(const bf16x8*)&Sbt[lr * SBP + ks * 32 + lh * 8];
            del = __builtin_amdgcn_mfma_f32_16x16x32_bf16(a, bb, del, 0, 0, 0);
        }
#pragma unroll
        for (int r = 0; r < 4; ++r)
            Dbt[lr * DBP + t0 + lh * 4 + r] = f2bf(del[r]);
        __syncthreads();

        // step B: S = Bc * (S + ktil^T @ delta)
        const float* bc = Bc + (cbase + ch) * HD;
#pragma unroll
        for (int ks = 0; ks < 2; ++ks) {
            const bf16x8 a = *(const bf16x8*)&Kt[(k1 + lr) * KTP2 + ks * 32 + lh * 8];
            const bf16x8 bb = *(const bf16x8*)&Dbt[lr * DBP + ks * 32 + lh * 8];
            accS1 = __builtin_amdgcn_mfma_f32_16x16x32_bf16(a, bb, accS1, 0, 0, 0);
        }
#pragma unroll
        for (int r = 0; r < 4; ++r) accS1[r] *= bc[k1 + lh * 4 + r];
        if (k2 >= 0) {
#pragma unroll
            for (int ks = 0; ks < 2; ++ks) {
                const bf16x8 a = *(const bf16x8*)&Kt[(k2 + lr) * KTP2 + ks * 32 + lh * 8];
                const bf16x8 bb = *(const bf16x8*)&Dbt[lr * DBP + ks * 32 + lh * 8];
                accS2 = __builtin_amdgcn_mfma_f32_16x16x32_bf16(a, bb, accS2, 0, 0, 0);
            }
#pragma unroll
            for (int r = 0; r < 4; ++r) accS2[r] *= bc[k2 + lh * 4 + r];
        }
        __syncthreads();

        // export S -> Sbt; stage next chunk
#pragma unroll
        for (int r = 0; r < 4; ++r)
            Sbt[lr * SBP + k1 + lh * 4 + r] = f2bf(accS1[r]);
        if (k2 >= 0) {
#pragma unroll
            for (int r = 0; r < 4; ++r)
                Sbt[lr * SBP + k2 + lh * 4 + r] = f2bf(accS2[r]);
        }
        if (ch + 1 < NCH) {
#pragma unroll
            for (int i = 0; i < 3; ++i) {
                const int u = i * 256 + tid;
                const int r = u / 12, c8 = (u % 12) * 8;
                *(u16x8*)&Wn[r * WNP + c8] = wpf[i];
            }
#pragma unroll
            for (int i = 0; i < 3; ++i) {
                const int u = i * 256 + tid;
                const int c = u / 8, t8 = (u % 8) * 8;
                *(u16x8*)&Kt[c * KTP2 + t8] = kpf[i];
            }
#pragma unroll
            for (int r = 0; r < 4; ++r) ucur[r] = upf[r];
        }
        __syncthreads();
    }

    // final states
    {
        float* sp = states + (size_t)bh * (HD * HD);
#pragma unroll
        for (int r = 0; r < 4; ++r)
            sp[(size_t)(k1 + lh * 4 + r) * HD + v0 + lr] = accS1[r];
        if (k2 >= 0) {
#pragma unroll
            for (int r = 0; r < 4; ++r)
                sp[(size_t)(k2 + lh * 4 + r) * HD + v0 + lr] = accS2[r];
        }
    }
}

// ---------------------------------------------------------------- KDA parallel O epilogue
__global__ __launch_bounds__(256)
void kda_epi(const float* __restrict__ Sin, const float* __restrict__ Qe,
             const unsigned short* __restrict__ Ol, const unsigned short* __restrict__ Gt,
             const float* __restrict__ onw, unsigned short* __restrict__ obf)
{
    __shared__ float Sl[96 * 100];
    __shared__ float Ql[64 * 100];
    __shared__ unsigned short Olb[64 * 104];
    __shared__ unsigned short Gl[64 * 104];

    const int bx = blockIdx.x;
    const int bh = bx >> 5, ch = bx & 31;
    const int b = bh >> 3, h = bh & 7;
    const int tid = threadIdx.x;
    const size_t cb = (size_t)b * (TT * HH * HD) + (size_t)(ch * CH) * (HH * HD) + h * HD;
    const float* Sg = Sin + (size_t)(bh * NCH + ch) * HD * HD;

#pragma unroll
    for (int i = 0; i < 9; ++i) {
        const int g = i * 256 + tid;
        const int k = g / 24, c4 = (g % 24) * 4;
        *(f32x4*)&Sl[k * 100 + c4] = *(const f32x4*)(Sg + (size_t)k * HD + c4);
    }
#pragma unroll
    for (int i = 0; i < 6; ++i) {
        const int g = i * 256 + tid;
        const int t = g / 24, c4 = (g % 24) * 4;
        *(f32x4*)&Ql[t * 100 + c4] = *(const f32x4*)(Qe + cb + (size_t)t * 768 + c4);
    }
#pragma unroll
    for (int i = 0; i < 3; ++i) {
        const int g = i * 256 + tid;
        const int t = g / 12, c8 = (g % 12) * 8;
        *(u16x8*)&Olb[t * 104 + c8] = *(const u16x8*)(Ol + cb + (size_t)t * 768 + c8);
        *(u16x8*)&Gl[t * 104 + c8]  = *(const u16x8*)(Gt + cb + (size_t)t * 768 + c8);
    }
    __syncthreads();

    const int t = tid >> 2, vq2 = tid & 3;
    const int v0 = vq2 * 24;
    f32x4 acc[6];
#pragma unroll
    for (int j = 0; j < 6; ++j) {
        acc[j].x = bf2f(Olb[t * 104 + v0 + j * 4 + 0]);
        acc[j].y = bf2f(Olb[t * 104 + v0 + j * 4 + 1]);
        acc[j].z = bf2f(Olb[t * 104 + v0 + j * 4 + 2]);
        acc[j].w = bf2f(Olb[t * 104 + v0 + j * 4 + 3]);
    }
#pragma unroll 2
    for (int k = 0; k < HD; ++k) {
        const float qv = Ql[t * 100 + k];
#pragma unroll
        for (int j = 0; j < 6; ++j)
            acc[j] += qv * *(const f32x4*)&Sl[k * 100 + v0 + j * 4];
    }
    float ss = 0.f;
#pragma unroll
    for (int j = 0; j < 6; ++j)
        ss += acc[j].x * acc[j].x + acc[j].y * acc[j].y + acc[j].z * acc[j].z + acc[j].w * acc[j].w;
    ss += __shfl_xor(ss, 1); ss += __shfl_xor(ss, 2);
    const float r = rsqrtf(ss * (1.f / HD) + 1e-6f);
#pragma unroll
    for (int j = 0; j < 6; ++j) {
#pragma unroll
        for (int e = 0; e < 4; ++e) {
            const int v = v0 + j * 4 + e;
            const float g = bf2f(Gl[t * 104 + v]);
            const float val = acc[j][e] * r * onw[v] * (g / (1.f + expf(-g)));
            obf[cb + (size_t)t * 768 + v] = f2bf(val);
        }
    }
}

// ---------------------------------------------------------------- host
extern "C" void kernel_launch(void* const* d_in, const int* in_sizes, int n_in,
                              void* d_out, int out_size, void* d_ws, size_t ws_size,
                              hipStream_t stream)
{
    (void)in_sizes; (void)n_in; (void)out_size; (void)ws_size;
    const float* hidden   = (const float*)d_in[0];
    const float* mask     = (const float*)d_in[1];
    const float* norm_a_w = (const float*)d_in[2];
    const float* norm_a_b = (const float*)d_in[3];
    const float* proj_a_w = (const float*)d_in[4];
    const float* proj_a_b = (const float*)d_in[5];
    const float* ln_w     = (const float*)d_in[6];
    const float* ln_b     = (const float*)d_in[7];
    const float* Wq       = (const float*)d_in[8];
    const float* Wk       = (const float*)d_in[9];
    const float* Wv       = (const float*)d_in[10];
    const float* Wfa      = (const float*)d_in[11];
    const float* Wfb      = (const float*)d_in[12];
    const float* dt_bias  = (const float*)d_in[13];
    const float* A_log    = (const float*)d_in[14];
    const float* Wb       = (const float*)d_in[15];
    const float* Wga      = (const float*)d_in[16];
    const float* Wgb      = (const float*)d_in[17];
    const float* onorm_w  = (const float*)d_in[18];
    const float* Wo       = (const float*)d_in[19];
    const float* Wgate    = (const float*)d_in[20];
    const float* Wup      = (const float*)d_in[21];
    const float* Wdown    = (const float*)d_in[22];

    float* ws    = (float*)d_ws;
    float* hbuf  = ws;
    float* qb    = ws + HROW;          // dead after pre -> Sin/mg live here
    float* kb    = ws + 2 * HROW;
    float* vb    = ws + 3 * HROW;      // U (f32)
    float* egb   = ws + 4 * HROW;      // g -> Qe (f32)
    float* betab = ws + 5 * HROW;                     // MM*HH
    float* BcP   = betab + (size_t)MM * HH;           // 32*32*96
    float* SinP  = qb;                                // 9.44M floats (qb+kb region)
    unsigned short* bfp = (unsigned short*)(BcP + 32 * NCH * HD);
    unsigned short* x_bf    = bfp;  bfp += HROW;
    unsigned short* fab_bf  = bfp;  bfp += (size_t)MM * HD;
    unsigned short* gab_bf  = bfp;  bfp += (size_t)MM * HD;
    unsigned short* gate_bf = bfp;  bfp += HROW;
    unsigned short* olb_bf  = bfp;  bfp += HROW;
    unsigned short* w_bf    = bfp;  bfp += HROW;
    unsigned short* k_bf    = bfp;  bfp += HROW;      // ktil^T [bh][ch][96][64]
    unsigned short* wt_proj = bfp;  bfp += 768 * 768;
    unsigned short *wt_q[LL], *wt_k[LL], *wt_v[LL], *wt_o[LL], *wt_fb[LL], *wt_gb[LL],
                   *wt_fg[LL], *wt_gate[LL], *wt_up[LL], *wt_down[LL];
    for (int l = 0; l < LL; ++l) {
        wt_q[l] = bfp;    bfp += 768 * 768;   // q,k,v contiguous -> fused N=2304 GEMM
        wt_k[l] = bfp;    bfp += 768 * 768;
        wt_v[l] = bfp;    bfp += 768 * 768;
        wt_o[l] = bfp;    bfp += 768 * 768;
        wt_fb[l] = bfp;   bfp += 768 * 96;
        wt_gb[l] = bfp;   bfp += 768 * 96;
        wt_fg[l] = bfp;   bfp += 192 * 768;   // [Wfa^T | Wga^T]
        wt_gate[l] = bfp; bfp += 2048 * 768;
        wt_up[l] = bfp;   bfp += 2048 * 768;
        wt_down[l] = bfp; bfp += 768 * 2048;
    }
    unsigned short* mg_bf = (unsigned short*)SinP;  // Sin dead after epi
    unsigned short* a_bf  = (unsigned short*)vb;    // U dead after seq

    float* out    = (float*)d_out;
    float* states = out + HROW;

    // weight transpose+convert
    transcvt<<<dim3(24, 24), 256, 0, stream>>>(proj_a_w, wt_proj, 768, 768);
    for (int l = 0; l < LL; ++l) {
        transcvt<<<dim3(24, 24), 256, 0, stream>>>(Wq + (size_t)l * 589824, wt_q[l], 768, 768);
        transcvt<<<dim3(24, 24), 256, 0, stream>>>(Wk + (size_t)l * 589824, wt_k[l], 768, 768);
        transcvt<<<dim3(24, 24), 256, 0, stream>>>(Wv + (size_t)l * 589824, wt_v[l], 768, 768);
        transcvt<<<dim3(24, 24), 256, 0, stream>>>(Wo + (size_t)l * 589824, wt_o[l], 768, 768);
        transcvt<<<dim3(24, 3), 256, 0, stream>>>(Wfb + (size_t)l * 73728, wt_fb[l], 96, 768);
        transcvt<<<dim3(24, 3), 256, 0, stream>>>(Wgb + (size_t)l * 73728, wt_gb[l], 96, 768);
        transcvt<<<dim3(3, 24), 256, 0, stream>>>(Wfa + (size_t)l * 73728, wt_fg[l], 768, 96);
        transcvt<<<dim3(3, 24), 256, 0, stream>>>(Wga + (size_t)l * 73728, wt_fg[l] + 96 * 768, 768, 96);
        transcvt<<<dim3(64, 24), 256, 0, stream>>>(Wgate + (size_t)l * 1572864, wt_gate[l], 768, 2048);
        transcvt<<<dim3(64, 24), 256, 0, stream>>>(Wup + (size_t)l * 1572864, wt_up[l], 768, 2048);
        transcvt<<<dim3(24, 64), 256, 0, stream>>>(Wdown + (size_t)l * 1572864, wt_down[l], 2048, 768);
    }

    layernorm_rows<<<MM, 256, 0, stream>>>(hidden, x_bf, norm_a_w, norm_a_b, nullptr);
    bgemm<BE_BIAS, 2><<<dim3(6, 64), 256, 0, stream>>>(x_bf, wt_proj, hbuf, nullptr,
                                                       proj_a_b, nullptr, MM, DD, DD);

    for (int l = 0; l < LL; ++l) {
        layernorm_rows<<<MM, 256, 0, stream>>>(hbuf, x_bf, ln_w + l * DD, ln_b + l * DD, mask);
        // fused q|k|v = silu(x @ [Wq|Wk|Wv]) -> qb, kb, vb
        bgemm<BE_QKV, 2><<<dim3(18, 64), 256, 0, stream>>>(x_bf, wt_q[l], qb, nullptr,
                                                           kb, vb, MM, 3 * DD, DD);
        l2norm_rows<<<(MM * HH) / 4, 256, 0, stream>>>(qb, 0.1020620726159658f);
        l2norm_rows<<<(MM * HH) / 4, 256, 0, stream>>>(kb, 1.f);
        // fa|ga = x @ [Wfa|Wga]  (bf16, one MFMA dispatch)
        bgemm_fg<<<dim3(3, 64), 256, 0, stream>>>(x_bf, wt_fg[l], fab_bf, gab_bf, DD);
        bgemm<BE_EG, 1><<<dim3(6, 64), 256, 0, stream>>>(fab_bf, wt_fb[l], egb, nullptr,
                                                         A_log + l * DD, dt_bias + l * DD, MM, DD, HD);
        gemm_small<1><<<dim3(1, 128), 256, 0, stream>>>(x_bf, Wb + (size_t)l * DD * HH, nullptr, betab, MM, HH, DD);
        // gate before scan (x_bf gets overwritten by o in epi)
        bgemm<BE_BF16, 1><<<dim3(6, 64), 256, 0, stream>>>(gab_bf, wt_gb[l], nullptr, gate_bf, nullptr, nullptr, MM, DD, HD);
        // chunkwise scan
        kda_pre<<<1024, 256, 0, stream>>>(qb, kb, vb, egb, betab, olb_bf, BcP, w_bf, k_bf);
        kda_seq<<<192, 256, 0, stream>>>(w_bf, k_bf, vb, BcP, SinP,
                                         states + (size_t)l * BB * HH * HD * HD);
        kda_epi<<<1024, 256, 0, stream>>>(SinP, egb, olb_bf, gate_bf, onorm_w + l * HD, x_bf);
        // a = o @ Wo
        bgemm<BE_BF16, 2><<<dim3(6, 64), 256, 0, stream>>>(x_bf, wt_o[l], nullptr, a_bf, nullptr, nullptr, MM, DD, DD);
        // swiglu
        bgemm_dual<<<dim3(32, 64), 256, 0, stream>>>(a_bf, wt_gate[l], wt_up[l], mg_bf, MM, FF, DD);
        float* dst = (l == LL - 1) ? out : hbuf;
        bgemm<BE_RES, 2><<<dim3(6, 64), 256, 0, stream>>>(mg_bf, wt_down[l], dst, nullptr,
                                                          hbuf, nullptr, MM, DD, FF);
    }
}

// Round 13
// 1095.490 us; speedup vs baseline: 3.5839x; 1.0634x over previous
//
#include <hip/hip_runtime.h>
#include <cstddef>
#include <cstdint>
#include <cmath>

// Problem constants
constexpr int BB = 4, TT = 2048, DD = 768, HH = 8, HD = 96, FF = 2048, LL = 2;
constexpr int MM = BB * TT;              // 8192
constexpr size_t HROW = (size_t)MM * DD; // 6291456
constexpr int CH = 64;                   // scan chunk length
constexpr int NCH = TT / CH;             // 32 chunks per sequence
constexpr int RP = 100;                  // padded LDS row (floats)
constexpr int KP = 104;                  // padded LDS row (ushorts)

typedef float f32x4 __attribute__((ext_vector_type(4)));
typedef short bf16x8 __attribute__((ext_vector_type(8)));
typedef unsigned short u16x8 __attribute__((ext_vector_type(8)));

__device__ __forceinline__ void gload16(const void* g, void* l) {
    __builtin_amdgcn_global_load_lds(
        (const __attribute__((address_space(1))) void*)g,
        (__attribute__((address_space(3))) void*)l, 16, 0, 0);
}
__device__ __forceinline__ float bf2f(unsigned short u) {
    return __uint_as_float(((unsigned)u) << 16);
}
__device__ __forceinline__ unsigned short f2bf(float f) {
    unsigned u = __float_as_uint(f);
    unsigned r = (u + 0x7fffu + ((u >> 16) & 1u)) >> 16;
    return (unsigned short)r;
}

// ---------------------------------------------------------------- LayerNorm -> bf16
__global__ __launch_bounds__(256)
void layernorm_rows(const float* __restrict__ x, unsigned short* __restrict__ y,
                    const float* __restrict__ w, const float* __restrict__ b,
                    const float* mask)
{
    const int row = blockIdx.x;
    const int tid = threadIdx.x;
    const float* xr = x + (size_t)row * DD;
    float v0 = xr[tid], v1 = xr[tid + 256], v2 = xr[tid + 512];
    float s = v0 + v1 + v2;
    float ss = v0 * v0 + v1 * v1 + v2 * v2;
#pragma unroll
    for (int i = 1; i < 64; i <<= 1) { s += __shfl_xor(s, i); ss += __shfl_xor(ss, i); }
    __shared__ float red[8];
    const int wid = tid >> 6, lane = tid & 63;
    if (lane == 0) { red[wid] = s; red[4 + wid] = ss; }
    __syncthreads();
    const float S  = red[0] + red[1] + red[2] + red[3];
    const float SS = red[4] + red[5] + red[6] + red[7];
    const float mean = S * (1.f / DD);
    const float var  = SS * (1.f / DD) - mean * mean;
    const float rstd = rsqrtf(var + 1e-5f);
    const float m = mask ? mask[row] : 1.f;
    unsigned short* yr = y + (size_t)row * DD;
    yr[tid]       = f2bf(((v0 - mean) * rstd * w[tid]       + b[tid])       * m);
    yr[tid + 256] = f2bf(((v1 - mean) * rstd * w[tid + 256] + b[tid + 256]) * m);
    yr[tid + 512] = f2bf(((v2 - mean) * rstd * w[tid + 512] + b[tid + 512]) * m);
}

// ---------------------------------------------------------------- transpose+convert W
__global__ __launch_bounds__(256)
void transcvt(const float* __restrict__ in, unsigned short* __restrict__ out, int K, int N)
{
    __shared__ float t[32][33];
    const int tx = threadIdx.x & 31, ty = threadIdx.x >> 5;
    const int k0 = blockIdx.y * 32, n0 = blockIdx.x * 32;
#pragma unroll
    for (int i = 0; i < 4; ++i)
        t[ty + i * 8][tx] = in[(size_t)(k0 + ty + i * 8) * N + n0 + tx];
    __syncthreads();
#pragma unroll
    for (int i = 0; i < 4; ++i)
        out[(size_t)(n0 + ty + i * 8) * K + k0 + tx] = f2bf(t[tx][ty + i * 8]);
}

// ---------------------------------------------------------------- bf16 MFMA GEMM
// NH = number of 32-col K-halves staged per barrier phase (1 or 2).
enum { BE_BIAS = 0, BE_SILU, BE_EG, BE_F32, BE_BF16, BE_RES, BE_QKV };

template <int EPI, int NH>
__global__ __launch_bounds__(256)
void bgemm(const unsigned short* __restrict__ A, const unsigned short* __restrict__ Bt,
           float* Cf, unsigned short* Cb,
           const float* P0, const float* P1,
           int M, int N, int K)
{
    __shared__ unsigned short As[NH][128 * 32];
    __shared__ unsigned short Bs[NH][128 * 32];
    const int tid = threadIdx.x;
    const int w = tid >> 6, l = tid & 63;
    const int wm = w >> 1, wn = w & 1;
    const int lr = l & 15, lh = l >> 4;
    const int m0 = blockIdx.y * 128, n0 = blockIdx.x * 128;

    f32x4 acc[4][4];
#pragma unroll
    for (int i = 0; i < 4; ++i)
#pragma unroll
        for (int j = 0; j < 4; ++j) acc[i][j] = (f32x4){0.f, 0.f, 0.f, 0.f};

    const int sr = l >> 2, sq = (l & 3) * 8;
    const unsigned short* Ag = A + (size_t)(m0 + w * 32 + sr) * K + sq;
    const unsigned short* Bg = Bt + (size_t)(n0 + w * 32 + sr) * K + sq;
    const int lofs = (w * 32) * 32;

    for (int kt = 0; kt < K; kt += 32 * NH) {
        __syncthreads();
#pragma unroll
        for (int hh = 0; hh < NH; ++hh) {
            gload16(Ag + kt + hh * 32, &As[hh][lofs]);
            gload16(Ag + kt + hh * 32 + 16 * (size_t)K, &As[hh][lofs + 16 * 32]);
            gload16(Bg + kt + hh * 32, &Bs[hh][lofs]);
            gload16(Bg + kt + hh * 32 + 16 * (size_t)K, &Bs[hh][lofs + 16 * 32]);
        }
        __syncthreads();
#pragma unroll
        for (int hh = 0; hh < NH; ++hh) {
            bf16x8 af[4], bfv[4];
#pragma unroll
            for (int mi = 0; mi < 4; ++mi)
                af[mi] = *(const bf16x8*)&As[hh][(wm * 64 + mi * 16 + lr) * 32 + lh * 8];
#pragma unroll
            for (int ni = 0; ni < 4; ++ni)
                bfv[ni] = *(const bf16x8*)&Bs[hh][(wn * 64 + ni * 16 + lr) * 32 + lh * 8];
#pragma unroll
            for (int mi = 0; mi < 4; ++mi)
#pragma unroll
                for (int ni = 0; ni < 4; ++ni)
                    acc[mi][ni] = __builtin_amdgcn_mfma_f32_16x16x32_bf16(af[mi], bfv[ni], acc[mi][ni], 0, 0, 0);
        }
    }

#pragma unroll
    for (int mi = 0; mi < 4; ++mi) {
#pragma unroll
        for (int j = 0; j < 4; ++j) {
            const int row = m0 + wm * 64 + mi * 16 + lh * 4 + j;
#pragma unroll
            for (int ni = 0; ni < 4; ++ni) {
                const int col = n0 + wn * 64 + ni * 16 + lr;
                const size_t idx = (size_t)row * N + col;
                float v = acc[mi][ni][j];
                if constexpr (EPI == BE_BIAS) { Cf[idx] = v + P0[col]; }
                else if constexpr (EPI == BE_SILU) { Cf[idx] = v / (1.f + expf(-v)); }
                else if constexpr (EPI == BE_EG) {
                    const float lin = v + P1[col];
                    const float sp = (lin > 20.f) ? lin : log1pf(expf(lin));
                    Cf[idx] = -expf(P0[col]) * sp;      // raw log-decay g
                }
                else if constexpr (EPI == BE_F32) { Cf[idx] = v; }
                else if constexpr (EPI == BE_BF16) { Cb[idx] = f2bf(v); }
                else if constexpr (EPI == BE_RES) { Cf[idx] = v + P0[idx]; }
                else if constexpr (EPI == BE_QKV) {
                    const int tgt = col / 768;
                    const int cl = col - tgt * 768;
                    float* dst = (tgt == 0) ? Cf
                               : (tgt == 1) ? const_cast<float*>(P0)
                                            : const_cast<float*>(P1);
                    dst[(size_t)row * 768 + cl] = v / (1.f + expf(-v));
                }
            }
        }
    }
}

// Dual-B GEMM for SwiGLU (BK=64 via half-buffers)
__global__ __launch_bounds__(256)
void bgemm_dual(const unsigned short* __restrict__ A,
                const unsigned short* __restrict__ Bg_, const unsigned short* __restrict__ Bu_,
                unsigned short* __restrict__ C, int M, int N, int K)
{
    __shared__ unsigned short As[2][128 * 32];
    __shared__ unsigned short Bs1[2][64 * 32];
    __shared__ unsigned short Bs2[2][64 * 32];
    const int tid = threadIdx.x;
    const int w = tid >> 6, l = tid & 63;
    const int wm = w >> 1, wn = w & 1;
    const int lr = l & 15, lh = l >> 4;
    const int m0 = blockIdx.y * 128, n0 = blockIdx.x * 64;

    f32x4 a1[4][2], a2[4][2];
#pragma unroll
    for (int i = 0; i < 4; ++i)
#pragma unroll
        for (int j = 0; j < 2; ++j) { a1[i][j] = (f32x4){0.f,0.f,0.f,0.f}; a2[i][j] = (f32x4){0.f,0.f,0.f,0.f}; }

    const int sr = l >> 2, sq = (l & 3) * 8;
    const unsigned short* Ag  = A   + (size_t)(m0 + w * 32 + sr) * K + sq;
    const unsigned short* B1g = Bg_ + (size_t)(n0 + w * 16 + sr) * K + sq;
    const unsigned short* B2g = Bu_ + (size_t)(n0 + w * 16 + sr) * K + sq;
    const int aofs = (w * 32) * 32;
    const int bofs = (w * 16) * 32;

    for (int kt = 0; kt < K; kt += 64) {
        __syncthreads();
#pragma unroll
        for (int hh = 0; hh < 2; ++hh) {
            gload16(Ag + kt + hh * 32, &As[hh][aofs]);
            gload16(Ag + kt + hh * 32 + 16 * (size_t)K, &As[hh][aofs + 16 * 32]);
            gload16(B1g + kt + hh * 32, &Bs1[hh][bofs]);
            gload16(B2g + kt + hh * 32, &Bs2[hh][bofs]);
        }
        __syncthreads();
#pragma unroll
        for (int hh = 0; hh < 2; ++hh) {
            bf16x8 af[4], b1[2], b2[2];
#pragma unroll
            for (int mi = 0; mi < 4; ++mi)
                af[mi] = *(const bf16x8*)&As[hh][(wm * 64 + mi * 16 + lr) * 32 + lh * 8];
#pragma unroll
            for (int ni = 0; ni < 2; ++ni) {
                b1[ni] = *(const bf16x8*)&Bs1[hh][(wn * 32 + ni * 16 + lr) * 32 + lh * 8];
                b2[ni] = *(const bf16x8*)&Bs2[hh][(wn * 32 + ni * 16 + lr) * 32 + lh * 8];
            }
#pragma unroll
            for (int mi = 0; mi < 4; ++mi)
#pragma unroll
                for (int ni = 0; ni < 2; ++ni) {
                    a1[mi][ni] = __builtin_amdgcn_mfma_f32_16x16x32_bf16(af[mi], b1[ni], a1[mi][ni], 0, 0, 0);
                    a2[mi][ni] = __builtin_amdgcn_mfma_f32_16x16x32_bf16(af[mi], b2[ni], a2[mi][ni], 0, 0, 0);
                }
        }
    }

#pragma unroll
    for (int mi = 0; mi < 4; ++mi)
#pragma unroll
        for (int j = 0; j < 4; ++j) {
            const int row = m0 + wm * 64 + mi * 16 + lh * 4 + j;
#pragma unroll
            for (int ni = 0; ni < 2; ++ni) {
                const int col = n0 + wn * 32 + ni * 16 + lr;
                const float g = a1[mi][ni][j], u = a2[mi][ni][j];
                C[(size_t)row * N + col] = f2bf((g / (1.f + expf(-g))) * u);
            }
        }
}

// fa|ga fused GEMM (BK=64): N fixed 192 ([Wfa|Wga]^T), routing epilogue.
__global__ __launch_bounds__(256)
void bgemm_fg(const unsigned short* __restrict__ A, const unsigned short* __restrict__ Bt,
              unsigned short* __restrict__ Cfa, unsigned short* __restrict__ Cga, int K)
{
    __shared__ unsigned short As[2][128 * 32];
    __shared__ unsigned short Bs[2][64 * 32];
    const int tid = threadIdx.x;
    const int w = tid >> 6, l = tid & 63;
    const int wm = w >> 1, wn = w & 1;
    const int lr = l & 15, lh = l >> 4;
    const int m0 = blockIdx.y * 128, n0 = blockIdx.x * 64;

    f32x4 acc[4][2];
#pragma unroll
    for (int i = 0; i < 4; ++i)
#pragma unroll
        for (int j = 0; j < 2; ++j) acc[i][j] = (f32x4){0.f, 0.f, 0.f, 0.f};

    const int sr = l >> 2, sq = (l & 3) * 8;
    const unsigned short* Ag = A + (size_t)(m0 + w * 32 + sr) * K + sq;
    const unsigned short* Bg = Bt + (size_t)(n0 + w * 16 + sr) * K + sq;
    const int aofs = (w * 32) * 32;
    const int bofs = (w * 16) * 32;

    for (int kt = 0; kt < K; kt += 64) {
        __syncthreads();
#pragma unroll
        for (int hh = 0; hh < 2; ++hh) {
            gload16(Ag + kt + hh * 32, &As[hh][aofs]);
            gload16(Ag + kt + hh * 32 + 16 * (size_t)K, &As[hh][aofs + 16 * 32]);
            gload16(Bg + kt + hh * 32, &Bs[hh][bofs]);
        }
        __syncthreads();
#pragma unroll
        for (int hh = 0; hh < 2; ++hh) {
            bf16x8 af[4], bfv[2];
#pragma unroll
            for (int mi = 0; mi < 4; ++mi)
                af[mi] = *(const bf16x8*)&As[hh][(wm * 64 + mi * 16 + lr) * 32 + lh * 8];
#pragma unroll
            for (int ni = 0; ni < 2; ++ni)
                bfv[ni] = *(const bf16x8*)&Bs[hh][(wn * 32 + ni * 16 + lr) * 32 + lh * 8];
#pragma unroll
            for (int mi = 0; mi < 4; ++mi)
#pragma unroll
                for (int ni = 0; ni < 2; ++ni)
                    acc[mi][ni] = __builtin_amdgcn_mfma_f32_16x16x32_bf16(af[mi], bfv[ni], acc[mi][ni], 0, 0, 0);
        }
    }

#pragma unroll
    for (int mi = 0; mi < 4; ++mi)
#pragma unroll
        for (int j = 0; j < 4; ++j) {
            const int row = m0 + wm * 64 + mi * 16 + lh * 4 + j;
#pragma unroll
            for (int ni = 0; ni < 2; ++ni) {
                const int col = n0 + wn * 32 + ni * 16 + lr;   // 0..191, 16-aligned tiles
                const int tgt = (col >= HD);
                const int cl = col - (tgt ? HD : 0);
                unsigned short* dst = tgt ? Cga : Cfa;
                dst[(size_t)row * HD + cl] = f2bf(acc[mi][ni][j]);
            }
        }
}

// ---------------------------------------------------------------- small fp32 GEMM (A bf16)
template <int MODE>
__global__ __launch_bounds__(256)
void gemm_small(const unsigned short* __restrict__ A, const float* __restrict__ Bm,
                unsigned short* Cb, float* Cf, int M, int N, int K)
{
    __shared__ float As[16][64];
    __shared__ float Bs[16][64];
    const int tid = threadIdx.x;
    const int tx = tid & 15, ty = tid >> 4;
    const int row0 = blockIdx.y * 64;
    const int col0 = blockIdx.x * 64;
    float acc[4][4] = {};
    const int ar  = tid >> 2;
    const int ac4 = (tid & 3) << 2;
    const int br  = tid >> 4;
    const int bc  = (tid & 15) << 2;
    const int gc  = col0 + bc;
    const bool bok = gc < N;

    for (int kt = 0; kt < K; kt += 16) {
        const ushort4 a4 = *(const ushort4*)(A + (size_t)(row0 + ar) * K + kt + ac4);
        float4 b4 = make_float4(0.f, 0.f, 0.f, 0.f);
        if (bok) b4 = *(const float4*)(Bm + (size_t)(kt + br) * N + gc);
        __syncthreads();
        As[ac4 + 0][ar] = bf2f(a4.x); As[ac4 + 1][ar] = bf2f(a4.y);
        As[ac4 + 2][ar] = bf2f(a4.z); As[ac4 + 3][ar] = bf2f(a4.w);
        *(float4*)&Bs[br][bc] = b4;
        __syncthreads();
#pragma unroll
        for (int kk = 0; kk < 16; ++kk) {
            const float4 av = *(const float4*)&As[kk][ty << 2];
            const float4 bv = *(const float4*)&Bs[kk][tx << 2];
            const float a_[4] = {av.x, av.y, av.z, av.w};
            const float b_[4] = {bv.x, bv.y, bv.z, bv.w};
#pragma unroll
            for (int i = 0; i < 4; ++i)
#pragma unroll
                for (int j = 0; j < 4; ++j)
                    acc[i][j] = fmaf(a_[i], b_[j], acc[i][j]);
        }
    }
#pragma unroll
    for (int i = 0; i < 4; ++i) {
        const int row = row0 + (ty << 2) + i;
#pragma unroll
        for (int j = 0; j < 4; ++j) {
            const int col = col0 + (tx << 2) + j;
            if (col >= N) continue;
            const size_t idx = (size_t)row * N + col;
            if constexpr (MODE == 0) Cb[idx] = f2bf(acc[i][j]);
            else                     Cf[idx] = 1.f / (1.f + expf(-acc[i][j]));
        }
    }
}

// ---------------------------------------------------------------- l2norm over HD=96
__global__ __launch_bounds__(256)
void l2norm_rows(float* x, float scale)
{
    const int row  = (blockIdx.x << 2) + (threadIdx.x >> 6);
    const int lane = threadIdx.x & 63;
    float* xr = x + (size_t)row * HD;
    const float a = xr[lane];
    const float b = (lane < 32) ? xr[64 + lane] : 0.f;
    float ss = a * a + b * b;
#pragma unroll
    for (int i = 1; i < 64; i <<= 1) ss += __shfl_xor(ss, i);
    const float r = rsqrtf(ss + 1e-6f) * scale;
    xr[lane] = a * r;
    if (lane < 32) xr[64 + lane] = b * r;
}

// ---------------------------------------------------------------- KDA chunkwise precompute
constexpr int TBP = 72;   // Tb row pad (u16)
constexpr int XLP = 72;   // Xl row pad (u16)
__global__ __launch_bounds__(256)
void kda_pre(const float* __restrict__ q, const float* __restrict__ k, float* v,
             const float* __restrict__ g,
             const float* __restrict__ beta,
             unsigned short* __restrict__ ol, float* __restrict__ Bc,
             unsigned short* __restrict__ Wbf, unsigned short* __restrict__ Ktg,
             unsigned short* __restrict__ qeb)
{
    __shared__ unsigned short Kb[CH * KP];   // k (bf16), then kappa_tilde (bf16)
    __shared__ float Qp[CH * RP];            // g -> L -> q'
    __shared__ float sb[CH];
    __shared__ __align__(16) char uR[36864];
    unsigned short* Kk = (unsigned short*)uR;
    float (*Am)[68] = (float(*)[68])(uR + 13312);
    unsigned short* Tb = (unsigned short*)uR;
    unsigned short* Xl = (unsigned short*)(uR + 9216);

    const int blk = blockIdx.x;
    const int ch = blk & 31, bh = blk >> 5;
    const int b = bh >> 3, h = bh & 7;
    const int tid = threadIdx.x;
    const size_t base = (size_t)b * (TT * HH * HD) + (size_t)(ch * CH) * (HH * HD) + h * HD;

    // P0: stage k (as bf16), g (f32), beta
    for (int e = tid; e < CH * 24; e += 256) {
        const int t = e / 24, c4 = (e % 24) * 4;
        const float4 kv = *(const float4*)(k + base + t * 768 + c4);
        ushort4 k4;
        k4.x = f2bf(kv.x); k4.y = f2bf(kv.y); k4.z = f2bf(kv.z); k4.w = f2bf(kv.w);
        *(ushort4*)&Kb[t * KP + c4] = k4;
        *(float4*)&Qp[t * RP + c4] = *(const float4*)(g + base + t * 768 + c4);
    }
    if (tid < CH) sb[tid] = beta[((size_t)b * TT + ch * CH + tid) * HH + h];
    __syncthreads();

    // P1: per-channel cumsum of g
    if (tid < HD) {
        float L = 0.f;
        for (int t = 0; t < CH; ++t) { L += Qp[t * RP + tid]; Qp[t * RP + tid] = L; }
    }
    __syncthreads();

    // P2: kappa, kappa_tilde (bf16), q', Bc
    for (int e = tid; e < CH * HD; e += 256) {
        const int t = e / HD, c = e % HD;
        const float L = Qp[t * RP + c];
        const float B = expf(L), iB = expf(-L);
        const float kv = bf2f(Kb[t * KP + c]);
        if (t == CH - 1) Bc[((size_t)bh * NCH + ch) * HD + c] = B;
        Kk[t * KP + c] = f2bf(kv * B);
        const unsigned short kti = f2bf(kv * iB);
        const float qv = q[base + t * 768 + c];
        Kb[t * KP + c] = kti;
        Qp[t * RP + c] = qv * B;                  // q'
    }
    __syncthreads();

    // P2b: export ktil^T -> Ktg[(bh,ch)][c][t]
#pragma unroll
    for (int i = 0; i < 3; ++i) {
        const int u = i * 256 + tid;
        const int c = u / 8, t8 = (u % 8) * 8;
        u16x8 vv;
#pragma unroll
        for (int j = 0; j < 8; ++j) vv[j] = Kb[(t8 + j) * KP + c];
        *(u16x8*)(Ktg + (((size_t)bh * NCH + ch) * HD + c) * CH + t8) = vv;
    }

    // P3 (MFMA): A[t][i] = beta_t * (kappa_t . ktil_i), i < t
    {
        const int lane = tid & 63;
        const int lr = lane & 15, lh = lane >> 4;
        const int t0 = (tid >> 6) * 16;
        bf16x8 afr[3];
#pragma unroll
        for (int ks = 0; ks < 3; ++ks)
            afr[ks] = *(const bf16x8*)&Kk[(t0 + lr) * KP + ks * 32 + lh * 8];
#pragma unroll
        for (int i0 = 0; i0 < 64; i0 += 16) {
            f32x4 acc = (f32x4){0.f, 0.f, 0.f, 0.f};
#pragma unroll
            for (int ks = 0; ks < 3; ++ks) {
                const bf16x8 bfr = *(const bf16x8*)&Kb[(i0 + lr) * KP + ks * 32 + lh * 8];
                acc = __builtin_amdgcn_mfma_f32_16x16x32_bf16(afr[ks], bfr, acc, 0, 0, 0);
            }
#pragma unroll
            for (int r = 0; r < 4; ++r) {
                const int t = t0 + lh * 4 + r;
                const int i = i0 + lr;
                Am[t][i] = (i < t) ? acc[r] * sb[t] : 0.f;
            }
        }
    }
    __syncthreads();

    // P4: forward solve, column j of [U | W] in registers
    float X[CH];
    const int j = tid;
    if (j < 192) {
        if (j < HD) {
#pragma unroll
            for (int t = 0; t < CH; ++t) X[t] = sb[t] * v[base + t * 768 + j];
        } else {
#pragma unroll
            for (int t = 0; t < CH; ++t) X[t] = sb[t] * bf2f(Kk[t * KP + (j - HD)]);
        }
#pragma unroll
        for (int t = 1; t < CH; ++t) {
            float a0 = 0, a1 = 0, a2 = 0, a3 = 0;
#pragma unroll
            for (int i4 = 0; i4 * 4 < t; ++i4) {
                const float4 a = *(const float4*)&Am[t][i4 * 4];
                if (i4 * 4 + 0 < t) a0 = fmaf(a.x, X[i4 * 4 + 0], a0);
                if (i4 * 4 + 1 < t) a1 = fmaf(a.y, X[i4 * 4 + 1], a1);
                if (i4 * 4 + 2 < t) a2 = fmaf(a.z, X[i4 * 4 + 2], a2);
                if (i4 * 4 + 3 < t) a3 = fmaf(a.w, X[i4 * 4 + 3], a3);
            }
            X[t] -= ((a0 + a1) + (a2 + a3));
        }
        // P5: store U (f32 over v) / -W (bf16)
        if (j < HD) {
#pragma unroll
            for (int t = 0; t < CH; ++t) v[base + t * 768 + j] = X[t];
        } else {
#pragma unroll
            for (int t = 0; t < CH; ++t) Wbf[base + t * 768 + (j - HD)] = f2bf(-X[t]);
        }
    }
    __syncthreads();   // Am/Kk dead past here

    // phase 2a: X -> Xl (bf16, [j][t]); P6 (MFMA): T -> Tb (bf16, [t][i])
    if (j < 192) {
#pragma unroll
        for (int t8 = 0; t8 < 8; ++t8) {
            u16x8 xv;
#pragma unroll
            for (int jj = 0; jj < 8; ++jj) xv[jj] = f2bf(X[t8 * 8 + jj]);
            *(u16x8*)&Xl[j * XLP + t8 * 8] = xv;
        }
    }
    {
        const int lane = tid & 63;
        const int lr = lane & 15, lh = lane >> 4;
        const int t0 = (tid >> 6) * 16;
        bf16x8 afr[3];
#pragma unroll
        for (int ks = 0; ks < 3; ++ks) {
            const float4 qa = *(const float4*)&Qp[(t0 + lr) * RP + ks * 32 + lh * 8];
            const float4 qc = *(const float4*)&Qp[(t0 + lr) * RP + ks * 32 + lh * 8 + 4];
            bf16x8 a;
            a[0] = (short)f2bf(qa.x); a[1] = (short)f2bf(qa.y);
            a[2] = (short)f2bf(qa.z); a[3] = (short)f2bf(qa.w);
            a[4] = (short)f2bf(qc.x); a[5] = (short)f2bf(qc.y);
            a[6] = (short)f2bf(qc.z); a[7] = (short)f2bf(qc.w);
            afr[ks] = a;
        }
#pragma unroll
        for (int i0 = 0; i0 < 64; i0 += 16) {
            f32x4 acc = (f32x4){0.f, 0.f, 0.f, 0.f};
#pragma unroll
            for (int ks = 0; ks < 3; ++ks) {
                const bf16x8 bfr = *(const bf16x8*)&Kb[(i0 + lr) * KP + ks * 32 + lh * 8];
                acc = __builtin_amdgcn_mfma_f32_16x16x32_bf16(afr[ks], bfr, acc, 0, 0, 0);
            }
#pragma unroll
            for (int r = 0; r < 4; ++r) {
                const int t = t0 + lh * 4 + r;
                const int i = i0 + lr;
                Tb[t * TBP + i] = (i <= t) ? f2bf(acc[r]) : (unsigned short)0;
            }
        }
    }
    __syncthreads();

    // P7 (MFMA): res = T @ X ; j<96 -> Ol ; j>=96 -> Qe(bf16) = q' - res
    {
        const int lane = tid & 63;
        const int lr = lane & 15, lh = lane >> 4;
        const int w = tid >> 6;
        const int t0 = w * 16;
        bf16x8 af0 = *(const bf16x8*)&Tb[(t0 + lr) * TBP + lh * 8];
        bf16x8 af1 = *(const bf16x8*)&Tb[(t0 + lr) * TBP + 32 + lh * 8];
#pragma unroll
        for (int nt = 0; nt < 12; ++nt) {
            const int n0 = nt * 16;
            f32x4 acc = (f32x4){0.f, 0.f, 0.f, 0.f};
            acc = __builtin_amdgcn_mfma_f32_16x16x32_bf16(
                af0, *(const bf16x8*)&Xl[(n0 + lr) * XLP + lh * 8], acc, 0, 0, 0);
            acc = __builtin_amdgcn_mfma_f32_16x16x32_bf16(
                af1, *(const bf16x8*)&Xl[(n0 + lr) * XLP + 32 + lh * 8], acc, 0, 0, 0);
            const int jc = n0 + lr;
#pragma unroll
            for (int r = 0; r < 4; ++r) {
                const int t = t0 + lh * 4 + r;
                if (jc < HD) ol[base + t * 768 + jc] = f2bf(acc[r]);
                else         qeb[base + t * 768 + (jc - HD)] = f2bf(Qp[t * RP + (jc - HD)] - acc[r]);
            }
        }
    }
}

// ---------------------------------------------------------------- KDA sequential recurrence (MFMA form)
constexpr int VSL = 16;
constexpr int WNP = 120;  // Wn row pad (u16)
constexpr int KTP2 = 72;  // Kt row pad
constexpr int DBP = 72;   // Dbt row pad
constexpr int SBP = 120;  // Sbt row pad
__global__ __launch_bounds__(256)
void kda_seq(const unsigned short* __restrict__ Wbf, const unsigned short* __restrict__ Ktg,
             const float* __restrict__ U, const float* __restrict__ Bc,
             unsigned short* __restrict__ SinT, float* __restrict__ states)
{
    __shared__ unsigned short Wn[CH * WNP];    // -W bf16, [t][k]
    __shared__ unsigned short Kt[HD * KTP2];   // ktil^T bf16, [k][t]
    __shared__ unsigned short Dbt[VSL * DBP];  // delta^T bf16, [v][t]
    __shared__ unsigned short Sbt[VSL * SBP];  // S^T bf16, [v][k]

    const int blk = blockIdx.x;
    const int bh = blk / 6, vq = blk - bh * 6;
    const int b = bh >> 3, h = bh & 7;
    const int tid = threadIdx.x;
    const int w = tid >> 6, lane = tid & 63;
    const int lr = lane & 15, lh = lane >> 4;
    const int v0 = vq * VSL;
    const size_t base = (size_t)b * (TT * HH * HD) + h * HD;
    const size_t cbase = (size_t)bh * NCH;

    const int t0 = w * 16;
    const int k1 = w * 16;
    const int k2 = (w < 2) ? (4 + w) * 16 : -1;

    f32x4 accS1 = (f32x4){0.f, 0.f, 0.f, 0.f};
    f32x4 accS2 = (f32x4){0.f, 0.f, 0.f, 0.f};

    for (int e = tid; e < VSL * SBP; e += 256) Sbt[e] = 0;

    u16x8 wpf[3], kpf[3];
    float upf[4], ucur[4];

    // ---- stage chunk 0
    {
        const size_t cb = base;
#pragma unroll
        for (int i = 0; i < 3; ++i) {
            const int u = i * 256 + tid;
            const int r = u / 12, c8 = (u % 12) * 8;
            wpf[i] = *(const u16x8*)(Wbf + cb + (size_t)r * 768 + c8);
        }
        const size_t kb_ = (cbase * HD) * CH;
#pragma unroll
        for (int i = 0; i < 3; ++i) {
            const int u = i * 256 + tid;
            const int c = u / 8, t8 = (u % 8) * 8;
            kpf[i] = *(const u16x8*)(Ktg + kb_ + (size_t)c * CH + t8);
        }
#pragma unroll
        for (int r = 0; r < 4; ++r)
            ucur[r] = U[cb + (size_t)(t0 + lh * 4 + r) * 768 + v0 + lr];
#pragma unroll
        for (int i = 0; i < 3; ++i) {
            const int u = i * 256 + tid;
            const int r = u / 12, c8 = (u % 12) * 8;
            *(u16x8*)&Wn[r * WNP + c8] = wpf[i];
        }
#pragma unroll
        for (int i = 0; i < 3; ++i) {
            const int u = i * 256 + tid;
            const int c = u / 8, t8 = (u % 8) * 8;
            *(u16x8*)&Kt[c * KTP2 + t8] = kpf[i];
        }
    }
    __syncthreads();

    for (int ch = 0; ch < NCH; ++ch) {
        if (ch + 1 < NCH) {
            const size_t cb = base + (size_t)((ch + 1) * CH) * (HH * HD);
#pragma unroll
            for (int i = 0; i < 3; ++i) {
                const int u = i * 256 + tid;
                const int r = u / 12, c8 = (u % 12) * 8;
                wpf[i] = *(const u16x8*)(Wbf + cb + (size_t)r * 768 + c8);
            }
            const size_t kb_ = ((cbase + ch + 1) * HD) * CH;
#pragma unroll
            for (int i = 0; i < 3; ++i) {
                const int u = i * 256 + tid;
                const int c = u / 8, t8 = (u % 8) * 8;
                kpf[i] = *(const u16x8*)(Ktg + kb_ + (size_t)c * CH + t8);
            }
#pragma unroll
            for (int r = 0; r < 4; ++r)
                upf[r] = U[cb + (size_t)(t0 + lh * 4 + r) * 768 + v0 + lr];
        }

        // store S_in (bf16 S^T slice) for the O-epilogue
        if (tid < 192) {
            const int row = tid / 12, c8 = (tid % 12) * 8;
            *(u16x8*)(SinT + (size_t)(cbase + ch) * 9216 + (size_t)(v0 + row) * 96 + c8)
                = *(const u16x8*)&Sbt[row * SBP + c8];
        }

        // step A: delta = U + (-W)@S
        f32x4 del = (f32x4){ucur[0], ucur[1], ucur[2], ucur[3]};
#pragma unroll
        for (int ks = 0; ks < 3; ++ks) {
            const bf16x8 a = *(const bf16x8*)&Wn[(t0 + lr) * WNP + ks * 32 + lh * 8];
            const bf16x8 bb = *(const bf16x8*)&Sbt[lr * SBP + ks * 32 + lh * 8];
            del = __builtin_amdgcn_mfma_f32_16x16x32_bf16(a, bb, del, 0, 0, 0);
        }
#pragma unroll
        for (int r = 0; r < 4; ++r)
            Dbt[lr * DBP + t0 + lh * 4 + r] = f2bf(del[r]);
        __syncthreads();

        // step B: S = Bc * (S + ktil^T @ delta)
        const float* bc = Bc + (cbase + ch) * HD;
#pragma unroll
        for (int ks = 0; ks < 2; ++ks) {
            const bf16x8 a = *(const bf16x8*)&Kt[(k1 + lr) * KTP2 + ks * 32 + lh * 8];
            const bf16x8 bb = *(const bf16x8*)&Dbt[lr * DBP + ks * 32 + lh * 8];
            accS1 = __builtin_amdgcn_mfma_f32_16x16x32_bf16(a, bb, accS1, 0, 0, 0);
        }
#pragma unroll
        for (int r = 0; r < 4; ++r) accS1[r] *= bc[k1 + lh * 4 + r];
        if (k2 >= 0) {
#pragma unroll
            for (int ks = 0; ks < 2; ++ks) {
                const bf16x8 a = *(const bf16x8*)&Kt[(k2 + lr) * KTP2 + ks * 32 + lh * 8];
                const bf16x8 bb = *(const bf16x8*)&Dbt[lr * DBP + ks * 32 + lh * 8];
                accS2 = __builtin_amdgcn_mfma_f32_16x16x32_bf16(a, bb, accS2, 0, 0, 0);
            }
#pragma unroll
            for (int r = 0; r < 4; ++r) accS2[r] *= bc[k2 + lh * 4 + r];
        }
        __syncthreads();

        // export S -> Sbt; stage next chunk
#pragma unroll
        for (int r = 0; r < 4; ++r)
            Sbt[lr * SBP + k1 + lh * 4 + r] = f2bf(accS1[r]);
        if (k2 >= 0) {
#pragma unroll
            for (int r = 0; r < 4; ++r)
                Sbt[lr * SBP + k2 + lh * 4 + r] = f2bf(accS2[r]);
        }
        if (ch + 1 < NCH) {
#pragma unroll
            for (int i = 0; i < 3; ++i) {
                const int u = i * 256 + tid;
                const int r = u / 12, c8 = (u % 12) * 8;
                *(u16x8*)&Wn[r * WNP + c8] = wpf[i];
            }
#pragma unroll
            for (int i = 0; i < 3; ++i) {
                const int u = i * 256 + tid;
                const int c = u / 8, t8 = (u % 8) * 8;
                *(u16x8*)&Kt[c * KTP2 + t8] = kpf[i];
            }
#pragma unroll
            for (int r = 0; r < 4; ++r) ucur[r] = upf[r];
        }
        __syncthreads();
    }

    // final states (f32)
    {
        float* sp = states + (size_t)bh * (HD * HD);
#pragma unroll
        for (int r = 0; r < 4; ++r)
            sp[(size_t)(k1 + lh * 4 + r) * HD + v0 + lr] = accS1[r];
        if (k2 >= 0) {
#pragma unroll
            for (int r = 0; r < 4; ++r)
                sp[(size_t)(k2 + lh * 4 + r) * HD + v0 + lr] = accS2[r];
        }
    }
}

// ---------------------------------------------------------------- KDA parallel O epilogue (MFMA)
// O = Ol + Qe @ S_in, then onorm * silu(gate) -> bf16. grid 1024 = bh x ch.
__global__ __launch_bounds__(256)
void kda_epi(const unsigned short* __restrict__ SinT, const unsigned short* __restrict__ Qe,
             const unsigned short* __restrict__ Ol, const unsigned short* __restrict__ Gt,
             const float* __restrict__ onw, unsigned short* __restrict__ obf)
{
    __shared__ unsigned short Sl[96 * 104];    // S^T bf16 [v][k]
    __shared__ unsigned short Ql[64 * 104];    // Qe bf16 [t][k]
    __shared__ unsigned short Olb[64 * 104];
    __shared__ unsigned short Gl[64 * 104];
    __shared__ float onws[HD];

    const int bx = blockIdx.x;
    const int bh = bx >> 5, ch = bx & 31;
    const int b = bh >> 3, h = bh & 7;
    const int tid = threadIdx.x;
    const size_t cb = (size_t)b * (TT * HH * HD) + (size_t)(ch * CH) * (HH * HD) + h * HD;
    const size_t sbase = (size_t)(bh * NCH + ch) * 9216;

#pragma unroll
    for (int i = 0; i < 5; ++i) {
        const int u = i * 256 + tid;
        if (u < 1152) {
            const int row = u / 12, c8 = (u % 12) * 8;
            *(u16x8*)&Sl[row * 104 + c8] = *(const u16x8*)(SinT + sbase + (size_t)row * 96 + c8);
        }
    }
#pragma unroll
    for (int i = 0; i < 3; ++i) {
        const int u = i * 256 + tid;
        const int t = u / 12, c8 = (u % 12) * 8;
        *(u16x8*)&Ql[t * 104 + c8]  = *(const u16x8*)(Qe + cb + (size_t)t * 768 + c8);
        *(u16x8*)&Olb[t * 104 + c8] = *(const u16x8*)(Ol + cb + (size_t)t * 768 + c8);
        *(u16x8*)&Gl[t * 104 + c8]  = *(const u16x8*)(Gt + cb + (size_t)t * 768 + c8);
    }
    if (tid < HD) onws[tid] = onw[tid];
    __syncthreads();

    const int lane = tid & 63, w = tid >> 6;
    const int lr = lane & 15, lh = lane >> 4;
    const int t0 = w * 16;
    bf16x8 af[3];
#pragma unroll
    for (int ks = 0; ks < 3; ++ks)
        af[ks] = *(const bf16x8*)&Ql[(t0 + lr) * 104 + ks * 32 + lh * 8];

    f32x4 acc[6];
#pragma unroll
    for (int nt = 0; nt < 6; ++nt) {
#pragma unroll
        for (int r = 0; r < 4; ++r)
            acc[nt][r] = bf2f(Olb[(t0 + lh * 4 + r) * 104 + nt * 16 + lr]);
#pragma unroll
        for (int ks = 0; ks < 3; ++ks)
            acc[nt] = __builtin_amdgcn_mfma_f32_16x16x32_bf16(
                af[ks], *(const bf16x8*)&Sl[(nt * 16 + lr) * 104 + ks * 32 + lh * 8],
                acc[nt], 0, 0, 0);
    }

    float ss0 = 0.f, ss1 = 0.f, ss2 = 0.f, ss3 = 0.f;
#pragma unroll
    for (int nt = 0; nt < 6; ++nt) {
        ss0 = fmaf(acc[nt][0], acc[nt][0], ss0);
        ss1 = fmaf(acc[nt][1], acc[nt][1], ss1);
        ss2 = fmaf(acc[nt][2], acc[nt][2], ss2);
        ss3 = fmaf(acc[nt][3], acc[nt][3], ss3);
    }
#pragma unroll
    for (int d = 1; d < 16; d <<= 1) {
        ss0 += __shfl_xor(ss0, d); ss1 += __shfl_xor(ss1, d);
        ss2 += __shfl_xor(ss2, d); ss3 += __shfl_xor(ss3, d);
    }
    const float rr0 = rsqrtf(ss0 * (1.f / HD) + 1e-6f);
    const float rr1 = rsqrtf(ss1 * (1.f / HD) + 1e-6f);
    const float rr2 = rsqrtf(ss2 * (1.f / HD) + 1e-6f);
    const float rr3 = rsqrtf(ss3 * (1.f / HD) + 1e-6f);

#pragma unroll
    for (int nt = 0; nt < 6; ++nt) {
        const int v = nt * 16 + lr;
        const float ow = onws[v];
#pragma unroll
        for (int r = 0; r < 4; ++r) {
            const int t = t0 + lh * 4 + r;
            const float rrv = (r == 0) ? rr0 : (r == 1) ? rr1 : (r == 2) ? rr2 : rr3;
            const float gg = bf2f(Gl[t * 104 + v]);
            const float val = acc[nt][r] * rrv * ow * (gg / (1.f + expf(-gg)));
            obf[cb + (size_t)t * 768 + v] = f2bf(val);
        }
    }
}

// ---------------------------------------------------------------- host
extern "C" void kernel_launch(void* const* d_in, const int* in_sizes, int n_in,
                              void* d_out, int out_size, void* d_ws, size_t ws_size,
                              hipStream_t stream)
{
    (void)in_sizes; (void)n_in; (void)out_size; (void)ws_size;
    const float* hidden   = (const float*)d_in[0];
    const float* mask     = (const float*)d_in[1];
    const float* norm_a_w = (const float*)d_in[2];
    const float* norm_a_b = (const float*)d_in[3];
    const float* proj_a_w = (const float*)d_in[4];
    const float* proj_a_b = (const float*)d_in[5];
    const float* ln_w     = (const float*)d_in[6];
    const float* ln_b     = (const float*)d_in[7];
    const float* Wq       = (const float*)d_in[8];
    const float* Wk       = (const float*)d_in[9];
    const float* Wv       = (const float*)d_in[10];
    const float* Wfa      = (const float*)d_in[11];
    const float* Wfb      = (const float*)d_in[12];
    const float* dt_bias  = (const float*)d_in[13];
    const float* A_log    = (const float*)d_in[14];
    const float* Wb       = (const float*)d_in[15];
    const float* Wga      = (const float*)d_in[16];
    const float* Wgb      = (const float*)d_in[17];
    const float* onorm_w  = (const float*)d_in[18];
    const float* Wo       = (const float*)d_in[19];
    const float* Wgate    = (const float*)d_in[20];
    const float* Wup      = (const float*)d_in[21];
    const float* Wdown    = (const float*)d_in[22];

    float* ws    = (float*)d_ws;
    float* hbuf  = ws;
    float* qb    = ws + HROW;          // dead after pre -> mg lives here
    float* kb    = ws + 2 * HROW;
    float* vb    = ws + 3 * HROW;      // U (f32)
    float* egb   = ws + 4 * HROW;      // g (f32); dead after pre -> SinT lives here
    float* betab = ws + 5 * HROW;                     // MM*HH
    float* BcP   = betab + (size_t)MM * HH;           // 32*32*96
    unsigned short* SinT = (unsigned short*)egb;      // 1024*96*96 u16 = 18.9MB <= 25.2MB
    unsigned short* bfp = (unsigned short*)(BcP + 32 * NCH * HD);
    unsigned short* x_bf    = bfp;  bfp += HROW;
    unsigned short* fab_bf  = bfp;  bfp += (size_t)MM * HD;
    unsigned short* gab_bf  = bfp;  bfp += (size_t)MM * HD;
    unsigned short* gate_bf = bfp;  bfp += HROW;
    unsigned short* olb_bf  = bfp;  bfp += HROW;
    unsigned short* w_bf    = bfp;  bfp += HROW;
    unsigned short* k_bf    = bfp;  bfp += HROW;      // ktil^T [bh][ch][96][64]
    unsigned short* qe_bf   = bfp;  bfp += HROW;      // Qe bf16
    unsigned short* wt_proj = bfp;  bfp += 768 * 768;
    unsigned short *wt_q[LL], *wt_k[LL], *wt_v[LL], *wt_o[LL], *wt_fb[LL], *wt_gb[LL],
                   *wt_fg[LL], *wt_gate[LL], *wt_up[LL], *wt_down[LL];
    for (int l = 0; l < LL; ++l) {
        wt_q[l] = bfp;    bfp += 768 * 768;   // q,k,v contiguous -> fused N=2304 GEMM
        wt_k[l] = bfp;    bfp += 768 * 768;
        wt_v[l] = bfp;    bfp += 768 * 768;
        wt_o[l] = bfp;    bfp += 768 * 768;
        wt_fb[l] = bfp;   bfp += 768 * 96;
        wt_gb[l] = bfp;   bfp += 768 * 96;
        wt_fg[l] = bfp;   bfp += 192 * 768;   // [Wfa^T | Wga^T]
        wt_gate[l] = bfp; bfp += 2048 * 768;
        wt_up[l] = bfp;   bfp += 2048 * 768;
        wt_down[l] = bfp; bfp += 768 * 2048;
    }
    unsigned short* mg_bf = (unsigned short*)qb;    // qb/kb dead after pre
    unsigned short* a_bf  = (unsigned short*)vb;    // U dead after seq

    float* out    = (float*)d_out;
    float* states = out + HROW;

    // weight transpose+convert
    transcvt<<<dim3(24, 24), 256, 0, stream>>>(proj_a_w, wt_proj, 768, 768);
    for (int l = 0; l < LL; ++l) {
        transcvt<<<dim3(24, 24), 256, 0, stream>>>(Wq + (size_t)l * 589824, wt_q[l], 768, 768);
        transcvt<<<dim3(24, 24), 256, 0, stream>>>(Wk + (size_t)l * 589824, wt_k[l], 768, 768);
        transcvt<<<dim3(24, 24), 256, 0, stream>>>(Wv + (size_t)l * 589824, wt_v[l], 768, 768);
        transcvt<<<dim3(24, 24), 256, 0, stream>>>(Wo + (size_t)l * 589824, wt_o[l], 768, 768);
        transcvt<<<dim3(24, 3), 256, 0, stream>>>(Wfb + (size_t)l * 73728, wt_fb[l], 96, 768);
        transcvt<<<dim3(24, 3), 256, 0, stream>>>(Wgb + (size_t)l * 73728, wt_gb[l], 96, 768);
        transcvt<<<dim3(3, 24), 256, 0, stream>>>(Wfa + (size_t)l * 73728, wt_fg[l], 768, 96);
        transcvt<<<dim3(3, 24), 256, 0, stream>>>(Wga + (size_t)l * 73728, wt_fg[l] + 96 * 768, 768, 96);
        transcvt<<<dim3(64, 24), 256, 0, stream>>>(Wgate + (size_t)l * 1572864, wt_gate[l], 768, 2048);
        transcvt<<<dim3(64, 24), 256, 0, stream>>>(Wup + (size_t)l * 1572864, wt_up[l], 768, 2048);
        transcvt<<<dim3(24, 64), 256, 0, stream>>>(Wdown + (size_t)l * 1572864, wt_down[l], 2048, 768);
    }

    layernorm_rows<<<MM, 256, 0, stream>>>(hidden, x_bf, norm_a_w, norm_a_b, nullptr);
    bgemm<BE_BIAS, 2><<<dim3(6, 64), 256, 0, stream>>>(x_bf, wt_proj, hbuf, nullptr,
                                                       proj_a_b, nullptr, MM, DD, DD);

    for (int l = 0; l < LL; ++l) {
        layernorm_rows<<<MM, 256, 0, stream>>>(hbuf, x_bf, ln_w + l * DD, ln_b + l * DD, mask);
        // fused q|k|v = silu(x @ [Wq|Wk|Wv]) -> qb, kb, vb
        bgemm<BE_QKV, 2><<<dim3(18, 64), 256, 0, stream>>>(x_bf, wt_q[l], qb, nullptr,
                                                           kb, vb, MM, 3 * DD, DD);
        l2norm_rows<<<(MM * HH) / 4, 256, 0, stream>>>(qb, 0.1020620726159658f);
        l2norm_rows<<<(MM * HH) / 4, 256, 0, stream>>>(kb, 1.f);
        // fa|ga = x @ [Wfa|Wga]  (bf16, one MFMA dispatch)
        bgemm_fg<<<dim3(3, 64), 256, 0, stream>>>(x_bf, wt_fg[l], fab_bf, gab_bf, DD);
        bgemm<BE_EG, 1><<<dim3(6, 64), 256, 0, stream>>>(fab_bf, wt_fb[l], egb, nullptr,
                                                         A_log + l * DD, dt_bias + l * DD, MM, DD, HD);
        gemm_small<1><<<dim3(1, 128), 256, 0, stream>>>(x_bf, Wb + (size_t)l * DD * HH, nullptr, betab, MM, HH, DD);
        // gate before scan (x_bf gets overwritten by o in epi)
        bgemm<BE_BF16, 1><<<dim3(6, 64), 256, 0, stream>>>(gab_bf, wt_gb[l], nullptr, gate_bf, nullptr, nullptr, MM, DD, HD);
        // chunkwise scan
        kda_pre<<<1024, 256, 0, stream>>>(qb, kb, vb, egb, betab, olb_bf, BcP, w_bf, k_bf, qe_bf);
        kda_seq<<<192, 256, 0, stream>>>(w_bf, k_bf, vb, BcP, SinT,
                                         states + (size_t)l * BB * HH * HD * HD);
        kda_epi<<<1024, 256, 0, stream>>>(SinT, qe_bf, olb_bf, gate_bf, onorm_w + l * HD, x_bf);
        // a = o @ Wo
        bgemm<BE_BF16, 2><<<dim3(6, 64), 256, 0, stream>>>(x_bf, wt_o[l], nullptr, a_bf, nullptr, nullptr, MM, DD, DD);
        // swiglu
        bgemm_dual<<<dim3(32, 64), 256, 0, stream>>>(a_bf, wt_gate[l], wt_up[l], mg_bf, MM, FF, DD);
        float* dst = (l == LL - 1) ? out : hbuf;
        bgemm<BE_RES, 2><<<dim3(6, 64), 256, 0, stream>>>(mg_bf, wt_down[l], dst, nullptr,
                                                          hbuf, nullptr, MM, DD, FF);
    }
}

// Round 14
// 1024.094 us; speedup vs baseline: 3.8338x; 1.0697x over previous
//
#include <hip/hip_runtime.h>
#include <cstddef>
#include <cstdint>
#include <cmath>

// Problem constants
constexpr int BB = 4, TT = 2048, DD = 768, HH = 8, HD = 96, FF = 2048, LL = 2;
constexpr int MM = BB * TT;              // 8192
constexpr size_t HROW = (size_t)MM * DD; // 6291456
constexpr int CH = 64;                   // scan chunk length
constexpr int NCH = TT / CH;             // 32 chunks per sequence
constexpr int RP = 100;                  // padded LDS row (floats)
constexpr int KP = 104;                  // padded LDS row (ushorts)

typedef float f32x4 __attribute__((ext_vector_type(4)));
typedef short bf16x8 __attribute__((ext_vector_type(8)));
typedef unsigned short u16x8 __attribute__((ext_vector_type(8)));

__device__ __forceinline__ void gload16(const void* g, void* l) {
    __builtin_amdgcn_global_load_lds(
        (const __attribute__((address_space(1))) void*)g,
        (__attribute__((address_space(3))) void*)l, 16, 0, 0);
}
__device__ __forceinline__ float bf2f(unsigned short u) {
    return __uint_as_float(((unsigned)u) << 16);
}
__device__ __forceinline__ unsigned short f2bf(float f) {
    unsigned u = __float_as_uint(f);
    unsigned r = (u + 0x7fffu + ((u >> 16) & 1u)) >> 16;
    return (unsigned short)r;
}

// ---------------------------------------------------------------- LayerNorm -> bf16
__global__ __launch_bounds__(256)
void layernorm_rows(const float* __restrict__ x, unsigned short* __restrict__ y,
                    const float* __restrict__ w, const float* __restrict__ b,
                    const float* mask)
{
    const int row = blockIdx.x;
    const int tid = threadIdx.x;
    const float* xr = x + (size_t)row * DD;
    float v0 = xr[tid], v1 = xr[tid + 256], v2 = xr[tid + 512];
    float s = v0 + v1 + v2;
    float ss = v0 * v0 + v1 * v1 + v2 * v2;
#pragma unroll
    for (int i = 1; i < 64; i <<= 1) { s += __shfl_xor(s, i); ss += __shfl_xor(ss, i); }
    __shared__ float red[8];
    const int wid = tid >> 6, lane = tid & 63;
    if (lane == 0) { red[wid] = s; red[4 + wid] = ss; }
    __syncthreads();
    const float S  = red[0] + red[1] + red[2] + red[3];
    const float SS = red[4] + red[5] + red[6] + red[7];
    const float mean = S * (1.f / DD);
    const float var  = SS * (1.f / DD) - mean * mean;
    const float rstd = rsqrtf(var + 1e-5f);
    const float m = mask ? mask[row] : 1.f;
    unsigned short* yr = y + (size_t)row * DD;
    yr[tid]       = f2bf(((v0 - mean) * rstd * w[tid]       + b[tid])       * m);
    yr[tid + 256] = f2bf(((v1 - mean) * rstd * w[tid + 256] + b[tid + 256]) * m);
    yr[tid + 512] = f2bf(((v2 - mean) * rstd * w[tid + 512] + b[tid + 512]) * m);
}

// ---------------------------------------------------------------- transpose+convert W
__global__ __launch_bounds__(256)
void transcvt(const float* __restrict__ in, unsigned short* __restrict__ out, int K, int N)
{
    __shared__ float t[32][33];
    const int tx = threadIdx.x & 31, ty = threadIdx.x >> 5;
    const int k0 = blockIdx.y * 32, n0 = blockIdx.x * 32;
#pragma unroll
    for (int i = 0; i < 4; ++i)
        t[ty + i * 8][tx] = in[(size_t)(k0 + ty + i * 8) * N + n0 + tx];
    __syncthreads();
#pragma unroll
    for (int i = 0; i < 4; ++i)
        out[(size_t)(n0 + ty + i * 8) * K + k0 + tx] = f2bf(t[tx][ty + i * 8]);
}

// ---------------------------------------------------------------- bf16 MFMA GEMM
// NH = number of 32-col K-halves staged per barrier phase (1 or 2).
enum { BE_BIAS = 0, BE_SILU, BE_F32, BE_BF16, BE_RES, BE_QKV };

template <int EPI, int NH>
__global__ __launch_bounds__(256)
void bgemm(const unsigned short* __restrict__ A, const unsigned short* __restrict__ Bt,
           float* Cf, unsigned short* Cb,
           const float* P0, const float* P1,
           int M, int N, int K)
{
    __shared__ unsigned short As[NH][128 * 32];
    __shared__ unsigned short Bs[NH][128 * 32];
    const int tid = threadIdx.x;
    const int w = tid >> 6, l = tid & 63;
    const int wm = w >> 1, wn = w & 1;
    const int lr = l & 15, lh = l >> 4;
    const int m0 = blockIdx.y * 128, n0 = blockIdx.x * 128;

    f32x4 acc[4][4];
#pragma unroll
    for (int i = 0; i < 4; ++i)
#pragma unroll
        for (int j = 0; j < 4; ++j) acc[i][j] = (f32x4){0.f, 0.f, 0.f, 0.f};

    const int sr = l >> 2, sq = (l & 3) * 8;
    const unsigned short* Ag = A + (size_t)(m0 + w * 32 + sr) * K + sq;
    const unsigned short* Bg = Bt + (size_t)(n0 + w * 32 + sr) * K + sq;
    const int lofs = (w * 32) * 32;

    for (int kt = 0; kt < K; kt += 32 * NH) {
        __syncthreads();
#pragma unroll
        for (int hh = 0; hh < NH; ++hh) {
            gload16(Ag + kt + hh * 32, &As[hh][lofs]);
            gload16(Ag + kt + hh * 32 + 16 * (size_t)K, &As[hh][lofs + 16 * 32]);
            gload16(Bg + kt + hh * 32, &Bs[hh][lofs]);
            gload16(Bg + kt + hh * 32 + 16 * (size_t)K, &Bs[hh][lofs + 16 * 32]);
        }
        __syncthreads();
#pragma unroll
        for (int hh = 0; hh < NH; ++hh) {
            bf16x8 af[4], bfv[4];
#pragma unroll
            for (int mi = 0; mi < 4; ++mi)
                af[mi] = *(const bf16x8*)&As[hh][(wm * 64 + mi * 16 + lr) * 32 + lh * 8];
#pragma unroll
            for (int ni = 0; ni < 4; ++ni)
                bfv[ni] = *(const bf16x8*)&Bs[hh][(wn * 64 + ni * 16 + lr) * 32 + lh * 8];
#pragma unroll
            for (int mi = 0; mi < 4; ++mi)
#pragma unroll
                for (int ni = 0; ni < 4; ++ni)
                    acc[mi][ni] = __builtin_amdgcn_mfma_f32_16x16x32_bf16(af[mi], bfv[ni], acc[mi][ni], 0, 0, 0);
        }
    }

#pragma unroll
    for (int mi = 0; mi < 4; ++mi) {
#pragma unroll
        for (int j = 0; j < 4; ++j) {
            const int row = m0 + wm * 64 + mi * 16 + lh * 4 + j;
#pragma unroll
            for (int ni = 0; ni < 4; ++ni) {
                const int col = n0 + wn * 64 + ni * 16 + lr;
                const size_t idx = (size_t)row * N + col;
                float v = acc[mi][ni][j];
                if constexpr (EPI == BE_BIAS) { Cf[idx] = v + P0[col]; }
                else if constexpr (EPI == BE_SILU) { Cf[idx] = v / (1.f + expf(-v)); }
                else if constexpr (EPI == BE_F32) { Cf[idx] = v; }
                else if constexpr (EPI == BE_BF16) { Cb[idx] = f2bf(v); }
                else if constexpr (EPI == BE_RES) { Cf[idx] = v + P0[idx]; }
                else if constexpr (EPI == BE_QKV) {
                    const int tgt = col / 768;
                    const int cl = col - tgt * 768;
                    float* dst = (tgt == 0) ? Cf
                               : (tgt == 1) ? const_cast<float*>(P0)
                                            : const_cast<float*>(P1);
                    dst[(size_t)row * 768 + cl] = v / (1.f + expf(-v));
                }
            }
        }
    }
}

// Dual-B GEMM for SwiGLU (BK=64 via half-buffers)
__global__ __launch_bounds__(256)
void bgemm_dual(const unsigned short* __restrict__ A,
                const unsigned short* __restrict__ Bg_, const unsigned short* __restrict__ Bu_,
                unsigned short* __restrict__ C, int M, int N, int K)
{
    __shared__ unsigned short As[2][128 * 32];
    __shared__ unsigned short Bs1[2][64 * 32];
    __shared__ unsigned short Bs2[2][64 * 32];
    const int tid = threadIdx.x;
    const int w = tid >> 6, l = tid & 63;
    const int wm = w >> 1, wn = w & 1;
    const int lr = l & 15, lh = l >> 4;
    const int m0 = blockIdx.y * 128, n0 = blockIdx.x * 64;

    f32x4 a1[4][2], a2[4][2];
#pragma unroll
    for (int i = 0; i < 4; ++i)
#pragma unroll
        for (int j = 0; j < 2; ++j) { a1[i][j] = (f32x4){0.f,0.f,0.f,0.f}; a2[i][j] = (f32x4){0.f,0.f,0.f,0.f}; }

    const int sr = l >> 2, sq = (l & 3) * 8;
    const unsigned short* Ag  = A   + (size_t)(m0 + w * 32 + sr) * K + sq;
    const unsigned short* B1g = Bg_ + (size_t)(n0 + w * 16 + sr) * K + sq;
    const unsigned short* B2g = Bu_ + (size_t)(n0 + w * 16 + sr) * K + sq;
    const int aofs = (w * 32) * 32;
    const int bofs = (w * 16) * 32;

    for (int kt = 0; kt < K; kt += 64) {
        __syncthreads();
#pragma unroll
        for (int hh = 0; hh < 2; ++hh) {
            gload16(Ag + kt + hh * 32, &As[hh][aofs]);
            gload16(Ag + kt + hh * 32 + 16 * (size_t)K, &As[hh][aofs + 16 * 32]);
            gload16(B1g + kt + hh * 32, &Bs1[hh][bofs]);
            gload16(B2g + kt + hh * 32, &Bs2[hh][bofs]);
        }
        __syncthreads();
#pragma unroll
        for (int hh = 0; hh < 2; ++hh) {
            bf16x8 af[4], b1[2], b2[2];
#pragma unroll
            for (int mi = 0; mi < 4; ++mi)
                af[mi] = *(const bf16x8*)&As[hh][(wm * 64 + mi * 16 + lr) * 32 + lh * 8];
#pragma unroll
            for (int ni = 0; ni < 2; ++ni) {
                b1[ni] = *(const bf16x8*)&Bs1[hh][(wn * 32 + ni * 16 + lr) * 32 + lh * 8];
                b2[ni] = *(const bf16x8*)&Bs2[hh][(wn * 32 + ni * 16 + lr) * 32 + lh * 8];
            }
#pragma unroll
            for (int mi = 0; mi < 4; ++mi)
#pragma unroll
                for (int ni = 0; ni < 2; ++ni) {
                    a1[mi][ni] = __builtin_amdgcn_mfma_f32_16x16x32_bf16(af[mi], b1[ni], a1[mi][ni], 0, 0, 0);
                    a2[mi][ni] = __builtin_amdgcn_mfma_f32_16x16x32_bf16(af[mi], b2[ni], a2[mi][ni], 0, 0, 0);
                }
        }
    }

#pragma unroll
    for (int mi = 0; mi < 4; ++mi)
#pragma unroll
        for (int j = 0; j < 4; ++j) {
            const int row = m0 + wm * 64 + mi * 16 + lh * 4 + j;
#pragma unroll
            for (int ni = 0; ni < 2; ++ni) {
                const int col = n0 + wn * 32 + ni * 16 + lr;
                const float g = a1[mi][ni][j], u = a2[mi][ni][j];
                C[(size_t)row * N + col] = f2bf((g / (1.f + expf(-g))) * u);
            }
        }
}

// fa|ga fused GEMM (BK=64): N fixed 192 ([Wfa|Wga]^T), routing epilogue.
__global__ __launch_bounds__(256)
void bgemm_fg(const unsigned short* __restrict__ A, const unsigned short* __restrict__ Bt,
              unsigned short* __restrict__ Cfa, unsigned short* __restrict__ Cga, int K)
{
    __shared__ unsigned short As[2][128 * 32];
    __shared__ unsigned short Bs[2][64 * 32];
    const int tid = threadIdx.x;
    const int w = tid >> 6, l = tid & 63;
    const int wm = w >> 1, wn = w & 1;
    const int lr = l & 15, lh = l >> 4;
    const int m0 = blockIdx.y * 128, n0 = blockIdx.x * 64;

    f32x4 acc[4][2];
#pragma unroll
    for (int i = 0; i < 4; ++i)
#pragma unroll
        for (int j = 0; j < 2; ++j) acc[i][j] = (f32x4){0.f, 0.f, 0.f, 0.f};

    const int sr = l >> 2, sq = (l & 3) * 8;
    const unsigned short* Ag = A + (size_t)(m0 + w * 32 + sr) * K + sq;
    const unsigned short* Bg = Bt + (size_t)(n0 + w * 16 + sr) * K + sq;
    const int aofs = (w * 32) * 32;
    const int bofs = (w * 16) * 32;

    for (int kt = 0; kt < K; kt += 64) {
        __syncthreads();
#pragma unroll
        for (int hh = 0; hh < 2; ++hh) {
            gload16(Ag + kt + hh * 32, &As[hh][aofs]);
            gload16(Ag + kt + hh * 32 + 16 * (size_t)K, &As[hh][aofs + 16 * 32]);
            gload16(Bg + kt + hh * 32, &Bs[hh][bofs]);
        }
        __syncthreads();
#pragma unroll
        for (int hh = 0; hh < 2; ++hh) {
            bf16x8 af[4], bfv[2];
#pragma unroll
            for (int mi = 0; mi < 4; ++mi)
                af[mi] = *(const bf16x8*)&As[hh][(wm * 64 + mi * 16 + lr) * 32 + lh * 8];
#pragma unroll
            for (int ni = 0; ni < 2; ++ni)
                bfv[ni] = *(const bf16x8*)&Bs[hh][(wn * 32 + ni * 16 + lr) * 32 + lh * 8];
#pragma unroll
            for (int mi = 0; mi < 4; ++mi)
#pragma unroll
                for (int ni = 0; ni < 2; ++ni)
                    acc[mi][ni] = __builtin_amdgcn_mfma_f32_16x16x32_bf16(af[mi], bfv[ni], acc[mi][ni], 0, 0, 0);
        }
    }

#pragma unroll
    for (int mi = 0; mi < 4; ++mi)
#pragma unroll
        for (int j = 0; j < 4; ++j) {
            const int row = m0 + wm * 64 + mi * 16 + lh * 4 + j;
#pragma unroll
            for (int ni = 0; ni < 2; ++ni) {
                const int col = n0 + wn * 32 + ni * 16 + lr;   // 0..191, 16-aligned tiles
                const int tgt = (col >= HD);
                const int cl = col - (tgt ? HD : 0);
                unsigned short* dst = tgt ? Cga : Cfa;
                dst[(size_t)row * HD + cl] = f2bf(acc[mi][ni][j]);
            }
        }
}

// ---------------------------------------------------------------- small fp32 GEMM (A bf16)
template <int MODE>
__global__ __launch_bounds__(256)
void gemm_small(const unsigned short* __restrict__ A, const float* __restrict__ Bm,
                unsigned short* Cb, float* Cf, int M, int N, int K)
{
    __shared__ float As[16][64];
    __shared__ float Bs[16][64];
    const int tid = threadIdx.x;
    const int tx = tid & 15, ty = tid >> 4;
    const int row0 = blockIdx.y * 64;
    const int col0 = blockIdx.x * 64;
    float acc[4][4] = {};
    const int ar  = tid >> 2;
    const int ac4 = (tid & 3) << 2;
    const int br  = tid >> 4;
    const int bc  = (tid & 15) << 2;
    const int gc  = col0 + bc;
    const bool bok = gc < N;

    for (int kt = 0; kt < K; kt += 16) {
        const ushort4 a4 = *(const ushort4*)(A + (size_t)(row0 + ar) * K + kt + ac4);
        float4 b4 = make_float4(0.f, 0.f, 0.f, 0.f);
        if (bok) b4 = *(const float4*)(Bm + (size_t)(kt + br) * N + gc);
        __syncthreads();
        As[ac4 + 0][ar] = bf2f(a4.x); As[ac4 + 1][ar] = bf2f(a4.y);
        As[ac4 + 2][ar] = bf2f(a4.z); As[ac4 + 3][ar] = bf2f(a4.w);
        *(float4*)&Bs[br][bc] = b4;
        __syncthreads();
#pragma unroll
        for (int kk = 0; kk < 16; ++kk) {
            const float4 av = *(const float4*)&As[kk][ty << 2];
            const float4 bv = *(const float4*)&Bs[kk][tx << 2];
            const float a_[4] = {av.x, av.y, av.z, av.w};
            const float b_[4] = {bv.x, bv.y, bv.z, bv.w};
#pragma unroll
            for (int i = 0; i < 4; ++i)
#pragma unroll
                for (int j = 0; j < 4; ++j)
                    acc[i][j] = fmaf(a_[i], b_[j], acc[i][j]);
        }
    }
#pragma unroll
    for (int i = 0; i < 4; ++i) {
        const int row = row0 + (ty << 2) + i;
#pragma unroll
        for (int j = 0; j < 4; ++j) {
            const int col = col0 + (tx << 2) + j;
            if (col >= N) continue;
            const size_t idx = (size_t)row * N + col;
            if constexpr (MODE == 0) Cb[idx] = f2bf(acc[i][j]);
            else                     Cf[idx] = 1.f / (1.f + expf(-acc[i][j]));
        }
    }
}

// ---------------------------------------------------------------- l2norm over HD=96
__global__ __launch_bounds__(256)
void l2norm_rows(float* x, float scale)
{
    const int row  = (blockIdx.x << 2) + (threadIdx.x >> 6);
    const int lane = threadIdx.x & 63;
    float* xr = x + (size_t)row * HD;
    const float a = xr[lane];
    const float b = (lane < 32) ? xr[64 + lane] : 0.f;
    float ss = a * a + b * b;
#pragma unroll
    for (int i = 1; i < 64; i <<= 1) ss += __shfl_xor(ss, i);
    const float r = rsqrtf(ss + 1e-6f) * scale;
    xr[lane] = a * r;
    if (lane < 32) xr[64 + lane] = b * r;
}

// ---------------------------------------------------------------- KDA chunkwise precompute
// Fuses the EG GEMM: g = -exp(A_log)*softplus(fab@Wfb + dt_bias) computed inline (MFMA).
constexpr int TBP = 72;   // Tb row pad (u16)
constexpr int XLP = 72;   // Xl row pad (u16)
__global__ __launch_bounds__(256)
void kda_pre(const float* __restrict__ q, const float* __restrict__ k, float* v,
             const unsigned short* __restrict__ fab, const float* __restrict__ Alog,
             const float* __restrict__ dtb, const unsigned short* __restrict__ wfb,
             const float* __restrict__ beta,
             unsigned short* __restrict__ ol, float* __restrict__ Bc,
             unsigned short* __restrict__ Wbf, unsigned short* __restrict__ Ktg,
             unsigned short* __restrict__ qeb)
{
    __shared__ unsigned short Kb[CH * KP];   // k (bf16), then kappa_tilde (bf16)
    __shared__ float Qp[CH * RP];            // g -> L -> q'
    __shared__ float sb[CH];
    __shared__ __align__(16) char uR[36864];
    unsigned short* Kk = (unsigned short*)uR;
    float (*Am)[68] = (float(*)[68])(uR + 13312);
    unsigned short* Tb = (unsigned short*)uR;
    unsigned short* Xl = (unsigned short*)(uR + 9216);

    const int blk = blockIdx.x;
    const int ch = blk & 31, bh = blk >> 5;
    const int b = bh >> 3, h = bh & 7;
    const int tid = threadIdx.x;
    const size_t base = (size_t)b * (TT * HH * HD) + (size_t)(ch * CH) * (HH * HD) + h * HD;
    const size_t tok0 = (size_t)b * TT + ch * CH;

    // P0: stage k (as bf16), beta
    for (int e = tid; e < CH * 24; e += 256) {
        const int t = e / 24, c4 = (e % 24) * 4;
        const float4 kv = *(const float4*)(k + base + t * 768 + c4);
        ushort4 k4;
        k4.x = f2bf(kv.x); k4.y = f2bf(kv.y); k4.z = f2bf(kv.z); k4.w = f2bf(kv.w);
        *(ushort4*)&Kb[t * KP + c4] = k4;
    }
    if (tid < CH) sb[tid] = beta[((size_t)b * TT + ch * CH + tid) * HH + h];

    // P0b (MFMA, fused EG): g = -exp(A_log)*softplus(fab@Wfb_h + dt_bias) -> Qp
    {
        const int lane = tid & 63, w = tid >> 6;
        const int lr = lane & 15, lh = lane >> 4;
        const int t0 = w * 16;
        bf16x8 afr[3];
#pragma unroll
        for (int ks = 0; ks < 3; ++ks)
            afr[ks] = *(const bf16x8*)(fab + (tok0 + t0 + lr) * HD + ks * 32 + lh * 8);
#pragma unroll
        for (int nt = 0; nt < 6; ++nt) {
            f32x4 acc = (f32x4){0.f, 0.f, 0.f, 0.f};
#pragma unroll
            for (int ks = 0; ks < 3; ++ks) {
                const bf16x8 bfr = *(const bf16x8*)(wfb +
                    (size_t)(h * HD + nt * 16 + lr) * HD + ks * 32 + lh * 8);
                acc = __builtin_amdgcn_mfma_f32_16x16x32_bf16(afr[ks], bfr, acc, 0, 0, 0);
            }
            const int c = nt * 16 + lr;
            const float na = -expf(Alog[h * HD + c]);
            const float db = dtb[h * HD + c];
#pragma unroll
            for (int r = 0; r < 4; ++r) {
                const int t = t0 + lh * 4 + r;
                const float lin = acc[r] + db;
                const float sp = (lin > 20.f) ? lin : log1pf(expf(lin));
                Qp[t * RP + c] = na * sp;
            }
        }
    }
    __syncthreads();

    // P1: per-channel cumsum of g
    if (tid < HD) {
        float L = 0.f;
        for (int t = 0; t < CH; ++t) { L += Qp[t * RP + tid]; Qp[t * RP + tid] = L; }
    }
    __syncthreads();

    // P2: kappa, kappa_tilde (bf16), q', Bc
    for (int e = tid; e < CH * HD; e += 256) {
        const int t = e / HD, c = e % HD;
        const float L = Qp[t * RP + c];
        const float B = expf(L), iB = expf(-L);
        const float kv = bf2f(Kb[t * KP + c]);
        if (t == CH - 1) Bc[((size_t)bh * NCH + ch) * HD + c] = B;
        Kk[t * KP + c] = f2bf(kv * B);
        const unsigned short kti = f2bf(kv * iB);
        const float qv = q[base + t * 768 + c];
        Kb[t * KP + c] = kti;
        Qp[t * RP + c] = qv * B;                  // q'
    }
    __syncthreads();

    // P2b: export ktil^T -> Ktg[(bh,ch)][c][t]
#pragma unroll
    for (int i = 0; i < 3; ++i) {
        const int u = i * 256 + tid;
        const int c = u / 8, t8 = (u % 8) * 8;
        u16x8 vv;
#pragma unroll
        for (int j = 0; j < 8; ++j) vv[j] = Kb[(t8 + j) * KP + c];
        *(u16x8*)(Ktg + (((size_t)bh * NCH + ch) * HD + c) * CH + t8) = vv;
    }

    // P3 (MFMA): A[t][i] = beta_t * (kappa_t . ktil_i), i < t
    {
        const int lane = tid & 63;
        const int lr = lane & 15, lh = lane >> 4;
        const int t0 = (tid >> 6) * 16;
        bf16x8 afr[3];
#pragma unroll
        for (int ks = 0; ks < 3; ++ks)
            afr[ks] = *(const bf16x8*)&Kk[(t0 + lr) * KP + ks * 32 + lh * 8];
#pragma unroll
        for (int i0 = 0; i0 < 64; i0 += 16) {
            f32x4 acc = (f32x4){0.f, 0.f, 0.f, 0.f};
#pragma unroll
            for (int ks = 0; ks < 3; ++ks) {
                const bf16x8 bfr = *(const bf16x8*)&Kb[(i0 + lr) * KP + ks * 32 + lh * 8];
                acc = __builtin_amdgcn_mfma_f32_16x16x32_bf16(afr[ks], bfr, acc, 0, 0, 0);
            }
#pragma unroll
            for (int r = 0; r < 4; ++r) {
                const int t = t0 + lh * 4 + r;
                const int i = i0 + lr;
                Am[t][i] = (i < t) ? acc[r] * sb[t] : 0.f;
            }
        }
    }
    __syncthreads();

    // P4: forward solve, column j of [U | W] in registers
    float X[CH];
    const int j = tid;
    if (j < 192) {
        if (j < HD) {
#pragma unroll
            for (int t = 0; t < CH; ++t) X[t] = sb[t] * v[base + t * 768 + j];
        } else {
#pragma unroll
            for (int t = 0; t < CH; ++t) X[t] = sb[t] * bf2f(Kk[t * KP + (j - HD)]);
        }
#pragma unroll
        for (int t = 1; t < CH; ++t) {
            float a0 = 0, a1 = 0, a2 = 0, a3 = 0;
#pragma unroll
            for (int i4 = 0; i4 * 4 < t; ++i4) {
                const float4 a = *(const float4*)&Am[t][i4 * 4];
                if (i4 * 4 + 0 < t) a0 = fmaf(a.x, X[i4 * 4 + 0], a0);
                if (i4 * 4 + 1 < t) a1 = fmaf(a.y, X[i4 * 4 + 1], a1);
                if (i4 * 4 + 2 < t) a2 = fmaf(a.z, X[i4 * 4 + 2], a2);
                if (i4 * 4 + 3 < t) a3 = fmaf(a.w, X[i4 * 4 + 3], a3);
            }
            X[t] -= ((a0 + a1) + (a2 + a3));
        }
        // P5: store U (f32 over v) / -W (bf16)
        if (j < HD) {
#pragma unroll
            for (int t = 0; t < CH; ++t) v[base + t * 768 + j] = X[t];
        } else {
#pragma unroll
            for (int t = 0; t < CH; ++t) Wbf[base + t * 768 + (j - HD)] = f2bf(-X[t]);
        }
    }
    __syncthreads();   // Am/Kk dead past here

    // phase 2a: X -> Xl (bf16, [j][t]); P6 (MFMA): T -> Tb (bf16, [t][i])
    if (j < 192) {
#pragma unroll
        for (int t8 = 0; t8 < 8; ++t8) {
            u16x8 xv;
#pragma unroll
            for (int jj = 0; jj < 8; ++jj) xv[jj] = f2bf(X[t8 * 8 + jj]);
            *(u16x8*)&Xl[j * XLP + t8 * 8] = xv;
        }
    }
    {
        const int lane = tid & 63;
        const int lr = lane & 15, lh = lane >> 4;
        const int t0 = (tid >> 6) * 16;
        bf16x8 afr[3];
#pragma unroll
        for (int ks = 0; ks < 3; ++ks) {
            const float4 qa = *(const float4*)&Qp[(t0 + lr) * RP + ks * 32 + lh * 8];
            const float4 qc = *(const float4*)&Qp[(t0 + lr) * RP + ks * 32 + lh * 8 + 4];
            bf16x8 a;
            a[0] = (short)f2bf(qa.x); a[1] = (short)f2bf(qa.y);
            a[2] = (short)f2bf(qa.z); a[3] = (short)f2bf(qa.w);
            a[4] = (short)f2bf(qc.x); a[5] = (short)f2bf(qc.y);
            a[6] = (short)f2bf(qc.z); a[7] = (short)f2bf(qc.w);
            afr[ks] = a;
        }
#pragma unroll
        for (int i0 = 0; i0 < 64; i0 += 16) {
            f32x4 acc = (f32x4){0.f, 0.f, 0.f, 0.f};
#pragma unroll
            for (int ks = 0; ks < 3; ++ks) {
                const bf16x8 bfr = *(const bf16x8*)&Kb[(i0 + lr) * KP + ks * 32 + lh * 8];
                acc = __builtin_amdgcn_mfma_f32_16x16x32_bf16(afr[ks], bfr, acc, 0, 0, 0);
            }
#pragma unroll
            for (int r = 0; r < 4; ++r) {
                const int t = t0 + lh * 4 + r;
                const int i = i0 + lr;
                Tb[t * TBP + i] = (i <= t) ? f2bf(acc[r]) : (unsigned short)0;
            }
        }
    }
    __syncthreads();

    // P7 (MFMA): res = T @ X ; j<96 -> Ol ; j>=96 -> Qe(bf16) = q' - res
    {
        const int lane = tid & 63;
        const int lr = lane & 15, lh = lane >> 4;
        const int w = tid >> 6;
        const int t0 = w * 16;
        bf16x8 af0 = *(const bf16x8*)&Tb[(t0 + lr) * TBP + lh * 8];
        bf16x8 af1 = *(const bf16x8*)&Tb[(t0 + lr) * TBP + 32 + lh * 8];
#pragma unroll
        for (int nt = 0; nt < 12; ++nt) {
            const int n0 = nt * 16;
            f32x4 acc = (f32x4){0.f, 0.f, 0.f, 0.f};
            acc = __builtin_amdgcn_mfma_f32_16x16x32_bf16(
                af0, *(const bf16x8*)&Xl[(n0 + lr) * XLP + lh * 8], acc, 0, 0, 0);
            acc = __builtin_amdgcn_mfma_f32_16x16x32_bf16(
                af1, *(const bf16x8*)&Xl[(n0 + lr) * XLP + 32 + lh * 8], acc, 0, 0, 0);
            const int jc = n0 + lr;
#pragma unroll
            for (int r = 0; r < 4; ++r) {
                const int t = t0 + lh * 4 + r;
                if (jc < HD) ol[base + t * 768 + jc] = f2bf(acc[r]);
                else         qeb[base + t * 768 + (jc - HD)] = f2bf(Qp[t * RP + (jc - HD)] - acc[r]);
            }
        }
    }
}

// ---------------------------------------------------------------- KDA sequential recurrence (MFMA form)
constexpr int VSL = 16;
constexpr int WNP = 120;  // Wn row pad (u16)
constexpr int KTP2 = 72;  // Kt row pad
constexpr int DBP = 72;   // Dbt row pad
constexpr int SBP = 120;  // Sbt row pad
__global__ __launch_bounds__(256)
void kda_seq(const unsigned short* __restrict__ Wbf, const unsigned short* __restrict__ Ktg,
             const float* __restrict__ U, const float* __restrict__ Bc,
             unsigned short* __restrict__ SinT, float* __restrict__ states)
{
    __shared__ unsigned short Wn[CH * WNP];    // -W bf16, [t][k]
    __shared__ unsigned short Kt[HD * KTP2];   // ktil^T bf16, [k][t]
    __shared__ unsigned short Dbt[VSL * DBP];  // delta^T bf16, [v][t]
    __shared__ unsigned short Sbt[VSL * SBP];  // S^T bf16, [v][k]

    const int blk = blockIdx.x;
    const int bh = blk / 6, vq = blk - bh * 6;
    const int b = bh >> 3, h = bh & 7;
    const int tid = threadIdx.x;
    const int w = tid >> 6, lane = tid & 63;
    const int lr = lane & 15, lh = lane >> 4;
    const int v0 = vq * VSL;
    const size_t base = (size_t)b * (TT * HH * HD) + h * HD;
    const size_t cbase = (size_t)bh * NCH;

    const int t0 = w * 16;
    const int k1 = w * 16;
    const int k2 = (w < 2) ? (4 + w) * 16 : -1;

    f32x4 accS1 = (f32x4){0.f, 0.f, 0.f, 0.f};
    f32x4 accS2 = (f32x4){0.f, 0.f, 0.f, 0.f};

    for (int e = tid; e < VSL * SBP; e += 256) Sbt[e] = 0;

    u16x8 wpf[3], kpf[3];
    float upf[4], ucur[4];

    // ---- stage chunk 0
    {
        const size_t cb = base;
#pragma unroll
        for (int i = 0; i < 3; ++i) {
            const int u = i * 256 + tid;
            const int r = u / 12, c8 = (u % 12) * 8;
            wpf[i] = *(const u16x8*)(Wbf + cb + (size_t)r * 768 + c8);
        }
        const size_t kb_ = (cbase * HD) * CH;
#pragma unroll
        for (int i = 0; i < 3; ++i) {
            const int u = i * 256 + tid;
            const int c = u / 8, t8 = (u % 8) * 8;
            kpf[i] = *(const u16x8*)(Ktg + kb_ + (size_t)c * CH + t8);
        }
#pragma unroll
        for (int r = 0; r < 4; ++r)
            ucur[r] = U[cb + (size_t)(t0 + lh * 4 + r) * 768 + v0 + lr];
#pragma unroll
        for (int i = 0; i < 3; ++i) {
            const int u = i * 256 + tid;
            const int r = u / 12, c8 = (u % 12) * 8;
            *(u16x8*)&Wn[r * WNP + c8] = wpf[i];
        }
#pragma unroll
        for (int i = 0; i < 3; ++i) {
            const int u = i * 256 + tid;
            const int c = u / 8, t8 = (u % 8) * 8;
            *(u16x8*)&Kt[c * KTP2 + t8] = kpf[i];
        }
    }
    __syncthreads();

    for (int ch = 0; ch < NCH; ++ch) {
        if (ch + 1 < NCH) {
            const size_t cb = base + (size_t)((ch + 1) * CH) * (HH * HD);
#pragma unroll
            for (int i = 0; i < 3; ++i) {
                const int u = i * 256 + tid;
                const int r = u / 12, c8 = (u % 12) * 8;
                wpf[i] = *(const u16x8*)(Wbf + cb + (size_t)r * 768 + c8);
            }
            const size_t kb_ = ((cbase + ch + 1) * HD) * CH;
#pragma unroll
            for (int i = 0; i < 3; ++i) {
                const int u = i * 256 + tid;
                const int c = u / 8, t8 = (u % 8) * 8;
                kpf[i] = *(const u16x8*)(Ktg + kb_ + (size_t)c * CH + t8);
            }
#pragma unroll
            for (int r = 0; r < 4; ++r)
                upf[r] = U[cb + (size_t)(t0 + lh * 4 + r) * 768 + v0 + lr];
        }

        // store S_in (bf16 S^T slice) for the O-epilogue
        if (tid < 192) {
            const int row = tid / 12, c8 = (tid % 12) * 8;
            *(u16x8*)(SinT + (size_t)(cbase + ch) * 9216 + (size_t)(v0 + row) * 96 + c8)
                = *(const u16x8*)&Sbt[row * SBP + c8];
        }

        // step A: delta = U + (-W)@S
        f32x4 del = (f32x4){ucur[0], ucur[1], ucur[2], ucur[3]};
#pragma unroll
        for (int ks = 0; ks < 3; ++ks) {
            const bf16x8 a = *(const bf16x8*)&Wn[(t0 + lr) * WNP + ks * 32 + lh * 8];
            const bf16x8 bb = *(const bf16x8*)&Sbt[lr * SBP + ks * 32 + lh * 8];
            del = __builtin_amdgcn_mfma_f32_16x16x32_bf16(a, bb, del, 0, 0, 0);
        }
#pragma unroll
        for (int r = 0; r < 4; ++r)
            Dbt[lr * DBP + t0 + lh * 4 + r] = f2bf(del[r]);
        __syncthreads();

        // step B: S = Bc * (S + ktil^T @ delta)
        const float* bc = Bc + (cbase + ch) * HD;
#pragma unroll
        for (int ks = 0; ks < 2; ++ks) {
            const bf16x8 a = *(const bf16x8*)&Kt[(k1 + lr) * KTP2 + ks * 32 + lh * 8];
            const bf16x8 bb = *(const bf16x8*)&Dbt[lr * DBP + ks * 32 + lh * 8];
            accS1 = __builtin_amdgcn_mfma_f32_16x16x32_bf16(a, bb, accS1, 0, 0, 0);
        }
#pragma unroll
        for (int r = 0; r < 4; ++r) accS1[r] *= bc[k1 + lh * 4 + r];
        if (k2 >= 0) {
#pragma unroll
            for (int ks = 0; ks < 2; ++ks) {
                const bf16x8 a = *(const bf16x8*)&Kt[(k2 + lr) * KTP2 + ks * 32 + lh * 8];
                const bf16x8 bb = *(const bf16x8*)&Dbt[lr * DBP + ks * 32 + lh * 8];
                accS2 = __builtin_amdgcn_mfma_f32_16x16x32_bf16(a, bb, accS2, 0, 0, 0);
            }
#pragma unroll
            for (int r = 0; r < 4; ++r) accS2[r] *= bc[k2 + lh * 4 + r];
        }
        __syncthreads();

        // export S -> Sbt; stage next chunk
#pragma unroll
        for (int r = 0; r < 4; ++r)
            Sbt[lr * SBP + k1 + lh * 4 + r] = f2bf(accS1[r]);
        if (k2 >= 0) {
#pragma unroll
            for (int r = 0; r < 4; ++r)
                Sbt[lr * SBP + k2 + lh * 4 + r] = f2bf(accS2[r]);
        }
        if (ch + 1 < NCH) {
#pragma unroll
            for (int i = 0; i < 3; ++i) {
                const int u = i * 256 + tid;
                const int r = u / 12, c8 = (u % 12) * 8;
                *(u16x8*)&Wn[r * WNP + c8] = wpf[i];
            }
#pragma unroll
            for (int i = 0; i < 3; ++i) {
                const int u = i * 256 + tid;
                const int c = u / 8, t8 = (u % 8) * 8;
                *(u16x8*)&Kt[c * KTP2 + t8] = kpf[i];
            }
#pragma unroll
            for (int r = 0; r < 4; ++r) ucur[r] = upf[r];
        }
        __syncthreads();
    }

    // final states (f32)
    {
        float* sp = states + (size_t)bh * (HD * HD);
#pragma unroll
        for (int r = 0; r < 4; ++r)
            sp[(size_t)(k1 + lh * 4 + r) * HD + v0 + lr] = accS1[r];
        if (k2 >= 0) {
#pragma unroll
            for (int r = 0; r < 4; ++r)
                sp[(size_t)(k2 + lh * 4 + r) * HD + v0 + lr] = accS2[r];
        }
    }
}

// ---------------------------------------------------------------- KDA parallel O epilogue (MFMA)
// O = Ol + Qe @ S_in; gate = gab@Wgb_h (fused MFMA); out = onorm(O)*silu(gate).
__global__ __launch_bounds__(256)
void kda_epi(const unsigned short* __restrict__ SinT, const unsigned short* __restrict__ Qe,
             const unsigned short* __restrict__ Ol,
             const unsigned short* __restrict__ gab, const unsigned short* __restrict__ wgb,
             const float* __restrict__ onw, unsigned short* __restrict__ obf)
{
    __shared__ unsigned short Sl[96 * 104];    // S^T bf16 [v][k]
    __shared__ unsigned short Ql[64 * 104];    // Qe bf16 [t][k]
    __shared__ unsigned short Olb[64 * 104];
    __shared__ float onws[HD];

    const int bx = blockIdx.x;
    const int bh = bx >> 5, ch = bx & 31;
    const int b = bh >> 3, h = bh & 7;
    const int tid = threadIdx.x;
    const size_t cb = (size_t)b * (TT * HH * HD) + (size_t)(ch * CH) * (HH * HD) + h * HD;
    const size_t sbase = (size_t)(bh * NCH + ch) * 9216;
    const size_t tok0 = (size_t)b * TT + ch * CH;

#pragma unroll
    for (int i = 0; i < 5; ++i) {
        const int u = i * 256 + tid;
        if (u < 1152) {
            const int row = u / 12, c8 = (u % 12) * 8;
            *(u16x8*)&Sl[row * 104 + c8] = *(const u16x8*)(SinT + sbase + (size_t)row * 96 + c8);
        }
    }
#pragma unroll
    for (int i = 0; i < 3; ++i) {
        const int u = i * 256 + tid;
        const int t = u / 12, c8 = (u % 12) * 8;
        *(u16x8*)&Ql[t * 104 + c8]  = *(const u16x8*)(Qe + cb + (size_t)t * 768 + c8);
        *(u16x8*)&Olb[t * 104 + c8] = *(const u16x8*)(Ol + cb + (size_t)t * 768 + c8);
    }
    if (tid < HD) onws[tid] = onw[tid];

    const int lane = tid & 63, w = tid >> 6;
    const int lr = lane & 15, lh = lane >> 4;
    const int t0 = w * 16;

    // fused gate GEMM (global operands, L2-hot): gacc[t][v] = gab @ Wgb_h
    bf16x8 gaf[3];
#pragma unroll
    for (int ks = 0; ks < 3; ++ks)
        gaf[ks] = *(const bf16x8*)(gab + (tok0 + t0 + lr) * HD + ks * 32 + lh * 8);
    f32x4 gacc[6];
#pragma unroll
    for (int nt = 0; nt < 6; ++nt) {
        gacc[nt] = (f32x4){0.f, 0.f, 0.f, 0.f};
#pragma unroll
        for (int ks = 0; ks < 3; ++ks) {
            const bf16x8 bfr = *(const bf16x8*)(wgb +
                (size_t)(h * HD + nt * 16 + lr) * HD + ks * 32 + lh * 8);
            gacc[nt] = __builtin_amdgcn_mfma_f32_16x16x32_bf16(gaf[ks], bfr, gacc[nt], 0, 0, 0);
        }
    }
    __syncthreads();

    bf16x8 af[3];
#pragma unroll
    for (int ks = 0; ks < 3; ++ks)
        af[ks] = *(const bf16x8*)&Ql[(t0 + lr) * 104 + ks * 32 + lh * 8];

    f32x4 acc[6];
#pragma unroll
    for (int nt = 0; nt < 6; ++nt) {
#pragma unroll
        for (int r = 0; r < 4; ++r)
            acc[nt][r] = bf2f(Olb[(t0 + lh * 4 + r) * 104 + nt * 16 + lr]);
#pragma unroll
        for (int ks = 0; ks < 3; ++ks)
            acc[nt] = __builtin_amdgcn_mfma_f32_16x16x32_bf16(
                af[ks], *(const bf16x8*)&Sl[(nt * 16 + lr) * 104 + ks * 32 + lh * 8],
                acc[nt], 0, 0, 0);
    }

    float ss0 = 0.f, ss1 = 0.f, ss2 = 0.f, ss3 = 0.f;
#pragma unroll
    for (int nt = 0; nt < 6; ++nt) {
        ss0 = fmaf(acc[nt][0], acc[nt][0], ss0);
        ss1 = fmaf(acc[nt][1], acc[nt][1], ss1);
        ss2 = fmaf(acc[nt][2], acc[nt][2], ss2);
        ss3 = fmaf(acc[nt][3], acc[nt][3], ss3);
    }
#pragma unroll
    for (int d = 1; d < 16; d <<= 1) {
        ss0 += __shfl_xor(ss0, d); ss1 += __shfl_xor(ss1, d);
        ss2 += __shfl_xor(ss2, d); ss3 += __shfl_xor(ss3, d);
    }
    const float rr0 = rsqrtf(ss0 * (1.f / HD) + 1e-6f);
    const float rr1 = rsqrtf(ss1 * (1.f / HD) + 1e-6f);
    const float rr2 = rsqrtf(ss2 * (1.f / HD) + 1e-6f);
    const float rr3 = rsqrtf(ss3 * (1.f / HD) + 1e-6f);

#pragma unroll
    for (int nt = 0; nt < 6; ++nt) {
        const int v = nt * 16 + lr;
        const float ow = onws[v];
#pragma unroll
        for (int r = 0; r < 4; ++r) {
            const int t = t0 + lh * 4 + r;
            const float rrv = (r == 0) ? rr0 : (r == 1) ? rr1 : (r == 2) ? rr2 : rr3;
            const float gg = gacc[nt][r];
            const float val = acc[nt][r] * rrv * ow * (gg / (1.f + expf(-gg)));
            obf[cb + (size_t)t * 768 + v] = f2bf(val);
        }
    }
}

// ---------------------------------------------------------------- host
extern "C" void kernel_launch(void* const* d_in, const int* in_sizes, int n_in,
                              void* d_out, int out_size, void* d_ws, size_t ws_size,
                              hipStream_t stream)
{
    (void)in_sizes; (void)n_in; (void)out_size; (void)ws_size;
    const float* hidden   = (const float*)d_in[0];
    const float* mask     = (const float*)d_in[1];
    const float* norm_a_w = (const float*)d_in[2];
    const float* norm_a_b = (const float*)d_in[3];
    const float* proj_a_w = (const float*)d_in[4];
    const float* proj_a_b = (const float*)d_in[5];
    const float* ln_w     = (const float*)d_in[6];
    const float* ln_b     = (const float*)d_in[7];
    const float* Wq       = (const float*)d_in[8];
    const float* Wk       = (const float*)d_in[9];
    const float* Wv       = (const float*)d_in[10];
    const float* Wfa      = (const float*)d_in[11];
    const float* Wfb      = (const float*)d_in[12];
    const float* dt_bias  = (const float*)d_in[13];
    const float* A_log    = (const float*)d_in[14];
    const float* Wb       = (const float*)d_in[15];
    const float* Wga      = (const float*)d_in[16];
    const float* Wgb      = (const float*)d_in[17];
    const float* onorm_w  = (const float*)d_in[18];
    const float* Wo       = (const float*)d_in[19];
    const float* Wgate    = (const float*)d_in[20];
    const float* Wup      = (const float*)d_in[21];
    const float* Wdown    = (const float*)d_in[22];

    float* ws    = (float*)d_ws;
    float* hbuf  = ws;
    float* qb    = ws + HROW;          // dead after pre -> mg lives here
    float* kb    = ws + 2 * HROW;
    float* vb    = ws + 3 * HROW;      // U (f32)
    float* egb   = ws + 4 * HROW;      // SinT region (EG GEMM now fused)
    float* betab = ws + 5 * HROW;                     // MM*HH
    float* BcP   = betab + (size_t)MM * HH;           // 32*32*96
    unsigned short* SinT = (unsigned short*)egb;      // 1024*96*96 u16 = 18.9MB <= 25.2MB
    unsigned short* bfp = (unsigned short*)(BcP + 32 * NCH * HD);
    unsigned short* x_bf    = bfp;  bfp += HROW;
    unsigned short* fab_bf  = bfp;  bfp += (size_t)MM * HD;
    unsigned short* gab_bf  = bfp;  bfp += (size_t)MM * HD;
    unsigned short* olb_bf  = bfp;  bfp += HROW;
    unsigned short* w_bf    = bfp;  bfp += HROW;
    unsigned short* k_bf    = bfp;  bfp += HROW;      // ktil^T [bh][ch][96][64]
    unsigned short* qe_bf   = bfp;  bfp += HROW;      // Qe bf16
    unsigned short* wt_proj = bfp;  bfp += 768 * 768;
    unsigned short *wt_q[LL], *wt_k[LL], *wt_v[LL], *wt_o[LL], *wt_fb[LL], *wt_gb[LL],
                   *wt_fg[LL], *wt_gate[LL], *wt_up[LL], *wt_down[LL];
    for (int l = 0; l < LL; ++l) {
        wt_q[l] = bfp;    bfp += 768 * 768;   // q,k,v contiguous -> fused N=2304 GEMM
        wt_k[l] = bfp;    bfp += 768 * 768;
        wt_v[l] = bfp;    bfp += 768 * 768;
        wt_o[l] = bfp;    bfp += 768 * 768;
        wt_fb[l] = bfp;   bfp += 768 * 96;
        wt_gb[l] = bfp;   bfp += 768 * 96;
        wt_fg[l] = bfp;   bfp += 192 * 768;   // [Wfa^T | Wga^T]
        wt_gate[l] = bfp; bfp += 2048 * 768;
        wt_up[l] = bfp;   bfp += 2048 * 768;
        wt_down[l] = bfp; bfp += 768 * 2048;
    }
    unsigned short* mg_bf = (unsigned short*)qb;    // qb/kb dead after pre
    unsigned short* a_bf  = (unsigned short*)vb;    // U dead after seq

    float* out    = (float*)d_out;
    float* states = out + HROW;

    // weight transpose+convert
    transcvt<<<dim3(24, 24), 256, 0, stream>>>(proj_a_w, wt_proj, 768, 768);
    for (int l = 0; l < LL; ++l) {
        transcvt<<<dim3(24, 24), 256, 0, stream>>>(Wq + (size_t)l * 589824, wt_q[l], 768, 768);
        transcvt<<<dim3(24, 24), 256, 0, stream>>>(Wk + (size_t)l * 589824, wt_k[l], 768, 768);
        transcvt<<<dim3(24, 24), 256, 0, stream>>>(Wv + (size_t)l * 589824, wt_v[l], 768, 768);
        transcvt<<<dim3(24, 24), 256, 0, stream>>>(Wo + (size_t)l * 589824, wt_o[l], 768, 768);
        transcvt<<<dim3(24, 3), 256, 0, stream>>>(Wfb + (size_t)l * 73728, wt_fb[l], 96, 768);
        transcvt<<<dim3(24, 3), 256, 0, stream>>>(Wgb + (size_t)l * 73728, wt_gb[l], 96, 768);
        transcvt<<<dim3(3, 24), 256, 0, stream>>>(Wfa + (size_t)l * 73728, wt_fg[l], 768, 96);
        transcvt<<<dim3(3, 24), 256, 0, stream>>>(Wga + (size_t)l * 73728, wt_fg[l] + 96 * 768, 768, 96);
        transcvt<<<dim3(64, 24), 256, 0, stream>>>(Wgate + (size_t)l * 1572864, wt_gate[l], 768, 2048);
        transcvt<<<dim3(64, 24), 256, 0, stream>>>(Wup + (size_t)l * 1572864, wt_up[l], 768, 2048);
        transcvt<<<dim3(24, 64), 256, 0, stream>>>(Wdown + (size_t)l * 1572864, wt_down[l], 2048, 768);
    }

    layernorm_rows<<<MM, 256, 0, stream>>>(hidden, x_bf, norm_a_w, norm_a_b, nullptr);
    bgemm<BE_BIAS, 2><<<dim3(6, 64), 256, 0, stream>>>(x_bf, wt_proj, hbuf, nullptr,
                                                       proj_a_b, nullptr, MM, DD, DD);

    for (int l = 0; l < LL; ++l) {
        layernorm_rows<<<MM, 256, 0, stream>>>(hbuf, x_bf, ln_w + l * DD, ln_b + l * DD, mask);
        // fused q|k|v = silu(x @ [Wq|Wk|Wv]) -> qb, kb, vb
        bgemm<BE_QKV, 2><<<dim3(18, 64), 256, 0, stream>>>(x_bf, wt_q[l], qb, nullptr,
                                                           kb, vb, MM, 3 * DD, DD);
        l2norm_rows<<<(MM * HH) / 4, 256, 0, stream>>>(qb, 0.1020620726159658f);
        l2norm_rows<<<(MM * HH) / 4, 256, 0, stream>>>(kb, 1.f);
        // fa|ga = x @ [Wfa|Wga]  (bf16, one MFMA dispatch)
        bgemm_fg<<<dim3(3, 64), 256, 0, stream>>>(x_bf, wt_fg[l], fab_bf, gab_bf, DD);
        gemm_small<1><<<dim3(1, 128), 256, 0, stream>>>(x_bf, Wb + (size_t)l * DD * HH, nullptr, betab, MM, HH, DD);
        // chunkwise scan (EG fused into pre; gate fused into epi)
        kda_pre<<<1024, 256, 0, stream>>>(qb, kb, vb, fab_bf, A_log + l * DD, dt_bias + l * DD,
                                          wt_fb[l], betab, olb_bf, BcP, w_bf, k_bf, qe_bf);
        kda_seq<<<192, 256, 0, stream>>>(w_bf, k_bf, vb, BcP, SinT,
                                         states + (size_t)l * BB * HH * HD * HD);
        kda_epi<<<1024, 256, 0, stream>>>(SinT, qe_bf, olb_bf, gab_bf, wt_gb[l],
                                          onorm_w + l * HD, x_bf);
        // a = o @ Wo
        bgemm<BE_BF16, 2><<<dim3(6, 64), 256, 0, stream>>>(x_bf, wt_o[l], nullptr, a_bf, nullptr, nullptr, MM, DD, DD);
        // swiglu
        bgemm_dual<<<dim3(32, 64), 256, 0, stream>>>(a_bf, wt_gate[l], wt_up[l], mg_bf, MM, FF, DD);
        float* dst = (l == LL - 1) ? out : hbuf;
        bgemm<BE_RES, 2><<<dim3(6, 64), 256, 0, stream>>>(mg_bf, wt_down[l], dst, nullptr,
                                                          hbuf, nullptr, MM, DD, FF);
    }
}